// Round 2
// baseline (10849.126 us; speedup 1.0000x reference)
//
#include <hip/hip_runtime.h>
#include <hip/hip_bf16.h>
#include <math.h>

#define BB 4
#define TT 4096
#define CC 1024
#define HH 16
#define NN 64
#define BT (BB*TT)            // 16384 rows
#define EPS_GN 6.4e-4f        // 1e-5 * 8^2

__device__ __forceinline__ float sigmoidf_(float x) {
    return 1.0f / (1.0f + expf(-x));
}

__device__ __forceinline__ float waveReduceSum(float v) {
    #pragma unroll
    for (int off = 32; off > 0; off >>= 1)
        v += __shfl_xor(v, off, 64);
    return v;
}

// ---------------------------------------------------------------------------
// GEMM: Out[m][n] = sum_k A[m][k] * B(k,n),  K = CC (compile-time)
//   A[m][k] = X[m][k]  (DOMIX=false)
//           = X + (X_prev - X)*mix[k]  (DOMIX=true; X_prev=0 at batch start)
//   WNK=true : W is (N,K) row-major (k contiguous)  -> x @ W.T
//   WNK=false: W is (K,N) row-major (n contiguous)  -> x @ W
//   EPI: 0 none, 1 tanh, 2 sigmoid
// Tile 128x128, TK=8, 256 threads, 8x8 per thread.
// ---------------------------------------------------------------------------
__device__ __forceinline__ float4 ldA(const float* __restrict__ X,
                                      const float* __restrict__ mix,
                                      int gm, int gk, bool domix) {
    const float* px = X + (size_t)gm * CC + gk;
    float4 xv = *(const float4*)px;
    if (domix) {
        float4 pv;
        if ((gm & (TT - 1)) == 0) pv = make_float4(0.f, 0.f, 0.f, 0.f);
        else pv = *(const float4*)(px - CC);
        float4 mv = *(const float4*)(mix + gk);
        xv.x += (pv.x - xv.x) * mv.x;
        xv.y += (pv.y - xv.y) * mv.y;
        xv.z += (pv.z - xv.z) * mv.z;
        xv.w += (pv.w - xv.w) * mv.w;
    }
    return xv;
}

template<bool DOMIX, bool WNK, int EPI>
__global__ __launch_bounds__(256) void gemm_mix(
    const float* __restrict__ X, const float* __restrict__ W,
    const float* __restrict__ mix, float* __restrict__ Out, int Ncols)
{
    __shared__ float As[8][128];
    __shared__ float Bs[8][128];
    const int tid = threadIdx.x;
    const int m0 = blockIdx.x * 128;
    const int n0 = blockIdx.y * 128;
    const int sr  = tid >> 1;          // staging row (A: m-idx, B WNK: n-idx)
    const int skq = (tid & 1) * 4;     // staging k offset
    const int bkr = tid >> 5;          // KN layout: k row 0..7
    const int bnq = (tid & 31) * 4;    // KN layout: n offset 0..124
    const int tm = (tid >> 4) * 8;
    const int tn = (tid & 15) * 8;

    float acc[8][8];
    #pragma unroll
    for (int i = 0; i < 8; i++)
        #pragma unroll
        for (int j = 0; j < 8; j++) acc[i][j] = 0.f;

    float4 aR, bR;
    // prologue loads (k0 = 0)
    aR = ldA(X, mix, m0 + sr, skq, DOMIX);
    if (WNK) {
        int gn = n0 + sr;
        bR = (gn < Ncols) ? *(const float4*)(W + (size_t)gn * CC + skq)
                          : make_float4(0.f, 0.f, 0.f, 0.f);
    } else {
        int gn = n0 + bnq;
        bR = (gn < Ncols) ? *(const float4*)(W + (size_t)bkr * Ncols + gn)
                          : make_float4(0.f, 0.f, 0.f, 0.f);
    }

    for (int k0 = 0; k0 < CC; k0 += 8) {
        __syncthreads();
        As[skq + 0][sr] = aR.x;
        As[skq + 1][sr] = aR.y;
        As[skq + 2][sr] = aR.z;
        As[skq + 3][sr] = aR.w;
        if (WNK) {
            Bs[skq + 0][sr] = bR.x;
            Bs[skq + 1][sr] = bR.y;
            Bs[skq + 2][sr] = bR.z;
            Bs[skq + 3][sr] = bR.w;
        } else {
            *(float4*)&Bs[bkr][bnq] = bR;
        }
        __syncthreads();

        if (k0 + 8 < CC) {
            aR = ldA(X, mix, m0 + sr, k0 + 8 + skq, DOMIX);
            if (WNK) {
                int gn = n0 + sr;
                bR = (gn < Ncols) ? *(const float4*)(W + (size_t)gn * CC + k0 + 8 + skq)
                                  : make_float4(0.f, 0.f, 0.f, 0.f);
            } else {
                int gn = n0 + bnq;
                bR = (gn < Ncols) ? *(const float4*)(W + (size_t)(k0 + 8 + bkr) * Ncols + gn)
                                  : make_float4(0.f, 0.f, 0.f, 0.f);
            }
        }

        #pragma unroll
        for (int kk = 0; kk < 8; ++kk) {
            float av[8], bv[8];
            *(float4*)&av[0] = *(const float4*)&As[kk][tm];
            *(float4*)&av[4] = *(const float4*)&As[kk][tm + 4];
            *(float4*)&bv[0] = *(const float4*)&Bs[kk][tn];
            *(float4*)&bv[4] = *(const float4*)&Bs[kk][tn + 4];
            #pragma unroll
            for (int i = 0; i < 8; i++)
                #pragma unroll
                for (int j = 0; j < 8; j++)
                    acc[i][j] = fmaf(av[i], bv[j], acc[i][j]);
        }
    }

    // epilogue (tn/gn multiples of 8; Ncols multiple of 8)
    #pragma unroll
    for (int i = 0; i < 8; i++) {
        int gm = m0 + tm + i;
        int gn = n0 + tn;
        if (gn < Ncols) {
            float o[8];
            #pragma unroll
            for (int j = 0; j < 8; j++) {
                float v = acc[i][j];
                if (EPI == 1) v = tanhf(v);
                if (EPI == 2) v = sigmoidf_(v);
                o[j] = v;
            }
            float* p = Out + (size_t)gm * Ncols + gn;
            *(float4*)p       = make_float4(o[0], o[1], o[2], o[3]);
            *(float4*)(p + 4) = make_float4(o[4], o[5], o[6], o[7]);
        }
    }
}

// ---------------------------------------------------------------------------
// LoRA stage-2 + elementwise fusion.
// Block: 8 rows x 1024 channels, 256 threads; thread owns c = tid + 256*j.
// Computes: ab = sigmoid(a0 + ta@a2); dec = exp(-exp(-softplus(-(w0+tw@w2))-0.5));
// v_final = v + (vf - v)*sigmoid(v0 + tv@v2) (in-place); g = tg@g2.
// ---------------------------------------------------------------------------
__global__ __launch_bounds__(256) void lora2_kernel(
    const float* __restrict__ tw, const float* __restrict__ ta,
    const float* __restrict__ tv, const float* __restrict__ tg,
    const float* __restrict__ w2, const float* __restrict__ a2,
    const float* __restrict__ v2, const float* __restrict__ g2,
    const float* __restrict__ w0, const float* __restrict__ a0v,
    const float* __restrict__ v0v, const float* __restrict__ v_first,
    float* __restrict__ vbuf, float* __restrict__ decb,
    float* __restrict__ ab, float* __restrict__ gb)
{
    __shared__ float s_w[8 * 64];
    __shared__ float s_a[8 * 64];
    __shared__ float s_v[8 * 32];
    __shared__ float s_g[8 * 160];
    const int tid = threadIdx.x;
    const int r0 = blockIdx.x * 8;

    for (int i = tid; i < 8 * 64; i += 256)  s_w[i] = tw[(size_t)r0 * 64 + i];
    for (int i = tid; i < 8 * 64; i += 256)  s_a[i] = ta[(size_t)r0 * 64 + i];
    s_v[tid] = tv[(size_t)r0 * 32 + tid];    // 256 == 8*32
    for (int i = tid; i < 8 * 160; i += 256) s_g[i] = tg[(size_t)r0 * 160 + i];
    __syncthreads();

    // ---- a pass -> ab ----
    {
        float acc[8][4];
        #pragma unroll
        for (int r = 0; r < 8; r++)
            #pragma unroll
            for (int j = 0; j < 4; j++) acc[r][j] = 0.f;
        for (int d = 0; d < 64; ++d) {
            float wr[4];
            #pragma unroll
            for (int j = 0; j < 4; j++) wr[j] = a2[(size_t)d * CC + tid + 256 * j];
            #pragma unroll
            for (int r = 0; r < 8; r++) {
                float xv = s_a[r * 64 + d];
                #pragma unroll
                for (int j = 0; j < 4; j++) acc[r][j] = fmaf(xv, wr[j], acc[r][j]);
            }
        }
        #pragma unroll
        for (int r = 0; r < 8; r++) {
            size_t base = (size_t)(r0 + r) * CC;
            #pragma unroll
            for (int j = 0; j < 4; j++) {
                int c = tid + 256 * j;
                ab[base + c] = sigmoidf_(a0v[c] + acc[r][j]);
            }
        }
    }
    // ---- w pass -> dec ----
    {
        float acc[8][4];
        #pragma unroll
        for (int r = 0; r < 8; r++)
            #pragma unroll
            for (int j = 0; j < 4; j++) acc[r][j] = 0.f;
        for (int d = 0; d < 64; ++d) {
            float wr[4];
            #pragma unroll
            for (int j = 0; j < 4; j++) wr[j] = w2[(size_t)d * CC + tid + 256 * j];
            #pragma unroll
            for (int r = 0; r < 8; r++) {
                float xv = s_w[r * 64 + d];
                #pragma unroll
                for (int j = 0; j < 4; j++) acc[r][j] = fmaf(xv, wr[j], acc[r][j]);
            }
        }
        #pragma unroll
        for (int r = 0; r < 8; r++) {
            size_t base = (size_t)(r0 + r) * CC;
            #pragma unroll
            for (int j = 0; j < 4; j++) {
                int c = tid + 256 * j;
                float dwv = w0[c] + acc[r][j];
                float wv = -log1pf(expf(-dwv)) - 0.5f;
                decb[base + c] = expf(-expf(wv));
            }
        }
    }
    // ---- v pass -> v_final (in place) ----
    {
        float acc[8][4];
        #pragma unroll
        for (int r = 0; r < 8; r++)
            #pragma unroll
            for (int j = 0; j < 4; j++) acc[r][j] = 0.f;
        for (int d = 0; d < 32; ++d) {
            float wr[4];
            #pragma unroll
            for (int j = 0; j < 4; j++) wr[j] = v2[(size_t)d * CC + tid + 256 * j];
            #pragma unroll
            for (int r = 0; r < 8; r++) {
                float xv = s_v[r * 32 + d];
                #pragma unroll
                for (int j = 0; j < 4; j++) acc[r][j] = fmaf(xv, wr[j], acc[r][j]);
            }
        }
        #pragma unroll
        for (int r = 0; r < 8; r++) {
            size_t base = (size_t)(r0 + r) * CC;
            #pragma unroll
            for (int j = 0; j < 4; j++) {
                int c = tid + 256 * j;
                float s = sigmoidf_(v0v[c] + acc[r][j]);
                float vraw = vbuf[base + c];
                float vf = v_first[base + c];
                vbuf[base + c] = vraw + (vf - vraw) * s;
            }
        }
    }
    // ---- g pass ----
    {
        float acc[8][4];
        #pragma unroll
        for (int r = 0; r < 8; r++)
            #pragma unroll
            for (int j = 0; j < 4; j++) acc[r][j] = 0.f;
        for (int d = 0; d < 160; ++d) {
            float wr[4];
            #pragma unroll
            for (int j = 0; j < 4; j++) wr[j] = g2[(size_t)d * CC + tid + 256 * j];
            #pragma unroll
            for (int r = 0; r < 8; r++) {
                float xv = s_g[r * 160 + d];
                #pragma unroll
                for (int j = 0; j < 4; j++) acc[r][j] = fmaf(xv, wr[j], acc[r][j]);
            }
        }
        #pragma unroll
        for (int r = 0; r < 8; r++) {
            size_t base = (size_t)(r0 + r) * CC;
            #pragma unroll
            for (int j = 0; j < 4; j++) {
                int c = tid + 256 * j;
                gb[base + c] = acc[r][j];
            }
        }
    }
}

// ---------------------------------------------------------------------------
// Bidirectional WKV scan. One 64-lane wave per (b, h, dir); the wave's 64
// lanes ARE the head's 64 channels, so the kk-normalization is an in-wave
// shuffle reduction (kk/bh/k_final never materialized in HBM).
// Lane i owns state row S[i][0..63] (64 VGPRs). Per-step derived vectors
// broadcast through LDS (double-buffered); next-step global loads prefetched
// under compute. Both directions atomicAdd (exactly 2 commutative fp32 adds
// per element -> deterministic) into the zeroed y buffer.
// ---------------------------------------------------------------------------
__global__ __launch_bounds__(64) void wkv_scan(
    const float* __restrict__ rb, const float* __restrict__ decb,
    const float* __restrict__ kb, const float* __restrict__ vb,
    const float* __restrict__ ab_, const float* __restrict__ kkw,
    const float* __restrict__ kaw, const float* __restrict__ alpha_p,
    float* __restrict__ yb)
{
    const int bh = blockIdx.x;        // 0..63 = b*H + h
    const int dir = blockIdx.y;       // 0 fwd, 1 bwd
    const int b = bh >> 4, h = bh & 15;
    const int lane = threadIdx.x;
    const float alpha = alpha_p[0];
    const float wscale = dir ? (1.0f - alpha) : alpha;
    const int ch = h * NN + lane;
    const float kkw_l = kkw[ch];
    const float kaw_l = kaw[ch];

    __shared__ float sh[2][5][64];    // dec, k_fin, bh, a(=-kk), r
    float S[64];
    #pragma unroll
    for (int j = 0; j < 64; j++) S[j] = 0.f;

    const size_t hoff = (size_t)ch;
    int t0 = dir ? (TT - 1) : 0;
    size_t base = ((size_t)(b * TT + t0)) * CC + hoff;
    float rv = rb[base], dv = decb[base], kv = kb[base];
    float vv = vb[base], av = ab_[base];

    for (int step = 0; step < TT; ++step) {
        int buf = step & 1;
        // derived per-step values (in-wave kk normalization)
        float kkv = kv * kkw_l;
        float s2 = waveReduceSum(kkv * kkv);
        float den = fmaxf(sqrtf(s2), 1e-12f);
        float kkn = kkv / den;
        sh[buf][0][lane] = dv;
        sh[buf][1][lane] = kv * (1.0f + (av - 1.0f) * kaw_l);  // k_final
        sh[buf][2][lane] = kkn * av;                            // b_t
        sh[buf][3][lane] = -kkn;                                // a_t
        sh[buf][4][lane] = rv;
        float vcur = vv;
        size_t curbase = base;
        __syncthreads();

        if (step + 1 < TT) {   // prefetch next step
            int tn = dir ? (TT - 2 - step) : (step + 1);
            base = ((size_t)(b * TT + tn)) * CC + hoff;
            rv = rb[base]; dv = decb[base]; kv = kb[base];
            vv = vb[base]; av = ab_[base];
        }

        float sa = 0.f;
        #pragma unroll
        for (int j = 0; j < 64; j++) sa = fmaf(S[j], sh[buf][3][j], sa);
        float y = 0.f;
        #pragma unroll
        for (int j = 0; j < 64; j++) {
            float s = fmaf(S[j], sh[buf][0][j],
                      fmaf(sa, sh[buf][2][j], vcur * sh[buf][1][j]));
            S[j] = s;
            y = fmaf(s, sh[buf][4][j], y);
        }
        atomicAdd(&yb[curbase], wscale * y);
    }
}

// ---------------------------------------------------------------------------
// Post: GroupNorm(H groups) + affine + bonus term + gating.
// k_final recomputed from raw k and a. Writes z to a separate buffer.
// Channel->lane map: c = tid+256j -> head = wave+4j, n = lane: per-head
// stats are full 64-lane wave reductions.
// ---------------------------------------------------------------------------
__global__ __launch_bounds__(256) void post_kernel(
    const float* __restrict__ yb, const float* __restrict__ rbv,
    const float* __restrict__ kbv, const float* __restrict__ abv,
    const float* __restrict__ vbv, const float* __restrict__ gbv,
    const float* __restrict__ kaw, const float* __restrict__ r_k,
    const float* __restrict__ ln_w, const float* __restrict__ ln_b,
    float* __restrict__ zb)
{
    const int t = blockIdx.x;
    const int tid = threadIdx.x;
    const size_t base = (size_t)t * CC;
    #pragma unroll
    for (int j = 0; j < 4; j++) {
        int c = tid + 256 * j;
        float y = yb[base + c];
        float s1 = waveReduceSum(y);
        float s2 = waveReduceSum(y * y);
        float mu = s1 * (1.0f / 64.0f);
        float var = s2 * (1.0f / 64.0f) - mu * mu;
        float yn = (y - mu) * rsqrtf(var + EPS_GN);
        yn = yn * ln_w[c] + ln_b[c];
        float rv = rbv[base + c];
        float kf = kbv[base + c] * (1.0f + (abv[base + c] - 1.0f) * kaw[c]);
        float vv = vbv[base + c];
        float dot = waveReduceSum(rv * kf * r_k[c]);   // r_k is (H,N) = C flat
        yn += dot * vv;
        zb[base + c] = yn * gbv[base + c];
    }
}

// ---------------------------------------------------------------------------
extern "C" void kernel_launch(void* const* d_in, const int* in_sizes, int n_in,
                              void* d_out, int out_size, void* d_ws, size_t ws_size,
                              hipStream_t stream)
{
    (void)in_sizes; (void)n_in; (void)out_size; (void)ws_size;
    const float* x      = (const float*)d_in[0];
    const float* vfirst = (const float*)d_in[1];
    const float* x_r    = (const float*)d_in[2];
    const float* x_w    = (const float*)d_in[3];
    const float* x_k    = (const float*)d_in[4];
    const float* x_v    = (const float*)d_in[5];
    const float* x_a    = (const float*)d_in[6];
    const float* x_g    = (const float*)d_in[7];
    const float* w0     = (const float*)d_in[8];
    const float* w1     = (const float*)d_in[9];
    const float* w2     = (const float*)d_in[10];
    const float* a0     = (const float*)d_in[11];
    const float* a1     = (const float*)d_in[12];
    const float* a2     = (const float*)d_in[13];
    const float* v0     = (const float*)d_in[14];
    const float* v1     = (const float*)d_in[15];
    const float* v2     = (const float*)d_in[16];
    const float* g1     = (const float*)d_in[17];
    const float* g2     = (const float*)d_in[18];
    const float* k_k    = (const float*)d_in[19];
    const float* k_a    = (const float*)d_in[20];
    const float* r_k    = (const float*)d_in[21];
    const float* Wr     = (const float*)d_in[22];
    const float* Wk     = (const float*)d_in[23];
    const float* Wv     = (const float*)d_in[24];
    const float* Wo     = (const float*)d_in[25];
    const float* ln_w   = (const float*)d_in[26];
    const float* ln_b   = (const float*)d_in[27];
    const float* alpha  = (const float*)d_in[28];

    const size_t SZ = (size_t)BT * CC;    // 16.78M floats per full stream
    float* ws   = (float*)d_ws;
    float* rb   = ws + 0 * SZ;            // r
    float* kb   = ws + 1 * SZ;            // raw k (pre-kk, pre-k_a)
    float* vb   = ws + 2 * SZ;            // v (raw -> final, in place)
    float* decb = ws + 3 * SZ;            // decay; reused as z after scan
    float* ab   = ws + 4 * SZ;            // a = sigmoid(...)
    float* tw   = ws + 5 * SZ;            // LoRA temps (BT x 64/64/32/160)
    float* ta   = tw + (size_t)BT * 64;
    float* tv   = ta + (size_t)BT * 64;
    float* tg   = tv + (size_t)BT * 32;
    // d_out aliases: gb lives in out[0:SZ] (dead before final GEMM writes it);
    // yb lives in out[SZ:2SZ] (dead before v_first passthrough copy).
    float* outp = (float*)d_out;
    float* gb   = outp;
    float* yb   = outp + SZ;
    float* zb   = decb;                   // dec dead after scan

    dim3 blk(256);
    // big projections with fused token-shift mix
    gemm_mix<true, true, 0><<<dim3(BT / 128, 8), blk, 0, stream>>>(x, Wr, x_r, rb, CC);
    gemm_mix<true, true, 0><<<dim3(BT / 128, 8), blk, 0, stream>>>(x, Wk, x_k, kb, CC);
    gemm_mix<true, true, 0><<<dim3(BT / 128, 8), blk, 0, stream>>>(x, Wv, x_v, vb, CC);
    // LoRA stage-1 (w: tanh, g: sigmoid fused)
    gemm_mix<true, false, 1><<<dim3(BT / 128, 1), blk, 0, stream>>>(x, w1, x_w, tw, 64);
    gemm_mix<true, false, 0><<<dim3(BT / 128, 1), blk, 0, stream>>>(x, a1, x_a, ta, 64);
    gemm_mix<true, false, 0><<<dim3(BT / 128, 1), blk, 0, stream>>>(x, v1, x_v, tv, 32);
    gemm_mix<true, false, 2><<<dim3(BT / 128, 2), blk, 0, stream>>>(x, g1, x_g, tg, 160);
    // LoRA stage-2 + elementwise prep (a, dec, v_final, g)
    lora2_kernel<<<dim3(BT / 8), blk, 0, stream>>>(tw, ta, tv, tg, w2, a2, v2, g2,
        w0, a0, v0, vfirst, vb, decb, ab, gb);
    // scan (fwd+bwd blended via atomics into zeroed y)
    hipMemsetAsync(yb, 0, SZ * sizeof(float), stream);
    wkv_scan<<<dim3(64, 2), dim3(64), 0, stream>>>(rb, decb, kb, vb, ab, k_k, k_a, alpha, yb);
    // groupnorm + bonus + gate -> z (in dec's slot)
    post_kernel<<<dim3(BT), blk, 0, stream>>>(yb, rb, kb, ab, vb, gb, k_a, r_k, ln_w, ln_b, zb);
    // v_first passthrough (yb region now dead)
    hipMemcpyAsync(outp + SZ, vfirst, SZ * sizeof(float),
                   hipMemcpyDeviceToDevice, stream);
    // output projection (overwrites gb region)
    gemm_mix<false, true, 0><<<dim3(BT / 128, 8), blk, 0, stream>>>(zb, Wo, nullptr, outp, CC);
}

// Round 3
// 6363.012 us; speedup vs baseline: 1.7050x; 1.7050x over previous
//
#include <hip/hip_runtime.h>
#include <hip/hip_bf16.h>
#include <math.h>

#define BB 4
#define TT 4096
#define CC 1024
#define HH 16
#define NN 64
#define BT (BB*TT)            // 16384 rows
#define EPS_GN 6.4e-4f        // 1e-5 * 8^2
#define TMAX (TT-1)
#define LCH 64                // chunk length
#define CB 8                  // chunks per batch
#define NB 8                  // batches  (LCH*CB*NB == TT)
#define STR 65                // padded LDS row stride

__device__ __forceinline__ float sigmoidf_(float x) {
    return 1.0f / (1.0f + expf(-x));
}

__device__ __forceinline__ float waveReduceSum(float v) {
    #pragma unroll
    for (int off = 32; off > 0; off >>= 1)
        v += __shfl_xor(v, off, 64);
    return v;
}

// acc[r][c] += sum_k A(tr+r,k)*B(tc+c,k); element A(i,k)=A[i*SA0+k*SA1].
template<int SA0,int SA1,int SB0,int SB1>
__device__ __forceinline__ void gemm64(const float* __restrict__ A,
                                       const float* __restrict__ B,
                                       float acc[4][4], int tr, int tc) {
    #pragma unroll 4
    for (int kx = 0; kx < 64; ++kx) {
        float av[4], bv[4];
        #pragma unroll
        for (int r = 0; r < 4; r++) av[r] = A[(tr + r) * SA0 + kx * SA1];
        #pragma unroll
        for (int cq = 0; cq < 4; cq++) bv[cq] = B[(tc + cq) * SB0 + kx * SB1];
        #pragma unroll
        for (int r = 0; r < 4; r++)
            #pragma unroll
            for (int cq = 0; cq < 4; cq++)
                acc[r][cq] = fmaf(av[r], bv[cq], acc[r][cq]);
    }
}

// ---------------------------------------------------------------------------
// GEMM: Out[m][n] = sum_k A[m][k] * B(k,n),  K = CC (compile-time)
// (unchanged from round 2 — passed)
// ---------------------------------------------------------------------------
__device__ __forceinline__ float4 ldA(const float* __restrict__ X,
                                      const float* __restrict__ mix,
                                      int gm, int gk, bool domix) {
    const float* px = X + (size_t)gm * CC + gk;
    float4 xv = *(const float4*)px;
    if (domix) {
        float4 pv;
        if ((gm & (TT - 1)) == 0) pv = make_float4(0.f, 0.f, 0.f, 0.f);
        else pv = *(const float4*)(px - CC);
        float4 mv = *(const float4*)(mix + gk);
        xv.x += (pv.x - xv.x) * mv.x;
        xv.y += (pv.y - xv.y) * mv.y;
        xv.z += (pv.z - xv.z) * mv.z;
        xv.w += (pv.w - xv.w) * mv.w;
    }
    return xv;
}

template<bool DOMIX, bool WNK, int EPI>
__global__ __launch_bounds__(256) void gemm_mix(
    const float* __restrict__ X, const float* __restrict__ W,
    const float* __restrict__ mix, float* __restrict__ Out, int Ncols)
{
    __shared__ float As[8][128];
    __shared__ float Bs[8][128];
    const int tid = threadIdx.x;
    const int m0 = blockIdx.x * 128;
    const int n0 = blockIdx.y * 128;
    const int sr  = tid >> 1;
    const int skq = (tid & 1) * 4;
    const int bkr = tid >> 5;
    const int bnq = (tid & 31) * 4;
    const int tm = (tid >> 4) * 8;
    const int tn = (tid & 15) * 8;

    float acc[8][8];
    #pragma unroll
    for (int i = 0; i < 8; i++)
        #pragma unroll
        for (int j = 0; j < 8; j++) acc[i][j] = 0.f;

    float4 aR, bR;
    aR = ldA(X, mix, m0 + sr, skq, DOMIX);
    if (WNK) {
        int gn = n0 + sr;
        bR = (gn < Ncols) ? *(const float4*)(W + (size_t)gn * CC + skq)
                          : make_float4(0.f, 0.f, 0.f, 0.f);
    } else {
        int gn = n0 + bnq;
        bR = (gn < Ncols) ? *(const float4*)(W + (size_t)bkr * Ncols + gn)
                          : make_float4(0.f, 0.f, 0.f, 0.f);
    }

    for (int k0 = 0; k0 < CC; k0 += 8) {
        __syncthreads();
        As[skq + 0][sr] = aR.x;
        As[skq + 1][sr] = aR.y;
        As[skq + 2][sr] = aR.z;
        As[skq + 3][sr] = aR.w;
        if (WNK) {
            Bs[skq + 0][sr] = bR.x;
            Bs[skq + 1][sr] = bR.y;
            Bs[skq + 2][sr] = bR.z;
            Bs[skq + 3][sr] = bR.w;
        } else {
            *(float4*)&Bs[bkr][bnq] = bR;
        }
        __syncthreads();

        if (k0 + 8 < CC) {
            aR = ldA(X, mix, m0 + sr, k0 + 8 + skq, DOMIX);
            if (WNK) {
                int gn = n0 + sr;
                bR = (gn < Ncols) ? *(const float4*)(W + (size_t)gn * CC + k0 + 8 + skq)
                                  : make_float4(0.f, 0.f, 0.f, 0.f);
            } else {
                int gn = n0 + bnq;
                bR = (gn < Ncols) ? *(const float4*)(W + (size_t)(k0 + 8 + bkr) * Ncols + gn)
                                  : make_float4(0.f, 0.f, 0.f, 0.f);
            }
        }

        #pragma unroll
        for (int kk = 0; kk < 8; ++kk) {
            float av[8], bv[8];
            *(float4*)&av[0] = *(const float4*)&As[kk][tm];
            *(float4*)&av[4] = *(const float4*)&As[kk][tm + 4];
            *(float4*)&bv[0] = *(const float4*)&Bs[kk][tn];
            *(float4*)&bv[4] = *(const float4*)&Bs[kk][tn + 4];
            #pragma unroll
            for (int i = 0; i < 8; i++)
                #pragma unroll
                for (int j = 0; j < 8; j++)
                    acc[i][j] = fmaf(av[i], bv[j], acc[i][j]);
        }
    }

    #pragma unroll
    for (int i = 0; i < 8; i++) {
        int gm = m0 + tm + i;
        int gn = n0 + tn;
        if (gn < Ncols) {
            float o[8];
            #pragma unroll
            for (int j = 0; j < 8; j++) {
                float v = acc[i][j];
                if (EPI == 1) v = tanhf(v);
                if (EPI == 2) v = sigmoidf_(v);
                o[j] = v;
            }
            float* p = Out + (size_t)gm * Ncols + gn;
            *(float4*)p       = make_float4(o[0], o[1], o[2], o[3]);
            *(float4*)(p + 4) = make_float4(o[4], o[5], o[6], o[7]);
        }
    }
}

// ---------------------------------------------------------------------------
// LoRA stage-2 + elementwise fusion (unchanged from round 2 — passed)
// ---------------------------------------------------------------------------
__global__ __launch_bounds__(256) void lora2_kernel(
    const float* __restrict__ tw, const float* __restrict__ ta,
    const float* __restrict__ tv, const float* __restrict__ tg,
    const float* __restrict__ w2, const float* __restrict__ a2,
    const float* __restrict__ v2, const float* __restrict__ g2,
    const float* __restrict__ w0, const float* __restrict__ a0v,
    const float* __restrict__ v0v, const float* __restrict__ v_first,
    float* __restrict__ vbuf, float* __restrict__ decb,
    float* __restrict__ ab, float* __restrict__ gb)
{
    __shared__ float s_w[8 * 64];
    __shared__ float s_a[8 * 64];
    __shared__ float s_v[8 * 32];
    __shared__ float s_g[8 * 160];
    const int tid = threadIdx.x;
    const int r0 = blockIdx.x * 8;

    for (int i = tid; i < 8 * 64; i += 256)  s_w[i] = tw[(size_t)r0 * 64 + i];
    for (int i = tid; i < 8 * 64; i += 256)  s_a[i] = ta[(size_t)r0 * 64 + i];
    s_v[tid] = tv[(size_t)r0 * 32 + tid];
    for (int i = tid; i < 8 * 160; i += 256) s_g[i] = tg[(size_t)r0 * 160 + i];
    __syncthreads();

    {
        float acc[8][4];
        #pragma unroll
        for (int r = 0; r < 8; r++)
            #pragma unroll
            for (int j = 0; j < 4; j++) acc[r][j] = 0.f;
        for (int d = 0; d < 64; ++d) {
            float wr[4];
            #pragma unroll
            for (int j = 0; j < 4; j++) wr[j] = a2[(size_t)d * CC + tid + 256 * j];
            #pragma unroll
            for (int r = 0; r < 8; r++) {
                float xv = s_a[r * 64 + d];
                #pragma unroll
                for (int j = 0; j < 4; j++) acc[r][j] = fmaf(xv, wr[j], acc[r][j]);
            }
        }
        #pragma unroll
        for (int r = 0; r < 8; r++) {
            size_t base = (size_t)(r0 + r) * CC;
            #pragma unroll
            for (int j = 0; j < 4; j++) {
                int c = tid + 256 * j;
                ab[base + c] = sigmoidf_(a0v[c] + acc[r][j]);
            }
        }
    }
    {
        float acc[8][4];
        #pragma unroll
        for (int r = 0; r < 8; r++)
            #pragma unroll
            for (int j = 0; j < 4; j++) acc[r][j] = 0.f;
        for (int d = 0; d < 64; ++d) {
            float wr[4];
            #pragma unroll
            for (int j = 0; j < 4; j++) wr[j] = w2[(size_t)d * CC + tid + 256 * j];
            #pragma unroll
            for (int r = 0; r < 8; r++) {
                float xv = s_w[r * 64 + d];
                #pragma unroll
                for (int j = 0; j < 4; j++) acc[r][j] = fmaf(xv, wr[j], acc[r][j]);
            }
        }
        #pragma unroll
        for (int r = 0; r < 8; r++) {
            size_t base = (size_t)(r0 + r) * CC;
            #pragma unroll
            for (int j = 0; j < 4; j++) {
                int c = tid + 256 * j;
                float dwv = w0[c] + acc[r][j];
                float wv = -log1pf(expf(-dwv)) - 0.5f;
                decb[base + c] = expf(-expf(wv));
            }
        }
    }
    {
        float acc[8][4];
        #pragma unroll
        for (int r = 0; r < 8; r++)
            #pragma unroll
            for (int j = 0; j < 4; j++) acc[r][j] = 0.f;
        for (int d = 0; d < 32; ++d) {
            float wr[4];
            #pragma unroll
            for (int j = 0; j < 4; j++) wr[j] = v2[(size_t)d * CC + tid + 256 * j];
            #pragma unroll
            for (int r = 0; r < 8; r++) {
                float xv = s_v[r * 32 + d];
                #pragma unroll
                for (int j = 0; j < 4; j++) acc[r][j] = fmaf(xv, wr[j], acc[r][j]);
            }
        }
        #pragma unroll
        for (int r = 0; r < 8; r++) {
            size_t base = (size_t)(r0 + r) * CC;
            #pragma unroll
            for (int j = 0; j < 4; j++) {
                int c = tid + 256 * j;
                float s = sigmoidf_(v0v[c] + acc[r][j]);
                float vraw = vbuf[base + c];
                float vf = v_first[base + c];
                vbuf[base + c] = vraw + (vf - vraw) * s;
            }
        }
    }
    {
        float acc[8][4];
        #pragma unroll
        for (int r = 0; r < 8; r++)
            #pragma unroll
            for (int j = 0; j < 4; j++) acc[r][j] = 0.f;
        for (int d = 0; d < 160; ++d) {
            float wr[4];
            #pragma unroll
            for (int j = 0; j < 4; j++) wr[j] = g2[(size_t)d * CC + tid + 256 * j];
            #pragma unroll
            for (int r = 0; r < 8; r++) {
                float xv = s_g[r * 160 + d];
                #pragma unroll
                for (int j = 0; j < 4; j++) acc[r][j] = fmaf(xv, wr[j], acc[r][j]);
            }
        }
        #pragma unroll
        for (int r = 0; r < 8; r++) {
            size_t base = (size_t)(r0 + r) * CC;
            #pragma unroll
            for (int j = 0; j < 4; j++) {
                int c = tid + 256 * j;
                gb[base + c] = acc[r][j];
            }
        }
    }
}

// ---------------------------------------------------------------------------
// Chunked WKV, phase A: per-chunk local quantities.
// One block per (bhd, local chunk). Computes cumprods, scaled vectors,
// X=tril(A'B'^T,-1), Yk=tril(A'K'^T,-1), Tinv=(I-X)^{-1},
// G=Tinv@A', U0=Tinv@(Yk@V). Stores Bp,Kp,wc,G,U0(into Ub).
// ---------------------------------------------------------------------------
__global__ __launch_bounds__(256) void wkvA(
    const float* __restrict__ kb, const float* __restrict__ ab,
    const float* __restrict__ vb, const float* __restrict__ decb,
    const float* __restrict__ k_k, const float* __restrict__ k_a,
    float* __restrict__ Gb, float* __restrict__ Ub,
    float* __restrict__ Bpb, float* __restrict__ Kpb,
    float* __restrict__ wcb, int cb)
{
    __shared__ float sm[6][64 * STR];
    __shared__ float sSeg[4][64];
    const int inst = blockIdx.x;
    const int bhd = inst >> 3, lc = inst & 7;
    const int dir = bhd & 1, bh = bhd >> 1, b = bh >> 4, h = bh & 15;
    const int c64 = (cb * CB + lc) * LCH;
    const int tid = threadIdx.x;
    const int lane = tid & 63, seg = tid >> 6;
    const int ch = h * 64 + lane;
    const size_t gbase = (size_t)inst * 4096;
    float* sWC = sm[0];   // wc[p][lane]; later V[s][n]
    float* sAp = sm[1];   // ApT[j][p]
    float* sBp = sm[2];   // BpT[j][p]; later Tinv[r][c]
    float* sKp = sm[3];   // KpT[j][p]; later YkV[s][i]
    float* sX  = sm[4];
    float* sYk = sm[5];

    // stage 0: decay cumprod
    {
        float run = 1.f; float loc[16];
        #pragma unroll
        for (int i = 0; i < 16; i++) {
            int p = seg * 16 + i;
            int t = dir ? (TMAX - (c64 + p)) : (c64 + p);
            float d = decb[((size_t)(b * TT + t)) * CC + ch];
            run *= d; loc[i] = run;
        }
        sSeg[seg][lane] = run;
        __syncthreads();
        float pre = 1.f;
        for (int s2 = 0; s2 < seg; ++s2) pre *= sSeg[s2][lane];
        #pragma unroll
        for (int i = 0; i < 16; i++) {
            int p = seg * 16 + i;
            float wcv = pre * loc[i];
            sWC[p * STR + lane] = wcv;
            wcb[gbase + p * 64 + lane] = wcv;
        }
    }
    __syncthreads();
    // stage 1: kk-normalize, scaled vectors
    {
        const float kkl = k_k[ch], kal = k_a[ch];
        for (int i = 0; i < 16; i++) {
            int p = seg * 16 + i;
            int t = dir ? (TMAX - (c64 + p)) : (c64 + p);
            size_t ra = ((size_t)(b * TT + t)) * CC + ch;
            float kraw = kb[ra], asig = ab[ra];
            float kkv = kraw * kkl;
            float s2 = waveReduceSum(kkv * kkv);
            float kkn = kkv / fmaxf(sqrtf(s2), 1e-12f);
            float wc = sWC[p * STR + lane];
            float wx = (p == 0) ? 1.f : sWC[(p - 1) * STR + lane];
            float apv = -kkn * wx;
            float bpv = kkn * asig / wc;
            float kpv = kraw * (1.f + (asig - 1.f) * kal) / wc;
            sAp[lane * STR + p] = apv;
            sBp[lane * STR + p] = bpv;
            sKp[lane * STR + p] = kpv;
            Bpb[gbase + p * 64 + lane] = bpv;
            Kpb[gbase + p * 64 + lane] = kpv;
        }
    }
    __syncthreads();   // [bar A]

    const int tr = (tid >> 4) * 4, tc = (tid & 15) * 4;
    // V load into sWC slot (wc no longer needed in LDS)
    #pragma unroll
    for (int i = 0; i < 16; i++) {
        int p = seg * 16 + i;
        int t = dir ? (TMAX - (c64 + p)) : (c64 + p);
        sWC[p * STR + lane] = vb[((size_t)(b * TT + t)) * CC + ch];
    }
    // X = tril(Ap@Bp^T, -1)
    {
        float acc[4][4] = {};
        gemm64<1, STR, 1, STR>(sAp, sBp, acc, tr, tc);
        #pragma unroll
        for (int r = 0; r < 4; r++)
            #pragma unroll
            for (int cq = 0; cq < 4; cq++)
                sX[(tr + r) * STR + tc + cq] = (tc + cq < tr + r) ? acc[r][cq] : 0.f;
    }
    // Yk = tril(Ap@Kp^T, -1)
    {
        float acc[4][4] = {};
        gemm64<1, STR, 1, STR>(sAp, sKp, acc, tr, tc);
        #pragma unroll
        for (int r = 0; r < 4; r++)
            #pragma unroll
            for (int cq = 0; cq < 4; cq++)
                sYk[(tr + r) * STR + tc + cq] = (tc + cq < tr + r) ? acc[r][cq] : 0.f;
    }
    __syncthreads();   // [bar B]
    // YkV = Yk @ V  → sKp slot
    {
        float acc[4][4] = {};
        gemm64<STR, 1, 1, STR>(sYk, sWC, acc, tr, tc);
        __syncthreads();   // ensure nothing still reads sKp (pre-bar-B readers done; this is belt+braces)
        #pragma unroll
        for (int r = 0; r < 4; r++)
            #pragma unroll
            for (int cq = 0; cq < 4; cq++)
                sKp[(tr + r) * STR + tc + cq] = acc[r][cq];
    }
    __syncthreads();   // [bar C]
    // Tinv = (I - X)^{-1}  → sBp slot (lower unitriangular; column per lane)
    if (tid < 64) {
        for (int r = 0; r < 64; ++r) {
            float acc = 0.f;
            for (int s = 0; s < r; ++s)
                acc = fmaf(sX[r * STR + s], sBp[s * STR + tid], acc);
            sBp[r * STR + tid] = (r == tid) ? 1.f : acc;
        }
    }
    __syncthreads();   // [bar D]
    // G = Tinv @ A'   ;  U0 = Tinv @ YkV
    {
        float accG[4][4] = {};
        gemm64<STR, 1, STR, 1>(sBp, sAp, accG, tr, tc);
        float accU[4][4] = {};
        gemm64<STR, 1, 1, STR>(sBp, sKp, accU, tr, tc);
        #pragma unroll
        for (int r = 0; r < 4; r++) {
            *(float4*)&Gb[gbase + (tr + r) * 64 + tc] =
                make_float4(accG[r][0], accG[r][1], accG[r][2], accG[r][3]);
            *(float4*)&Ub[gbase + (tr + r) * 64 + tc] =
                make_float4(accU[r][0], accU[r][1], accU[r][2], accU[r][3]);
        }
    }
}

// ---------------------------------------------------------------------------
// Chunked WKV, phase B: sequential state pass over the batch's 8 chunks.
// One block per (b,h,dir). S0b = chunk-initial state; Ub := U = U0 + G@S0^T;
// Snew = (S + U^T@Bp + V^T@Kp) * wc63[cols].
// ---------------------------------------------------------------------------
__global__ __launch_bounds__(256) void wkvB(
    const float* __restrict__ vb,
    const float* __restrict__ Gb, float* __restrict__ Ub,
    const float* __restrict__ Bpb, const float* __restrict__ Kpb,
    const float* __restrict__ wcb, float* __restrict__ S0b,
    float* __restrict__ Scur, int cb)
{
    __shared__ float sS[64 * STR];
    __shared__ float sG[64 * STR];
    __shared__ float sU[64 * STR];
    __shared__ float sB[64 * STR];
    __shared__ float sK[64 * STR];
    __shared__ float sV[64 * STR];
    const int bhd = blockIdx.x;
    const int dir = bhd & 1, bh = bhd >> 1, b = bh >> 4, h = bh & 15;
    const int tid = threadIdx.x;
    const int tr = (tid >> 4) * 4, tc = (tid & 15) * 4;

    for (int i = tid; i < 4096; i += 256)
        sS[(i >> 6) * STR + (i & 63)] = Scur[(size_t)bhd * 4096 + i];
    __syncthreads();

    for (int lc = 0; lc < CB; ++lc) {
        const int inst = bhd * CB + lc;
        const size_t gbase = (size_t)inst * 4096;
        const int c64 = (cb * CB + lc) * LCH;
        for (int i = tid; i < 4096; i += 256) {
            int rr = i >> 6, jj = i & 63;
            sG[rr * STR + jj] = Gb[gbase + i];
            sB[rr * STR + jj] = Bpb[gbase + i];
            sK[rr * STR + jj] = Kpb[gbase + i];
            int t = dir ? (TMAX - (c64 + rr)) : (c64 + rr);
            sV[rr * STR + jj] = vb[((size_t)(b * TT + t)) * CC + h * 64 + jj];
            S0b[gbase + i] = sS[rr * STR + jj];
        }
        __syncthreads();
        // U = U0 + G @ S^T
        {
            float acc[4][4];
            #pragma unroll
            for (int r = 0; r < 4; r++) {
                float4 u0 = *(const float4*)&Ub[gbase + (tr + r) * 64 + tc];
                acc[r][0] = u0.x; acc[r][1] = u0.y; acc[r][2] = u0.z; acc[r][3] = u0.w;
            }
            gemm64<STR, 1, STR, 1>(sG, sS, acc, tr, tc);
            #pragma unroll
            for (int r = 0; r < 4; r++) {
                #pragma unroll
                for (int cq = 0; cq < 4; cq++) sU[(tr + r) * STR + tc + cq] = acc[r][cq];
                *(float4*)&Ub[gbase + (tr + r) * 64 + tc] =
                    make_float4(acc[r][0], acc[r][1], acc[r][2], acc[r][3]);
            }
        }
        __syncthreads();
        // Snew[i][j] = (S[i][j] + sum_s U[s][i]*Bp[s][j] + sum_s V[s][i]*Kp[s][j]) * wc63[j]
        {
            float acc[4][4] = {};
            gemm64<1, STR, 1, STR>(sU, sB, acc, tr, tc);
            gemm64<1, STR, 1, STR>(sV, sK, acc, tr, tc);
            float w63[4];
            #pragma unroll
            for (int cq = 0; cq < 4; cq++) w63[cq] = wcb[gbase + 63 * 64 + tc + cq];
            #pragma unroll
            for (int r = 0; r < 4; r++)
                #pragma unroll
                for (int cq = 0; cq < 4; cq++) {
                    float sv = sS[(tr + r) * STR + tc + cq];
                    acc[r][cq] = (sv + acc[r][cq]) * w63[cq];
                }
            #pragma unroll
            for (int r = 0; r < 4; r++)
                #pragma unroll
                for (int cq = 0; cq < 4; cq++)
                    sS[(tr + r) * STR + tc + cq] = acc[r][cq];
        }
        __syncthreads();
    }
    for (int i = tid; i < 4096; i += 256)
        Scur[(size_t)bhd * 4096 + i] = sS[(i >> 6) * STR + (i & 63)];
}

// ---------------------------------------------------------------------------
// Chunked WKV, phase C: outputs.
// Yout = R'@S0^T + tril(R'Bp^T,0)@U + tril(R'Kp^T,0)@V ; y += wscale*Yout.
// fwd/bwd instances within one batch touch disjoint t ranges -> plain RMW.
// ---------------------------------------------------------------------------
__global__ __launch_bounds__(256) void wkvC(
    const float* __restrict__ rb, const float* __restrict__ vb,
    const float* __restrict__ Bpb, const float* __restrict__ Kpb,
    const float* __restrict__ Ub, const float* __restrict__ S0b,
    const float* __restrict__ wcb, const float* __restrict__ alpha_p,
    float* __restrict__ yb, int cb)
{
    __shared__ float sm[6][64 * STR];
    float* sRp = sm[0];   // RpT[j][p]
    float* sBt = sm[1];   // BpT[j][s]; later U[s][i]
    float* sKt = sm[2];   // KpT[j][s]; later S0[i][j]
    float* sMb = sm[3];   // Mrb[p][s]
    float* sMk = sm[4];   // Mrk[p][s]
    float* sV  = sm[5];   // V[s][n]
    const int inst = blockIdx.x;
    const int bhd = inst >> 3, lc = inst & 7;
    const int dir = bhd & 1, bh = bhd >> 1, b = bh >> 4, h = bh & 15;
    const int c64 = (cb * CB + lc) * LCH;
    const int tid = threadIdx.x, lane = tid & 63, seg = tid >> 6;
    const size_t gbase = (size_t)inst * 4096;
    const float alpha = alpha_p[0];
    const float wscale = dir ? (1.f - alpha) : alpha;

    #pragma unroll
    for (int i = 0; i < 16; i++) {
        int p = seg * 16 + i;
        int t = dir ? (TMAX - (c64 + p)) : (c64 + p);
        size_t ra = ((size_t)(b * TT + t)) * CC + h * 64 + lane;
        float wc = wcb[gbase + p * 64 + lane];
        sRp[lane * STR + p] = rb[ra] * wc;
        sBt[lane * STR + p] = Bpb[gbase + p * 64 + lane];
        sKt[lane * STR + p] = Kpb[gbase + p * 64 + lane];
        sV[p * STR + lane]  = vb[ra];
    }
    __syncthreads();
    const int tr = (tid >> 4) * 4, tc = (tid & 15) * 4;
    {
        float acc[4][4] = {};
        gemm64<1, STR, 1, STR>(sRp, sBt, acc, tr, tc);
        #pragma unroll
        for (int r = 0; r < 4; r++)
            #pragma unroll
            for (int cq = 0; cq < 4; cq++)
                sMb[(tr + r) * STR + tc + cq] = (tc + cq <= tr + r) ? acc[r][cq] : 0.f;
        float acc2[4][4] = {};
        gemm64<1, STR, 1, STR>(sRp, sKt, acc2, tr, tc);
        #pragma unroll
        for (int r = 0; r < 4; r++)
            #pragma unroll
            for (int cq = 0; cq < 4; cq++)
                sMk[(tr + r) * STR + tc + cq] = (tc + cq <= tr + r) ? acc2[r][cq] : 0.f;
    }
    __syncthreads();
    // overwrite sBt <- U[s][i], sKt <- S0[i][j]
    #pragma unroll
    for (int i = 0; i < 16; i++) {
        int rr = seg * 16 + i;
        sBt[rr * STR + lane] = Ub[gbase + rr * 64 + lane];
        sKt[rr * STR + lane] = S0b[gbase + rr * 64 + lane];
    }
    __syncthreads();
    {
        float acc[4][4] = {};
        gemm64<1, STR, STR, 1>(sRp, sKt, acc, tr, tc);   // R' @ S0^T
        gemm64<STR, 1, 1, STR>(sMb, sBt, acc, tr, tc);   // Mrb @ U
        gemm64<STR, 1, 1, STR>(sMk, sV,  acc, tr, tc);   // Mrk @ V
        #pragma unroll
        for (int r = 0; r < 4; r++) {
            int p = tr + r;
            int t = dir ? (TMAX - (c64 + p)) : (c64 + p);
            float* yp = &yb[((size_t)(b * TT + t)) * CC + h * 64 + tc];
            float4 old = *(float4*)yp;
            old.x += wscale * acc[r][0];
            old.y += wscale * acc[r][1];
            old.z += wscale * acc[r][2];
            old.w += wscale * acc[r][3];
            *(float4*)yp = old;
        }
    }
}

// ---------------------------------------------------------------------------
// Post: GroupNorm + affine + bonus term + gating (unchanged from round 2)
// ---------------------------------------------------------------------------
__global__ __launch_bounds__(256) void post_kernel(
    const float* __restrict__ yb, const float* __restrict__ rbv,
    const float* __restrict__ kbv, const float* __restrict__ abv,
    const float* __restrict__ vbv, const float* __restrict__ gbv,
    const float* __restrict__ kaw, const float* __restrict__ r_k,
    const float* __restrict__ ln_w, const float* __restrict__ ln_b,
    float* __restrict__ zb)
{
    const int t = blockIdx.x;
    const int tid = threadIdx.x;
    const size_t base = (size_t)t * CC;
    #pragma unroll
    for (int j = 0; j < 4; j++) {
        int c = tid + 256 * j;
        float y = yb[base + c];
        float s1 = waveReduceSum(y);
        float s2 = waveReduceSum(y * y);
        float mu = s1 * (1.0f / 64.0f);
        float var = s2 * (1.0f / 64.0f) - mu * mu;
        float yn = (y - mu) * rsqrtf(var + EPS_GN);
        yn = yn * ln_w[c] + ln_b[c];
        float rv = rbv[base + c];
        float kf = kbv[base + c] * (1.0f + (abv[base + c] - 1.0f) * kaw[c]);
        float vv = vbv[base + c];
        float dot = waveReduceSum(rv * kf * r_k[c]);
        yn += dot * vv;
        zb[base + c] = yn * gbv[base + c];
    }
}

// ---------------------------------------------------------------------------
extern "C" void kernel_launch(void* const* d_in, const int* in_sizes, int n_in,
                              void* d_out, int out_size, void* d_ws, size_t ws_size,
                              hipStream_t stream)
{
    (void)in_sizes; (void)n_in; (void)out_size; (void)ws_size;
    const float* x      = (const float*)d_in[0];
    const float* vfirst = (const float*)d_in[1];
    const float* x_r    = (const float*)d_in[2];
    const float* x_w    = (const float*)d_in[3];
    const float* x_k    = (const float*)d_in[4];
    const float* x_v    = (const float*)d_in[5];
    const float* x_a    = (const float*)d_in[6];
    const float* x_g    = (const float*)d_in[7];
    const float* w0     = (const float*)d_in[8];
    const float* w1     = (const float*)d_in[9];
    const float* w2     = (const float*)d_in[10];
    const float* a0     = (const float*)d_in[11];
    const float* a1     = (const float*)d_in[12];
    const float* a2     = (const float*)d_in[13];
    const float* v0     = (const float*)d_in[14];
    const float* v1     = (const float*)d_in[15];
    const float* v2     = (const float*)d_in[16];
    const float* g1     = (const float*)d_in[17];
    const float* g2     = (const float*)d_in[18];
    const float* k_k    = (const float*)d_in[19];
    const float* k_a    = (const float*)d_in[20];
    const float* r_k    = (const float*)d_in[21];
    const float* Wr     = (const float*)d_in[22];
    const float* Wk     = (const float*)d_in[23];
    const float* Wv     = (const float*)d_in[24];
    const float* Wo     = (const float*)d_in[25];
    const float* ln_w   = (const float*)d_in[26];
    const float* ln_b   = (const float*)d_in[27];
    const float* alpha  = (const float*)d_in[28];

    const size_t SZ = (size_t)BT * CC;
    const size_t CHB = (size_t)1024 * 4096;   // per-batch chunk-buffer floats
    float* ws   = (float*)d_ws;
    float* rb   = ws + 0 * SZ;
    float* kb   = ws + 1 * SZ;             // raw k
    float* vb   = ws + 2 * SZ;             // v final
    float* decb = ws + 3 * SZ;             // decay; reused as z after scan
    float* ab   = ws + 4 * SZ;             // sigmoid(a)
    float* tw   = ws + 5 * SZ;
    float* ta   = tw + (size_t)BT * 64;
    float* tv   = ta + (size_t)BT * 64;
    float* tg   = tv + (size_t)BT * 32;
    float* Gb   = tg + (size_t)BT * 160;
    float* Ub   = Gb + CHB;
    float* Bpb  = Ub + CHB;
    float* Kpb  = Bpb + CHB;
    float* S0b  = Kpb + CHB;
    float* wcb  = S0b + CHB;
    float* Scur = wcb + CHB;               // [128][4096]
    float* outp = (float*)d_out;
    float* gb   = outp;                    // g lives in out[0:SZ] until final GEMM
    float* yb   = outp + SZ;               // y lives in out[SZ:2SZ] until v_first copy
    float* zb   = decb;

    dim3 blk(256);
    gemm_mix<true, true, 0><<<dim3(BT / 128, 8), blk, 0, stream>>>(x, Wr, x_r, rb, CC);
    gemm_mix<true, true, 0><<<dim3(BT / 128, 8), blk, 0, stream>>>(x, Wk, x_k, kb, CC);
    gemm_mix<true, true, 0><<<dim3(BT / 128, 8), blk, 0, stream>>>(x, Wv, x_v, vb, CC);
    gemm_mix<true, false, 1><<<dim3(BT / 128, 1), blk, 0, stream>>>(x, w1, x_w, tw, 64);
    gemm_mix<true, false, 0><<<dim3(BT / 128, 1), blk, 0, stream>>>(x, a1, x_a, ta, 64);
    gemm_mix<true, false, 0><<<dim3(BT / 128, 1), blk, 0, stream>>>(x, v1, x_v, tv, 32);
    gemm_mix<true, false, 2><<<dim3(BT / 128, 2), blk, 0, stream>>>(x, g1, x_g, tg, 160);
    lora2_kernel<<<dim3(BT / 8), blk, 0, stream>>>(tw, ta, tv, tg, w2, a2, v2, g2,
        w0, a0, v0, vfirst, vb, decb, ab, gb);

    hipMemsetAsync(yb, 0, SZ * sizeof(float), stream);
    hipMemsetAsync(Scur, 0, (size_t)128 * 4096 * sizeof(float), stream);
    for (int cb = 0; cb < NB; ++cb) {
        wkvA<<<dim3(1024), blk, 0, stream>>>(kb, ab, vb, decb, k_k, k_a,
                                             Gb, Ub, Bpb, Kpb, wcb, cb);
        wkvB<<<dim3(128), blk, 0, stream>>>(vb, Gb, Ub, Bpb, Kpb, wcb, S0b, Scur, cb);
        wkvC<<<dim3(1024), blk, 0, stream>>>(rb, vb, Bpb, Kpb, Ub, S0b, wcb,
                                             alpha, yb, cb);
    }

    post_kernel<<<dim3(BT), blk, 0, stream>>>(yb, rb, kb, ab, vb, gb, k_a, r_k,
                                              ln_w, ln_b, zb);
    hipMemcpyAsync(outp + SZ, vfirst, SZ * sizeof(float),
                   hipMemcpyDeviceToDevice, stream);
    gemm_mix<false, true, 0><<<dim3(BT / 128, 8), blk, 0, stream>>>(zb, Wo, nullptr, outp, CC);
}

// Round 4
// 6048.290 us; speedup vs baseline: 1.7938x; 1.0520x over previous
//
#include <hip/hip_runtime.h>
#include <hip/hip_bf16.h>
#include <math.h>

#define BB 4
#define TT 4096
#define CC 1024
#define HH 16
#define NN 64
#define BT (BB*TT)            // 16384 rows
#define EPS_GN 6.4e-4f        // 1e-5 * 8^2
#define TMAX (TT-1)
#define LCH 64                // chunk length
#define CB 8                  // chunks per batch
#define NB 8                  // batches  (LCH*CB*NB == TT)
#define STR 65                // padded LDS row stride

typedef __attribute__((ext_vector_type(8))) short bf16x8;
typedef __attribute__((ext_vector_type(4))) float f32x4;

__device__ __forceinline__ float sigmoidf_(float x) {
    return 1.0f / (1.0f + expf(-x));
}

__device__ __forceinline__ float waveReduceSum(float v) {
    #pragma unroll
    for (int off = 32; off > 0; off >>= 1)
        v += __shfl_xor(v, off, 64);
    return v;
}

__device__ __forceinline__ unsigned short f2bf(float f) {
    unsigned u = __float_as_uint(f);
    u += 0x7FFFu + ((u >> 16) & 1u);
    return (unsigned short)(u >> 16);
}
__device__ __forceinline__ float bf2f(unsigned short h) {
    return __uint_as_float(((unsigned)h) << 16);
}

// acc[r][c] += sum_k A(tr+r,k)*B(tc+c,k); element A(i,k)=A[i*SA0+k*SA1].
template<int SA0,int SA1,int SB0,int SB1>
__device__ __forceinline__ void gemm64(const float* __restrict__ A,
                                       const float* __restrict__ B,
                                       float acc[4][4], int tr, int tc) {
    #pragma unroll 4
    for (int kx = 0; kx < 64; ++kx) {
        float av[4], bv[4];
        #pragma unroll
        for (int r = 0; r < 4; r++) av[r] = A[(tr + r) * SA0 + kx * SA1];
        #pragma unroll
        for (int cq = 0; cq < 4; cq++) bv[cq] = B[(tc + cq) * SB0 + kx * SB1];
        #pragma unroll
        for (int r = 0; r < 4; r++)
            #pragma unroll
            for (int cq = 0; cq < 4; cq++)
                acc[r][cq] = fmaf(av[r], bv[cq], acc[r][cq]);
    }
}

// ---------------------------------------------------------------------------
// Split-conversion: fp32 (rows x CC, k-contig) -> bf16 hi + bf16 lo residual.
// DOMIX: apply token-shift mix A = x + (x_prev - x)*mix (x_prev=0 at batch
// start, rows interpreted as b*TT+t).
// ---------------------------------------------------------------------------
template<bool DOMIX>
__global__ __launch_bounds__(256) void conv_split(
    const float* __restrict__ X, const float* __restrict__ mix,
    unsigned short* __restrict__ Hi, unsigned short* __restrict__ Lo,
    int ngroups)
{
    int g = blockIdx.x * 256 + threadIdx.x;
    if (g >= ngroups) return;
    int m = g >> 7;                 // CC/8 = 128 groups per row
    int k = (g & 127) * 8;
    const float* px = X + (size_t)m * CC + k;
    float a[8];
    {
        float4 x0 = *(const float4*)px;
        float4 x1 = *(const float4*)(px + 4);
        a[0]=x0.x; a[1]=x0.y; a[2]=x0.z; a[3]=x0.w;
        a[4]=x1.x; a[5]=x1.y; a[6]=x1.z; a[7]=x1.w;
    }
    if (DOMIX) {
        float4 p0, p1;
        if ((m & (TT - 1)) == 0) {
            p0 = make_float4(0.f,0.f,0.f,0.f); p1 = p0;
        } else {
            p0 = *(const float4*)(px - CC);
            p1 = *(const float4*)(px - CC + 4);
        }
        float4 m0 = *(const float4*)(mix + k);
        float4 m1 = *(const float4*)(mix + k + 4);
        float pv[8] = {p0.x,p0.y,p0.z,p0.w,p1.x,p1.y,p1.z,p1.w};
        float mv[8] = {m0.x,m0.y,m0.z,m0.w,m1.x,m1.y,m1.z,m1.w};
        #pragma unroll
        for (int j = 0; j < 8; j++) a[j] += (pv[j] - a[j]) * mv[j];
    }
    unsigned short hi[8], lo[8];
    #pragma unroll
    for (int j = 0; j < 8; j++) {
        hi[j] = f2bf(a[j]);
        lo[j] = f2bf(a[j] - bf2f(hi[j]));
    }
    uint4 H, L;
    H.x = (unsigned)hi[0] | ((unsigned)hi[1] << 16);
    H.y = (unsigned)hi[2] | ((unsigned)hi[3] << 16);
    H.z = (unsigned)hi[4] | ((unsigned)hi[5] << 16);
    H.w = (unsigned)hi[6] | ((unsigned)hi[7] << 16);
    L.x = (unsigned)lo[0] | ((unsigned)lo[1] << 16);
    L.y = (unsigned)lo[2] | ((unsigned)lo[3] << 16);
    L.z = (unsigned)lo[4] | ((unsigned)lo[5] << 16);
    L.w = (unsigned)lo[6] | ((unsigned)lo[7] << 16);
    *(uint4*)(Hi + (size_t)g * 8) = H;
    *(uint4*)(Lo + (size_t)g * 8) = L;
}

// ---------------------------------------------------------------------------
// Split-bf16 MFMA GEMM: Out[M=BT][N=CC] = A @ W^T with
// A = Ah+Al (M,K=CC bf16, k-contig), W = Bh+Bl (N,K bf16, k-contig).
// 3-term: AhBh + AlBh + AhBl, fp32 accum. Tile 128x128, BK=64, 4 waves of
// 64x64, mfma_f32_16x16x32_bf16. LDS XOR-swizzled (16B granule ^= row&7).
// ---------------------------------------------------------------------------
__global__ __launch_bounds__(256) void gemm_split_bf16(
    const unsigned short* __restrict__ Ah, const unsigned short* __restrict__ Al,
    const unsigned short* __restrict__ Bh, const unsigned short* __restrict__ Bl,
    float* __restrict__ Out)
{
    __shared__ __align__(16) unsigned short lds[4][128 * 64];  // Ah,Al,Bh,Bl
    const int tid = threadIdx.x;
    const int lane = tid & 63;
    const int wave = tid >> 6;
    const int wm = (wave >> 1) * 64, wn = (wave & 1) * 64;
    const int m0 = blockIdx.x * 128, n0 = blockIdx.y * 128;

    f32x4 acc[4][4];
    #pragma unroll
    for (int i = 0; i < 4; i++)
        #pragma unroll
        for (int j = 0; j < 4; j++)
            acc[i][j] = (f32x4){0.f, 0.f, 0.f, 0.f};

    float4 stg[16];
    // prologue: k0 = 0
    #pragma unroll
    for (int p = 0; p < 4; p++) {
        const unsigned short* s = (p == 0) ? Ah : (p == 1) ? Al : (p == 2) ? Bh : Bl;
        const int rbase = (p < 2) ? m0 : n0;
        #pragma unroll
        for (int i = 0; i < 4; i++) {
            int g = tid + 256 * i;
            int row = g >> 3, grn = g & 7;
            stg[p * 4 + i] = *(const float4*)(s + (size_t)(rbase + row) * CC + grn * 8);
        }
    }

    for (int k0 = 0; k0 < CC; k0 += 64) {
        __syncthreads();
        #pragma unroll
        for (int p = 0; p < 4; p++)
            #pragma unroll
            for (int i = 0; i < 4; i++) {
                int g = tid + 256 * i;
                int row = g >> 3, grn = g & 7;
                int el = row * 64 + ((grn ^ (row & 7)) * 8);
                *(float4*)&lds[p][el] = stg[p * 4 + i];
            }
        __syncthreads();
        if (k0 + 64 < CC) {
            #pragma unroll
            for (int p = 0; p < 4; p++) {
                const unsigned short* s = (p == 0) ? Ah : (p == 1) ? Al : (p == 2) ? Bh : Bl;
                const int rbase = (p < 2) ? m0 : n0;
                #pragma unroll
                for (int i = 0; i < 4; i++) {
                    int g = tid + 256 * i;
                    int row = g >> 3, grn = g & 7;
                    stg[p * 4 + i] = *(const float4*)(s + (size_t)(rbase + row) * CC + k0 + 64 + grn * 8);
                }
            }
        }
        #pragma unroll
        for (int ks = 0; ks < 2; ks++) {
            bf16x8 ah[4], al[4], bh[4], bl[4];
            #pragma unroll
            for (int mt = 0; mt < 4; mt++) {
                int row = wm + mt * 16 + (lane & 15);
                int gk = ks * 4 + (lane >> 4);
                int el = row * 64 + ((gk ^ (row & 7)) * 8);
                ah[mt] = *(const bf16x8*)&lds[0][el];
                al[mt] = *(const bf16x8*)&lds[1][el];
            }
            #pragma unroll
            for (int nt = 0; nt < 4; nt++) {
                int col = wn + nt * 16 + (lane & 15);
                int gk = ks * 4 + (lane >> 4);
                int el = col * 64 + ((gk ^ (col & 7)) * 8);
                bh[nt] = *(const bf16x8*)&lds[2][el];
                bl[nt] = *(const bf16x8*)&lds[3][el];
            }
            #pragma unroll
            for (int mt = 0; mt < 4; mt++)
                #pragma unroll
                for (int nt = 0; nt < 4; nt++) {
                    acc[mt][nt] = __builtin_amdgcn_mfma_f32_16x16x32_bf16(
                        ah[mt], bh[nt], acc[mt][nt], 0, 0, 0);
                    acc[mt][nt] = __builtin_amdgcn_mfma_f32_16x16x32_bf16(
                        al[mt], bh[nt], acc[mt][nt], 0, 0, 0);
                    acc[mt][nt] = __builtin_amdgcn_mfma_f32_16x16x32_bf16(
                        ah[mt], bl[nt], acc[mt][nt], 0, 0, 0);
                }
        }
    }
    // epilogue: C/D layout col=lane&15, row=(lane>>4)*4+reg  [m89/m91]
    #pragma unroll
    for (int mt = 0; mt < 4; mt++)
        #pragma unroll
        for (int nt = 0; nt < 4; nt++) {
            int n = n0 + wn + nt * 16 + (lane & 15);
            #pragma unroll
            for (int r = 0; r < 4; r++) {
                int m = m0 + wm + mt * 16 + (lane >> 4) * 4 + r;
                Out[(size_t)m * CC + n] = acc[mt][nt][r];
            }
        }
}

// ---------------------------------------------------------------------------
// fp32 GEMM (LoRA stage-1 only now): Out = A @ W, W (K,N) n-contig.
// ---------------------------------------------------------------------------
__device__ __forceinline__ float4 ldA(const float* __restrict__ X,
                                      const float* __restrict__ mix,
                                      int gm, int gk, bool domix) {
    const float* px = X + (size_t)gm * CC + gk;
    float4 xv = *(const float4*)px;
    if (domix) {
        float4 pv;
        if ((gm & (TT - 1)) == 0) pv = make_float4(0.f, 0.f, 0.f, 0.f);
        else pv = *(const float4*)(px - CC);
        float4 mv = *(const float4*)(mix + gk);
        xv.x += (pv.x - xv.x) * mv.x;
        xv.y += (pv.y - xv.y) * mv.y;
        xv.z += (pv.z - xv.z) * mv.z;
        xv.w += (pv.w - xv.w) * mv.w;
    }
    return xv;
}

template<bool DOMIX, bool WNK, int EPI>
__global__ __launch_bounds__(256) void gemm_mix(
    const float* __restrict__ X, const float* __restrict__ W,
    const float* __restrict__ mix, float* __restrict__ Out, int Ncols)
{
    __shared__ float As[8][128];
    __shared__ float Bs[8][128];
    const int tid = threadIdx.x;
    const int m0 = blockIdx.x * 128;
    const int n0 = blockIdx.y * 128;
    const int sr  = tid >> 1;
    const int skq = (tid & 1) * 4;
    const int bkr = tid >> 5;
    const int bnq = (tid & 31) * 4;
    const int tm = (tid >> 4) * 8;
    const int tn = (tid & 15) * 8;

    float acc[8][8];
    #pragma unroll
    for (int i = 0; i < 8; i++)
        #pragma unroll
        for (int j = 0; j < 8; j++) acc[i][j] = 0.f;

    float4 aR, bR;
    aR = ldA(X, mix, m0 + sr, skq, DOMIX);
    if (WNK) {
        int gn = n0 + sr;
        bR = (gn < Ncols) ? *(const float4*)(W + (size_t)gn * CC + skq)
                          : make_float4(0.f, 0.f, 0.f, 0.f);
    } else {
        int gn = n0 + bnq;
        bR = (gn < Ncols) ? *(const float4*)(W + (size_t)bkr * Ncols + gn)
                          : make_float4(0.f, 0.f, 0.f, 0.f);
    }

    for (int k0 = 0; k0 < CC; k0 += 8) {
        __syncthreads();
        As[skq + 0][sr] = aR.x;
        As[skq + 1][sr] = aR.y;
        As[skq + 2][sr] = aR.z;
        As[skq + 3][sr] = aR.w;
        if (WNK) {
            Bs[skq + 0][sr] = bR.x;
            Bs[skq + 1][sr] = bR.y;
            Bs[skq + 2][sr] = bR.z;
            Bs[skq + 3][sr] = bR.w;
        } else {
            *(float4*)&Bs[bkr][bnq] = bR;
        }
        __syncthreads();

        if (k0 + 8 < CC) {
            aR = ldA(X, mix, m0 + sr, k0 + 8 + skq, DOMIX);
            if (WNK) {
                int gn = n0 + sr;
                bR = (gn < Ncols) ? *(const float4*)(W + (size_t)gn * CC + k0 + 8 + skq)
                                  : make_float4(0.f, 0.f, 0.f, 0.f);
            } else {
                int gn = n0 + bnq;
                bR = (gn < Ncols) ? *(const float4*)(W + (size_t)(k0 + 8 + bkr) * Ncols + gn)
                                  : make_float4(0.f, 0.f, 0.f, 0.f);
            }
        }

        #pragma unroll
        for (int kk = 0; kk < 8; ++kk) {
            float av[8], bv[8];
            *(float4*)&av[0] = *(const float4*)&As[kk][tm];
            *(float4*)&av[4] = *(const float4*)&As[kk][tm + 4];
            *(float4*)&bv[0] = *(const float4*)&Bs[kk][tn];
            *(float4*)&bv[4] = *(const float4*)&Bs[kk][tn + 4];
            #pragma unroll
            for (int i = 0; i < 8; i++)
                #pragma unroll
                for (int j = 0; j < 8; j++)
                    acc[i][j] = fmaf(av[i], bv[j], acc[i][j]);
        }
    }

    #pragma unroll
    for (int i = 0; i < 8; i++) {
        int gm = m0 + tm + i;
        int gn = n0 + tn;
        if (gn < Ncols) {
            float o[8];
            #pragma unroll
            for (int j = 0; j < 8; j++) {
                float v = acc[i][j];
                if (EPI == 1) v = tanhf(v);
                if (EPI == 2) v = sigmoidf_(v);
                o[j] = v;
            }
            float* p = Out + (size_t)gm * Ncols + gn;
            *(float4*)p       = make_float4(o[0], o[1], o[2], o[3]);
            *(float4*)(p + 4) = make_float4(o[4], o[5], o[6], o[7]);
        }
    }
}

// ---------------------------------------------------------------------------
// LoRA stage-2 + elementwise fusion (unchanged — passed)
// ---------------------------------------------------------------------------
__global__ __launch_bounds__(256) void lora2_kernel(
    const float* __restrict__ tw, const float* __restrict__ ta,
    const float* __restrict__ tv, const float* __restrict__ tg,
    const float* __restrict__ w2, const float* __restrict__ a2,
    const float* __restrict__ v2, const float* __restrict__ g2,
    const float* __restrict__ w0, const float* __restrict__ a0v,
    const float* __restrict__ v0v, const float* __restrict__ v_first,
    float* __restrict__ vbuf, float* __restrict__ decb,
    float* __restrict__ ab, float* __restrict__ gb)
{
    __shared__ float s_w[8 * 64];
    __shared__ float s_a[8 * 64];
    __shared__ float s_v[8 * 32];
    __shared__ float s_g[8 * 160];
    const int tid = threadIdx.x;
    const int r0 = blockIdx.x * 8;

    for (int i = tid; i < 8 * 64; i += 256)  s_w[i] = tw[(size_t)r0 * 64 + i];
    for (int i = tid; i < 8 * 64; i += 256)  s_a[i] = ta[(size_t)r0 * 64 + i];
    s_v[tid] = tv[(size_t)r0 * 32 + tid];
    for (int i = tid; i < 8 * 160; i += 256) s_g[i] = tg[(size_t)r0 * 160 + i];
    __syncthreads();

    {
        float acc[8][4];
        #pragma unroll
        for (int r = 0; r < 8; r++)
            #pragma unroll
            for (int j = 0; j < 4; j++) acc[r][j] = 0.f;
        for (int d = 0; d < 64; ++d) {
            float wr[4];
            #pragma unroll
            for (int j = 0; j < 4; j++) wr[j] = a2[(size_t)d * CC + tid + 256 * j];
            #pragma unroll
            for (int r = 0; r < 8; r++) {
                float xv = s_a[r * 64 + d];
                #pragma unroll
                for (int j = 0; j < 4; j++) acc[r][j] = fmaf(xv, wr[j], acc[r][j]);
            }
        }
        #pragma unroll
        for (int r = 0; r < 8; r++) {
            size_t base = (size_t)(r0 + r) * CC;
            #pragma unroll
            for (int j = 0; j < 4; j++) {
                int c = tid + 256 * j;
                ab[base + c] = sigmoidf_(a0v[c] + acc[r][j]);
            }
        }
    }
    {
        float acc[8][4];
        #pragma unroll
        for (int r = 0; r < 8; r++)
            #pragma unroll
            for (int j = 0; j < 4; j++) acc[r][j] = 0.f;
        for (int d = 0; d < 64; ++d) {
            float wr[4];
            #pragma unroll
            for (int j = 0; j < 4; j++) wr[j] = w2[(size_t)d * CC + tid + 256 * j];
            #pragma unroll
            for (int r = 0; r < 8; r++) {
                float xv = s_w[r * 64 + d];
                #pragma unroll
                for (int j = 0; j < 4; j++) acc[r][j] = fmaf(xv, wr[j], acc[r][j]);
            }
        }
        #pragma unroll
        for (int r = 0; r < 8; r++) {
            size_t base = (size_t)(r0 + r) * CC;
            #pragma unroll
            for (int j = 0; j < 4; j++) {
                int c = tid + 256 * j;
                float dwv = w0[c] + acc[r][j];
                float wv = -log1pf(expf(-dwv)) - 0.5f;
                decb[base + c] = expf(-expf(wv));
            }
        }
    }
    {
        float acc[8][4];
        #pragma unroll
        for (int r = 0; r < 8; r++)
            #pragma unroll
            for (int j = 0; j < 4; j++) acc[r][j] = 0.f;
        for (int d = 0; d < 32; ++d) {
            float wr[4];
            #pragma unroll
            for (int j = 0; j < 4; j++) wr[j] = v2[(size_t)d * CC + tid + 256 * j];
            #pragma unroll
            for (int r = 0; r < 8; r++) {
                float xv = s_v[r * 32 + d];
                #pragma unroll
                for (int j = 0; j < 4; j++) acc[r][j] = fmaf(xv, wr[j], acc[r][j]);
            }
        }
        #pragma unroll
        for (int r = 0; r < 8; r++) {
            size_t base = (size_t)(r0 + r) * CC;
            #pragma unroll
            for (int j = 0; j < 4; j++) {
                int c = tid + 256 * j;
                float s = sigmoidf_(v0v[c] + acc[r][j]);
                float vraw = vbuf[base + c];
                float vf = v_first[base + c];
                vbuf[base + c] = vraw + (vf - vraw) * s;
            }
        }
    }
    {
        float acc[8][4];
        #pragma unroll
        for (int r = 0; r < 8; r++)
            #pragma unroll
            for (int j = 0; j < 4; j++) acc[r][j] = 0.f;
        for (int d = 0; d < 160; ++d) {
            float wr[4];
            #pragma unroll
            for (int j = 0; j < 4; j++) wr[j] = g2[(size_t)d * CC + tid + 256 * j];
            #pragma unroll
            for (int r = 0; r < 8; r++) {
                float xv = s_g[r * 160 + d];
                #pragma unroll
                for (int j = 0; j < 4; j++) acc[r][j] = fmaf(xv, wr[j], acc[r][j]);
            }
        }
        #pragma unroll
        for (int r = 0; r < 8; r++) {
            size_t base = (size_t)(r0 + r) * CC;
            #pragma unroll
            for (int j = 0; j < 4; j++) {
                int c = tid + 256 * j;
                gb[base + c] = acc[r][j];
            }
        }
    }
}

// ---------------------------------------------------------------------------
// Chunked WKV (unchanged from round 3 — passed)
// ---------------------------------------------------------------------------
__global__ __launch_bounds__(256) void wkvA(
    const float* __restrict__ kb, const float* __restrict__ ab,
    const float* __restrict__ vb, const float* __restrict__ decb,
    const float* __restrict__ k_k, const float* __restrict__ k_a,
    float* __restrict__ Gb, float* __restrict__ Ub,
    float* __restrict__ Bpb, float* __restrict__ Kpb,
    float* __restrict__ wcb, int cb)
{
    __shared__ float sm[6][64 * STR];
    __shared__ float sSeg[4][64];
    const int inst = blockIdx.x;
    const int bhd = inst >> 3, lc = inst & 7;
    const int dir = bhd & 1, bh = bhd >> 1, b = bh >> 4, h = bh & 15;
    const int c64 = (cb * CB + lc) * LCH;
    const int tid = threadIdx.x;
    const int lane = tid & 63, seg = tid >> 6;
    const int ch = h * 64 + lane;
    const size_t gbase = (size_t)inst * 4096;
    float* sWC = sm[0];
    float* sAp = sm[1];
    float* sBp = sm[2];
    float* sKp = sm[3];
    float* sX  = sm[4];
    float* sYk = sm[5];

    {
        float run = 1.f; float loc[16];
        #pragma unroll
        for (int i = 0; i < 16; i++) {
            int p = seg * 16 + i;
            int t = dir ? (TMAX - (c64 + p)) : (c64 + p);
            float d = decb[((size_t)(b * TT + t)) * CC + ch];
            run *= d; loc[i] = run;
        }
        sSeg[seg][lane] = run;
        __syncthreads();
        float pre = 1.f;
        for (int s2 = 0; s2 < seg; ++s2) pre *= sSeg[s2][lane];
        #pragma unroll
        for (int i = 0; i < 16; i++) {
            int p = seg * 16 + i;
            float wcv = pre * loc[i];
            sWC[p * STR + lane] = wcv;
            wcb[gbase + p * 64 + lane] = wcv;
        }
    }
    __syncthreads();
    {
        const float kkl = k_k[ch], kal = k_a[ch];
        for (int i = 0; i < 16; i++) {
            int p = seg * 16 + i;
            int t = dir ? (TMAX - (c64 + p)) : (c64 + p);
            size_t ra = ((size_t)(b * TT + t)) * CC + ch;
            float kraw = kb[ra], asig = ab[ra];
            float kkv = kraw * kkl;
            float s2 = waveReduceSum(kkv * kkv);
            float kkn = kkv / fmaxf(sqrtf(s2), 1e-12f);
            float wc = sWC[p * STR + lane];
            float wx = (p == 0) ? 1.f : sWC[(p - 1) * STR + lane];
            float apv = -kkn * wx;
            float bpv = kkn * asig / wc;
            float kpv = kraw * (1.f + (asig - 1.f) * kal) / wc;
            sAp[lane * STR + p] = apv;
            sBp[lane * STR + p] = bpv;
            sKp[lane * STR + p] = kpv;
            Bpb[gbase + p * 64 + lane] = bpv;
            Kpb[gbase + p * 64 + lane] = kpv;
        }
    }
    __syncthreads();

    const int tr = (tid >> 4) * 4, tc = (tid & 15) * 4;
    #pragma unroll
    for (int i = 0; i < 16; i++) {
        int p = seg * 16 + i;
        int t = dir ? (TMAX - (c64 + p)) : (c64 + p);
        sWC[p * STR + lane] = vb[((size_t)(b * TT + t)) * CC + ch];
    }
    {
        float acc[4][4] = {};
        gemm64<1, STR, 1, STR>(sAp, sBp, acc, tr, tc);
        #pragma unroll
        for (int r = 0; r < 4; r++)
            #pragma unroll
            for (int cq = 0; cq < 4; cq++)
                sX[(tr + r) * STR + tc + cq] = (tc + cq < tr + r) ? acc[r][cq] : 0.f;
    }
    {
        float acc[4][4] = {};
        gemm64<1, STR, 1, STR>(sAp, sKp, acc, tr, tc);
        #pragma unroll
        for (int r = 0; r < 4; r++)
            #pragma unroll
            for (int cq = 0; cq < 4; cq++)
                sYk[(tr + r) * STR + tc + cq] = (tc + cq < tr + r) ? acc[r][cq] : 0.f;
    }
    __syncthreads();
    {
        float acc[4][4] = {};
        gemm64<STR, 1, 1, STR>(sYk, sWC, acc, tr, tc);
        __syncthreads();
        #pragma unroll
        for (int r = 0; r < 4; r++)
            #pragma unroll
            for (int cq = 0; cq < 4; cq++)
                sKp[(tr + r) * STR + tc + cq] = acc[r][cq];
    }
    __syncthreads();
    if (tid < 64) {
        for (int r = 0; r < 64; ++r) {
            float acc = 0.f;
            for (int s = 0; s < r; ++s)
                acc = fmaf(sX[r * STR + s], sBp[s * STR + tid], acc);
            sBp[r * STR + tid] = (r == tid) ? 1.f : acc;
        }
    }
    __syncthreads();
    {
        float accG[4][4] = {};
        gemm64<STR, 1, STR, 1>(sBp, sAp, accG, tr, tc);
        float accU[4][4] = {};
        gemm64<STR, 1, 1, STR>(sBp, sKp, accU, tr, tc);
        #pragma unroll
        for (int r = 0; r < 4; r++) {
            *(float4*)&Gb[gbase + (tr + r) * 64 + tc] =
                make_float4(accG[r][0], accG[r][1], accG[r][2], accG[r][3]);
            *(float4*)&Ub[gbase + (tr + r) * 64 + tc] =
                make_float4(accU[r][0], accU[r][1], accU[r][2], accU[r][3]);
        }
    }
}

__global__ __launch_bounds__(256) void wkvB(
    const float* __restrict__ vb,
    const float* __restrict__ Gb, float* __restrict__ Ub,
    const float* __restrict__ Bpb, const float* __restrict__ Kpb,
    const float* __restrict__ wcb, float* __restrict__ S0b,
    float* __restrict__ Scur, int cb)
{
    __shared__ float sS[64 * STR];
    __shared__ float sG[64 * STR];
    __shared__ float sU[64 * STR];
    __shared__ float sB[64 * STR];
    __shared__ float sK[64 * STR];
    __shared__ float sV[64 * STR];
    const int bhd = blockIdx.x;
    const int dir = bhd & 1, bh = bhd >> 1, b = bh >> 4, h = bh & 15;
    const int tid = threadIdx.x;
    const int tr = (tid >> 4) * 4, tc = (tid & 15) * 4;

    for (int i = tid; i < 4096; i += 256)
        sS[(i >> 6) * STR + (i & 63)] = Scur[(size_t)bhd * 4096 + i];
    __syncthreads();

    for (int lc = 0; lc < CB; ++lc) {
        const int inst = bhd * CB + lc;
        const size_t gbase = (size_t)inst * 4096;
        const int c64 = (cb * CB + lc) * LCH;
        for (int i = tid; i < 4096; i += 256) {
            int rr = i >> 6, jj = i & 63;
            sG[rr * STR + jj] = Gb[gbase + i];
            sB[rr * STR + jj] = Bpb[gbase + i];
            sK[rr * STR + jj] = Kpb[gbase + i];
            int t = dir ? (TMAX - (c64 + rr)) : (c64 + rr);
            sV[rr * STR + jj] = vb[((size_t)(b * TT + t)) * CC + h * 64 + jj];
            S0b[gbase + i] = sS[rr * STR + jj];
        }
        __syncthreads();
        {
            float acc[4][4];
            #pragma unroll
            for (int r = 0; r < 4; r++) {
                float4 u0 = *(const float4*)&Ub[gbase + (tr + r) * 64 + tc];
                acc[r][0] = u0.x; acc[r][1] = u0.y; acc[r][2] = u0.z; acc[r][3] = u0.w;
            }
            gemm64<STR, 1, STR, 1>(sG, sS, acc, tr, tc);
            #pragma unroll
            for (int r = 0; r < 4; r++) {
                #pragma unroll
                for (int cq = 0; cq < 4; cq++) sU[(tr + r) * STR + tc + cq] = acc[r][cq];
                *(float4*)&Ub[gbase + (tr + r) * 64 + tc] =
                    make_float4(acc[r][0], acc[r][1], acc[r][2], acc[r][3]);
            }
        }
        __syncthreads();
        {
            float acc[4][4] = {};
            gemm64<1, STR, 1, STR>(sU, sB, acc, tr, tc);
            gemm64<1, STR, 1, STR>(sV, sK, acc, tr, tc);
            float w63[4];
            #pragma unroll
            for (int cq = 0; cq < 4; cq++) w63[cq] = wcb[gbase + 63 * 64 + tc + cq];
            #pragma unroll
            for (int r = 0; r < 4; r++)
                #pragma unroll
                for (int cq = 0; cq < 4; cq++) {
                    float sv = sS[(tr + r) * STR + tc + cq];
                    acc[r][cq] = (sv + acc[r][cq]) * w63[cq];
                }
            #pragma unroll
            for (int r = 0; r < 4; r++)
                #pragma unroll
                for (int cq = 0; cq < 4; cq++)
                    sS[(tr + r) * STR + tc + cq] = acc[r][cq];
        }
        __syncthreads();
    }
    for (int i = tid; i < 4096; i += 256)
        Scur[(size_t)bhd * 4096 + i] = sS[(i >> 6) * STR + (i & 63)];
}

__global__ __launch_bounds__(256) void wkvC(
    const float* __restrict__ rb, const float* __restrict__ vb,
    const float* __restrict__ Bpb, const float* __restrict__ Kpb,
    const float* __restrict__ Ub, const float* __restrict__ S0b,
    const float* __restrict__ wcb, const float* __restrict__ alpha_p,
    float* __restrict__ yb, int cb)
{
    __shared__ float sm[6][64 * STR];
    float* sRp = sm[0];
    float* sBt = sm[1];
    float* sKt = sm[2];
    float* sMb = sm[3];
    float* sMk = sm[4];
    float* sV  = sm[5];
    const int inst = blockIdx.x;
    const int bhd = inst >> 3, lc = inst & 7;
    const int dir = bhd & 1, bh = bhd >> 1, b = bh >> 4, h = bh & 15;
    const int c64 = (cb * CB + lc) * LCH;
    const int tid = threadIdx.x, lane = tid & 63, seg = tid >> 6;
    const size_t gbase = (size_t)inst * 4096;
    const float alpha = alpha_p[0];
    const float wscale = dir ? (1.f - alpha) : alpha;

    #pragma unroll
    for (int i = 0; i < 16; i++) {
        int p = seg * 16 + i;
        int t = dir ? (TMAX - (c64 + p)) : (c64 + p);
        size_t ra = ((size_t)(b * TT + t)) * CC + h * 64 + lane;
        float wc = wcb[gbase + p * 64 + lane];
        sRp[lane * STR + p] = rb[ra] * wc;
        sBt[lane * STR + p] = Bpb[gbase + p * 64 + lane];
        sKt[lane * STR + p] = Kpb[gbase + p * 64 + lane];
        sV[p * STR + lane]  = vb[ra];
    }
    __syncthreads();
    const int tr = (tid >> 4) * 4, tc = (tid & 15) * 4;
    {
        float acc[4][4] = {};
        gemm64<1, STR, 1, STR>(sRp, sBt, acc, tr, tc);
        #pragma unroll
        for (int r = 0; r < 4; r++)
            #pragma unroll
            for (int cq = 0; cq < 4; cq++)
                sMb[(tr + r) * STR + tc + cq] = (tc + cq <= tr + r) ? acc[r][cq] : 0.f;
        float acc2[4][4] = {};
        gemm64<1, STR, 1, STR>(sRp, sKt, acc2, tr, tc);
        #pragma unroll
        for (int r = 0; r < 4; r++)
            #pragma unroll
            for (int cq = 0; cq < 4; cq++)
                sMk[(tr + r) * STR + tc + cq] = (tc + cq <= tr + r) ? acc2[r][cq] : 0.f;
    }
    __syncthreads();
    #pragma unroll
    for (int i = 0; i < 16; i++) {
        int rr = seg * 16 + i;
        sBt[rr * STR + lane] = Ub[gbase + rr * 64 + lane];
        sKt[rr * STR + lane] = S0b[gbase + rr * 64 + lane];
    }
    __syncthreads();
    {
        float acc[4][4] = {};
        gemm64<1, STR, STR, 1>(sRp, sKt, acc, tr, tc);
        gemm64<STR, 1, 1, STR>(sMb, sBt, acc, tr, tc);
        gemm64<STR, 1, 1, STR>(sMk, sV,  acc, tr, tc);
        #pragma unroll
        for (int r = 0; r < 4; r++) {
            int p = tr + r;
            int t = dir ? (TMAX - (c64 + p)) : (c64 + p);
            float* yp = &yb[((size_t)(b * TT + t)) * CC + h * 64 + tc];
            float4 old = *(float4*)yp;
            old.x += wscale * acc[r][0];
            old.y += wscale * acc[r][1];
            old.z += wscale * acc[r][2];
            old.w += wscale * acc[r][3];
            *(float4*)yp = old;
        }
    }
}

// ---------------------------------------------------------------------------
// Post: GroupNorm + affine + bonus term + gating (unchanged — passed)
// ---------------------------------------------------------------------------
__global__ __launch_bounds__(256) void post_kernel(
    const float* __restrict__ yb, const float* __restrict__ rbv,
    const float* __restrict__ kbv, const float* __restrict__ abv,
    const float* __restrict__ vbv, const float* __restrict__ gbv,
    const float* __restrict__ kaw, const float* __restrict__ r_k,
    const float* __restrict__ ln_w, const float* __restrict__ ln_b,
    float* __restrict__ zb)
{
    const int t = blockIdx.x;
    const int tid = threadIdx.x;
    const size_t base = (size_t)t * CC;
    #pragma unroll
    for (int j = 0; j < 4; j++) {
        int c = tid + 256 * j;
        float y = yb[base + c];
        float s1 = waveReduceSum(y);
        float s2 = waveReduceSum(y * y);
        float mu = s1 * (1.0f / 64.0f);
        float var = s2 * (1.0f / 64.0f) - mu * mu;
        float yn = (y - mu) * rsqrtf(var + EPS_GN);
        yn = yn * ln_w[c] + ln_b[c];
        float rv = rbv[base + c];
        float kf = kbv[base + c] * (1.0f + (abv[base + c] - 1.0f) * kaw[c]);
        float vv = vbv[base + c];
        float dot = waveReduceSum(rv * kf * r_k[c]);
        yn += dot * vv;
        zb[base + c] = yn * gbv[base + c];
    }
}

// ---------------------------------------------------------------------------
extern "C" void kernel_launch(void* const* d_in, const int* in_sizes, int n_in,
                              void* d_out, int out_size, void* d_ws, size_t ws_size,
                              hipStream_t stream)
{
    (void)in_sizes; (void)n_in; (void)out_size; (void)ws_size;
    const float* x      = (const float*)d_in[0];
    const float* vfirst = (const float*)d_in[1];
    const float* x_r    = (const float*)d_in[2];
    const float* x_w    = (const float*)d_in[3];
    const float* x_k    = (const float*)d_in[4];
    const float* x_v    = (const float*)d_in[5];
    const float* x_a    = (const float*)d_in[6];
    const float* x_g    = (const float*)d_in[7];
    const float* w0     = (const float*)d_in[8];
    const float* w1     = (const float*)d_in[9];
    const float* w2     = (const float*)d_in[10];
    const float* a0     = (const float*)d_in[11];
    const float* a1     = (const float*)d_in[12];
    const float* a2     = (const float*)d_in[13];
    const float* v0     = (const float*)d_in[14];
    const float* v1     = (const float*)d_in[15];
    const float* v2     = (const float*)d_in[16];
    const float* g1     = (const float*)d_in[17];
    const float* g2     = (const float*)d_in[18];
    const float* k_k    = (const float*)d_in[19];
    const float* k_a    = (const float*)d_in[20];
    const float* r_k    = (const float*)d_in[21];
    const float* Wr     = (const float*)d_in[22];
    const float* Wk     = (const float*)d_in[23];
    const float* Wv     = (const float*)d_in[24];
    const float* Wo     = (const float*)d_in[25];
    const float* ln_w   = (const float*)d_in[26];
    const float* ln_b   = (const float*)d_in[27];
    const float* alpha  = (const float*)d_in[28];

    const size_t SZ = (size_t)BT * CC;
    const size_t CHB = (size_t)1024 * 4096;
    float* ws   = (float*)d_ws;
    float* rb   = ws + 0 * SZ;
    float* kb   = ws + 1 * SZ;
    float* vb   = ws + 2 * SZ;
    float* decb = ws + 3 * SZ;
    float* ab   = ws + 4 * SZ;
    float* tw   = ws + 5 * SZ;
    float* ta   = tw + (size_t)BT * 64;
    float* tv   = ta + (size_t)BT * 64;
    float* tg   = tv + (size_t)BT * 32;
    float* Gb   = tg + (size_t)BT * 160;
    float* Ub   = Gb + CHB;
    float* Bpb  = Ub + CHB;
    float* Kpb  = Bpb + CHB;
    float* S0b  = Kpb + CHB;
    float* wcb  = S0b + CHB;
    float* Scur = wcb + CHB;                     // 128*4096 floats
    unsigned short* Whb = (unsigned short*)(Scur + (size_t)128 * 4096);
    unsigned short* Wlb = Whb + (size_t)CC * CC; // 2x 1M bf16 = 4 MB
    float* outp = (float*)d_out;
    float* gb   = outp;                          // g in out[0:SZ] until final GEMM
    float* yb   = outp + SZ;                     // y in out[SZ:2SZ] until v_first copy
    float* zb   = decb;
    // A-operand split buffers (bf16): alias dead regions
    unsigned short* Ahp = (unsigned short*)(outp + SZ);   // projections phase
    unsigned short* Alp = Ahp + SZ;
    unsigned short* zAh = (unsigned short*)rb;            // final GEMM phase
    unsigned short* zAl = zAh + SZ;

    dim3 blk(256);
    const int NG_A = BT * (CC / 8);    // 2,097,152 groups
    const int NG_W = CC * (CC / 8);    // 131,072 groups
    dim3 gridA(NG_A / 256), gridW(NG_W / 256);
    dim3 gridG(BT / 128, CC / 128);

    // big projections: split-convert then MFMA (3-term split-bf16)
    conv_split<false><<<gridW, blk, 0, stream>>>(Wr, nullptr, Whb, Wlb, NG_W);
    conv_split<true ><<<gridA, blk, 0, stream>>>(x, x_r, Ahp, Alp, NG_A);
    gemm_split_bf16<<<gridG, blk, 0, stream>>>(Ahp, Alp, Whb, Wlb, rb);
    conv_split<false><<<gridW, blk, 0, stream>>>(Wk, nullptr, Whb, Wlb, NG_W);
    conv_split<true ><<<gridA, blk, 0, stream>>>(x, x_k, Ahp, Alp, NG_A);
    gemm_split_bf16<<<gridG, blk, 0, stream>>>(Ahp, Alp, Whb, Wlb, kb);
    conv_split<false><<<gridW, blk, 0, stream>>>(Wv, nullptr, Whb, Wlb, NG_W);
    conv_split<true ><<<gridA, blk, 0, stream>>>(x, x_v, Ahp, Alp, NG_A);
    gemm_split_bf16<<<gridG, blk, 0, stream>>>(Ahp, Alp, Whb, Wlb, vb);

    // LoRA stage-1 (fp32, w: tanh, g: sigmoid fused)
    gemm_mix<true, false, 1><<<dim3(BT / 128, 1), blk, 0, stream>>>(x, w1, x_w, tw, 64);
    gemm_mix<true, false, 0><<<dim3(BT / 128, 1), blk, 0, stream>>>(x, a1, x_a, ta, 64);
    gemm_mix<true, false, 0><<<dim3(BT / 128, 1), blk, 0, stream>>>(x, v1, x_v, tv, 32);
    gemm_mix<true, false, 2><<<dim3(BT / 128, 2), blk, 0, stream>>>(x, g1, x_g, tg, 160);
    lora2_kernel<<<dim3(BT / 8), blk, 0, stream>>>(tw, ta, tv, tg, w2, a2, v2, g2,
        w0, a0, v0, vfirst, vb, decb, ab, gb);

    // chunked bidirectional WKV
    hipMemsetAsync(yb, 0, SZ * sizeof(float), stream);
    hipMemsetAsync(Scur, 0, (size_t)128 * 4096 * sizeof(float), stream);
    for (int cb = 0; cb < NB; ++cb) {
        wkvA<<<dim3(1024), blk, 0, stream>>>(kb, ab, vb, decb, k_k, k_a,
                                             Gb, Ub, Bpb, Kpb, wcb, cb);
        wkvB<<<dim3(128), blk, 0, stream>>>(vb, Gb, Ub, Bpb, Kpb, wcb, S0b, Scur, cb);
        wkvC<<<dim3(1024), blk, 0, stream>>>(rb, vb, Bpb, Kpb, Ub, S0b, wcb,
                                             alpha, yb, cb);
    }

    // groupnorm + bonus + gate -> z (in dec's slot)
    post_kernel<<<dim3(BT), blk, 0, stream>>>(yb, rb, kb, ab, vb, gb, k_a, r_k,
                                              ln_w, ln_b, zb);
    // final projection: split-convert z (rb region now dead) and Wo
    conv_split<false><<<gridW, blk, 0, stream>>>(Wo, nullptr, Whb, Wlb, NG_W);
    conv_split<false><<<gridA, blk, 0, stream>>>(zb, nullptr, zAh, zAl, NG_A);
    hipMemcpyAsync(outp + SZ, vfirst, SZ * sizeof(float),
                   hipMemcpyDeviceToDevice, stream);
    gemm_split_bf16<<<gridG, blk, 0, stream>>>(zAh, zAl, Whb, Wlb, outp);
}

// Round 5
// 5962.459 us; speedup vs baseline: 1.8196x; 1.0144x over previous
//
#include <hip/hip_runtime.h>
#include <hip/hip_bf16.h>
#include <math.h>

#define BB 4
#define TT 4096
#define CC 1024
#define HH 16
#define NN 64
#define BT (BB*TT)            // 16384 rows
#define EPS_GN 6.4e-4f        // 1e-5 * 8^2
#define TMAX (TT-1)
#define LCH 64                // chunk length
#define CB 8                  // chunks per batch
#define NB 8                  // batches  (LCH*CB*NB == TT)
#define STR 65                // padded LDS row stride

typedef __attribute__((ext_vector_type(8))) short bf16x8;
typedef __attribute__((ext_vector_type(4))) float f32x4;

__device__ __forceinline__ float sigmoidf_(float x) {
    return 1.0f / (1.0f + expf(-x));
}

__device__ __forceinline__ float waveReduceSum(float v) {
    #pragma unroll
    for (int off = 32; off > 0; off >>= 1)
        v += __shfl_xor(v, off, 64);
    return v;
}

__device__ __forceinline__ unsigned short f2bf(float f) {
    unsigned u = __float_as_uint(f);
    u += 0x7FFFu + ((u >> 16) & 1u);
    return (unsigned short)(u >> 16);
}
__device__ __forceinline__ float bf2f(unsigned short h) {
    return __uint_as_float(((unsigned)h) << 16);
}

// acc[r][c] += sum_k A(tr+r,k)*B(tc+c,k); element A(i,k)=A[i*SA0+k*SA1].
template<int SA0,int SA1,int SB0,int SB1>
__device__ __forceinline__ void gemm64(const float* __restrict__ A,
                                       const float* __restrict__ B,
                                       float acc[4][4], int tr, int tc) {
    #pragma unroll 4
    for (int kx = 0; kx < 64; ++kx) {
        float av[4], bv[4];
        #pragma unroll
        for (int r = 0; r < 4; r++) av[r] = A[(tr + r) * SA0 + kx * SA1];
        #pragma unroll
        for (int cq = 0; cq < 4; cq++) bv[cq] = B[(tc + cq) * SB0 + kx * SB1];
        #pragma unroll
        for (int r = 0; r < 4; r++)
            #pragma unroll
            for (int cq = 0; cq < 4; cq++)
                acc[r][cq] = fmaf(av[r], bv[cq], acc[r][cq]);
    }
}

// ---------------------------------------------------------------------------
// Split-conversion: fp32 (rows x CC, k-contig) -> bf16 hi + bf16 lo residual.
// ---------------------------------------------------------------------------
template<bool DOMIX>
__global__ __launch_bounds__(256) void conv_split(
    const float* __restrict__ X, const float* __restrict__ mix,
    unsigned short* __restrict__ Hi, unsigned short* __restrict__ Lo,
    int ngroups)
{
    int g = blockIdx.x * 256 + threadIdx.x;
    if (g >= ngroups) return;
    int m = g >> 7;                 // CC/8 = 128 groups per row
    int k = (g & 127) * 8;
    const float* px = X + (size_t)m * CC + k;
    float a[8];
    {
        float4 x0 = *(const float4*)px;
        float4 x1 = *(const float4*)(px + 4);
        a[0]=x0.x; a[1]=x0.y; a[2]=x0.z; a[3]=x0.w;
        a[4]=x1.x; a[5]=x1.y; a[6]=x1.z; a[7]=x1.w;
    }
    if (DOMIX) {
        float4 p0, p1;
        if ((m & (TT - 1)) == 0) {
            p0 = make_float4(0.f,0.f,0.f,0.f); p1 = p0;
        } else {
            p0 = *(const float4*)(px - CC);
            p1 = *(const float4*)(px - CC + 4);
        }
        float4 m0 = *(const float4*)(mix + k);
        float4 m1 = *(const float4*)(mix + k + 4);
        float pv[8] = {p0.x,p0.y,p0.z,p0.w,p1.x,p1.y,p1.z,p1.w};
        float mv[8] = {m0.x,m0.y,m0.z,m0.w,m1.x,m1.y,m1.z,m1.w};
        #pragma unroll
        for (int j = 0; j < 8; j++) a[j] += (pv[j] - a[j]) * mv[j];
    }
    unsigned short hi[8], lo[8];
    #pragma unroll
    for (int j = 0; j < 8; j++) {
        hi[j] = f2bf(a[j]);
        lo[j] = f2bf(a[j] - bf2f(hi[j]));
    }
    uint4 H, L;
    H.x = (unsigned)hi[0] | ((unsigned)hi[1] << 16);
    H.y = (unsigned)hi[2] | ((unsigned)hi[3] << 16);
    H.z = (unsigned)hi[4] | ((unsigned)hi[5] << 16);
    H.w = (unsigned)hi[6] | ((unsigned)hi[7] << 16);
    L.x = (unsigned)lo[0] | ((unsigned)lo[1] << 16);
    L.y = (unsigned)lo[2] | ((unsigned)lo[3] << 16);
    L.z = (unsigned)lo[4] | ((unsigned)lo[5] << 16);
    L.w = (unsigned)lo[6] | ((unsigned)lo[7] << 16);
    *(uint4*)(Hi + (size_t)g * 8) = H;
    *(uint4*)(Lo + (size_t)g * 8) = L;
}

// ---------------------------------------------------------------------------
// Split-bf16 MFMA GEMM: Out[M=BT][N=CC] = A @ W^T.
// 3-term: AhBh + AlBh + AhBl, fp32 accum. Tile 128x128, BK=64, 4 waves.
// Grid: 1D 1024; wg&7 selects XCD-co-located N-walk of one M-panel group.
// Epilogue: LDS-staged (2 passes of 64 rows) coalesced float4 stores.
// ---------------------------------------------------------------------------
__global__ __launch_bounds__(256) void gemm_split_bf16(
    const unsigned short* __restrict__ Ah, const unsigned short* __restrict__ Al,
    const unsigned short* __restrict__ Bh, const unsigned short* __restrict__ Bl,
    float* __restrict__ Out)
{
    __shared__ __align__(16) unsigned short lds[4][128 * 64];  // Ah,Al,Bh,Bl
    const int tid = threadIdx.x;
    const int lane = tid & 63;
    const int wave = tid >> 6;
    const int wm = (wave >> 1) * 64, wn = (wave & 1) * 64;
    // XCD-aware decode: xcd = wg&7 (round-robin dispatch), each xcd owns 16
    // M-panels; walk all 8 N-tiles of a panel consecutively for A reuse in L2.
    const int wg = blockIdx.x;
    const int xcd = wg & 7;
    const int j = wg >> 3;
    const int m0 = ((j >> 3) * 8 + xcd) * 128;
    const int n0 = (j & 7) * 128;

    f32x4 acc[4][4];
    #pragma unroll
    for (int i = 0; i < 4; i++)
        #pragma unroll
        for (int jj = 0; jj < 4; jj++)
            acc[i][jj] = (f32x4){0.f, 0.f, 0.f, 0.f};

    float4 stg[16];
    #pragma unroll
    for (int p = 0; p < 4; p++) {
        const unsigned short* s = (p == 0) ? Ah : (p == 1) ? Al : (p == 2) ? Bh : Bl;
        const int rbase = (p < 2) ? m0 : n0;
        #pragma unroll
        for (int i = 0; i < 4; i++) {
            int g = tid + 256 * i;
            int row = g >> 3, grn = g & 7;
            stg[p * 4 + i] = *(const float4*)(s + (size_t)(rbase + row) * CC + grn * 8);
        }
    }

    for (int k0 = 0; k0 < CC; k0 += 64) {
        __syncthreads();
        #pragma unroll
        for (int p = 0; p < 4; p++)
            #pragma unroll
            for (int i = 0; i < 4; i++) {
                int g = tid + 256 * i;
                int row = g >> 3, grn = g & 7;
                int el = row * 64 + ((grn ^ (row & 7)) * 8);
                *(float4*)&lds[p][el] = stg[p * 4 + i];
            }
        __syncthreads();
        if (k0 + 64 < CC) {
            #pragma unroll
            for (int p = 0; p < 4; p++) {
                const unsigned short* s = (p == 0) ? Ah : (p == 1) ? Al : (p == 2) ? Bh : Bl;
                const int rbase = (p < 2) ? m0 : n0;
                #pragma unroll
                for (int i = 0; i < 4; i++) {
                    int g = tid + 256 * i;
                    int row = g >> 3, grn = g & 7;
                    stg[p * 4 + i] = *(const float4*)(s + (size_t)(rbase + row) * CC + k0 + 64 + grn * 8);
                }
            }
        }
        #pragma unroll
        for (int ks = 0; ks < 2; ks++) {
            bf16x8 ah[4], al[4], bh[4], bl[4];
            #pragma unroll
            for (int mt = 0; mt < 4; mt++) {
                int row = wm + mt * 16 + (lane & 15);
                int gk = ks * 4 + (lane >> 4);
                int el = row * 64 + ((gk ^ (row & 7)) * 8);
                ah[mt] = *(const bf16x8*)&lds[0][el];
                al[mt] = *(const bf16x8*)&lds[1][el];
            }
            #pragma unroll
            for (int nt = 0; nt < 4; nt++) {
                int col = wn + nt * 16 + (lane & 15);
                int gk = ks * 4 + (lane >> 4);
                int el = col * 64 + ((gk ^ (col & 7)) * 8);
                bh[nt] = *(const bf16x8*)&lds[2][el];
                bl[nt] = *(const bf16x8*)&lds[3][el];
            }
            #pragma unroll
            for (int mt = 0; mt < 4; mt++)
                #pragma unroll
                for (int nt = 0; nt < 4; nt++) {
                    acc[mt][nt] = __builtin_amdgcn_mfma_f32_16x16x32_bf16(
                        ah[mt], bh[nt], acc[mt][nt], 0, 0, 0);
                    acc[mt][nt] = __builtin_amdgcn_mfma_f32_16x16x32_bf16(
                        al[mt], bh[nt], acc[mt][nt], 0, 0, 0);
                    acc[mt][nt] = __builtin_amdgcn_mfma_f32_16x16x32_bf16(
                        ah[mt], bl[nt], acc[mt][nt], 0, 0, 0);
                }
        }
    }
    // Epilogue: two 64-row passes through LDS (stride 132: 16B-aligned,
    // 2-way banks = free), then coalesced float4 stores (full lines).
    float* cf = (float*)&lds[0][0];    // 64*132*4 = 33.8 KB < 64 KB
    #pragma unroll
    for (int pass = 0; pass < 2; ++pass) {
        __syncthreads();
        if ((wave >> 1) == pass) {
            #pragma unroll
            for (int mt = 0; mt < 4; mt++)
                #pragma unroll
                for (int nt = 0; nt < 4; nt++)
                    #pragma unroll
                    for (int r = 0; r < 4; r++) {
                        int row = mt * 16 + (lane >> 4) * 4 + r;   // 0..63
                        int col = wn + nt * 16 + (lane & 15);
                        cf[row * 132 + col] = acc[mt][nt][r];
                    }
        }
        __syncthreads();
        #pragma unroll
        for (int i = 0; i < 8; i++) {
            int g = tid + 256 * i;
            int row = g >> 5, c4 = (g & 31) * 4;
            float4 v = *(float4*)&cf[row * 132 + c4];
            *(float4*)&Out[(size_t)(m0 + pass * 64 + row) * CC + n0 + c4] = v;
        }
    }
}

// ---------------------------------------------------------------------------
// fp32 GEMM (LoRA stage-1): Out = A @ W, W (K,N) n-contig.
// ---------------------------------------------------------------------------
__device__ __forceinline__ float4 ldA(const float* __restrict__ X,
                                      const float* __restrict__ mix,
                                      int gm, int gk, bool domix) {
    const float* px = X + (size_t)gm * CC + gk;
    float4 xv = *(const float4*)px;
    if (domix) {
        float4 pv;
        if ((gm & (TT - 1)) == 0) pv = make_float4(0.f, 0.f, 0.f, 0.f);
        else pv = *(const float4*)(px - CC);
        float4 mv = *(const float4*)(mix + gk);
        xv.x += (pv.x - xv.x) * mv.x;
        xv.y += (pv.y - xv.y) * mv.y;
        xv.z += (pv.z - xv.z) * mv.z;
        xv.w += (pv.w - xv.w) * mv.w;
    }
    return xv;
}

template<bool DOMIX, bool WNK, int EPI>
__global__ __launch_bounds__(256) void gemm_mix(
    const float* __restrict__ X, const float* __restrict__ W,
    const float* __restrict__ mix, float* __restrict__ Out, int Ncols)
{
    __shared__ float As[8][128];
    __shared__ float Bs[8][128];
    const int tid = threadIdx.x;
    const int m0 = blockIdx.x * 128;
    const int n0 = blockIdx.y * 128;
    const int sr  = tid >> 1;
    const int skq = (tid & 1) * 4;
    const int bkr = tid >> 5;
    const int bnq = (tid & 31) * 4;
    const int tm = (tid >> 4) * 8;
    const int tn = (tid & 15) * 8;

    float acc[8][8];
    #pragma unroll
    for (int i = 0; i < 8; i++)
        #pragma unroll
        for (int j = 0; j < 8; j++) acc[i][j] = 0.f;

    float4 aR, bR;
    aR = ldA(X, mix, m0 + sr, skq, DOMIX);
    if (WNK) {
        int gn = n0 + sr;
        bR = (gn < Ncols) ? *(const float4*)(W + (size_t)gn * CC + skq)
                          : make_float4(0.f, 0.f, 0.f, 0.f);
    } else {
        int gn = n0 + bnq;
        bR = (gn < Ncols) ? *(const float4*)(W + (size_t)bkr * Ncols + gn)
                          : make_float4(0.f, 0.f, 0.f, 0.f);
    }

    for (int k0 = 0; k0 < CC; k0 += 8) {
        __syncthreads();
        As[skq + 0][sr] = aR.x;
        As[skq + 1][sr] = aR.y;
        As[skq + 2][sr] = aR.z;
        As[skq + 3][sr] = aR.w;
        if (WNK) {
            Bs[skq + 0][sr] = bR.x;
            Bs[skq + 1][sr] = bR.y;
            Bs[skq + 2][sr] = bR.z;
            Bs[skq + 3][sr] = bR.w;
        } else {
            *(float4*)&Bs[bkr][bnq] = bR;
        }
        __syncthreads();

        if (k0 + 8 < CC) {
            aR = ldA(X, mix, m0 + sr, k0 + 8 + skq, DOMIX);
            if (WNK) {
                int gn = n0 + sr;
                bR = (gn < Ncols) ? *(const float4*)(W + (size_t)gn * CC + k0 + 8 + skq)
                                  : make_float4(0.f, 0.f, 0.f, 0.f);
            } else {
                int gn = n0 + bnq;
                bR = (gn < Ncols) ? *(const float4*)(W + (size_t)(k0 + 8 + bkr) * Ncols + gn)
                                  : make_float4(0.f, 0.f, 0.f, 0.f);
            }
        }

        #pragma unroll
        for (int kk = 0; kk < 8; ++kk) {
            float av[8], bv[8];
            *(float4*)&av[0] = *(const float4*)&As[kk][tm];
            *(float4*)&av[4] = *(const float4*)&As[kk][tm + 4];
            *(float4*)&bv[0] = *(const float4*)&Bs[kk][tn];
            *(float4*)&bv[4] = *(const float4*)&Bs[kk][tn + 4];
            #pragma unroll
            for (int i = 0; i < 8; i++)
                #pragma unroll
                for (int j = 0; j < 8; j++)
                    acc[i][j] = fmaf(av[i], bv[j], acc[i][j]);
        }
    }

    #pragma unroll
    for (int i = 0; i < 8; i++) {
        int gm = m0 + tm + i;
        int gn = n0 + tn;
        if (gn < Ncols) {
            float o[8];
            #pragma unroll
            for (int j = 0; j < 8; j++) {
                float v = acc[i][j];
                if (EPI == 1) v = tanhf(v);
                if (EPI == 2) v = sigmoidf_(v);
                o[j] = v;
            }
            float* p = Out + (size_t)gm * Ncols + gn;
            *(float4*)p       = make_float4(o[0], o[1], o[2], o[3]);
            *(float4*)(p + 4) = make_float4(o[4], o[5], o[6], o[7]);
        }
    }
}

// ---------------------------------------------------------------------------
// LoRA stage-2 + elementwise fusion (unchanged — passed)
// ---------------------------------------------------------------------------
__global__ __launch_bounds__(256) void lora2_kernel(
    const float* __restrict__ tw, const float* __restrict__ ta,
    const float* __restrict__ tv, const float* __restrict__ tg,
    const float* __restrict__ w2, const float* __restrict__ a2,
    const float* __restrict__ v2, const float* __restrict__ g2,
    const float* __restrict__ w0, const float* __restrict__ a0v,
    const float* __restrict__ v0v, const float* __restrict__ v_first,
    float* __restrict__ vbuf, float* __restrict__ decb,
    float* __restrict__ ab, float* __restrict__ gb)
{
    __shared__ float s_w[8 * 64];
    __shared__ float s_a[8 * 64];
    __shared__ float s_v[8 * 32];
    __shared__ float s_g[8 * 160];
    const int tid = threadIdx.x;
    const int r0 = blockIdx.x * 8;

    for (int i = tid; i < 8 * 64; i += 256)  s_w[i] = tw[(size_t)r0 * 64 + i];
    for (int i = tid; i < 8 * 64; i += 256)  s_a[i] = ta[(size_t)r0 * 64 + i];
    s_v[tid] = tv[(size_t)r0 * 32 + tid];
    for (int i = tid; i < 8 * 160; i += 256) s_g[i] = tg[(size_t)r0 * 160 + i];
    __syncthreads();

    {
        float acc[8][4];
        #pragma unroll
        for (int r = 0; r < 8; r++)
            #pragma unroll
            for (int j = 0; j < 4; j++) acc[r][j] = 0.f;
        for (int d = 0; d < 64; ++d) {
            float wr[4];
            #pragma unroll
            for (int j = 0; j < 4; j++) wr[j] = a2[(size_t)d * CC + tid + 256 * j];
            #pragma unroll
            for (int r = 0; r < 8; r++) {
                float xv = s_a[r * 64 + d];
                #pragma unroll
                for (int j = 0; j < 4; j++) acc[r][j] = fmaf(xv, wr[j], acc[r][j]);
            }
        }
        #pragma unroll
        for (int r = 0; r < 8; r++) {
            size_t base = (size_t)(r0 + r) * CC;
            #pragma unroll
            for (int j = 0; j < 4; j++) {
                int c = tid + 256 * j;
                ab[base + c] = sigmoidf_(a0v[c] + acc[r][j]);
            }
        }
    }
    {
        float acc[8][4];
        #pragma unroll
        for (int r = 0; r < 8; r++)
            #pragma unroll
            for (int j = 0; j < 4; j++) acc[r][j] = 0.f;
        for (int d = 0; d < 64; ++d) {
            float wr[4];
            #pragma unroll
            for (int j = 0; j < 4; j++) wr[j] = w2[(size_t)d * CC + tid + 256 * j];
            #pragma unroll
            for (int r = 0; r < 8; r++) {
                float xv = s_w[r * 64 + d];
                #pragma unroll
                for (int j = 0; j < 4; j++) acc[r][j] = fmaf(xv, wr[j], acc[r][j]);
            }
        }
        #pragma unroll
        for (int r = 0; r < 8; r++) {
            size_t base = (size_t)(r0 + r) * CC;
            #pragma unroll
            for (int j = 0; j < 4; j++) {
                int c = tid + 256 * j;
                float dwv = w0[c] + acc[r][j];
                float wv = -log1pf(expf(-dwv)) - 0.5f;
                decb[base + c] = expf(-expf(wv));
            }
        }
    }
    {
        float acc[8][4];
        #pragma unroll
        for (int r = 0; r < 8; r++)
            #pragma unroll
            for (int j = 0; j < 4; j++) acc[r][j] = 0.f;
        for (int d = 0; d < 32; ++d) {
            float wr[4];
            #pragma unroll
            for (int j = 0; j < 4; j++) wr[j] = v2[(size_t)d * CC + tid + 256 * j];
            #pragma unroll
            for (int r = 0; r < 8; r++) {
                float xv = s_v[r * 32 + d];
                #pragma unroll
                for (int j = 0; j < 4; j++) acc[r][j] = fmaf(xv, wr[j], acc[r][j]);
            }
        }
        #pragma unroll
        for (int r = 0; r < 8; r++) {
            size_t base = (size_t)(r0 + r) * CC;
            #pragma unroll
            for (int j = 0; j < 4; j++) {
                int c = tid + 256 * j;
                float s = sigmoidf_(v0v[c] + acc[r][j]);
                float vraw = vbuf[base + c];
                float vf = v_first[base + c];
                vbuf[base + c] = vraw + (vf - vraw) * s;
            }
        }
    }
    {
        float acc[8][4];
        #pragma unroll
        for (int r = 0; r < 8; r++)
            #pragma unroll
            for (int j = 0; j < 4; j++) acc[r][j] = 0.f;
        for (int d = 0; d < 160; ++d) {
            float wr[4];
            #pragma unroll
            for (int j = 0; j < 4; j++) wr[j] = g2[(size_t)d * CC + tid + 256 * j];
            #pragma unroll
            for (int r = 0; r < 8; r++) {
                float xv = s_g[r * 160 + d];
                #pragma unroll
                for (int j = 0; j < 4; j++) acc[r][j] = fmaf(xv, wr[j], acc[r][j]);
            }
        }
        #pragma unroll
        for (int r = 0; r < 8; r++) {
            size_t base = (size_t)(r0 + r) * CC;
            #pragma unroll
            for (int j = 0; j < 4; j++) {
                int c = tid + 256 * j;
                gb[base + c] = acc[r][j];
            }
        }
    }
}

// ---------------------------------------------------------------------------
// Chunked WKV (unchanged from round 3 — passed)
// ---------------------------------------------------------------------------
__global__ __launch_bounds__(256) void wkvA(
    const float* __restrict__ kb, const float* __restrict__ ab,
    const float* __restrict__ vb, const float* __restrict__ decb,
    const float* __restrict__ k_k, const float* __restrict__ k_a,
    float* __restrict__ Gb, float* __restrict__ Ub,
    float* __restrict__ Bpb, float* __restrict__ Kpb,
    float* __restrict__ wcb, int cb)
{
    __shared__ float sm[6][64 * STR];
    __shared__ float sSeg[4][64];
    const int inst = blockIdx.x;
    const int bhd = inst >> 3, lc = inst & 7;
    const int dir = bhd & 1, bh = bhd >> 1, b = bh >> 4, h = bh & 15;
    const int c64 = (cb * CB + lc) * LCH;
    const int tid = threadIdx.x;
    const int lane = tid & 63, seg = tid >> 6;
    const int ch = h * 64 + lane;
    const size_t gbase = (size_t)inst * 4096;
    float* sWC = sm[0];
    float* sAp = sm[1];
    float* sBp = sm[2];
    float* sKp = sm[3];
    float* sX  = sm[4];
    float* sYk = sm[5];

    {
        float run = 1.f; float loc[16];
        #pragma unroll
        for (int i = 0; i < 16; i++) {
            int p = seg * 16 + i;
            int t = dir ? (TMAX - (c64 + p)) : (c64 + p);
            float d = decb[((size_t)(b * TT + t)) * CC + ch];
            run *= d; loc[i] = run;
        }
        sSeg[seg][lane] = run;
        __syncthreads();
        float pre = 1.f;
        for (int s2 = 0; s2 < seg; ++s2) pre *= sSeg[s2][lane];
        #pragma unroll
        for (int i = 0; i < 16; i++) {
            int p = seg * 16 + i;
            float wcv = pre * loc[i];
            sWC[p * STR + lane] = wcv;
            wcb[gbase + p * 64 + lane] = wcv;
        }
    }
    __syncthreads();
    {
        const float kkl = k_k[ch], kal = k_a[ch];
        for (int i = 0; i < 16; i++) {
            int p = seg * 16 + i;
            int t = dir ? (TMAX - (c64 + p)) : (c64 + p);
            size_t ra = ((size_t)(b * TT + t)) * CC + ch;
            float kraw = kb[ra], asig = ab[ra];
            float kkv = kraw * kkl;
            float s2 = waveReduceSum(kkv * kkv);
            float kkn = kkv / fmaxf(sqrtf(s2), 1e-12f);
            float wc = sWC[p * STR + lane];
            float wx = (p == 0) ? 1.f : sWC[(p - 1) * STR + lane];
            float apv = -kkn * wx;
            float bpv = kkn * asig / wc;
            float kpv = kraw * (1.f + (asig - 1.f) * kal) / wc;
            sAp[lane * STR + p] = apv;
            sBp[lane * STR + p] = bpv;
            sKp[lane * STR + p] = kpv;
            Bpb[gbase + p * 64 + lane] = bpv;
            Kpb[gbase + p * 64 + lane] = kpv;
        }
    }
    __syncthreads();

    const int tr = (tid >> 4) * 4, tc = (tid & 15) * 4;
    #pragma unroll
    for (int i = 0; i < 16; i++) {
        int p = seg * 16 + i;
        int t = dir ? (TMAX - (c64 + p)) : (c64 + p);
        sWC[p * STR + lane] = vb[((size_t)(b * TT + t)) * CC + ch];
    }
    {
        float acc[4][4] = {};
        gemm64<1, STR, 1, STR>(sAp, sBp, acc, tr, tc);
        #pragma unroll
        for (int r = 0; r < 4; r++)
            #pragma unroll
            for (int cq = 0; cq < 4; cq++)
                sX[(tr + r) * STR + tc + cq] = (tc + cq < tr + r) ? acc[r][cq] : 0.f;
    }
    {
        float acc[4][4] = {};
        gemm64<1, STR, 1, STR>(sAp, sKp, acc, tr, tc);
        #pragma unroll
        for (int r = 0; r < 4; r++)
            #pragma unroll
            for (int cq = 0; cq < 4; cq++)
                sYk[(tr + r) * STR + tc + cq] = (tc + cq < tr + r) ? acc[r][cq] : 0.f;
    }
    __syncthreads();
    {
        float acc[4][4] = {};
        gemm64<STR, 1, 1, STR>(sYk, sWC, acc, tr, tc);
        __syncthreads();
        #pragma unroll
        for (int r = 0; r < 4; r++)
            #pragma unroll
            for (int cq = 0; cq < 4; cq++)
                sKp[(tr + r) * STR + tc + cq] = acc[r][cq];
    }
    __syncthreads();
    if (tid < 64) {
        for (int r = 0; r < 64; ++r) {
            float acc = 0.f;
            for (int s = 0; s < r; ++s)
                acc = fmaf(sX[r * STR + s], sBp[s * STR + tid], acc);
            sBp[r * STR + tid] = (r == tid) ? 1.f : acc;
        }
    }
    __syncthreads();
    {
        float accG[4][4] = {};
        gemm64<STR, 1, STR, 1>(sBp, sAp, accG, tr, tc);
        float accU[4][4] = {};
        gemm64<STR, 1, 1, STR>(sBp, sKp, accU, tr, tc);
        #pragma unroll
        for (int r = 0; r < 4; r++) {
            *(float4*)&Gb[gbase + (tr + r) * 64 + tc] =
                make_float4(accG[r][0], accG[r][1], accG[r][2], accG[r][3]);
            *(float4*)&Ub[gbase + (tr + r) * 64 + tc] =
                make_float4(accU[r][0], accU[r][1], accU[r][2], accU[r][3]);
        }
    }
}

__global__ __launch_bounds__(256) void wkvB(
    const float* __restrict__ vb,
    const float* __restrict__ Gb, float* __restrict__ Ub,
    const float* __restrict__ Bpb, const float* __restrict__ Kpb,
    const float* __restrict__ wcb, float* __restrict__ S0b,
    float* __restrict__ Scur, int cb)
{
    __shared__ float sS[64 * STR];
    __shared__ float sG[64 * STR];
    __shared__ float sU[64 * STR];
    __shared__ float sB[64 * STR];
    __shared__ float sK[64 * STR];
    __shared__ float sV[64 * STR];
    const int bhd = blockIdx.x;
    const int dir = bhd & 1, bh = bhd >> 1, b = bh >> 4, h = bh & 15;
    const int tid = threadIdx.x;
    const int tr = (tid >> 4) * 4, tc = (tid & 15) * 4;

    for (int i = tid; i < 4096; i += 256)
        sS[(i >> 6) * STR + (i & 63)] = Scur[(size_t)bhd * 4096 + i];
    __syncthreads();

    for (int lc = 0; lc < CB; ++lc) {
        const int inst = bhd * CB + lc;
        const size_t gbase = (size_t)inst * 4096;
        const int c64 = (cb * CB + lc) * LCH;
        for (int i = tid; i < 4096; i += 256) {
            int rr = i >> 6, jj = i & 63;
            sG[rr * STR + jj] = Gb[gbase + i];
            sB[rr * STR + jj] = Bpb[gbase + i];
            sK[rr * STR + jj] = Kpb[gbase + i];
            int t = dir ? (TMAX - (c64 + rr)) : (c64 + rr);
            sV[rr * STR + jj] = vb[((size_t)(b * TT + t)) * CC + h * 64 + jj];
            S0b[gbase + i] = sS[rr * STR + jj];
        }
        __syncthreads();
        {
            float acc[4][4];
            #pragma unroll
            for (int r = 0; r < 4; r++) {
                float4 u0 = *(const float4*)&Ub[gbase + (tr + r) * 64 + tc];
                acc[r][0] = u0.x; acc[r][1] = u0.y; acc[r][2] = u0.z; acc[r][3] = u0.w;
            }
            gemm64<STR, 1, STR, 1>(sG, sS, acc, tr, tc);
            #pragma unroll
            for (int r = 0; r < 4; r++) {
                #pragma unroll
                for (int cq = 0; cq < 4; cq++) sU[(tr + r) * STR + tc + cq] = acc[r][cq];
                *(float4*)&Ub[gbase + (tr + r) * 64 + tc] =
                    make_float4(acc[r][0], acc[r][1], acc[r][2], acc[r][3]);
            }
        }
        __syncthreads();
        {
            float acc[4][4] = {};
            gemm64<1, STR, 1, STR>(sU, sB, acc, tr, tc);
            gemm64<1, STR, 1, STR>(sV, sK, acc, tr, tc);
            float w63[4];
            #pragma unroll
            for (int cq = 0; cq < 4; cq++) w63[cq] = wcb[gbase + 63 * 64 + tc + cq];
            #pragma unroll
            for (int r = 0; r < 4; r++)
                #pragma unroll
                for (int cq = 0; cq < 4; cq++) {
                    float sv = sS[(tr + r) * STR + tc + cq];
                    acc[r][cq] = (sv + acc[r][cq]) * w63[cq];
                }
            #pragma unroll
            for (int r = 0; r < 4; r++)
                #pragma unroll
                for (int cq = 0; cq < 4; cq++)
                    sS[(tr + r) * STR + tc + cq] = acc[r][cq];
        }
        __syncthreads();
    }
    for (int i = tid; i < 4096; i += 256)
        Scur[(size_t)bhd * 4096 + i] = sS[(i >> 6) * STR + (i & 63)];
}

__global__ __launch_bounds__(256) void wkvC(
    const float* __restrict__ rb, const float* __restrict__ vb,
    const float* __restrict__ Bpb, const float* __restrict__ Kpb,
    const float* __restrict__ Ub, const float* __restrict__ S0b,
    const float* __restrict__ wcb, const float* __restrict__ alpha_p,
    float* __restrict__ yb, int cb)
{
    __shared__ float sm[6][64 * STR];
    float* sRp = sm[0];
    float* sBt = sm[1];
    float* sKt = sm[2];
    float* sMb = sm[3];
    float* sMk = sm[4];
    float* sV  = sm[5];
    const int inst = blockIdx.x;
    const int bhd = inst >> 3, lc = inst & 7;
    const int dir = bhd & 1, bh = bhd >> 1, b = bh >> 4, h = bh & 15;
    const int c64 = (cb * CB + lc) * LCH;
    const int tid = threadIdx.x, lane = tid & 63, seg = tid >> 6;
    const size_t gbase = (size_t)inst * 4096;
    const float alpha = alpha_p[0];
    const float wscale = dir ? (1.f - alpha) : alpha;

    #pragma unroll
    for (int i = 0; i < 16; i++) {
        int p = seg * 16 + i;
        int t = dir ? (TMAX - (c64 + p)) : (c64 + p);
        size_t ra = ((size_t)(b * TT + t)) * CC + h * 64 + lane;
        float wc = wcb[gbase + p * 64 + lane];
        sRp[lane * STR + p] = rb[ra] * wc;
        sBt[lane * STR + p] = Bpb[gbase + p * 64 + lane];
        sKt[lane * STR + p] = Kpb[gbase + p * 64 + lane];
        sV[p * STR + lane]  = vb[ra];
    }
    __syncthreads();
    const int tr = (tid >> 4) * 4, tc = (tid & 15) * 4;
    {
        float acc[4][4] = {};
        gemm64<1, STR, 1, STR>(sRp, sBt, acc, tr, tc);
        #pragma unroll
        for (int r = 0; r < 4; r++)
            #pragma unroll
            for (int cq = 0; cq < 4; cq++)
                sMb[(tr + r) * STR + tc + cq] = (tc + cq <= tr + r) ? acc[r][cq] : 0.f;
        float acc2[4][4] = {};
        gemm64<1, STR, 1, STR>(sRp, sKt, acc2, tr, tc);
        #pragma unroll
        for (int r = 0; r < 4; r++)
            #pragma unroll
            for (int cq = 0; cq < 4; cq++)
                sMk[(tr + r) * STR + tc + cq] = (tc + cq <= tr + r) ? acc2[r][cq] : 0.f;
    }
    __syncthreads();
    #pragma unroll
    for (int i = 0; i < 16; i++) {
        int rr = seg * 16 + i;
        sBt[rr * STR + lane] = Ub[gbase + rr * 64 + lane];
        sKt[rr * STR + lane] = S0b[gbase + rr * 64 + lane];
    }
    __syncthreads();
    {
        float acc[4][4] = {};
        gemm64<1, STR, STR, 1>(sRp, sKt, acc, tr, tc);
        gemm64<STR, 1, 1, STR>(sMb, sBt, acc, tr, tc);
        gemm64<STR, 1, 1, STR>(sMk, sV,  acc, tr, tc);
        #pragma unroll
        for (int r = 0; r < 4; r++) {
            int p = tr + r;
            int t = dir ? (TMAX - (c64 + p)) : (c64 + p);
            float* yp = &yb[((size_t)(b * TT + t)) * CC + h * 64 + tc];
            float4 old = *(float4*)yp;
            old.x += wscale * acc[r][0];
            old.y += wscale * acc[r][1];
            old.z += wscale * acc[r][2];
            old.w += wscale * acc[r][3];
            *(float4*)yp = old;
        }
    }
}

// ---------------------------------------------------------------------------
// Post: GroupNorm + affine + bonus + gating; emits z directly as split bf16
// (hi+lo) for the final MFMA GEMM — skips the fp32 z roundtrip.
// ---------------------------------------------------------------------------
__global__ __launch_bounds__(256) void post_kernel(
    const float* __restrict__ yb, const float* __restrict__ rbv,
    const float* __restrict__ kbv, const float* __restrict__ abv,
    const float* __restrict__ vbv, const float* __restrict__ gbv,
    const float* __restrict__ kaw, const float* __restrict__ r_k,
    const float* __restrict__ ln_w, const float* __restrict__ ln_b,
    unsigned short* __restrict__ zh, unsigned short* __restrict__ zl)
{
    const int t = blockIdx.x;
    const int tid = threadIdx.x;
    const size_t base = (size_t)t * CC;
    #pragma unroll
    for (int j = 0; j < 4; j++) {
        int c = tid + 256 * j;
        float y = yb[base + c];
        float s1 = waveReduceSum(y);
        float s2 = waveReduceSum(y * y);
        float mu = s1 * (1.0f / 64.0f);
        float var = s2 * (1.0f / 64.0f) - mu * mu;
        float yn = (y - mu) * rsqrtf(var + EPS_GN);
        yn = yn * ln_w[c] + ln_b[c];
        float rv = rbv[base + c];
        float kf = kbv[base + c] * (1.0f + (abv[base + c] - 1.0f) * kaw[c]);
        float vv = vbv[base + c];
        float dot = waveReduceSum(rv * kf * r_k[c]);
        yn += dot * vv;
        float z = yn * gbv[base + c];
        unsigned short h = f2bf(z);
        zh[base + c] = h;
        zl[base + c] = f2bf(z - bf2f(h));
    }
}

// ---------------------------------------------------------------------------
extern "C" void kernel_launch(void* const* d_in, const int* in_sizes, int n_in,
                              void* d_out, int out_size, void* d_ws, size_t ws_size,
                              hipStream_t stream)
{
    (void)in_sizes; (void)n_in; (void)out_size; (void)ws_size;
    const float* x      = (const float*)d_in[0];
    const float* vfirst = (const float*)d_in[1];
    const float* x_r    = (const float*)d_in[2];
    const float* x_w    = (const float*)d_in[3];
    const float* x_k    = (const float*)d_in[4];
    const float* x_v    = (const float*)d_in[5];
    const float* x_a    = (const float*)d_in[6];
    const float* x_g    = (const float*)d_in[7];
    const float* w0     = (const float*)d_in[8];
    const float* w1     = (const float*)d_in[9];
    const float* w2     = (const float*)d_in[10];
    const float* a0     = (const float*)d_in[11];
    const float* a1     = (const float*)d_in[12];
    const float* a2     = (const float*)d_in[13];
    const float* v0     = (const float*)d_in[14];
    const float* v1     = (const float*)d_in[15];
    const float* v2     = (const float*)d_in[16];
    const float* g1     = (const float*)d_in[17];
    const float* g2     = (const float*)d_in[18];
    const float* k_k    = (const float*)d_in[19];
    const float* k_a    = (const float*)d_in[20];
    const float* r_k    = (const float*)d_in[21];
    const float* Wr     = (const float*)d_in[22];
    const float* Wk     = (const float*)d_in[23];
    const float* Wv     = (const float*)d_in[24];
    const float* Wo     = (const float*)d_in[25];
    const float* ln_w   = (const float*)d_in[26];
    const float* ln_b   = (const float*)d_in[27];
    const float* alpha  = (const float*)d_in[28];

    const size_t SZ = (size_t)BT * CC;
    const size_t CHB = (size_t)1024 * 4096;
    float* ws   = (float*)d_ws;
    float* rb   = ws + 0 * SZ;
    float* kb   = ws + 1 * SZ;
    float* vb   = ws + 2 * SZ;
    float* decb = ws + 3 * SZ;
    float* ab   = ws + 4 * SZ;
    float* tw   = ws + 5 * SZ;
    float* ta   = tw + (size_t)BT * 64;
    float* tv   = ta + (size_t)BT * 64;
    float* tg   = tv + (size_t)BT * 32;
    float* Gb   = tg + (size_t)BT * 160;
    float* Ub   = Gb + CHB;
    float* Bpb  = Ub + CHB;
    float* Kpb  = Bpb + CHB;
    float* S0b  = Kpb + CHB;
    float* wcb  = S0b + CHB;
    float* Scur = wcb + CHB;                     // 128*4096 floats
    unsigned short* Whb = (unsigned short*)(Scur + (size_t)128 * 4096);
    unsigned short* Wlb = Whb + (size_t)CC * CC; // 2x 1M bf16 = 4 MB
    float* outp = (float*)d_out;
    float* gb   = outp;                          // g in out[0:SZ] until final GEMM
    float* yb   = outp + SZ;                     // y in out[SZ:2SZ] until v_first copy
    // A-operand split buffers (bf16): alias dead regions
    unsigned short* Ahp = (unsigned short*)(outp + SZ);   // projections phase
    unsigned short* Alp = Ahp + SZ;
    unsigned short* zAh = (unsigned short*)decb;          // z split (decb dead after scan)
    unsigned short* zAl = zAh + SZ;

    dim3 blk(256);
    const int NG_A = BT * (CC / 8);    // 2,097,152 groups
    const int NG_W = CC * (CC / 8);    // 131,072 groups
    dim3 gridA(NG_A / 256), gridW(NG_W / 256);
    dim3 gridG(1024);                  // 1D XCD-aware decode in kernel

    // big projections: split-convert then MFMA (3-term split-bf16)
    conv_split<false><<<gridW, blk, 0, stream>>>(Wr, nullptr, Whb, Wlb, NG_W);
    conv_split<true ><<<gridA, blk, 0, stream>>>(x, x_r, Ahp, Alp, NG_A);
    gemm_split_bf16<<<gridG, blk, 0, stream>>>(Ahp, Alp, Whb, Wlb, rb);
    conv_split<false><<<gridW, blk, 0, stream>>>(Wk, nullptr, Whb, Wlb, NG_W);
    conv_split<true ><<<gridA, blk, 0, stream>>>(x, x_k, Ahp, Alp, NG_A);
    gemm_split_bf16<<<gridG, blk, 0, stream>>>(Ahp, Alp, Whb, Wlb, kb);
    conv_split<false><<<gridW, blk, 0, stream>>>(Wv, nullptr, Whb, Wlb, NG_W);
    conv_split<true ><<<gridA, blk, 0, stream>>>(x, x_v, Ahp, Alp, NG_A);
    gemm_split_bf16<<<gridG, blk, 0, stream>>>(Ahp, Alp, Whb, Wlb, vb);

    // LoRA stage-1 (fp32, w: tanh, g: sigmoid fused)
    gemm_mix<true, false, 1><<<dim3(BT / 128, 1), blk, 0, stream>>>(x, w1, x_w, tw, 64);
    gemm_mix<true, false, 0><<<dim3(BT / 128, 1), blk, 0, stream>>>(x, a1, x_a, ta, 64);
    gemm_mix<true, false, 0><<<dim3(BT / 128, 1), blk, 0, stream>>>(x, v1, x_v, tv, 32);
    gemm_mix<true, false, 2><<<dim3(BT / 128, 2), blk, 0, stream>>>(x, g1, x_g, tg, 160);
    lora2_kernel<<<dim3(BT / 8), blk, 0, stream>>>(tw, ta, tv, tg, w2, a2, v2, g2,
        w0, a0, v0, vfirst, vb, decb, ab, gb);

    // chunked bidirectional WKV
    hipMemsetAsync(yb, 0, SZ * sizeof(float), stream);
    hipMemsetAsync(Scur, 0, (size_t)128 * 4096 * sizeof(float), stream);
    for (int cb = 0; cb < NB; ++cb) {
        wkvA<<<dim3(1024), blk, 0, stream>>>(kb, ab, vb, decb, k_k, k_a,
                                             Gb, Ub, Bpb, Kpb, wcb, cb);
        wkvB<<<dim3(128), blk, 0, stream>>>(vb, Gb, Ub, Bpb, Kpb, wcb, S0b, Scur, cb);
        wkvC<<<dim3(1024), blk, 0, stream>>>(rb, vb, Bpb, Kpb, Ub, S0b, wcb,
                                             alpha, yb, cb);
    }

    // groupnorm + bonus + gate -> split bf16 z (into decb's slot, dead now)
    post_kernel<<<dim3(BT), blk, 0, stream>>>(yb, rb, kb, ab, vb, gb, k_a, r_k,
                                              ln_w, ln_b, zAh, zAl);
    // final projection
    conv_split<false><<<gridW, blk, 0, stream>>>(Wo, nullptr, Whb, Wlb, NG_W);
    hipMemcpyAsync(outp + SZ, vfirst, SZ * sizeof(float),
                   hipMemcpyDeviceToDevice, stream);
    gemm_split_bf16<<<gridG, blk, 0, stream>>>(zAh, zAl, Whb, Wlb, outp);
}

// Round 6
// 5024.364 us; speedup vs baseline: 2.1593x; 1.1867x over previous
//
#include <hip/hip_runtime.h>
#include <hip/hip_bf16.h>
#include <math.h>

#define BB 4
#define TT 4096
#define CC 1024
#define HH 16
#define NN 64
#define BT (BB*TT)            // 16384 rows
#define EPS_GN 6.4e-4f        // 1e-5 * 8^2
#define TMAX (TT-1)
#define LCH 64                // chunk length
#define CB 8                  // chunks per batch
#define NB 8                  // batches  (LCH*CB*NB == TT)
#define STR 65                // padded LDS row stride

typedef __attribute__((ext_vector_type(8))) short bf16x8;
typedef __attribute__((ext_vector_type(4))) float f32x4;

__device__ __forceinline__ float sigmoidf_(float x) {
    return 1.0f / (1.0f + expf(-x));
}

__device__ __forceinline__ float waveReduceSum(float v) {
    #pragma unroll
    for (int off = 32; off > 0; off >>= 1)
        v += __shfl_xor(v, off, 64);
    return v;
}

__device__ __forceinline__ unsigned short f2bf(float f) {
    unsigned u = __float_as_uint(f);
    u += 0x7FFFu + ((u >> 16) & 1u);
    return (unsigned short)(u >> 16);
}
__device__ __forceinline__ float bf2f(unsigned short h) {
    return __uint_as_float(((unsigned)h) << 16);
}

// direct global->LDS 16B DMA (no VGPR roundtrip). LDS dest: wave-uniform
// base + lane*16; global src is per-lane.
__device__ __forceinline__ void gll16(const unsigned short* g, unsigned short* l) {
    __builtin_amdgcn_global_load_lds(
        (__attribute__((address_space(1))) void*)(g),
        (__attribute__((address_space(3))) void*)(l), 16, 0, 0);
}

// acc[r][c] += sum_k A(tr+r,k)*B(tc+c,k); element A(i,k)=A[i*SA0+k*SA1].
template<int SA0,int SA1,int SB0,int SB1>
__device__ __forceinline__ void gemm64(const float* __restrict__ A,
                                       const float* __restrict__ B,
                                       float acc[4][4], int tr, int tc) {
    #pragma unroll 4
    for (int kx = 0; kx < 64; ++kx) {
        float av[4], bv[4];
        #pragma unroll
        for (int r = 0; r < 4; r++) av[r] = A[(tr + r) * SA0 + kx * SA1];
        #pragma unroll
        for (int cq = 0; cq < 4; cq++) bv[cq] = B[(tc + cq) * SB0 + kx * SB1];
        #pragma unroll
        for (int r = 0; r < 4; r++)
            #pragma unroll
            for (int cq = 0; cq < 4; cq++)
                acc[r][cq] = fmaf(av[r], bv[cq], acc[r][cq]);
    }
}

// ---------------------------------------------------------------------------
// Split-conversion: fp32 (rows x CC, k-contig) -> bf16 hi + bf16 lo residual.
// ---------------------------------------------------------------------------
template<bool DOMIX>
__global__ __launch_bounds__(256) void conv_split(
    const float* __restrict__ X, const float* __restrict__ mix,
    unsigned short* __restrict__ Hi, unsigned short* __restrict__ Lo,
    int ngroups)
{
    int g = blockIdx.x * 256 + threadIdx.x;
    if (g >= ngroups) return;
    int m = g >> 7;                 // CC/8 = 128 groups per row
    int k = (g & 127) * 8;
    const float* px = X + (size_t)m * CC + k;
    float a[8];
    {
        float4 x0 = *(const float4*)px;
        float4 x1 = *(const float4*)(px + 4);
        a[0]=x0.x; a[1]=x0.y; a[2]=x0.z; a[3]=x0.w;
        a[4]=x1.x; a[5]=x1.y; a[6]=x1.z; a[7]=x1.w;
    }
    if (DOMIX) {
        float4 p0, p1;
        if ((m & (TT - 1)) == 0) {
            p0 = make_float4(0.f,0.f,0.f,0.f); p1 = p0;
        } else {
            p0 = *(const float4*)(px - CC);
            p1 = *(const float4*)(px - CC + 4);
        }
        float4 m0 = *(const float4*)(mix + k);
        float4 m1 = *(const float4*)(mix + k + 4);
        float pv[8] = {p0.x,p0.y,p0.z,p0.w,p1.x,p1.y,p1.z,p1.w};
        float mv[8] = {m0.x,m0.y,m0.z,m0.w,m1.x,m1.y,m1.z,m1.w};
        #pragma unroll
        for (int j = 0; j < 8; j++) a[j] += (pv[j] - a[j]) * mv[j];
    }
    unsigned short hi[8], lo[8];
    #pragma unroll
    for (int j = 0; j < 8; j++) {
        hi[j] = f2bf(a[j]);
        lo[j] = f2bf(a[j] - bf2f(hi[j]));
    }
    uint4 H, L;
    H.x = (unsigned)hi[0] | ((unsigned)hi[1] << 16);
    H.y = (unsigned)hi[2] | ((unsigned)hi[3] << 16);
    H.z = (unsigned)hi[4] | ((unsigned)hi[5] << 16);
    H.w = (unsigned)hi[6] | ((unsigned)hi[7] << 16);
    L.x = (unsigned)lo[0] | ((unsigned)lo[1] << 16);
    L.y = (unsigned)lo[2] | ((unsigned)lo[3] << 16);
    L.z = (unsigned)lo[4] | ((unsigned)lo[5] << 16);
    L.w = (unsigned)lo[6] | ((unsigned)lo[7] << 16);
    *(uint4*)(Hi + (size_t)g * 8) = H;
    *(uint4*)(Lo + (size_t)g * 8) = L;
}

// ---------------------------------------------------------------------------
// Split-bf16 MFMA GEMM: Out[M=BT][N=CC] = A @ W^T.
// 3-term: AhBh + AlBh + AhBl, fp32 accum. Tile 128x128, BK=64, 4 waves.
// Staging: global_load_lds (16B) with pre-swizzled SOURCE granule
// (slot g holds global granule g^(row&7); involution matches ds_read XOR).
// Grid: 1D 1024; wg&7 = XCD; each XCD walks 8 N-tiles of its M-panels.
// Epilogue: LDS-staged coalesced float4 stores.
// ---------------------------------------------------------------------------
__global__ __launch_bounds__(256, 2) void gemm_split_bf16(
    const unsigned short* __restrict__ Ah, const unsigned short* __restrict__ Al,
    const unsigned short* __restrict__ Bh, const unsigned short* __restrict__ Bl,
    float* __restrict__ Out)
{
    __shared__ __align__(16) unsigned short lds[4][128 * 64];  // Ah,Al,Bh,Bl
    const int tid = threadIdx.x;
    const int lane = tid & 63;
    const int wave = tid >> 6;
    const int wm = (wave >> 1) * 64, wn = (wave & 1) * 64;
    const int wg = blockIdx.x;
    const int xcd = wg & 7;
    const int j = wg >> 3;
    const int m0 = ((j >> 3) * 8 + xcd) * 128;
    const int n0 = (j & 7) * 128;

    f32x4 acc[4][4];
    #pragma unroll
    for (int i = 0; i < 4; i++)
        #pragma unroll
        for (int jj = 0; jj < 4; jj++)
            acc[i][jj] = (f32x4){0.f, 0.f, 0.f, 0.f};

    for (int k0 = 0; k0 < CC; k0 += 64) {
        // stage all 4 planes: 16 global_load_lds per thread, no VGPR staging
        #pragma unroll
        for (int p = 0; p < 4; p++) {
            const unsigned short* sbase = (p == 0) ? Ah : (p == 1) ? Al
                                        : (p == 2) ? Bh : Bl;
            const int rbase = (p < 2) ? m0 : n0;
            #pragma unroll
            for (int i = 0; i < 4; i++) {
                int slot = i * 256 + wave * 64 + lane;       // per-lane slot
                int row = slot >> 3, gsl = slot & 7;
                const unsigned short* src = sbase
                    + (size_t)(rbase + row) * CC + k0 + ((gsl ^ (row & 7)) * 8);
                // wave-uniform LDS base (lane*16 added by HW)
                gll16(src, &lds[p][(size_t)(i * 256 + wave * 64) * 8]);
            }
        }
        __syncthreads();   // compiler drains vmcnt(0) before barrier

        #pragma unroll
        for (int ks = 0; ks < 2; ks++) {
            bf16x8 bhf[4], blf[4];
            #pragma unroll
            for (int nt = 0; nt < 4; nt++) {
                int col = wn + nt * 16 + (lane & 15);
                int gk = ks * 4 + (lane >> 4);
                int el = col * 64 + ((gk ^ (col & 7)) * 8);
                bhf[nt] = *(const bf16x8*)&lds[2][el];
                blf[nt] = *(const bf16x8*)&lds[3][el];
            }
            #pragma unroll
            for (int mt = 0; mt < 4; mt++) {
                int row = wm + mt * 16 + (lane & 15);
                int gk = ks * 4 + (lane >> 4);
                int el = row * 64 + ((gk ^ (row & 7)) * 8);
                bf16x8 ahf = *(const bf16x8*)&lds[0][el];
                bf16x8 alf = *(const bf16x8*)&lds[1][el];
                #pragma unroll
                for (int nt = 0; nt < 4; nt++) {
                    acc[mt][nt] = __builtin_amdgcn_mfma_f32_16x16x32_bf16(
                        ahf, bhf[nt], acc[mt][nt], 0, 0, 0);
                    acc[mt][nt] = __builtin_amdgcn_mfma_f32_16x16x32_bf16(
                        alf, bhf[nt], acc[mt][nt], 0, 0, 0);
                    acc[mt][nt] = __builtin_amdgcn_mfma_f32_16x16x32_bf16(
                        ahf, blf[nt], acc[mt][nt], 0, 0, 0);
                }
            }
        }
        __syncthreads();   // all reads done before next stage overwrites
    }
    // Epilogue: two 64-row passes through LDS, coalesced float4 stores.
    float* cf = (float*)&lds[0][0];    // 64*132*4 = 33.8 KB
    #pragma unroll
    for (int pass = 0; pass < 2; ++pass) {
        __syncthreads();
        if ((wave >> 1) == pass) {
            #pragma unroll
            for (int mt = 0; mt < 4; mt++)
                #pragma unroll
                for (int nt = 0; nt < 4; nt++)
                    #pragma unroll
                    for (int r = 0; r < 4; r++) {
                        int row = mt * 16 + (lane >> 4) * 4 + r;   // 0..63
                        int col = wn + nt * 16 + (lane & 15);
                        cf[row * 132 + col] = acc[mt][nt][r];
                    }
        }
        __syncthreads();
        #pragma unroll
        for (int i = 0; i < 8; i++) {
            int g = tid + 256 * i;
            int row = g >> 5, c4 = (g & 31) * 4;
            float4 v = *(float4*)&cf[row * 132 + c4];
            *(float4*)&Out[(size_t)(m0 + pass * 64 + row) * CC + n0 + c4] = v;
        }
    }
}

// ---------------------------------------------------------------------------
// fp32 GEMM (LoRA stage-1): Out = A @ W, W (K,N) n-contig.
// ---------------------------------------------------------------------------
__device__ __forceinline__ float4 ldA(const float* __restrict__ X,
                                      const float* __restrict__ mix,
                                      int gm, int gk, bool domix) {
    const float* px = X + (size_t)gm * CC + gk;
    float4 xv = *(const float4*)px;
    if (domix) {
        float4 pv;
        if ((gm & (TT - 1)) == 0) pv = make_float4(0.f, 0.f, 0.f, 0.f);
        else pv = *(const float4*)(px - CC);
        float4 mv = *(const float4*)(mix + gk);
        xv.x += (pv.x - xv.x) * mv.x;
        xv.y += (pv.y - xv.y) * mv.y;
        xv.z += (pv.z - xv.z) * mv.z;
        xv.w += (pv.w - xv.w) * mv.w;
    }
    return xv;
}

template<bool DOMIX, bool WNK, int EPI>
__global__ __launch_bounds__(256) void gemm_mix(
    const float* __restrict__ X, const float* __restrict__ W,
    const float* __restrict__ mix, float* __restrict__ Out, int Ncols)
{
    __shared__ float As[8][128];
    __shared__ float Bs[8][128];
    const int tid = threadIdx.x;
    const int m0 = blockIdx.x * 128;
    const int n0 = blockIdx.y * 128;
    const int sr  = tid >> 1;
    const int skq = (tid & 1) * 4;
    const int bkr = tid >> 5;
    const int bnq = (tid & 31) * 4;
    const int tm = (tid >> 4) * 8;
    const int tn = (tid & 15) * 8;

    float acc[8][8];
    #pragma unroll
    for (int i = 0; i < 8; i++)
        #pragma unroll
        for (int j = 0; j < 8; j++) acc[i][j] = 0.f;

    float4 aR, bR;
    aR = ldA(X, mix, m0 + sr, skq, DOMIX);
    if (WNK) {
        int gn = n0 + sr;
        bR = (gn < Ncols) ? *(const float4*)(W + (size_t)gn * CC + skq)
                          : make_float4(0.f, 0.f, 0.f, 0.f);
    } else {
        int gn = n0 + bnq;
        bR = (gn < Ncols) ? *(const float4*)(W + (size_t)bkr * Ncols + gn)
                          : make_float4(0.f, 0.f, 0.f, 0.f);
    }

    for (int k0 = 0; k0 < CC; k0 += 8) {
        __syncthreads();
        As[skq + 0][sr] = aR.x;
        As[skq + 1][sr] = aR.y;
        As[skq + 2][sr] = aR.z;
        As[skq + 3][sr] = aR.w;
        if (WNK) {
            Bs[skq + 0][sr] = bR.x;
            Bs[skq + 1][sr] = bR.y;
            Bs[skq + 2][sr] = bR.z;
            Bs[skq + 3][sr] = bR.w;
        } else {
            *(float4*)&Bs[bkr][bnq] = bR;
        }
        __syncthreads();

        if (k0 + 8 < CC) {
            aR = ldA(X, mix, m0 + sr, k0 + 8 + skq, DOMIX);
            if (WNK) {
                int gn = n0 + sr;
                bR = (gn < Ncols) ? *(const float4*)(W + (size_t)gn * CC + k0 + 8 + skq)
                                  : make_float4(0.f, 0.f, 0.f, 0.f);
            } else {
                int gn = n0 + bnq;
                bR = (gn < Ncols) ? *(const float4*)(W + (size_t)(k0 + 8 + bkr) * Ncols + gn)
                                  : make_float4(0.f, 0.f, 0.f, 0.f);
            }
        }

        #pragma unroll
        for (int kk = 0; kk < 8; ++kk) {
            float av[8], bv[8];
            *(float4*)&av[0] = *(const float4*)&As[kk][tm];
            *(float4*)&av[4] = *(const float4*)&As[kk][tm + 4];
            *(float4*)&bv[0] = *(const float4*)&Bs[kk][tn];
            *(float4*)&bv[4] = *(const float4*)&Bs[kk][tn + 4];
            #pragma unroll
            for (int i = 0; i < 8; i++)
                #pragma unroll
                for (int j = 0; j < 8; j++)
                    acc[i][j] = fmaf(av[i], bv[j], acc[i][j]);
        }
    }

    #pragma unroll
    for (int i = 0; i < 8; i++) {
        int gm = m0 + tm + i;
        int gn = n0 + tn;
        if (gn < Ncols) {
            float o[8];
            #pragma unroll
            for (int j = 0; j < 8; j++) {
                float v = acc[i][j];
                if (EPI == 1) v = tanhf(v);
                if (EPI == 2) v = sigmoidf_(v);
                o[j] = v;
            }
            float* p = Out + (size_t)gm * Ncols + gn;
            *(float4*)p       = make_float4(o[0], o[1], o[2], o[3]);
            *(float4*)(p + 4) = make_float4(o[4], o[5], o[6], o[7]);
        }
    }
}

// ---------------------------------------------------------------------------
// LoRA stage-2 + elementwise fusion (unchanged — passed)
// ---------------------------------------------------------------------------
__global__ __launch_bounds__(256) void lora2_kernel(
    const float* __restrict__ tw, const float* __restrict__ ta,
    const float* __restrict__ tv, const float* __restrict__ tg,
    const float* __restrict__ w2, const float* __restrict__ a2,
    const float* __restrict__ v2, const float* __restrict__ g2,
    const float* __restrict__ w0, const float* __restrict__ a0v,
    const float* __restrict__ v0v, const float* __restrict__ v_first,
    float* __restrict__ vbuf, float* __restrict__ decb,
    float* __restrict__ ab, float* __restrict__ gb)
{
    __shared__ float s_w[8 * 64];
    __shared__ float s_a[8 * 64];
    __shared__ float s_v[8 * 32];
    __shared__ float s_g[8 * 160];
    const int tid = threadIdx.x;
    const int r0 = blockIdx.x * 8;

    for (int i = tid; i < 8 * 64; i += 256)  s_w[i] = tw[(size_t)r0 * 64 + i];
    for (int i = tid; i < 8 * 64; i += 256)  s_a[i] = ta[(size_t)r0 * 64 + i];
    s_v[tid] = tv[(size_t)r0 * 32 + tid];
    for (int i = tid; i < 8 * 160; i += 256) s_g[i] = tg[(size_t)r0 * 160 + i];
    __syncthreads();

    {
        float acc[8][4];
        #pragma unroll
        for (int r = 0; r < 8; r++)
            #pragma unroll
            for (int j = 0; j < 4; j++) acc[r][j] = 0.f;
        for (int d = 0; d < 64; ++d) {
            float wr[4];
            #pragma unroll
            for (int j = 0; j < 4; j++) wr[j] = a2[(size_t)d * CC + tid + 256 * j];
            #pragma unroll
            for (int r = 0; r < 8; r++) {
                float xv = s_a[r * 64 + d];
                #pragma unroll
                for (int j = 0; j < 4; j++) acc[r][j] = fmaf(xv, wr[j], acc[r][j]);
            }
        }
        #pragma unroll
        for (int r = 0; r < 8; r++) {
            size_t base = (size_t)(r0 + r) * CC;
            #pragma unroll
            for (int j = 0; j < 4; j++) {
                int c = tid + 256 * j;
                ab[base + c] = sigmoidf_(a0v[c] + acc[r][j]);
            }
        }
    }
    {
        float acc[8][4];
        #pragma unroll
        for (int r = 0; r < 8; r++)
            #pragma unroll
            for (int j = 0; j < 4; j++) acc[r][j] = 0.f;
        for (int d = 0; d < 64; ++d) {
            float wr[4];
            #pragma unroll
            for (int j = 0; j < 4; j++) wr[j] = w2[(size_t)d * CC + tid + 256 * j];
            #pragma unroll
            for (int r = 0; r < 8; r++) {
                float xv = s_w[r * 64 + d];
                #pragma unroll
                for (int j = 0; j < 4; j++) acc[r][j] = fmaf(xv, wr[j], acc[r][j]);
            }
        }
        #pragma unroll
        for (int r = 0; r < 8; r++) {
            size_t base = (size_t)(r0 + r) * CC;
            #pragma unroll
            for (int j = 0; j < 4; j++) {
                int c = tid + 256 * j;
                float dwv = w0[c] + acc[r][j];
                float wv = -log1pf(expf(-dwv)) - 0.5f;
                decb[base + c] = expf(-expf(wv));
            }
        }
    }
    {
        float acc[8][4];
        #pragma unroll
        for (int r = 0; r < 8; r++)
            #pragma unroll
            for (int j = 0; j < 4; j++) acc[r][j] = 0.f;
        for (int d = 0; d < 32; ++d) {
            float wr[4];
            #pragma unroll
            for (int j = 0; j < 4; j++) wr[j] = v2[(size_t)d * CC + tid + 256 * j];
            #pragma unroll
            for (int r = 0; r < 8; r++) {
                float xv = s_v[r * 32 + d];
                #pragma unroll
                for (int j = 0; j < 4; j++) acc[r][j] = fmaf(xv, wr[j], acc[r][j]);
            }
        }
        #pragma unroll
        for (int r = 0; r < 8; r++) {
            size_t base = (size_t)(r0 + r) * CC;
            #pragma unroll
            for (int j = 0; j < 4; j++) {
                int c = tid + 256 * j;
                float s = sigmoidf_(v0v[c] + acc[r][j]);
                float vraw = vbuf[base + c];
                float vf = v_first[base + c];
                vbuf[base + c] = vraw + (vf - vraw) * s;
            }
        }
    }
    {
        float acc[8][4];
        #pragma unroll
        for (int r = 0; r < 8; r++)
            #pragma unroll
            for (int j = 0; j < 4; j++) acc[r][j] = 0.f;
        for (int d = 0; d < 160; ++d) {
            float wr[4];
            #pragma unroll
            for (int j = 0; j < 4; j++) wr[j] = g2[(size_t)d * CC + tid + 256 * j];
            #pragma unroll
            for (int r = 0; r < 8; r++) {
                float xv = s_g[r * 160 + d];
                #pragma unroll
                for (int j = 0; j < 4; j++) acc[r][j] = fmaf(xv, wr[j], acc[r][j]);
            }
        }
        #pragma unroll
        for (int r = 0; r < 8; r++) {
            size_t base = (size_t)(r0 + r) * CC;
            #pragma unroll
            for (int j = 0; j < 4; j++) {
                int c = tid + 256 * j;
                gb[base + c] = acc[r][j];
            }
        }
    }
}

// ---------------------------------------------------------------------------
// Chunked WKV (unchanged — passed)
// ---------------------------------------------------------------------------
__global__ __launch_bounds__(256) void wkvA(
    const float* __restrict__ kb, const float* __restrict__ ab,
    const float* __restrict__ vb, const float* __restrict__ decb,
    const float* __restrict__ k_k, const float* __restrict__ k_a,
    float* __restrict__ Gb, float* __restrict__ Ub,
    float* __restrict__ Bpb, float* __restrict__ Kpb,
    float* __restrict__ wcb, int cb)
{
    __shared__ float sm[6][64 * STR];
    __shared__ float sSeg[4][64];
    const int inst = blockIdx.x;
    const int bhd = inst >> 3, lc = inst & 7;
    const int dir = bhd & 1, bh = bhd >> 1, b = bh >> 4, h = bh & 15;
    const int c64 = (cb * CB + lc) * LCH;
    const int tid = threadIdx.x;
    const int lane = tid & 63, seg = tid >> 6;
    const int ch = h * 64 + lane;
    const size_t gbase = (size_t)inst * 4096;
    float* sWC = sm[0];
    float* sAp = sm[1];
    float* sBp = sm[2];
    float* sKp = sm[3];
    float* sX  = sm[4];
    float* sYk = sm[5];

    {
        float run = 1.f; float loc[16];
        #pragma unroll
        for (int i = 0; i < 16; i++) {
            int p = seg * 16 + i;
            int t = dir ? (TMAX - (c64 + p)) : (c64 + p);
            float d = decb[((size_t)(b * TT + t)) * CC + ch];
            run *= d; loc[i] = run;
        }
        sSeg[seg][lane] = run;
        __syncthreads();
        float pre = 1.f;
        for (int s2 = 0; s2 < seg; ++s2) pre *= sSeg[s2][lane];
        #pragma unroll
        for (int i = 0; i < 16; i++) {
            int p = seg * 16 + i;
            float wcv = pre * loc[i];
            sWC[p * STR + lane] = wcv;
            wcb[gbase + p * 64 + lane] = wcv;
        }
    }
    __syncthreads();
    {
        const float kkl = k_k[ch], kal = k_a[ch];
        for (int i = 0; i < 16; i++) {
            int p = seg * 16 + i;
            int t = dir ? (TMAX - (c64 + p)) : (c64 + p);
            size_t ra = ((size_t)(b * TT + t)) * CC + ch;
            float kraw = kb[ra], asig = ab[ra];
            float kkv = kraw * kkl;
            float s2 = waveReduceSum(kkv * kkv);
            float kkn = kkv / fmaxf(sqrtf(s2), 1e-12f);
            float wc = sWC[p * STR + lane];
            float wx = (p == 0) ? 1.f : sWC[(p - 1) * STR + lane];
            float apv = -kkn * wx;
            float bpv = kkn * asig / wc;
            float kpv = kraw * (1.f + (asig - 1.f) * kal) / wc;
            sAp[lane * STR + p] = apv;
            sBp[lane * STR + p] = bpv;
            sKp[lane * STR + p] = kpv;
            Bpb[gbase + p * 64 + lane] = bpv;
            Kpb[gbase + p * 64 + lane] = kpv;
        }
    }
    __syncthreads();

    const int tr = (tid >> 4) * 4, tc = (tid & 15) * 4;
    #pragma unroll
    for (int i = 0; i < 16; i++) {
        int p = seg * 16 + i;
        int t = dir ? (TMAX - (c64 + p)) : (c64 + p);
        sWC[p * STR + lane] = vb[((size_t)(b * TT + t)) * CC + ch];
    }
    {
        float acc[4][4] = {};
        gemm64<1, STR, 1, STR>(sAp, sBp, acc, tr, tc);
        #pragma unroll
        for (int r = 0; r < 4; r++)
            #pragma unroll
            for (int cq = 0; cq < 4; cq++)
                sX[(tr + r) * STR + tc + cq] = (tc + cq < tr + r) ? acc[r][cq] : 0.f;
    }
    {
        float acc[4][4] = {};
        gemm64<1, STR, 1, STR>(sAp, sKp, acc, tr, tc);
        #pragma unroll
        for (int r = 0; r < 4; r++)
            #pragma unroll
            for (int cq = 0; cq < 4; cq++)
                sYk[(tr + r) * STR + tc + cq] = (tc + cq < tr + r) ? acc[r][cq] : 0.f;
    }
    __syncthreads();
    {
        float acc[4][4] = {};
        gemm64<STR, 1, 1, STR>(sYk, sWC, acc, tr, tc);
        __syncthreads();
        #pragma unroll
        for (int r = 0; r < 4; r++)
            #pragma unroll
            for (int cq = 0; cq < 4; cq++)
                sKp[(tr + r) * STR + tc + cq] = acc[r][cq];
    }
    __syncthreads();
    if (tid < 64) {
        for (int r = 0; r < 64; ++r) {
            float acc = 0.f;
            for (int s = 0; s < r; ++s)
                acc = fmaf(sX[r * STR + s], sBp[s * STR + tid], acc);
            sBp[r * STR + tid] = (r == tid) ? 1.f : acc;
        }
    }
    __syncthreads();
    {
        float accG[4][4] = {};
        gemm64<STR, 1, STR, 1>(sBp, sAp, accG, tr, tc);
        float accU[4][4] = {};
        gemm64<STR, 1, 1, STR>(sBp, sKp, accU, tr, tc);
        #pragma unroll
        for (int r = 0; r < 4; r++) {
            *(float4*)&Gb[gbase + (tr + r) * 64 + tc] =
                make_float4(accG[r][0], accG[r][1], accG[r][2], accG[r][3]);
            *(float4*)&Ub[gbase + (tr + r) * 64 + tc] =
                make_float4(accU[r][0], accU[r][1], accU[r][2], accU[r][3]);
        }
    }
}

__global__ __launch_bounds__(256) void wkvB(
    const float* __restrict__ vb,
    const float* __restrict__ Gb, float* __restrict__ Ub,
    const float* __restrict__ Bpb, const float* __restrict__ Kpb,
    const float* __restrict__ wcb, float* __restrict__ S0b,
    float* __restrict__ Scur, int cb)
{
    __shared__ float sS[64 * STR];
    __shared__ float sG[64 * STR];
    __shared__ float sU[64 * STR];
    __shared__ float sB[64 * STR];
    __shared__ float sK[64 * STR];
    __shared__ float sV[64 * STR];
    const int bhd = blockIdx.x;
    const int dir = bhd & 1, bh = bhd >> 1, b = bh >> 4, h = bh & 15;
    const int tid = threadIdx.x;
    const int tr = (tid >> 4) * 4, tc = (tid & 15) * 4;

    for (int i = tid; i < 4096; i += 256)
        sS[(i >> 6) * STR + (i & 63)] = Scur[(size_t)bhd * 4096 + i];
    __syncthreads();

    for (int lc = 0; lc < CB; ++lc) {
        const int inst = bhd * CB + lc;
        const size_t gbase = (size_t)inst * 4096;
        const int c64 = (cb * CB + lc) * LCH;
        for (int i = tid; i < 4096; i += 256) {
            int rr = i >> 6, jj = i & 63;
            sG[rr * STR + jj] = Gb[gbase + i];
            sB[rr * STR + jj] = Bpb[gbase + i];
            sK[rr * STR + jj] = Kpb[gbase + i];
            int t = dir ? (TMAX - (c64 + rr)) : (c64 + rr);
            sV[rr * STR + jj] = vb[((size_t)(b * TT + t)) * CC + h * 64 + jj];
            S0b[gbase + i] = sS[rr * STR + jj];
        }
        __syncthreads();
        {
            float acc[4][4];
            #pragma unroll
            for (int r = 0; r < 4; r++) {
                float4 u0 = *(const float4*)&Ub[gbase + (tr + r) * 64 + tc];
                acc[r][0] = u0.x; acc[r][1] = u0.y; acc[r][2] = u0.z; acc[r][3] = u0.w;
            }
            gemm64<STR, 1, STR, 1>(sG, sS, acc, tr, tc);
            #pragma unroll
            for (int r = 0; r < 4; r++) {
                #pragma unroll
                for (int cq = 0; cq < 4; cq++) sU[(tr + r) * STR + tc + cq] = acc[r][cq];
                *(float4*)&Ub[gbase + (tr + r) * 64 + tc] =
                    make_float4(acc[r][0], acc[r][1], acc[r][2], acc[r][3]);
            }
        }
        __syncthreads();
        {
            float acc[4][4] = {};
            gemm64<1, STR, 1, STR>(sU, sB, acc, tr, tc);
            gemm64<1, STR, 1, STR>(sV, sK, acc, tr, tc);
            float w63[4];
            #pragma unroll
            for (int cq = 0; cq < 4; cq++) w63[cq] = wcb[gbase + 63 * 64 + tc + cq];
            #pragma unroll
            for (int r = 0; r < 4; r++)
                #pragma unroll
                for (int cq = 0; cq < 4; cq++) {
                    float sv = sS[(tr + r) * STR + tc + cq];
                    acc[r][cq] = (sv + acc[r][cq]) * w63[cq];
                }
            #pragma unroll
            for (int r = 0; r < 4; r++)
                #pragma unroll
                for (int cq = 0; cq < 4; cq++)
                    sS[(tr + r) * STR + tc + cq] = acc[r][cq];
        }
        __syncthreads();
    }
    for (int i = tid; i < 4096; i += 256)
        Scur[(size_t)bhd * 4096 + i] = sS[(i >> 6) * STR + (i & 63)];
}

__global__ __launch_bounds__(256) void wkvC(
    const float* __restrict__ rb, const float* __restrict__ vb,
    const float* __restrict__ Bpb, const float* __restrict__ Kpb,
    const float* __restrict__ Ub, const float* __restrict__ S0b,
    const float* __restrict__ wcb, const float* __restrict__ alpha_p,
    float* __restrict__ yb, int cb)
{
    __shared__ float sm[6][64 * STR];
    float* sRp = sm[0];
    float* sBt = sm[1];
    float* sKt = sm[2];
    float* sMb = sm[3];
    float* sMk = sm[4];
    float* sV  = sm[5];
    const int inst = blockIdx.x;
    const int bhd = inst >> 3, lc = inst & 7;
    const int dir = bhd & 1, bh = bhd >> 1, b = bh >> 4, h = bh & 15;
    const int c64 = (cb * CB + lc) * LCH;
    const int tid = threadIdx.x, lane = tid & 63, seg = tid >> 6;
    const size_t gbase = (size_t)inst * 4096;
    const float alpha = alpha_p[0];
    const float wscale = dir ? (1.f - alpha) : alpha;

    #pragma unroll
    for (int i = 0; i < 16; i++) {
        int p = seg * 16 + i;
        int t = dir ? (TMAX - (c64 + p)) : (c64 + p);
        size_t ra = ((size_t)(b * TT + t)) * CC + h * 64 + lane;
        float wc = wcb[gbase + p * 64 + lane];
        sRp[lane * STR + p] = rb[ra] * wc;
        sBt[lane * STR + p] = Bpb[gbase + p * 64 + lane];
        sKt[lane * STR + p] = Kpb[gbase + p * 64 + lane];
        sV[p * STR + lane]  = vb[ra];
    }
    __syncthreads();
    const int tr = (tid >> 4) * 4, tc = (tid & 15) * 4;
    {
        float acc[4][4] = {};
        gemm64<1, STR, 1, STR>(sRp, sBt, acc, tr, tc);
        #pragma unroll
        for (int r = 0; r < 4; r++)
            #pragma unroll
            for (int cq = 0; cq < 4; cq++)
                sMb[(tr + r) * STR + tc + cq] = (tc + cq <= tr + r) ? acc[r][cq] : 0.f;
        float acc2[4][4] = {};
        gemm64<1, STR, 1, STR>(sRp, sKt, acc2, tr, tc);
        #pragma unroll
        for (int r = 0; r < 4; r++)
            #pragma unroll
            for (int cq = 0; cq < 4; cq++)
                sMk[(tr + r) * STR + tc + cq] = (tc + cq <= tr + r) ? acc2[r][cq] : 0.f;
    }
    __syncthreads();
    #pragma unroll
    for (int i = 0; i < 16; i++) {
        int rr = seg * 16 + i;
        sBt[rr * STR + lane] = Ub[gbase + rr * 64 + lane];
        sKt[rr * STR + lane] = S0b[gbase + rr * 64 + lane];
    }
    __syncthreads();
    {
        float acc[4][4] = {};
        gemm64<1, STR, STR, 1>(sRp, sKt, acc, tr, tc);
        gemm64<STR, 1, 1, STR>(sMb, sBt, acc, tr, tc);
        gemm64<STR, 1, 1, STR>(sMk, sV,  acc, tr, tc);
        #pragma unroll
        for (int r = 0; r < 4; r++) {
            int p = tr + r;
            int t = dir ? (TMAX - (c64 + p)) : (c64 + p);
            float* yp = &yb[((size_t)(b * TT + t)) * CC + h * 64 + tc];
            float4 old = *(float4*)yp;
            old.x += wscale * acc[r][0];
            old.y += wscale * acc[r][1];
            old.z += wscale * acc[r][2];
            old.w += wscale * acc[r][3];
            *(float4*)yp = old;
        }
    }
}

// ---------------------------------------------------------------------------
// Post: GroupNorm + affine + bonus + gating; emits z as split bf16 (hi+lo).
// ---------------------------------------------------------------------------
__global__ __launch_bounds__(256) void post_kernel(
    const float* __restrict__ yb, const float* __restrict__ rbv,
    const float* __restrict__ kbv, const float* __restrict__ abv,
    const float* __restrict__ vbv, const float* __restrict__ gbv,
    const float* __restrict__ kaw, const float* __restrict__ r_k,
    const float* __restrict__ ln_w, const float* __restrict__ ln_b,
    unsigned short* __restrict__ zh, unsigned short* __restrict__ zl)
{
    const int t = blockIdx.x;
    const int tid = threadIdx.x;
    const size_t base = (size_t)t * CC;
    #pragma unroll
    for (int j = 0; j < 4; j++) {
        int c = tid + 256 * j;
        float y = yb[base + c];
        float s1 = waveReduceSum(y);
        float s2 = waveReduceSum(y * y);
        float mu = s1 * (1.0f / 64.0f);
        float var = s2 * (1.0f / 64.0f) - mu * mu;
        float yn = (y - mu) * rsqrtf(var + EPS_GN);
        yn = yn * ln_w[c] + ln_b[c];
        float rv = rbv[base + c];
        float kf = kbv[base + c] * (1.0f + (abv[base + c] - 1.0f) * kaw[c]);
        float vv = vbv[base + c];
        float dot = waveReduceSum(rv * kf * r_k[c]);
        yn += dot * vv;
        float z = yn * gbv[base + c];
        unsigned short h = f2bf(z);
        zh[base + c] = h;
        zl[base + c] = f2bf(z - bf2f(h));
    }
}

// ---------------------------------------------------------------------------
extern "C" void kernel_launch(void* const* d_in, const int* in_sizes, int n_in,
                              void* d_out, int out_size, void* d_ws, size_t ws_size,
                              hipStream_t stream)
{
    (void)in_sizes; (void)n_in; (void)out_size; (void)ws_size;
    const float* x      = (const float*)d_in[0];
    const float* vfirst = (const float*)d_in[1];
    const float* x_r    = (const float*)d_in[2];
    const float* x_w    = (const float*)d_in[3];
    const float* x_k    = (const float*)d_in[4];
    const float* x_v    = (const float*)d_in[5];
    const float* x_a    = (const float*)d_in[6];
    const float* x_g    = (const float*)d_in[7];
    const float* w0     = (const float*)d_in[8];
    const float* w1     = (const float*)d_in[9];
    const float* w2     = (const float*)d_in[10];
    const float* a0     = (const float*)d_in[11];
    const float* a1     = (const float*)d_in[12];
    const float* a2     = (const float*)d_in[13];
    const float* v0     = (const float*)d_in[14];
    const float* v1     = (const float*)d_in[15];
    const float* v2     = (const float*)d_in[16];
    const float* g1     = (const float*)d_in[17];
    const float* g2     = (const float*)d_in[18];
    const float* k_k    = (const float*)d_in[19];
    const float* k_a    = (const float*)d_in[20];
    const float* r_k    = (const float*)d_in[21];
    const float* Wr     = (const float*)d_in[22];
    const float* Wk     = (const float*)d_in[23];
    const float* Wv     = (const float*)d_in[24];
    const float* Wo     = (const float*)d_in[25];
    const float* ln_w   = (const float*)d_in[26];
    const float* ln_b   = (const float*)d_in[27];
    const float* alpha  = (const float*)d_in[28];

    const size_t SZ = (size_t)BT * CC;
    const size_t CHB = (size_t)1024 * 4096;
    float* ws   = (float*)d_ws;
    float* rb   = ws + 0 * SZ;
    float* kb   = ws + 1 * SZ;
    float* vb   = ws + 2 * SZ;
    float* decb = ws + 3 * SZ;
    float* ab   = ws + 4 * SZ;
    float* tw   = ws + 5 * SZ;
    float* ta   = tw + (size_t)BT * 64;
    float* tv   = ta + (size_t)BT * 64;
    float* tg   = tv + (size_t)BT * 32;
    float* Gb   = tg + (size_t)BT * 160;
    float* Ub   = Gb + CHB;
    float* Bpb  = Ub + CHB;
    float* Kpb  = Bpb + CHB;
    float* S0b  = Kpb + CHB;
    float* wcb  = S0b + CHB;
    float* Scur = wcb + CHB;                     // 128*4096 floats
    unsigned short* Whb = (unsigned short*)(Scur + (size_t)128 * 4096);
    unsigned short* Wlb = Whb + (size_t)CC * CC; // 2x 1M bf16 = 4 MB
    float* outp = (float*)d_out;
    float* gb   = outp;                          // g in out[0:SZ] until final GEMM
    float* yb   = outp + SZ;                     // y in out[SZ:2SZ] until v_first copy
    // A-operand split buffers (bf16): alias dead regions
    unsigned short* Ahp = (unsigned short*)(outp + SZ);   // projections phase
    unsigned short* Alp = Ahp + SZ;
    unsigned short* zAh = (unsigned short*)decb;          // z split (decb dead after scan)
    unsigned short* zAl = zAh + SZ;

    dim3 blk(256);
    const int NG_A = BT * (CC / 8);    // 2,097,152 groups
    const int NG_W = CC * (CC / 8);    // 131,072 groups
    dim3 gridA(NG_A / 256), gridW(NG_W / 256);
    dim3 gridG(1024);                  // 1D XCD-aware decode in kernel

    // big projections: split-convert then MFMA (3-term split-bf16)
    conv_split<false><<<gridW, blk, 0, stream>>>(Wr, nullptr, Whb, Wlb, NG_W);
    conv_split<true ><<<gridA, blk, 0, stream>>>(x, x_r, Ahp, Alp, NG_A);
    gemm_split_bf16<<<gridG, blk, 0, stream>>>(Ahp, Alp, Whb, Wlb, rb);
    conv_split<false><<<gridW, blk, 0, stream>>>(Wk, nullptr, Whb, Wlb, NG_W);
    conv_split<true ><<<gridA, blk, 0, stream>>>(x, x_k, Ahp, Alp, NG_A);
    gemm_split_bf16<<<gridG, blk, 0, stream>>>(Ahp, Alp, Whb, Wlb, kb);
    conv_split<false><<<gridW, blk, 0, stream>>>(Wv, nullptr, Whb, Wlb, NG_W);
    conv_split<true ><<<gridA, blk, 0, stream>>>(x, x_v, Ahp, Alp, NG_A);
    gemm_split_bf16<<<gridG, blk, 0, stream>>>(Ahp, Alp, Whb, Wlb, vb);

    // LoRA stage-1 (fp32, w: tanh, g: sigmoid fused)
    gemm_mix<true, false, 1><<<dim3(BT / 128, 1), blk, 0, stream>>>(x, w1, x_w, tw, 64);
    gemm_mix<true, false, 0><<<dim3(BT / 128, 1), blk, 0, stream>>>(x, a1, x_a, ta, 64);
    gemm_mix<true, false, 0><<<dim3(BT / 128, 1), blk, 0, stream>>>(x, v1, x_v, tv, 32);
    gemm_mix<true, false, 2><<<dim3(BT / 128, 2), blk, 0, stream>>>(x, g1, x_g, tg, 160);
    lora2_kernel<<<dim3(BT / 8), blk, 0, stream>>>(tw, ta, tv, tg, w2, a2, v2, g2,
        w0, a0, v0, vfirst, vb, decb, ab, gb);

    // chunked bidirectional WKV
    hipMemsetAsync(yb, 0, SZ * sizeof(float), stream);
    hipMemsetAsync(Scur, 0, (size_t)128 * 4096 * sizeof(float), stream);
    for (int cb = 0; cb < NB; ++cb) {
        wkvA<<<dim3(1024), blk, 0, stream>>>(kb, ab, vb, decb, k_k, k_a,
                                             Gb, Ub, Bpb, Kpb, wcb, cb);
        wkvB<<<dim3(128), blk, 0, stream>>>(vb, Gb, Ub, Bpb, Kpb, wcb, S0b, Scur, cb);
        wkvC<<<dim3(1024), blk, 0, stream>>>(rb, vb, Bpb, Kpb, Ub, S0b, wcb,
                                             alpha, yb, cb);
    }

    // groupnorm + bonus + gate -> split bf16 z (into decb's slot, dead now)
    post_kernel<<<dim3(BT), blk, 0, stream>>>(yb, rb, kb, ab, vb, gb, k_a, r_k,
                                              ln_w, ln_b, zAh, zAl);
    // final projection
    conv_split<false><<<gridW, blk, 0, stream>>>(Wo, nullptr, Whb, Wlb, NG_W);
    hipMemcpyAsync(outp + SZ, vfirst, SZ * sizeof(float),
                   hipMemcpyDeviceToDevice, stream);
    gemm_split_bf16<<<gridG, blk, 0, stream>>>(zAh, zAl, Whb, Wlb, outp);
}

// Round 7
// 5004.311 us; speedup vs baseline: 2.1680x; 1.0040x over previous
//
#include <hip/hip_runtime.h>
#include <hip/hip_bf16.h>
#include <math.h>

#define BB 4
#define TT 4096
#define CC 1024
#define HH 16
#define NN 64
#define BT (BB*TT)            // 16384 rows
#define EPS_GN 6.4e-4f        // 1e-5 * 8^2
#define TMAX (TT-1)
#define LCH 64                // chunk length
#define CB 8                  // chunks per batch
#define NB 8                  // batches  (LCH*CB*NB == TT)
#define STR 65                // padded LDS row stride

typedef __attribute__((ext_vector_type(8))) short bf16x8;
typedef __attribute__((ext_vector_type(4))) float f32x4;

__device__ __forceinline__ float sigmoidf_(float x) {
    return 1.0f / (1.0f + expf(-x));
}

__device__ __forceinline__ float waveReduceSum(float v) {
    #pragma unroll
    for (int off = 32; off > 0; off >>= 1)
        v += __shfl_xor(v, off, 64);
    return v;
}

__device__ __forceinline__ unsigned short f2bf(float f) {
    unsigned u = __float_as_uint(f);
    u += 0x7FFFu + ((u >> 16) & 1u);
    return (unsigned short)(u >> 16);
}
__device__ __forceinline__ float bf2f(unsigned short h) {
    return __uint_as_float(((unsigned)h) << 16);
}

// direct global->LDS 16B DMA (no VGPR roundtrip). LDS dest: wave-uniform
// base + lane*16; global src is per-lane.
__device__ __forceinline__ void gll16(const unsigned short* g, unsigned short* l) {
    __builtin_amdgcn_global_load_lds(
        (__attribute__((address_space(1))) void*)(g),
        (__attribute__((address_space(3))) void*)(l), 16, 0, 0);
}

// acc[r][c] += sum_k A(tr+r,k)*B(tc+c,k); element A(i,k)=A[i*SA0+k*SA1].
template<int SA0,int SA1,int SB0,int SB1>
__device__ __forceinline__ void gemm64(const float* __restrict__ A,
                                       const float* __restrict__ B,
                                       float acc[4][4], int tr, int tc) {
    #pragma unroll 4
    for (int kx = 0; kx < 64; ++kx) {
        float av[4], bv[4];
        #pragma unroll
        for (int r = 0; r < 4; r++) av[r] = A[(tr + r) * SA0 + kx * SA1];
        #pragma unroll
        for (int cq = 0; cq < 4; cq++) bv[cq] = B[(tc + cq) * SB0 + kx * SB1];
        #pragma unroll
        for (int r = 0; r < 4; r++)
            #pragma unroll
            for (int cq = 0; cq < 4; cq++)
                acc[r][cq] = fmaf(av[r], bv[cq], acc[r][cq]);
    }
}

// ---------------------------------------------------------------------------
// Split-conversion: fp32 (rows x CC, k-contig) -> bf16 hi + bf16 lo residual.
// ---------------------------------------------------------------------------
template<bool DOMIX>
__global__ __launch_bounds__(256) void conv_split(
    const float* __restrict__ X, const float* __restrict__ mix,
    unsigned short* __restrict__ Hi, unsigned short* __restrict__ Lo,
    int ngroups)
{
    int g = blockIdx.x * 256 + threadIdx.x;
    if (g >= ngroups) return;
    int m = g >> 7;                 // CC/8 = 128 groups per row
    int k = (g & 127) * 8;
    const float* px = X + (size_t)m * CC + k;
    float a[8];
    {
        float4 x0 = *(const float4*)px;
        float4 x1 = *(const float4*)(px + 4);
        a[0]=x0.x; a[1]=x0.y; a[2]=x0.z; a[3]=x0.w;
        a[4]=x1.x; a[5]=x1.y; a[6]=x1.z; a[7]=x1.w;
    }
    if (DOMIX) {
        float4 p0, p1;
        if ((m & (TT - 1)) == 0) {
            p0 = make_float4(0.f,0.f,0.f,0.f); p1 = p0;
        } else {
            p0 = *(const float4*)(px - CC);
            p1 = *(const float4*)(px - CC + 4);
        }
        float4 m0 = *(const float4*)(mix + k);
        float4 m1 = *(const float4*)(mix + k + 4);
        float pv[8] = {p0.x,p0.y,p0.z,p0.w,p1.x,p1.y,p1.z,p1.w};
        float mv[8] = {m0.x,m0.y,m0.z,m0.w,m1.x,m1.y,m1.z,m1.w};
        #pragma unroll
        for (int j = 0; j < 8; j++) a[j] += (pv[j] - a[j]) * mv[j];
    }
    unsigned short hi[8], lo[8];
    #pragma unroll
    for (int j = 0; j < 8; j++) {
        hi[j] = f2bf(a[j]);
        lo[j] = f2bf(a[j] - bf2f(hi[j]));
    }
    uint4 H, L;
    H.x = (unsigned)hi[0] | ((unsigned)hi[1] << 16);
    H.y = (unsigned)hi[2] | ((unsigned)hi[3] << 16);
    H.z = (unsigned)hi[4] | ((unsigned)hi[5] << 16);
    H.w = (unsigned)hi[6] | ((unsigned)hi[7] << 16);
    L.x = (unsigned)lo[0] | ((unsigned)lo[1] << 16);
    L.y = (unsigned)lo[2] | ((unsigned)lo[3] << 16);
    L.z = (unsigned)lo[4] | ((unsigned)lo[5] << 16);
    L.w = (unsigned)lo[6] | ((unsigned)lo[7] << 16);
    *(uint4*)(Hi + (size_t)g * 8) = H;
    *(uint4*)(Lo + (size_t)g * 8) = L;
}

// ---------------------------------------------------------------------------
// Split-bf16 MFMA GEMM (unchanged from round 6 — passed)
// ---------------------------------------------------------------------------
__global__ __launch_bounds__(256, 2) void gemm_split_bf16(
    const unsigned short* __restrict__ Ah, const unsigned short* __restrict__ Al,
    const unsigned short* __restrict__ Bh, const unsigned short* __restrict__ Bl,
    float* __restrict__ Out)
{
    __shared__ __align__(16) unsigned short lds[4][128 * 64];  // Ah,Al,Bh,Bl
    const int tid = threadIdx.x;
    const int lane = tid & 63;
    const int wave = tid >> 6;
    const int wm = (wave >> 1) * 64, wn = (wave & 1) * 64;
    const int wg = blockIdx.x;
    const int xcd = wg & 7;
    const int j = wg >> 3;
    const int m0 = ((j >> 3) * 8 + xcd) * 128;
    const int n0 = (j & 7) * 128;

    f32x4 acc[4][4];
    #pragma unroll
    for (int i = 0; i < 4; i++)
        #pragma unroll
        for (int jj = 0; jj < 4; jj++)
            acc[i][jj] = (f32x4){0.f, 0.f, 0.f, 0.f};

    for (int k0 = 0; k0 < CC; k0 += 64) {
        #pragma unroll
        for (int p = 0; p < 4; p++) {
            const unsigned short* sbase = (p == 0) ? Ah : (p == 1) ? Al
                                        : (p == 2) ? Bh : Bl;
            const int rbase = (p < 2) ? m0 : n0;
            #pragma unroll
            for (int i = 0; i < 4; i++) {
                int slot = i * 256 + wave * 64 + lane;       // per-lane slot
                int row = slot >> 3, gsl = slot & 7;
                const unsigned short* src = sbase
                    + (size_t)(rbase + row) * CC + k0 + ((gsl ^ (row & 7)) * 8);
                gll16(src, &lds[p][(size_t)(i * 256 + wave * 64) * 8]);
            }
        }
        __syncthreads();

        #pragma unroll
        for (int ks = 0; ks < 2; ks++) {
            bf16x8 bhf[4], blf[4];
            #pragma unroll
            for (int nt = 0; nt < 4; nt++) {
                int col = wn + nt * 16 + (lane & 15);
                int gk = ks * 4 + (lane >> 4);
                int el = col * 64 + ((gk ^ (col & 7)) * 8);
                bhf[nt] = *(const bf16x8*)&lds[2][el];
                blf[nt] = *(const bf16x8*)&lds[3][el];
            }
            #pragma unroll
            for (int mt = 0; mt < 4; mt++) {
                int row = wm + mt * 16 + (lane & 15);
                int gk = ks * 4 + (lane >> 4);
                int el = row * 64 + ((gk ^ (row & 7)) * 8);
                bf16x8 ahf = *(const bf16x8*)&lds[0][el];
                bf16x8 alf = *(const bf16x8*)&lds[1][el];
                #pragma unroll
                for (int nt = 0; nt < 4; nt++) {
                    acc[mt][nt] = __builtin_amdgcn_mfma_f32_16x16x32_bf16(
                        ahf, bhf[nt], acc[mt][nt], 0, 0, 0);
                    acc[mt][nt] = __builtin_amdgcn_mfma_f32_16x16x32_bf16(
                        alf, bhf[nt], acc[mt][nt], 0, 0, 0);
                    acc[mt][nt] = __builtin_amdgcn_mfma_f32_16x16x32_bf16(
                        ahf, blf[nt], acc[mt][nt], 0, 0, 0);
                }
            }
        }
        __syncthreads();
    }
    float* cf = (float*)&lds[0][0];    // 64*132*4 = 33.8 KB
    #pragma unroll
    for (int pass = 0; pass < 2; ++pass) {
        __syncthreads();
        if ((wave >> 1) == pass) {
            #pragma unroll
            for (int mt = 0; mt < 4; mt++)
                #pragma unroll
                for (int nt = 0; nt < 4; nt++)
                    #pragma unroll
                    for (int r = 0; r < 4; r++) {
                        int row = mt * 16 + (lane >> 4) * 4 + r;   // 0..63
                        int col = wn + nt * 16 + (lane & 15);
                        cf[row * 132 + col] = acc[mt][nt][r];
                    }
        }
        __syncthreads();
        #pragma unroll
        for (int i = 0; i < 8; i++) {
            int g = tid + 256 * i;
            int row = g >> 5, c4 = (g & 31) * 4;
            float4 v = *(float4*)&cf[row * 132 + c4];
            *(float4*)&Out[(size_t)(m0 + pass * 64 + row) * CC + n0 + c4] = v;
        }
    }
}

// ---------------------------------------------------------------------------
// fp32 GEMM (LoRA stage-1): Out = A @ W, W (K,N) n-contig.
// ---------------------------------------------------------------------------
__device__ __forceinline__ float4 ldA(const float* __restrict__ X,
                                      const float* __restrict__ mix,
                                      int gm, int gk, bool domix) {
    const float* px = X + (size_t)gm * CC + gk;
    float4 xv = *(const float4*)px;
    if (domix) {
        float4 pv;
        if ((gm & (TT - 1)) == 0) pv = make_float4(0.f, 0.f, 0.f, 0.f);
        else pv = *(const float4*)(px - CC);
        float4 mv = *(const float4*)(mix + gk);
        xv.x += (pv.x - xv.x) * mv.x;
        xv.y += (pv.y - xv.y) * mv.y;
        xv.z += (pv.z - xv.z) * mv.z;
        xv.w += (pv.w - xv.w) * mv.w;
    }
    return xv;
}

template<bool DOMIX, bool WNK, int EPI>
__global__ __launch_bounds__(256) void gemm_mix(
    const float* __restrict__ X, const float* __restrict__ W,
    const float* __restrict__ mix, float* __restrict__ Out, int Ncols)
{
    __shared__ float As[8][128];
    __shared__ float Bs[8][128];
    const int tid = threadIdx.x;
    const int m0 = blockIdx.x * 128;
    const int n0 = blockIdx.y * 128;
    const int sr  = tid >> 1;
    const int skq = (tid & 1) * 4;
    const int bkr = tid >> 5;
    const int bnq = (tid & 31) * 4;
    const int tm = (tid >> 4) * 8;
    const int tn = (tid & 15) * 8;

    float acc[8][8];
    #pragma unroll
    for (int i = 0; i < 8; i++)
        #pragma unroll
        for (int j = 0; j < 8; j++) acc[i][j] = 0.f;

    float4 aR, bR;
    aR = ldA(X, mix, m0 + sr, skq, DOMIX);
    if (WNK) {
        int gn = n0 + sr;
        bR = (gn < Ncols) ? *(const float4*)(W + (size_t)gn * CC + skq)
                          : make_float4(0.f, 0.f, 0.f, 0.f);
    } else {
        int gn = n0 + bnq;
        bR = (gn < Ncols) ? *(const float4*)(W + (size_t)bkr * Ncols + gn)
                          : make_float4(0.f, 0.f, 0.f, 0.f);
    }

    for (int k0 = 0; k0 < CC; k0 += 8) {
        __syncthreads();
        As[skq + 0][sr] = aR.x;
        As[skq + 1][sr] = aR.y;
        As[skq + 2][sr] = aR.z;
        As[skq + 3][sr] = aR.w;
        if (WNK) {
            Bs[skq + 0][sr] = bR.x;
            Bs[skq + 1][sr] = bR.y;
            Bs[skq + 2][sr] = bR.z;
            Bs[skq + 3][sr] = bR.w;
        } else {
            *(float4*)&Bs[bkr][bnq] = bR;
        }
        __syncthreads();

        if (k0 + 8 < CC) {
            aR = ldA(X, mix, m0 + sr, k0 + 8 + skq, DOMIX);
            if (WNK) {
                int gn = n0 + sr;
                bR = (gn < Ncols) ? *(const float4*)(W + (size_t)gn * CC + k0 + 8 + skq)
                                  : make_float4(0.f, 0.f, 0.f, 0.f);
            } else {
                int gn = n0 + bnq;
                bR = (gn < Ncols) ? *(const float4*)(W + (size_t)(k0 + 8 + bkr) * Ncols + gn)
                                  : make_float4(0.f, 0.f, 0.f, 0.f);
            }
        }

        #pragma unroll
        for (int kk = 0; kk < 8; ++kk) {
            float av[8], bv[8];
            *(float4*)&av[0] = *(const float4*)&As[kk][tm];
            *(float4*)&av[4] = *(const float4*)&As[kk][tm + 4];
            *(float4*)&bv[0] = *(const float4*)&Bs[kk][tn];
            *(float4*)&bv[4] = *(const float4*)&Bs[kk][tn + 4];
            #pragma unroll
            for (int i = 0; i < 8; i++)
                #pragma unroll
                for (int j = 0; j < 8; j++)
                    acc[i][j] = fmaf(av[i], bv[j], acc[i][j]);
        }
    }

    #pragma unroll
    for (int i = 0; i < 8; i++) {
        int gm = m0 + tm + i;
        int gn = n0 + tn;
        if (gn < Ncols) {
            float o[8];
            #pragma unroll
            for (int j = 0; j < 8; j++) {
                float v = acc[i][j];
                if (EPI == 1) v = tanhf(v);
                if (EPI == 2) v = sigmoidf_(v);
                o[j] = v;
            }
            float* p = Out + (size_t)gm * Ncols + gn;
            *(float4*)p       = make_float4(o[0], o[1], o[2], o[3]);
            *(float4*)(p + 4) = make_float4(o[4], o[5], o[6], o[7]);
        }
    }
}

// ---------------------------------------------------------------------------
// LoRA stage-2 + elementwise fusion, v2.
// 16 rows/block (1024 blocks). Thread owns cols 4*tid..4*tid+3 -> all weight
// loads are one float4 per d; all global I/O float4. x-tiles broadcast-read
// from LDS. No cross-lane ops (kk-norm lives in wkvA; stats in post_kernel).
// ---------------------------------------------------------------------------
#define LR 16
__global__ __launch_bounds__(256) void lora2_kernel(
    const float* __restrict__ tw, const float* __restrict__ ta,
    const float* __restrict__ tv, const float* __restrict__ tg,
    const float* __restrict__ w2, const float* __restrict__ a2,
    const float* __restrict__ v2, const float* __restrict__ g2,
    const float* __restrict__ w0, const float* __restrict__ a0v,
    const float* __restrict__ v0v, const float* __restrict__ v_first,
    float* __restrict__ vbuf, float* __restrict__ decb,
    float* __restrict__ ab, float* __restrict__ gb)
{
    __shared__ float s_w[LR * 64];
    __shared__ float s_a[LR * 64];
    __shared__ float s_v[LR * 32];
    __shared__ float s_g[LR * 160];
    const int tid = threadIdx.x;
    const int r0 = blockIdx.x * LR;
    const int c0 = tid * 4;

    // vectorized LDS fill (rows are contiguous in all four temp buffers)
    {
        const float4* p = (const float4*)(tw + (size_t)r0 * 64);
        *(float4*)&s_w[tid * 4] = p[tid];                       // 1024 floats
        const float4* q = (const float4*)(ta + (size_t)r0 * 64);
        *(float4*)&s_a[tid * 4] = q[tid];
        if (tid < 128) {
            const float4* r = (const float4*)(tv + (size_t)r0 * 32);
            *(float4*)&s_v[tid * 4] = r[tid];                   // 512 floats
        }
        const float4* s = (const float4*)(tg + (size_t)r0 * 160);
        #pragma unroll
        for (int i = tid; i < 640; i += 256)
            *(float4*)&s_g[i * 4] = s[i];                       // 2560 floats
    }
    __syncthreads();

    // ---- a pass -> ab ----
    {
        float4 acc[LR] = {};
        for (int d = 0; d < 64; ++d) {
            float4 wv = *(const float4*)(a2 + (size_t)d * CC + c0);
            #pragma unroll
            for (int r = 0; r < LR; r++) {
                float xv = s_a[r * 64 + d];
                acc[r].x = fmaf(xv, wv.x, acc[r].x);
                acc[r].y = fmaf(xv, wv.y, acc[r].y);
                acc[r].z = fmaf(xv, wv.z, acc[r].z);
                acc[r].w = fmaf(xv, wv.w, acc[r].w);
            }
        }
        float4 a0q = *(const float4*)(a0v + c0);
        #pragma unroll
        for (int r = 0; r < LR; r++) {
            float4 o;
            o.x = sigmoidf_(a0q.x + acc[r].x);
            o.y = sigmoidf_(a0q.y + acc[r].y);
            o.z = sigmoidf_(a0q.z + acc[r].z);
            o.w = sigmoidf_(a0q.w + acc[r].w);
            *(float4*)&ab[(size_t)(r0 + r) * CC + c0] = o;
        }
    }
    // ---- w pass -> dec ----
    {
        float4 acc[LR] = {};
        for (int d = 0; d < 64; ++d) {
            float4 wv = *(const float4*)(w2 + (size_t)d * CC + c0);
            #pragma unroll
            for (int r = 0; r < LR; r++) {
                float xv = s_w[r * 64 + d];
                acc[r].x = fmaf(xv, wv.x, acc[r].x);
                acc[r].y = fmaf(xv, wv.y, acc[r].y);
                acc[r].z = fmaf(xv, wv.z, acc[r].z);
                acc[r].w = fmaf(xv, wv.w, acc[r].w);
            }
        }
        float4 w0q = *(const float4*)(w0 + c0);
        #pragma unroll
        for (int r = 0; r < LR; r++) {
            float4 o;
            float d0 = w0q.x + acc[r].x, d1 = w0q.y + acc[r].y;
            float d2 = w0q.z + acc[r].z, d3 = w0q.w + acc[r].w;
            o.x = expf(-expf(-log1pf(expf(-d0)) - 0.5f));
            o.y = expf(-expf(-log1pf(expf(-d1)) - 0.5f));
            o.z = expf(-expf(-log1pf(expf(-d2)) - 0.5f));
            o.w = expf(-expf(-log1pf(expf(-d3)) - 0.5f));
            *(float4*)&decb[(size_t)(r0 + r) * CC + c0] = o;
        }
    }
    // ---- v pass -> v_final (in place) ----
    {
        float4 acc[LR] = {};
        for (int d = 0; d < 32; ++d) {
            float4 wv = *(const float4*)(v2 + (size_t)d * CC + c0);
            #pragma unroll
            for (int r = 0; r < LR; r++) {
                float xv = s_v[r * 32 + d];
                acc[r].x = fmaf(xv, wv.x, acc[r].x);
                acc[r].y = fmaf(xv, wv.y, acc[r].y);
                acc[r].z = fmaf(xv, wv.z, acc[r].z);
                acc[r].w = fmaf(xv, wv.w, acc[r].w);
            }
        }
        float4 v0q = *(const float4*)(v0v + c0);
        #pragma unroll
        for (int r = 0; r < LR; r++) {
            size_t off = (size_t)(r0 + r) * CC + c0;
            float4 vr = *(const float4*)&vbuf[off];
            float4 vf = *(const float4*)&v_first[off];
            float4 o;
            o.x = vr.x + (vf.x - vr.x) * sigmoidf_(v0q.x + acc[r].x);
            o.y = vr.y + (vf.y - vr.y) * sigmoidf_(v0q.y + acc[r].y);
            o.z = vr.z + (vf.z - vr.z) * sigmoidf_(v0q.z + acc[r].z);
            o.w = vr.w + (vf.w - vr.w) * sigmoidf_(v0q.w + acc[r].w);
            *(float4*)&vbuf[off] = o;
        }
    }
    // ---- g pass ----
    {
        float4 acc[LR] = {};
        for (int d = 0; d < 160; ++d) {
            float4 wv = *(const float4*)(g2 + (size_t)d * CC + c0);
            #pragma unroll
            for (int r = 0; r < LR; r++) {
                float xv = s_g[r * 160 + d];
                acc[r].x = fmaf(xv, wv.x, acc[r].x);
                acc[r].y = fmaf(xv, wv.y, acc[r].y);
                acc[r].z = fmaf(xv, wv.z, acc[r].z);
                acc[r].w = fmaf(xv, wv.w, acc[r].w);
            }
        }
        #pragma unroll
        for (int r = 0; r < LR; r++)
            *(float4*)&gb[(size_t)(r0 + r) * CC + c0] = acc[r];
    }
}

// ---------------------------------------------------------------------------
// Chunked WKV phases A, B (unchanged — passed)
// ---------------------------------------------------------------------------
__global__ __launch_bounds__(256) void wkvA(
    const float* __restrict__ kb, const float* __restrict__ ab,
    const float* __restrict__ vb, const float* __restrict__ decb,
    const float* __restrict__ k_k, const float* __restrict__ k_a,
    float* __restrict__ Gb, float* __restrict__ Ub,
    float* __restrict__ Bpb, float* __restrict__ Kpb,
    float* __restrict__ wcb, int cb)
{
    __shared__ float sm[6][64 * STR];
    __shared__ float sSeg[4][64];
    const int inst = blockIdx.x;
    const int bhd = inst >> 3, lc = inst & 7;
    const int dir = bhd & 1, bh = bhd >> 1, b = bh >> 4, h = bh & 15;
    const int c64 = (cb * CB + lc) * LCH;
    const int tid = threadIdx.x;
    const int lane = tid & 63, seg = tid >> 6;
    const int ch = h * 64 + lane;
    const size_t gbase = (size_t)inst * 4096;
    float* sWC = sm[0];
    float* sAp = sm[1];
    float* sBp = sm[2];
    float* sKp = sm[3];
    float* sX  = sm[4];
    float* sYk = sm[5];

    {
        float run = 1.f; float loc[16];
        #pragma unroll
        for (int i = 0; i < 16; i++) {
            int p = seg * 16 + i;
            int t = dir ? (TMAX - (c64 + p)) : (c64 + p);
            float d = decb[((size_t)(b * TT + t)) * CC + ch];
            run *= d; loc[i] = run;
        }
        sSeg[seg][lane] = run;
        __syncthreads();
        float pre = 1.f;
        for (int s2 = 0; s2 < seg; ++s2) pre *= sSeg[s2][lane];
        #pragma unroll
        for (int i = 0; i < 16; i++) {
            int p = seg * 16 + i;
            float wcv = pre * loc[i];
            sWC[p * STR + lane] = wcv;
            wcb[gbase + p * 64 + lane] = wcv;
        }
    }
    __syncthreads();
    {
        const float kkl = k_k[ch], kal = k_a[ch];
        for (int i = 0; i < 16; i++) {
            int p = seg * 16 + i;
            int t = dir ? (TMAX - (c64 + p)) : (c64 + p);
            size_t ra = ((size_t)(b * TT + t)) * CC + ch;
            float kraw = kb[ra], asig = ab[ra];
            float kkv = kraw * kkl;
            float s2 = waveReduceSum(kkv * kkv);
            float kkn = kkv / fmaxf(sqrtf(s2), 1e-12f);
            float wc = sWC[p * STR + lane];
            float wx = (p == 0) ? 1.f : sWC[(p - 1) * STR + lane];
            float apv = -kkn * wx;
            float bpv = kkn * asig / wc;
            float kpv = kraw * (1.f + (asig - 1.f) * kal) / wc;
            sAp[lane * STR + p] = apv;
            sBp[lane * STR + p] = bpv;
            sKp[lane * STR + p] = kpv;
            Bpb[gbase + p * 64 + lane] = bpv;
            Kpb[gbase + p * 64 + lane] = kpv;
        }
    }
    __syncthreads();

    const int tr = (tid >> 4) * 4, tc = (tid & 15) * 4;
    #pragma unroll
    for (int i = 0; i < 16; i++) {
        int p = seg * 16 + i;
        int t = dir ? (TMAX - (c64 + p)) : (c64 + p);
        sWC[p * STR + lane] = vb[((size_t)(b * TT + t)) * CC + ch];
    }
    {
        float acc[4][4] = {};
        gemm64<1, STR, 1, STR>(sAp, sBp, acc, tr, tc);
        #pragma unroll
        for (int r = 0; r < 4; r++)
            #pragma unroll
            for (int cq = 0; cq < 4; cq++)
                sX[(tr + r) * STR + tc + cq] = (tc + cq < tr + r) ? acc[r][cq] : 0.f;
    }
    {
        float acc[4][4] = {};
        gemm64<1, STR, 1, STR>(sAp, sKp, acc, tr, tc);
        #pragma unroll
        for (int r = 0; r < 4; r++)
            #pragma unroll
            for (int cq = 0; cq < 4; cq++)
                sYk[(tr + r) * STR + tc + cq] = (tc + cq < tr + r) ? acc[r][cq] : 0.f;
    }
    __syncthreads();
    {
        float acc[4][4] = {};
        gemm64<STR, 1, 1, STR>(sYk, sWC, acc, tr, tc);
        __syncthreads();
        #pragma unroll
        for (int r = 0; r < 4; r++)
            #pragma unroll
            for (int cq = 0; cq < 4; cq++)
                sKp[(tr + r) * STR + tc + cq] = acc[r][cq];
    }
    __syncthreads();
    if (tid < 64) {
        for (int r = 0; r < 64; ++r) {
            float acc = 0.f;
            for (int s = 0; s < r; ++s)
                acc = fmaf(sX[r * STR + s], sBp[s * STR + tid], acc);
            sBp[r * STR + tid] = (r == tid) ? 1.f : acc;
        }
    }
    __syncthreads();
    {
        float accG[4][4] = {};
        gemm64<STR, 1, STR, 1>(sBp, sAp, accG, tr, tc);
        float accU[4][4] = {};
        gemm64<STR, 1, 1, STR>(sBp, sKp, accU, tr, tc);
        #pragma unroll
        for (int r = 0; r < 4; r++) {
            *(float4*)&Gb[gbase + (tr + r) * 64 + tc] =
                make_float4(accG[r][0], accG[r][1], accG[r][2], accG[r][3]);
            *(float4*)&Ub[gbase + (tr + r) * 64 + tc] =
                make_float4(accU[r][0], accU[r][1], accU[r][2], accU[r][3]);
        }
    }
}

__global__ __launch_bounds__(256) void wkvB(
    const float* __restrict__ vb,
    const float* __restrict__ Gb, float* __restrict__ Ub,
    const float* __restrict__ Bpb, const float* __restrict__ Kpb,
    const float* __restrict__ wcb, float* __restrict__ S0b,
    float* __restrict__ Scur, int cb)
{
    __shared__ float sS[64 * STR];
    __shared__ float sG[64 * STR];
    __shared__ float sU[64 * STR];
    __shared__ float sB[64 * STR];
    __shared__ float sK[64 * STR];
    __shared__ float sV[64 * STR];
    const int bhd = blockIdx.x;
    const int dir = bhd & 1, bh = bhd >> 1, b = bh >> 4, h = bh & 15;
    const int tid = threadIdx.x;
    const int tr = (tid >> 4) * 4, tc = (tid & 15) * 4;

    for (int i = tid; i < 4096; i += 256)
        sS[(i >> 6) * STR + (i & 63)] = Scur[(size_t)bhd * 4096 + i];
    __syncthreads();

    for (int lc = 0; lc < CB; ++lc) {
        const int inst = bhd * CB + lc;
        const size_t gbase = (size_t)inst * 4096;
        const int c64 = (cb * CB + lc) * LCH;
        for (int i = tid; i < 4096; i += 256) {
            int rr = i >> 6, jj = i & 63;
            sG[rr * STR + jj] = Gb[gbase + i];
            sB[rr * STR + jj] = Bpb[gbase + i];
            sK[rr * STR + jj] = Kpb[gbase + i];
            int t = dir ? (TMAX - (c64 + rr)) : (c64 + rr);
            sV[rr * STR + jj] = vb[((size_t)(b * TT + t)) * CC + h * 64 + jj];
            S0b[gbase + i] = sS[rr * STR + jj];
        }
        __syncthreads();
        {
            float acc[4][4];
            #pragma unroll
            for (int r = 0; r < 4; r++) {
                float4 u0 = *(const float4*)&Ub[gbase + (tr + r) * 64 + tc];
                acc[r][0] = u0.x; acc[r][1] = u0.y; acc[r][2] = u0.z; acc[r][3] = u0.w;
            }
            gemm64<STR, 1, STR, 1>(sG, sS, acc, tr, tc);
            #pragma unroll
            for (int r = 0; r < 4; r++) {
                #pragma unroll
                for (int cq = 0; cq < 4; cq++) sU[(tr + r) * STR + tc + cq] = acc[r][cq];
                *(float4*)&Ub[gbase + (tr + r) * 64 + tc] =
                    make_float4(acc[r][0], acc[r][1], acc[r][2], acc[r][3]);
            }
        }
        __syncthreads();
        {
            float acc[4][4] = {};
            gemm64<1, STR, 1, STR>(sU, sB, acc, tr, tc);
            gemm64<1, STR, 1, STR>(sV, sK, acc, tr, tc);
            float w63[4];
            #pragma unroll
            for (int cq = 0; cq < 4; cq++) w63[cq] = wcb[gbase + 63 * 64 + tc + cq];
            #pragma unroll
            for (int r = 0; r < 4; r++)
                #pragma unroll
                for (int cq = 0; cq < 4; cq++) {
                    float sv = sS[(tr + r) * STR + tc + cq];
                    acc[r][cq] = (sv + acc[r][cq]) * w63[cq];
                }
            #pragma unroll
            for (int r = 0; r < 4; r++)
                #pragma unroll
                for (int cq = 0; cq < 4; cq++)
                    sS[(tr + r) * STR + tc + cq] = acc[r][cq];
        }
        __syncthreads();
    }
    for (int i = tid; i < 4096; i += 256)
        Scur[(size_t)bhd * 4096 + i] = sS[(i >> 6) * STR + (i & 63)];
}

// ---------------------------------------------------------------------------
// wkvC: outputs. Launches cb<NB/2 are provably the FIRST writer of their
// y-regions (fwd writes R_cb, bwd writes R_{NB-1-cb}; first writer of R_j is
// launch min(j,NB-1-j)) -> plain store; cb>=NB/2 -> accumulate. No memset.
// ---------------------------------------------------------------------------
__global__ __launch_bounds__(256) void wkvC(
    const float* __restrict__ rb, const float* __restrict__ vb,
    const float* __restrict__ Bpb, const float* __restrict__ Kpb,
    const float* __restrict__ Ub, const float* __restrict__ S0b,
    const float* __restrict__ wcb, const float* __restrict__ alpha_p,
    float* __restrict__ yb, int cb)
{
    __shared__ float sm[6][64 * STR];
    float* sRp = sm[0];
    float* sBt = sm[1];
    float* sKt = sm[2];
    float* sMb = sm[3];
    float* sMk = sm[4];
    float* sV  = sm[5];
    const int inst = blockIdx.x;
    const int bhd = inst >> 3, lc = inst & 7;
    const int dir = bhd & 1, bh = bhd >> 1, b = bh >> 4, h = bh & 15;
    const int c64 = (cb * CB + lc) * LCH;
    const int tid = threadIdx.x, lane = tid & 63, seg = tid >> 6;
    const size_t gbase = (size_t)inst * 4096;
    const float alpha = alpha_p[0];
    const float wscale = dir ? (1.f - alpha) : alpha;
    const bool first = (cb < NB / 2);

    #pragma unroll
    for (int i = 0; i < 16; i++) {
        int p = seg * 16 + i;
        int t = dir ? (TMAX - (c64 + p)) : (c64 + p);
        size_t ra = ((size_t)(b * TT + t)) * CC + h * 64 + lane;
        float wc = wcb[gbase + p * 64 + lane];
        sRp[lane * STR + p] = rb[ra] * wc;
        sBt[lane * STR + p] = Bpb[gbase + p * 64 + lane];
        sKt[lane * STR + p] = Kpb[gbase + p * 64 + lane];
        sV[p * STR + lane]  = vb[ra];
    }
    __syncthreads();
    const int tr = (tid >> 4) * 4, tc = (tid & 15) * 4;
    {
        float acc[4][4] = {};
        gemm64<1, STR, 1, STR>(sRp, sBt, acc, tr, tc);
        #pragma unroll
        for (int r = 0; r < 4; r++)
            #pragma unroll
            for (int cq = 0; cq < 4; cq++)
                sMb[(tr + r) * STR + tc + cq] = (tc + cq <= tr + r) ? acc[r][cq] : 0.f;
        float acc2[4][4] = {};
        gemm64<1, STR, 1, STR>(sRp, sKt, acc2, tr, tc);
        #pragma unroll
        for (int r = 0; r < 4; r++)
            #pragma unroll
            for (int cq = 0; cq < 4; cq++)
                sMk[(tr + r) * STR + tc + cq] = (tc + cq <= tr + r) ? acc2[r][cq] : 0.f;
    }
    __syncthreads();
    #pragma unroll
    for (int i = 0; i < 16; i++) {
        int rr = seg * 16 + i;
        sBt[rr * STR + lane] = Ub[gbase + rr * 64 + lane];
        sKt[rr * STR + lane] = S0b[gbase + rr * 64 + lane];
    }
    __syncthreads();
    {
        float acc[4][4] = {};
        gemm64<1, STR, STR, 1>(sRp, sKt, acc, tr, tc);
        gemm64<STR, 1, 1, STR>(sMb, sBt, acc, tr, tc);
        gemm64<STR, 1, 1, STR>(sMk, sV,  acc, tr, tc);
        #pragma unroll
        for (int r = 0; r < 4; r++) {
            int p = tr + r;
            int t = dir ? (TMAX - (c64 + p)) : (c64 + p);
            float* yp = &yb[((size_t)(b * TT + t)) * CC + h * 64 + tc];
            float4 o;
            if (first) {
                o.x = wscale * acc[r][0];
                o.y = wscale * acc[r][1];
                o.z = wscale * acc[r][2];
                o.w = wscale * acc[r][3];
            } else {
                float4 old = *(float4*)yp;
                o.x = old.x + wscale * acc[r][0];
                o.y = old.y + wscale * acc[r][1];
                o.z = old.z + wscale * acc[r][2];
                o.w = old.w + wscale * acc[r][3];
            }
            *(float4*)yp = o;
        }
    }
}

// ---------------------------------------------------------------------------
// Post: GroupNorm + affine + bonus + gating; emits z as split bf16 (hi+lo).
// ---------------------------------------------------------------------------
__global__ __launch_bounds__(256) void post_kernel(
    const float* __restrict__ yb, const float* __restrict__ rbv,
    const float* __restrict__ kbv, const float* __restrict__ abv,
    const float* __restrict__ vbv, const float* __restrict__ gbv,
    const float* __restrict__ kaw, const float* __restrict__ r_k,
    const float* __restrict__ ln_w, const float* __restrict__ ln_b,
    unsigned short* __restrict__ zh, unsigned short* __restrict__ zl)
{
    const int t = blockIdx.x;
    const int tid = threadIdx.x;
    const size_t base = (size_t)t * CC;
    #pragma unroll
    for (int j = 0; j < 4; j++) {
        int c = tid + 256 * j;
        float y = yb[base + c];
        float s1 = waveReduceSum(y);
        float s2 = waveReduceSum(y * y);
        float mu = s1 * (1.0f / 64.0f);
        float var = s2 * (1.0f / 64.0f) - mu * mu;
        float yn = (y - mu) * rsqrtf(var + EPS_GN);
        yn = yn * ln_w[c] + ln_b[c];
        float rv = rbv[base + c];
        float kf = kbv[base + c] * (1.0f + (abv[base + c] - 1.0f) * kaw[c]);
        float vv = vbv[base + c];
        float dot = waveReduceSum(rv * kf * r_k[c]);
        yn += dot * vv;
        float z = yn * gbv[base + c];
        unsigned short h = f2bf(z);
        zh[base + c] = h;
        zl[base + c] = f2bf(z - bf2f(h));
    }
}

// ---------------------------------------------------------------------------
extern "C" void kernel_launch(void* const* d_in, const int* in_sizes, int n_in,
                              void* d_out, int out_size, void* d_ws, size_t ws_size,
                              hipStream_t stream)
{
    (void)in_sizes; (void)n_in; (void)out_size; (void)ws_size;
    const float* x      = (const float*)d_in[0];
    const float* vfirst = (const float*)d_in[1];
    const float* x_r    = (const float*)d_in[2];
    const float* x_w    = (const float*)d_in[3];
    const float* x_k    = (const float*)d_in[4];
    const float* x_v    = (const float*)d_in[5];
    const float* x_a    = (const float*)d_in[6];
    const float* x_g    = (const float*)d_in[7];
    const float* w0     = (const float*)d_in[8];
    const float* w1     = (const float*)d_in[9];
    const float* w2     = (const float*)d_in[10];
    const float* a0     = (const float*)d_in[11];
    const float* a1     = (const float*)d_in[12];
    const float* a2     = (const float*)d_in[13];
    const float* v0     = (const float*)d_in[14];
    const float* v1     = (const float*)d_in[15];
    const float* v2     = (const float*)d_in[16];
    const float* g1     = (const float*)d_in[17];
    const float* g2     = (const float*)d_in[18];
    const float* k_k    = (const float*)d_in[19];
    const float* k_a    = (const float*)d_in[20];
    const float* r_k    = (const float*)d_in[21];
    const float* Wr     = (const float*)d_in[22];
    const float* Wk     = (const float*)d_in[23];
    const float* Wv     = (const float*)d_in[24];
    const float* Wo     = (const float*)d_in[25];
    const float* ln_w   = (const float*)d_in[26];
    const float* ln_b   = (const float*)d_in[27];
    const float* alpha  = (const float*)d_in[28];

    const size_t SZ = (size_t)BT * CC;
    const size_t CHB = (size_t)1024 * 4096;
    float* ws   = (float*)d_ws;
    float* rb   = ws + 0 * SZ;
    float* kb   = ws + 1 * SZ;
    float* vb   = ws + 2 * SZ;
    float* decb = ws + 3 * SZ;
    float* ab   = ws + 4 * SZ;
    float* tw   = ws + 5 * SZ;
    float* ta   = tw + (size_t)BT * 64;
    float* tv   = ta + (size_t)BT * 64;
    float* tg   = tv + (size_t)BT * 32;
    float* Gb   = tg + (size_t)BT * 160;
    float* Ub   = Gb + CHB;
    float* Bpb  = Ub + CHB;
    float* Kpb  = Bpb + CHB;
    float* S0b  = Kpb + CHB;
    float* wcb  = S0b + CHB;
    float* Scur = wcb + CHB;                     // 128*4096 floats
    unsigned short* Whb = (unsigned short*)(Scur + (size_t)128 * 4096);
    unsigned short* Wlb = Whb + (size_t)CC * CC; // 2x 1M bf16 = 4 MB
    float* outp = (float*)d_out;
    float* gb   = outp;                          // g in out[0:SZ] until final GEMM
    float* yb   = outp + SZ;                     // y in out[SZ:2SZ] until v_first copy
    unsigned short* Ahp = (unsigned short*)(outp + SZ);   // projections phase
    unsigned short* Alp = Ahp + SZ;
    unsigned short* zAh = (unsigned short*)decb;          // z split (decb dead after scan)
    unsigned short* zAl = zAh + SZ;

    dim3 blk(256);
    const int NG_A = BT * (CC / 8);    // 2,097,152 groups
    const int NG_W = CC * (CC / 8);    // 131,072 groups
    dim3 gridA(NG_A / 256), gridW(NG_W / 256);
    dim3 gridG(1024);                  // 1D XCD-aware decode in kernel

    // big projections: split-convert then MFMA (3-term split-bf16)
    conv_split<false><<<gridW, blk, 0, stream>>>(Wr, nullptr, Whb, Wlb, NG_W);
    conv_split<true ><<<gridA, blk, 0, stream>>>(x, x_r, Ahp, Alp, NG_A);
    gemm_split_bf16<<<gridG, blk, 0, stream>>>(Ahp, Alp, Whb, Wlb, rb);
    conv_split<false><<<gridW, blk, 0, stream>>>(Wk, nullptr, Whb, Wlb, NG_W);
    conv_split<true ><<<gridA, blk, 0, stream>>>(x, x_k, Ahp, Alp, NG_A);
    gemm_split_bf16<<<gridG, blk, 0, stream>>>(Ahp, Alp, Whb, Wlb, kb);
    conv_split<false><<<gridW, blk, 0, stream>>>(Wv, nullptr, Whb, Wlb, NG_W);
    conv_split<true ><<<gridA, blk, 0, stream>>>(x, x_v, Ahp, Alp, NG_A);
    gemm_split_bf16<<<gridG, blk, 0, stream>>>(Ahp, Alp, Whb, Wlb, vb);

    // LoRA stage-1 (fp32, w: tanh, g: sigmoid fused)
    gemm_mix<true, false, 1><<<dim3(BT / 128, 1), blk, 0, stream>>>(x, w1, x_w, tw, 64);
    gemm_mix<true, false, 0><<<dim3(BT / 128, 1), blk, 0, stream>>>(x, a1, x_a, ta, 64);
    gemm_mix<true, false, 0><<<dim3(BT / 128, 1), blk, 0, stream>>>(x, v1, x_v, tv, 32);
    gemm_mix<true, false, 2><<<dim3(BT / 128, 2), blk, 0, stream>>>(x, g1, x_g, tg, 160);
    lora2_kernel<<<dim3(BT / LR), blk, 0, stream>>>(tw, ta, tv, tg, w2, a2, v2, g2,
        w0, a0, v0, vfirst, vb, decb, ab, gb);

    // chunked bidirectional WKV (wkvC first-writer batches store, rest accumulate)
    hipMemsetAsync(Scur, 0, (size_t)128 * 4096 * sizeof(float), stream);
    for (int cb = 0; cb < NB; ++cb) {
        wkvA<<<dim3(1024), blk, 0, stream>>>(kb, ab, vb, decb, k_k, k_a,
                                             Gb, Ub, Bpb, Kpb, wcb, cb);
        wkvB<<<dim3(128), blk, 0, stream>>>(vb, Gb, Ub, Bpb, Kpb, wcb, S0b, Scur, cb);
        wkvC<<<dim3(1024), blk, 0, stream>>>(rb, vb, Bpb, Kpb, Ub, S0b, wcb,
                                             alpha, yb, cb);
    }

    // groupnorm + bonus + gate -> split bf16 z (into decb's slot, dead now)
    post_kernel<<<dim3(BT), blk, 0, stream>>>(yb, rb, kb, ab, vb, gb, k_a, r_k,
                                              ln_w, ln_b, zAh, zAl);
    // final projection
    conv_split<false><<<gridW, blk, 0, stream>>>(Wo, nullptr, Whb, Wlb, NG_W);
    hipMemcpyAsync(outp + SZ, vfirst, SZ * sizeof(float),
                   hipMemcpyDeviceToDevice, stream);
    gemm_split_bf16<<<gridG, blk, 0, stream>>>(zAh, zAl, Whb, Wlb, outp);
}

// Round 8
// 4414.951 us; speedup vs baseline: 2.4574x; 1.1335x over previous
//
#include <hip/hip_runtime.h>
#include <hip/hip_bf16.h>
#include <math.h>

#define BB 4
#define TT 4096
#define CC 1024
#define HH 16
#define NN 64
#define BT (BB*TT)            // 16384 rows
#define EPS_GN 6.4e-4f        // 1e-5 * 8^2
#define TMAX (TT-1)
#define LCH 64                // chunk length
#define CB 8                  // chunks per batch
#define NB 8                  // batches  (LCH*CB*NB == TT)
#define STR 68                // padded LDS row stride (multiple of 4 -> b128)

typedef __attribute__((ext_vector_type(8))) short bf16x8;
typedef __attribute__((ext_vector_type(4))) float f32x4;

__device__ __forceinline__ float sigmoidf_(float x) {
    return 1.0f / (1.0f + expf(-x));
}

__device__ __forceinline__ float waveReduceSum(float v) {
    #pragma unroll
    for (int off = 32; off > 0; off >>= 1)
        v += __shfl_xor(v, off, 64);
    return v;
}

__device__ __forceinline__ unsigned short f2bf(float f) {
    unsigned u = __float_as_uint(f);
    u += 0x7FFFu + ((u >> 16) & 1u);
    return (unsigned short)(u >> 16);
}
__device__ __forceinline__ float bf2f(unsigned short h) {
    return __uint_as_float(((unsigned)h) << 16);
}

__device__ __forceinline__ void gll16(const unsigned short* g, unsigned short* l) {
    __builtin_amdgcn_global_load_lds(
        (__attribute__((address_space(1))) void*)(g),
        (__attribute__((address_space(3))) void*)(l), 16, 0, 0);
}

// acc[r][c] += sum_k A(tr+r,k)*B(tc+c,k); element A(i,k)=A[i*SA0+k*SA1].
// Vectorized: all LDS traffic as b128 (requires STR%4==0, tr/tc%4==0).
template<int SA0,int SA1,int SB0,int SB1>
__device__ __forceinline__ void gemm64(const float* __restrict__ A,
                                       const float* __restrict__ B,
                                       float acc[4][4], int tr, int tc) {
    #pragma unroll 2
    for (int kx = 0; kx < 64; kx += 4) {
        float a_[4][4];   // [r][kk]
        if (SA0 == 1) {
            #pragma unroll
            for (int kk = 0; kk < 4; kk++) {
                float4 t = *(const float4*)&A[tr + (kx + kk) * SA1];
                a_[0][kk] = t.x; a_[1][kk] = t.y; a_[2][kk] = t.z; a_[3][kk] = t.w;
            }
        } else {
            #pragma unroll
            for (int r = 0; r < 4; r++) {
                float4 t = *(const float4*)&A[(tr + r) * SA0 + kx];
                a_[r][0] = t.x; a_[r][1] = t.y; a_[r][2] = t.z; a_[r][3] = t.w;
            }
        }
        float b_[4][4];   // [cq][kk]
        if (SB0 == 1) {
            #pragma unroll
            for (int kk = 0; kk < 4; kk++) {
                float4 t = *(const float4*)&B[tc + (kx + kk) * SB1];
                b_[0][kk] = t.x; b_[1][kk] = t.y; b_[2][kk] = t.z; b_[3][kk] = t.w;
            }
        } else {
            #pragma unroll
            for (int cq = 0; cq < 4; cq++) {
                float4 t = *(const float4*)&B[(tc + cq) * SB0 + kx];
                b_[cq][0] = t.x; b_[cq][1] = t.y; b_[cq][2] = t.z; b_[cq][3] = t.w;
            }
        }
        #pragma unroll
        for (int r = 0; r < 4; r++)
            #pragma unroll
            for (int cq = 0; cq < 4; cq++)
                #pragma unroll
                for (int kk = 0; kk < 4; kk++)
                    acc[r][cq] = fmaf(a_[r][kk], b_[cq][kk], acc[r][cq]);
    }
}

// ---------------------------------------------------------------------------
// Split-conversion: fp32 (rows x CC, k-contig) -> bf16 hi + bf16 lo residual.
// ---------------------------------------------------------------------------
template<bool DOMIX>
__global__ __launch_bounds__(256) void conv_split(
    const float* __restrict__ X, const float* __restrict__ mix,
    unsigned short* __restrict__ Hi, unsigned short* __restrict__ Lo,
    int ngroups)
{
    int g = blockIdx.x * 256 + threadIdx.x;
    if (g >= ngroups) return;
    int m = g >> 7;                 // CC/8 = 128 groups per row
    int k = (g & 127) * 8;
    const float* px = X + (size_t)m * CC + k;
    float a[8];
    {
        float4 x0 = *(const float4*)px;
        float4 x1 = *(const float4*)(px + 4);
        a[0]=x0.x; a[1]=x0.y; a[2]=x0.z; a[3]=x0.w;
        a[4]=x1.x; a[5]=x1.y; a[6]=x1.z; a[7]=x1.w;
    }
    if (DOMIX) {
        float4 p0, p1;
        if ((m & (TT - 1)) == 0) {
            p0 = make_float4(0.f,0.f,0.f,0.f); p1 = p0;
        } else {
            p0 = *(const float4*)(px - CC);
            p1 = *(const float4*)(px - CC + 4);
        }
        float4 m0 = *(const float4*)(mix + k);
        float4 m1 = *(const float4*)(mix + k + 4);
        float pv[8] = {p0.x,p0.y,p0.z,p0.w,p1.x,p1.y,p1.z,p1.w};
        float mv[8] = {m0.x,m0.y,m0.z,m0.w,m1.x,m1.y,m1.z,m1.w};
        #pragma unroll
        for (int j = 0; j < 8; j++) a[j] += (pv[j] - a[j]) * mv[j];
    }
    unsigned short hi[8], lo[8];
    #pragma unroll
    for (int j = 0; j < 8; j++) {
        hi[j] = f2bf(a[j]);
        lo[j] = f2bf(a[j] - bf2f(hi[j]));
    }
    uint4 H, L;
    H.x = (unsigned)hi[0] | ((unsigned)hi[1] << 16);
    H.y = (unsigned)hi[2] | ((unsigned)hi[3] << 16);
    H.z = (unsigned)hi[4] | ((unsigned)hi[5] << 16);
    H.w = (unsigned)hi[6] | ((unsigned)hi[7] << 16);
    L.x = (unsigned)lo[0] | ((unsigned)lo[1] << 16);
    L.y = (unsigned)lo[2] | ((unsigned)lo[3] << 16);
    L.z = (unsigned)lo[4] | ((unsigned)lo[5] << 16);
    L.w = (unsigned)lo[6] | ((unsigned)lo[7] << 16);
    *(uint4*)(Hi + (size_t)g * 8) = H;
    *(uint4*)(Lo + (size_t)g * 8) = L;
}

// ---------------------------------------------------------------------------
// Split-bf16 MFMA GEMM (unchanged from round 6/7 — passed)
// ---------------------------------------------------------------------------
__global__ __launch_bounds__(256, 2) void gemm_split_bf16(
    const unsigned short* __restrict__ Ah, const unsigned short* __restrict__ Al,
    const unsigned short* __restrict__ Bh, const unsigned short* __restrict__ Bl,
    float* __restrict__ Out)
{
    __shared__ __align__(16) unsigned short lds[4][128 * 64];  // Ah,Al,Bh,Bl
    const int tid = threadIdx.x;
    const int lane = tid & 63;
    const int wave = tid >> 6;
    const int wm = (wave >> 1) * 64, wn = (wave & 1) * 64;
    const int wg = blockIdx.x;
    const int xcd = wg & 7;
    const int j = wg >> 3;
    const int m0 = ((j >> 3) * 8 + xcd) * 128;
    const int n0 = (j & 7) * 128;

    f32x4 acc[4][4];
    #pragma unroll
    for (int i = 0; i < 4; i++)
        #pragma unroll
        for (int jj = 0; jj < 4; jj++)
            acc[i][jj] = (f32x4){0.f, 0.f, 0.f, 0.f};

    for (int k0 = 0; k0 < CC; k0 += 64) {
        #pragma unroll
        for (int p = 0; p < 4; p++) {
            const unsigned short* sbase = (p == 0) ? Ah : (p == 1) ? Al
                                        : (p == 2) ? Bh : Bl;
            const int rbase = (p < 2) ? m0 : n0;
            #pragma unroll
            for (int i = 0; i < 4; i++) {
                int slot = i * 256 + wave * 64 + lane;       // per-lane slot
                int row = slot >> 3, gsl = slot & 7;
                const unsigned short* src = sbase
                    + (size_t)(rbase + row) * CC + k0 + ((gsl ^ (row & 7)) * 8);
                gll16(src, &lds[p][(size_t)(i * 256 + wave * 64) * 8]);
            }
        }
        __syncthreads();

        #pragma unroll
        for (int ks = 0; ks < 2; ks++) {
            bf16x8 bhf[4], blf[4];
            #pragma unroll
            for (int nt = 0; nt < 4; nt++) {
                int col = wn + nt * 16 + (lane & 15);
                int gk = ks * 4 + (lane >> 4);
                int el = col * 64 + ((gk ^ (col & 7)) * 8);
                bhf[nt] = *(const bf16x8*)&lds[2][el];
                blf[nt] = *(const bf16x8*)&lds[3][el];
            }
            #pragma unroll
            for (int mt = 0; mt < 4; mt++) {
                int row = wm + mt * 16 + (lane & 15);
                int gk = ks * 4 + (lane >> 4);
                int el = row * 64 + ((gk ^ (row & 7)) * 8);
                bf16x8 ahf = *(const bf16x8*)&lds[0][el];
                bf16x8 alf = *(const bf16x8*)&lds[1][el];
                #pragma unroll
                for (int nt = 0; nt < 4; nt++) {
                    acc[mt][nt] = __builtin_amdgcn_mfma_f32_16x16x32_bf16(
                        ahf, bhf[nt], acc[mt][nt], 0, 0, 0);
                    acc[mt][nt] = __builtin_amdgcn_mfma_f32_16x16x32_bf16(
                        alf, bhf[nt], acc[mt][nt], 0, 0, 0);
                    acc[mt][nt] = __builtin_amdgcn_mfma_f32_16x16x32_bf16(
                        ahf, blf[nt], acc[mt][nt], 0, 0, 0);
                }
            }
        }
        __syncthreads();
    }
    float* cf = (float*)&lds[0][0];    // 64*132*4 = 33.8 KB
    #pragma unroll
    for (int pass = 0; pass < 2; ++pass) {
        __syncthreads();
        if ((wave >> 1) == pass) {
            #pragma unroll
            for (int mt = 0; mt < 4; mt++)
                #pragma unroll
                for (int nt = 0; nt < 4; nt++)
                    #pragma unroll
                    for (int r = 0; r < 4; r++) {
                        int row = mt * 16 + (lane >> 4) * 4 + r;   // 0..63
                        int col = wn + nt * 16 + (lane & 15);
                        cf[row * 132 + col] = acc[mt][nt][r];
                    }
        }
        __syncthreads();
        #pragma unroll
        for (int i = 0; i < 8; i++) {
            int g = tid + 256 * i;
            int row = g >> 5, c4 = (g & 31) * 4;
            float4 v = *(float4*)&cf[row * 132 + c4];
            *(float4*)&Out[(size_t)(m0 + pass * 64 + row) * CC + n0 + c4] = v;
        }
    }
}

// ---------------------------------------------------------------------------
// LoRA stage-1, merged: one launch, blockIdx.y selects target.
// y=0: w1 (N=64, tanh)  y=1: a1 (64)  y=2: v1 (32)  y=3/4: g1 (160, sigmoid).
// ---------------------------------------------------------------------------
__global__ __launch_bounds__(256) void lora1_all(
    const float* __restrict__ X,
    const float* __restrict__ w1, const float* __restrict__ a1,
    const float* __restrict__ v1, const float* __restrict__ g1,
    const float* __restrict__ xw, const float* __restrict__ xa,
    const float* __restrict__ xv, const float* __restrict__ xg,
    float* __restrict__ tw, float* __restrict__ ta,
    float* __restrict__ tv, float* __restrict__ tg)
{
    const int y = blockIdx.y;
    const float* W;  const float* mix;  float* Out;  int Ncols, n0, epi;
    if (y == 0)      { W = w1; mix = xw; Out = tw; Ncols = 64;  n0 = 0;   epi = 1; }
    else if (y == 1) { W = a1; mix = xa; Out = ta; Ncols = 64;  n0 = 0;   epi = 0; }
    else if (y == 2) { W = v1; mix = xv; Out = tv; Ncols = 32;  n0 = 0;   epi = 0; }
    else if (y == 3) { W = g1; mix = xg; Out = tg; Ncols = 160; n0 = 0;   epi = 2; }
    else             { W = g1; mix = xg; Out = tg; Ncols = 160; n0 = 128; epi = 2; }

    __shared__ float As[8][128];
    __shared__ float Bs[8][128];
    const int tid = threadIdx.x;
    const int m0 = blockIdx.x * 128;
    const int sr  = tid >> 1;
    const int skq = (tid & 1) * 4;
    const int bkr = tid >> 5;
    const int bnq = (tid & 31) * 4;
    const int tm = (tid >> 4) * 8;
    const int tn = (tid & 15) * 8;

    float acc[8][8];
    #pragma unroll
    for (int i = 0; i < 8; i++)
        #pragma unroll
        for (int j = 0; j < 8; j++) acc[i][j] = 0.f;

    auto ldAm = [&](int gm, int gk) -> float4 {
        const float* px = X + (size_t)gm * CC + gk;
        float4 xvv = *(const float4*)px;
        float4 pv;
        if ((gm & (TT - 1)) == 0) pv = make_float4(0.f, 0.f, 0.f, 0.f);
        else pv = *(const float4*)(px - CC);
        float4 mv = *(const float4*)(mix + gk);
        xvv.x += (pv.x - xvv.x) * mv.x;
        xvv.y += (pv.y - xvv.y) * mv.y;
        xvv.z += (pv.z - xvv.z) * mv.z;
        xvv.w += (pv.w - xvv.w) * mv.w;
        return xvv;
    };

    float4 aR, bR;
    aR = ldAm(m0 + sr, skq);
    {
        int gn = n0 + bnq;
        bR = (gn < Ncols) ? *(const float4*)(W + (size_t)bkr * Ncols + gn)
                          : make_float4(0.f, 0.f, 0.f, 0.f);
    }

    for (int k0 = 0; k0 < CC; k0 += 8) {
        __syncthreads();
        As[skq + 0][sr] = aR.x;
        As[skq + 1][sr] = aR.y;
        As[skq + 2][sr] = aR.z;
        As[skq + 3][sr] = aR.w;
        *(float4*)&Bs[bkr][bnq] = bR;
        __syncthreads();

        if (k0 + 8 < CC) {
            aR = ldAm(m0 + sr, k0 + 8 + skq);
            int gn = n0 + bnq;
            bR = (gn < Ncols) ? *(const float4*)(W + (size_t)(k0 + 8 + bkr) * Ncols + gn)
                              : make_float4(0.f, 0.f, 0.f, 0.f);
        }

        #pragma unroll
        for (int kk = 0; kk < 8; ++kk) {
            float av[8], bv[8];
            *(float4*)&av[0] = *(const float4*)&As[kk][tm];
            *(float4*)&av[4] = *(const float4*)&As[kk][tm + 4];
            *(float4*)&bv[0] = *(const float4*)&Bs[kk][tn];
            *(float4*)&bv[4] = *(const float4*)&Bs[kk][tn + 4];
            #pragma unroll
            for (int i = 0; i < 8; i++)
                #pragma unroll
                for (int j = 0; j < 8; j++)
                    acc[i][j] = fmaf(av[i], bv[j], acc[i][j]);
        }
    }

    #pragma unroll
    for (int i = 0; i < 8; i++) {
        int gm = m0 + tm + i;
        int gn = n0 + tn;
        if (gn < Ncols) {
            float o[8];
            #pragma unroll
            for (int j = 0; j < 8; j++) {
                float v = acc[i][j];
                if (epi == 1) v = tanhf(v);
                else if (epi == 2) v = sigmoidf_(v);
                o[j] = v;
            }
            float* p = Out + (size_t)gm * Ncols + gn;
            *(float4*)p       = make_float4(o[0], o[1], o[2], o[3]);
            *(float4*)(p + 4) = make_float4(o[4], o[5], o[6], o[7]);
        }
    }
}

// ---------------------------------------------------------------------------
// LoRA stage-2 + elementwise fusion, v3: d4-vectorized LDS reads.
// 16 rows/block; thread owns cols 4*tid..4*tid+3.
// ---------------------------------------------------------------------------
#define LR 16
__global__ __launch_bounds__(256) void lora2_kernel(
    const float* __restrict__ tw, const float* __restrict__ ta,
    const float* __restrict__ tv, const float* __restrict__ tg,
    const float* __restrict__ w2, const float* __restrict__ a2,
    const float* __restrict__ v2, const float* __restrict__ g2,
    const float* __restrict__ w0, const float* __restrict__ a0v,
    const float* __restrict__ v0v, const float* __restrict__ v_first,
    float* __restrict__ vbuf, float* __restrict__ decb,
    float* __restrict__ ab, float* __restrict__ gb)
{
    __shared__ __align__(16) float s_w[LR * 64];
    __shared__ __align__(16) float s_a[LR * 64];
    __shared__ __align__(16) float s_v[LR * 32];
    __shared__ __align__(16) float s_g[LR * 160];
    const int tid = threadIdx.x;
    const int r0 = blockIdx.x * LR;
    const int c0 = tid * 4;

    {
        const float4* p = (const float4*)(tw + (size_t)r0 * 64);
        *(float4*)&s_w[tid * 4] = p[tid];
        const float4* q = (const float4*)(ta + (size_t)r0 * 64);
        *(float4*)&s_a[tid * 4] = q[tid];
        if (tid < 128) {
            const float4* r = (const float4*)(tv + (size_t)r0 * 32);
            *(float4*)&s_v[tid * 4] = r[tid];
        }
        const float4* s = (const float4*)(tg + (size_t)r0 * 160);
        #pragma unroll
        for (int i = tid; i < 640; i += 256)
            *(float4*)&s_g[i * 4] = s[i];
    }
    __syncthreads();

    // ---- a pass -> ab ----
    {
        float4 acc[LR] = {};
        for (int d4 = 0; d4 < 64; d4 += 4) {
            float4 w4[4];
            #pragma unroll
            for (int kk = 0; kk < 4; kk++)
                w4[kk] = *(const float4*)(a2 + (size_t)(d4 + kk) * CC + c0);
            #pragma unroll
            for (int r = 0; r < LR; r++) {
                float4 xq = *(const float4*)&s_a[r * 64 + d4];
                acc[r].x = fmaf(xq.x, w4[0].x, fmaf(xq.y, w4[1].x, fmaf(xq.z, w4[2].x, fmaf(xq.w, w4[3].x, acc[r].x))));
                acc[r].y = fmaf(xq.x, w4[0].y, fmaf(xq.y, w4[1].y, fmaf(xq.z, w4[2].y, fmaf(xq.w, w4[3].y, acc[r].y))));
                acc[r].z = fmaf(xq.x, w4[0].z, fmaf(xq.y, w4[1].z, fmaf(xq.z, w4[2].z, fmaf(xq.w, w4[3].z, acc[r].z))));
                acc[r].w = fmaf(xq.x, w4[0].w, fmaf(xq.y, w4[1].w, fmaf(xq.z, w4[2].w, fmaf(xq.w, w4[3].w, acc[r].w))));
            }
        }
        float4 a0q = *(const float4*)(a0v + c0);
        #pragma unroll
        for (int r = 0; r < LR; r++) {
            float4 o;
            o.x = sigmoidf_(a0q.x + acc[r].x);
            o.y = sigmoidf_(a0q.y + acc[r].y);
            o.z = sigmoidf_(a0q.z + acc[r].z);
            o.w = sigmoidf_(a0q.w + acc[r].w);
            *(float4*)&ab[(size_t)(r0 + r) * CC + c0] = o;
        }
    }
    // ---- w pass -> dec ----
    {
        float4 acc[LR] = {};
        for (int d4 = 0; d4 < 64; d4 += 4) {
            float4 w4[4];
            #pragma unroll
            for (int kk = 0; kk < 4; kk++)
                w4[kk] = *(const float4*)(w2 + (size_t)(d4 + kk) * CC + c0);
            #pragma unroll
            for (int r = 0; r < LR; r++) {
                float4 xq = *(const float4*)&s_w[r * 64 + d4];
                acc[r].x = fmaf(xq.x, w4[0].x, fmaf(xq.y, w4[1].x, fmaf(xq.z, w4[2].x, fmaf(xq.w, w4[3].x, acc[r].x))));
                acc[r].y = fmaf(xq.x, w4[0].y, fmaf(xq.y, w4[1].y, fmaf(xq.z, w4[2].y, fmaf(xq.w, w4[3].y, acc[r].y))));
                acc[r].z = fmaf(xq.x, w4[0].z, fmaf(xq.y, w4[1].z, fmaf(xq.z, w4[2].z, fmaf(xq.w, w4[3].z, acc[r].z))));
                acc[r].w = fmaf(xq.x, w4[0].w, fmaf(xq.y, w4[1].w, fmaf(xq.z, w4[2].w, fmaf(xq.w, w4[3].w, acc[r].w))));
            }
        }
        float4 w0q = *(const float4*)(w0 + c0);
        #pragma unroll
        for (int r = 0; r < LR; r++) {
            float4 o;
            float d0 = w0q.x + acc[r].x, d1 = w0q.y + acc[r].y;
            float d2 = w0q.z + acc[r].z, d3 = w0q.w + acc[r].w;
            o.x = expf(-expf(-log1pf(expf(-d0)) - 0.5f));
            o.y = expf(-expf(-log1pf(expf(-d1)) - 0.5f));
            o.z = expf(-expf(-log1pf(expf(-d2)) - 0.5f));
            o.w = expf(-expf(-log1pf(expf(-d3)) - 0.5f));
            *(float4*)&decb[(size_t)(r0 + r) * CC + c0] = o;
        }
    }
    // ---- v pass -> v_final (in place) ----
    {
        float4 acc[LR] = {};
        for (int d4 = 0; d4 < 32; d4 += 4) {
            float4 w4[4];
            #pragma unroll
            for (int kk = 0; kk < 4; kk++)
                w4[kk] = *(const float4*)(v2 + (size_t)(d4 + kk) * CC + c0);
            #pragma unroll
            for (int r = 0; r < LR; r++) {
                float4 xq = *(const float4*)&s_v[r * 32 + d4];
                acc[r].x = fmaf(xq.x, w4[0].x, fmaf(xq.y, w4[1].x, fmaf(xq.z, w4[2].x, fmaf(xq.w, w4[3].x, acc[r].x))));
                acc[r].y = fmaf(xq.x, w4[0].y, fmaf(xq.y, w4[1].y, fmaf(xq.z, w4[2].y, fmaf(xq.w, w4[3].y, acc[r].y))));
                acc[r].z = fmaf(xq.x, w4[0].z, fmaf(xq.y, w4[1].z, fmaf(xq.z, w4[2].z, fmaf(xq.w, w4[3].z, acc[r].z))));
                acc[r].w = fmaf(xq.x, w4[0].w, fmaf(xq.y, w4[1].w, fmaf(xq.z, w4[2].w, fmaf(xq.w, w4[3].w, acc[r].w))));
            }
        }
        float4 v0q = *(const float4*)(v0v + c0);
        #pragma unroll
        for (int r = 0; r < LR; r++) {
            size_t off = (size_t)(r0 + r) * CC + c0;
            float4 vr = *(const float4*)&vbuf[off];
            float4 vf = *(const float4*)&v_first[off];
            float4 o;
            o.x = vr.x + (vf.x - vr.x) * sigmoidf_(v0q.x + acc[r].x);
            o.y = vr.y + (vf.y - vr.y) * sigmoidf_(v0q.y + acc[r].y);
            o.z = vr.z + (vf.z - vr.z) * sigmoidf_(v0q.z + acc[r].z);
            o.w = vr.w + (vf.w - vr.w) * sigmoidf_(v0q.w + acc[r].w);
            *(float4*)&vbuf[off] = o;
        }
    }
    // ---- g pass ----
    {
        float4 acc[LR] = {};
        for (int d4 = 0; d4 < 160; d4 += 4) {
            float4 w4[4];
            #pragma unroll
            for (int kk = 0; kk < 4; kk++)
                w4[kk] = *(const float4*)(g2 + (size_t)(d4 + kk) * CC + c0);
            #pragma unroll
            for (int r = 0; r < LR; r++) {
                float4 xq = *(const float4*)&s_g[r * 160 + d4];
                acc[r].x = fmaf(xq.x, w4[0].x, fmaf(xq.y, w4[1].x, fmaf(xq.z, w4[2].x, fmaf(xq.w, w4[3].x, acc[r].x))));
                acc[r].y = fmaf(xq.x, w4[0].y, fmaf(xq.y, w4[1].y, fmaf(xq.z, w4[2].y, fmaf(xq.w, w4[3].y, acc[r].y))));
                acc[r].z = fmaf(xq.x, w4[0].z, fmaf(xq.y, w4[1].z, fmaf(xq.z, w4[2].z, fmaf(xq.w, w4[3].z, acc[r].z))));
                acc[r].w = fmaf(xq.x, w4[0].w, fmaf(xq.y, w4[1].w, fmaf(xq.z, w4[2].w, fmaf(xq.w, w4[3].w, acc[r].w))));
            }
        }
        #pragma unroll
        for (int r = 0; r < LR; r++)
            *(float4*)&gb[(size_t)(r0 + r) * CC + c0] = acc[r];
    }
}

// ---------------------------------------------------------------------------
// Chunked WKV phases A, B, C (structure unchanged; gemm64 now vectorized,
// STR=68 for b128 alignment)
// ---------------------------------------------------------------------------
__global__ __launch_bounds__(256) void wkvA(
    const float* __restrict__ kb, const float* __restrict__ ab,
    const float* __restrict__ vb, const float* __restrict__ decb,
    const float* __restrict__ k_k, const float* __restrict__ k_a,
    float* __restrict__ Gb, float* __restrict__ Ub,
    float* __restrict__ Bpb, float* __restrict__ Kpb,
    float* __restrict__ wcb, int cb)
{
    __shared__ __align__(16) float sm[6][64 * STR];
    __shared__ float sSeg[4][64];
    const int inst = blockIdx.x;
    const int bhd = inst >> 3, lc = inst & 7;
    const int dir = bhd & 1, bh = bhd >> 1, b = bh >> 4, h = bh & 15;
    const int c64 = (cb * CB + lc) * LCH;
    const int tid = threadIdx.x;
    const int lane = tid & 63, seg = tid >> 6;
    const int ch = h * 64 + lane;
    const size_t gbase = (size_t)inst * 4096;
    float* sWC = sm[0];
    float* sAp = sm[1];
    float* sBp = sm[2];
    float* sKp = sm[3];
    float* sX  = sm[4];
    float* sYk = sm[5];

    {
        float run = 1.f; float loc[16];
        #pragma unroll
        for (int i = 0; i < 16; i++) {
            int p = seg * 16 + i;
            int t = dir ? (TMAX - (c64 + p)) : (c64 + p);
            float d = decb[((size_t)(b * TT + t)) * CC + ch];
            run *= d; loc[i] = run;
        }
        sSeg[seg][lane] = run;
        __syncthreads();
        float pre = 1.f;
        for (int s2 = 0; s2 < seg; ++s2) pre *= sSeg[s2][lane];
        #pragma unroll
        for (int i = 0; i < 16; i++) {
            int p = seg * 16 + i;
            float wcv = pre * loc[i];
            sWC[p * STR + lane] = wcv;
            wcb[gbase + p * 64 + lane] = wcv;
        }
    }
    __syncthreads();
    {
        const float kkl = k_k[ch], kal = k_a[ch];
        for (int i = 0; i < 16; i++) {
            int p = seg * 16 + i;
            int t = dir ? (TMAX - (c64 + p)) : (c64 + p);
            size_t ra = ((size_t)(b * TT + t)) * CC + ch;
            float kraw = kb[ra], asig = ab[ra];
            float kkv = kraw * kkl;
            float s2 = waveReduceSum(kkv * kkv);
            float kkn = kkv / fmaxf(sqrtf(s2), 1e-12f);
            float wc = sWC[p * STR + lane];
            float wx = (p == 0) ? 1.f : sWC[(p - 1) * STR + lane];
            float apv = -kkn * wx;
            float bpv = kkn * asig / wc;
            float kpv = kraw * (1.f + (asig - 1.f) * kal) / wc;
            sAp[lane * STR + p] = apv;
            sBp[lane * STR + p] = bpv;
            sKp[lane * STR + p] = kpv;
            Bpb[gbase + p * 64 + lane] = bpv;
            Kpb[gbase + p * 64 + lane] = kpv;
        }
    }
    __syncthreads();

    const int tr = (tid >> 4) * 4, tc = (tid & 15) * 4;
    #pragma unroll
    for (int i = 0; i < 16; i++) {
        int p = seg * 16 + i;
        int t = dir ? (TMAX - (c64 + p)) : (c64 + p);
        sWC[p * STR + lane] = vb[((size_t)(b * TT + t)) * CC + ch];
    }
    {
        float acc[4][4] = {};
        gemm64<1, STR, 1, STR>(sAp, sBp, acc, tr, tc);
        #pragma unroll
        for (int r = 0; r < 4; r++)
            #pragma unroll
            for (int cq = 0; cq < 4; cq++)
                sX[(tr + r) * STR + tc + cq] = (tc + cq < tr + r) ? acc[r][cq] : 0.f;
    }
    {
        float acc[4][4] = {};
        gemm64<1, STR, 1, STR>(sAp, sKp, acc, tr, tc);
        #pragma unroll
        for (int r = 0; r < 4; r++)
            #pragma unroll
            for (int cq = 0; cq < 4; cq++)
                sYk[(tr + r) * STR + tc + cq] = (tc + cq < tr + r) ? acc[r][cq] : 0.f;
    }
    __syncthreads();
    {
        float acc[4][4] = {};
        gemm64<STR, 1, 1, STR>(sYk, sWC, acc, tr, tc);
        __syncthreads();
        #pragma unroll
        for (int r = 0; r < 4; r++)
            #pragma unroll
            for (int cq = 0; cq < 4; cq++)
                sKp[(tr + r) * STR + tc + cq] = acc[r][cq];
    }
    __syncthreads();
    if (tid < 64) {
        for (int r = 0; r < 64; ++r) {
            float acc = 0.f;
            for (int s = 0; s < r; ++s)
                acc = fmaf(sX[r * STR + s], sBp[s * STR + tid], acc);
            sBp[r * STR + tid] = (r == tid) ? 1.f : acc;
        }
    }
    __syncthreads();
    {
        float accG[4][4] = {};
        gemm64<STR, 1, STR, 1>(sBp, sAp, accG, tr, tc);
        float accU[4][4] = {};
        gemm64<STR, 1, 1, STR>(sBp, sKp, accU, tr, tc);
        #pragma unroll
        for (int r = 0; r < 4; r++) {
            *(float4*)&Gb[gbase + (tr + r) * 64 + tc] =
                make_float4(accG[r][0], accG[r][1], accG[r][2], accG[r][3]);
            *(float4*)&Ub[gbase + (tr + r) * 64 + tc] =
                make_float4(accU[r][0], accU[r][1], accU[r][2], accU[r][3]);
        }
    }
}

__global__ __launch_bounds__(256) void wkvB(
    const float* __restrict__ vb,
    const float* __restrict__ Gb, float* __restrict__ Ub,
    const float* __restrict__ Bpb, const float* __restrict__ Kpb,
    const float* __restrict__ wcb, float* __restrict__ S0b,
    float* __restrict__ Scur, int cb)
{
    __shared__ __align__(16) float sS[64 * STR];
    __shared__ __align__(16) float sG[64 * STR];
    __shared__ __align__(16) float sU[64 * STR];
    __shared__ __align__(16) float sB[64 * STR];
    __shared__ __align__(16) float sK[64 * STR];
    __shared__ __align__(16) float sV[64 * STR];
    const int bhd = blockIdx.x;
    const int dir = bhd & 1, bh = bhd >> 1, b = bh >> 4, h = bh & 15;
    const int tid = threadIdx.x;
    const int tr = (tid >> 4) * 4, tc = (tid & 15) * 4;

    for (int i = tid; i < 4096; i += 256)
        sS[(i >> 6) * STR + (i & 63)] = Scur[(size_t)bhd * 4096 + i];
    __syncthreads();

    for (int lc = 0; lc < CB; ++lc) {
        const int inst = bhd * CB + lc;
        const size_t gbase = (size_t)inst * 4096;
        const int c64 = (cb * CB + lc) * LCH;
        for (int i = tid; i < 4096; i += 256) {
            int rr = i >> 6, jj = i & 63;
            sG[rr * STR + jj] = Gb[gbase + i];
            sB[rr * STR + jj] = Bpb[gbase + i];
            sK[rr * STR + jj] = Kpb[gbase + i];
            int t = dir ? (TMAX - (c64 + rr)) : (c64 + rr);
            sV[rr * STR + jj] = vb[((size_t)(b * TT + t)) * CC + h * 64 + jj];
            S0b[gbase + i] = sS[rr * STR + jj];
        }
        __syncthreads();
        {
            float acc[4][4];
            #pragma unroll
            for (int r = 0; r < 4; r++) {
                float4 u0 = *(const float4*)&Ub[gbase + (tr + r) * 64 + tc];
                acc[r][0] = u0.x; acc[r][1] = u0.y; acc[r][2] = u0.z; acc[r][3] = u0.w;
            }
            gemm64<STR, 1, STR, 1>(sG, sS, acc, tr, tc);
            #pragma unroll
            for (int r = 0; r < 4; r++) {
                #pragma unroll
                for (int cq = 0; cq < 4; cq++) sU[(tr + r) * STR + tc + cq] = acc[r][cq];
                *(float4*)&Ub[gbase + (tr + r) * 64 + tc] =
                    make_float4(acc[r][0], acc[r][1], acc[r][2], acc[r][3]);
            }
        }
        __syncthreads();
        {
            float acc[4][4] = {};
            gemm64<1, STR, 1, STR>(sU, sB, acc, tr, tc);
            gemm64<1, STR, 1, STR>(sV, sK, acc, tr, tc);
            float w63[4];
            #pragma unroll
            for (int cq = 0; cq < 4; cq++) w63[cq] = wcb[gbase + 63 * 64 + tc + cq];
            #pragma unroll
            for (int r = 0; r < 4; r++)
                #pragma unroll
                for (int cq = 0; cq < 4; cq++) {
                    float sv = sS[(tr + r) * STR + tc + cq];
                    acc[r][cq] = (sv + acc[r][cq]) * w63[cq];
                }
            #pragma unroll
            for (int r = 0; r < 4; r++)
                #pragma unroll
                for (int cq = 0; cq < 4; cq++)
                    sS[(tr + r) * STR + tc + cq] = acc[r][cq];
        }
        __syncthreads();
    }
    for (int i = tid; i < 4096; i += 256)
        Scur[(size_t)bhd * 4096 + i] = sS[(i >> 6) * STR + (i & 63)];
}

__global__ __launch_bounds__(256) void wkvC(
    const float* __restrict__ rb, const float* __restrict__ vb,
    const float* __restrict__ Bpb, const float* __restrict__ Kpb,
    const float* __restrict__ Ub, const float* __restrict__ S0b,
    const float* __restrict__ wcb, const float* __restrict__ alpha_p,
    float* __restrict__ yb, int cb)
{
    __shared__ __align__(16) float sm[6][64 * STR];
    float* sRp = sm[0];
    float* sBt = sm[1];
    float* sKt = sm[2];
    float* sMb = sm[3];
    float* sMk = sm[4];
    float* sV  = sm[5];
    const int inst = blockIdx.x;
    const int bhd = inst >> 3, lc = inst & 7;
    const int dir = bhd & 1, bh = bhd >> 1, b = bh >> 4, h = bh & 15;
    const int c64 = (cb * CB + lc) * LCH;
    const int tid = threadIdx.x, lane = tid & 63, seg = tid >> 6;
    const size_t gbase = (size_t)inst * 4096;
    const float alpha = alpha_p[0];
    const float wscale = dir ? (1.f - alpha) : alpha;
    const bool first = (cb < NB / 2);

    #pragma unroll
    for (int i = 0; i < 16; i++) {
        int p = seg * 16 + i;
        int t = dir ? (TMAX - (c64 + p)) : (c64 + p);
        size_t ra = ((size_t)(b * TT + t)) * CC + h * 64 + lane;
        float wc = wcb[gbase + p * 64 + lane];
        sRp[lane * STR + p] = rb[ra] * wc;
        sBt[lane * STR + p] = Bpb[gbase + p * 64 + lane];
        sKt[lane * STR + p] = Kpb[gbase + p * 64 + lane];
        sV[p * STR + lane]  = vb[ra];
    }
    __syncthreads();
    const int tr = (tid >> 4) * 4, tc = (tid & 15) * 4;
    {
        float acc[4][4] = {};
        gemm64<1, STR, 1, STR>(sRp, sBt, acc, tr, tc);
        #pragma unroll
        for (int r = 0; r < 4; r++)
            #pragma unroll
            for (int cq = 0; cq < 4; cq++)
                sMb[(tr + r) * STR + tc + cq] = (tc + cq <= tr + r) ? acc[r][cq] : 0.f;
        float acc2[4][4] = {};
        gemm64<1, STR, 1, STR>(sRp, sKt, acc2, tr, tc);
        #pragma unroll
        for (int r = 0; r < 4; r++)
            #pragma unroll
            for (int cq = 0; cq < 4; cq++)
                sMk[(tr + r) * STR + tc + cq] = (tc + cq <= tr + r) ? acc2[r][cq] : 0.f;
    }
    __syncthreads();
    #pragma unroll
    for (int i = 0; i < 16; i++) {
        int rr = seg * 16 + i;
        sBt[rr * STR + lane] = Ub[gbase + rr * 64 + lane];
        sKt[rr * STR + lane] = S0b[gbase + rr * 64 + lane];
    }
    __syncthreads();
    {
        float acc[4][4] = {};
        gemm64<1, STR, STR, 1>(sRp, sKt, acc, tr, tc);
        gemm64<STR, 1, 1, STR>(sMb, sBt, acc, tr, tc);
        gemm64<STR, 1, 1, STR>(sMk, sV,  acc, tr, tc);
        #pragma unroll
        for (int r = 0; r < 4; r++) {
            int p = tr + r;
            int t = dir ? (TMAX - (c64 + p)) : (c64 + p);
            float* yp = &yb[((size_t)(b * TT + t)) * CC + h * 64 + tc];
            float4 o;
            if (first) {
                o.x = wscale * acc[r][0];
                o.y = wscale * acc[r][1];
                o.z = wscale * acc[r][2];
                o.w = wscale * acc[r][3];
            } else {
                float4 old = *(float4*)yp;
                o.x = old.x + wscale * acc[r][0];
                o.y = old.y + wscale * acc[r][1];
                o.z = old.z + wscale * acc[r][2];
                o.w = old.w + wscale * acc[r][3];
            }
            *(float4*)yp = o;
        }
    }
}

// ---------------------------------------------------------------------------
// Post: GroupNorm + affine + bonus + gating; emits z as split bf16 (hi+lo).
// ---------------------------------------------------------------------------
__global__ __launch_bounds__(256) void post_kernel(
    const float* __restrict__ yb, const float* __restrict__ rbv,
    const float* __restrict__ kbv, const float* __restrict__ abv,
    const float* __restrict__ vbv, const float* __restrict__ gbv,
    const float* __restrict__ kaw, const float* __restrict__ r_k,
    const float* __restrict__ ln_w, const float* __restrict__ ln_b,
    unsigned short* __restrict__ zh, unsigned short* __restrict__ zl)
{
    const int t = blockIdx.x;
    const int tid = threadIdx.x;
    const size_t base = (size_t)t * CC;
    #pragma unroll
    for (int j = 0; j < 4; j++) {
        int c = tid + 256 * j;
        float y = yb[base + c];
        float s1 = waveReduceSum(y);
        float s2 = waveReduceSum(y * y);
        float mu = s1 * (1.0f / 64.0f);
        float var = s2 * (1.0f / 64.0f) - mu * mu;
        float yn = (y - mu) * rsqrtf(var + EPS_GN);
        yn = yn * ln_w[c] + ln_b[c];
        float rv = rbv[base + c];
        float kf = kbv[base + c] * (1.0f + (abv[base + c] - 1.0f) * kaw[c]);
        float vv = vbv[base + c];
        float dot = waveReduceSum(rv * kf * r_k[c]);
        yn += dot * vv;
        float z = yn * gbv[base + c];
        unsigned short h = f2bf(z);
        zh[base + c] = h;
        zl[base + c] = f2bf(z - bf2f(h));
    }
}

// ---------------------------------------------------------------------------
extern "C" void kernel_launch(void* const* d_in, const int* in_sizes, int n_in,
                              void* d_out, int out_size, void* d_ws, size_t ws_size,
                              hipStream_t stream)
{
    (void)in_sizes; (void)n_in; (void)out_size; (void)ws_size;
    const float* x      = (const float*)d_in[0];
    const float* vfirst = (const float*)d_in[1];
    const float* x_r    = (const float*)d_in[2];
    const float* x_w    = (const float*)d_in[3];
    const float* x_k    = (const float*)d_in[4];
    const float* x_v    = (const float*)d_in[5];
    const float* x_a    = (const float*)d_in[6];
    const float* x_g    = (const float*)d_in[7];
    const float* w0     = (const float*)d_in[8];
    const float* w1     = (const float*)d_in[9];
    const float* w2     = (const float*)d_in[10];
    const float* a0     = (const float*)d_in[11];
    const float* a1     = (const float*)d_in[12];
    const float* a2     = (const float*)d_in[13];
    const float* v0     = (const float*)d_in[14];
    const float* v1     = (const float*)d_in[15];
    const float* v2     = (const float*)d_in[16];
    const float* g1     = (const float*)d_in[17];
    const float* g2     = (const float*)d_in[18];
    const float* k_k    = (const float*)d_in[19];
    const float* k_a    = (const float*)d_in[20];
    const float* r_k    = (const float*)d_in[21];
    const float* Wr     = (const float*)d_in[22];
    const float* Wk     = (const float*)d_in[23];
    const float* Wv     = (const float*)d_in[24];
    const float* Wo     = (const float*)d_in[25];
    const float* ln_w   = (const float*)d_in[26];
    const float* ln_b   = (const float*)d_in[27];
    const float* alpha  = (const float*)d_in[28];

    const size_t SZ = (size_t)BT * CC;
    const size_t CHB = (size_t)1024 * 4096;
    float* ws   = (float*)d_ws;
    float* rb   = ws + 0 * SZ;
    float* kb   = ws + 1 * SZ;
    float* vb   = ws + 2 * SZ;
    float* decb = ws + 3 * SZ;
    float* ab   = ws + 4 * SZ;
    float* tw   = ws + 5 * SZ;
    float* ta   = tw + (size_t)BT * 64;
    float* tv   = ta + (size_t)BT * 64;
    float* tg   = tv + (size_t)BT * 32;
    float* Gb   = tg + (size_t)BT * 160;
    float* Ub   = Gb + CHB;
    float* Bpb  = Ub + CHB;
    float* Kpb  = Bpb + CHB;
    float* S0b  = Kpb + CHB;
    float* wcb  = S0b + CHB;
    float* Scur = wcb + CHB;                     // 128*4096 floats
    unsigned short* Whb = (unsigned short*)(Scur + (size_t)128 * 4096);
    unsigned short* Wlb = Whb + (size_t)CC * CC; // 2x 1M bf16 = 4 MB
    float* outp = (float*)d_out;
    float* gb   = outp;                          // g in out[0:SZ] until final GEMM
    float* yb   = outp + SZ;                     // y in out[SZ:2SZ] until v_first copy
    unsigned short* Ahp = (unsigned short*)(outp + SZ);   // projections phase
    unsigned short* Alp = Ahp + SZ;
    unsigned short* zAh = (unsigned short*)decb;          // z split (decb dead after scan)
    unsigned short* zAl = zAh + SZ;

    dim3 blk(256);
    const int NG_A = BT * (CC / 8);    // 2,097,152 groups
    const int NG_W = CC * (CC / 8);    // 131,072 groups
    dim3 gridA(NG_A / 256), gridW(NG_W / 256);
    dim3 gridG(1024);                  // 1D XCD-aware decode in kernel

    // big projections: split-convert then MFMA (3-term split-bf16)
    conv_split<false><<<gridW, blk, 0, stream>>>(Wr, nullptr, Whb, Wlb, NG_W);
    conv_split<true ><<<gridA, blk, 0, stream>>>(x, x_r, Ahp, Alp, NG_A);
    gemm_split_bf16<<<gridG, blk, 0, stream>>>(Ahp, Alp, Whb, Wlb, rb);
    conv_split<false><<<gridW, blk, 0, stream>>>(Wk, nullptr, Whb, Wlb, NG_W);
    conv_split<true ><<<gridA, blk, 0, stream>>>(x, x_k, Ahp, Alp, NG_A);
    gemm_split_bf16<<<gridG, blk, 0, stream>>>(Ahp, Alp, Whb, Wlb, kb);
    conv_split<false><<<gridW, blk, 0, stream>>>(Wv, nullptr, Whb, Wlb, NG_W);
    conv_split<true ><<<gridA, blk, 0, stream>>>(x, x_v, Ahp, Alp, NG_A);
    gemm_split_bf16<<<gridG, blk, 0, stream>>>(Ahp, Alp, Whb, Wlb, vb);

    // LoRA stage-1: one merged launch (w:tanh, a, v, g:sigmoid)
    lora1_all<<<dim3(BT / 128, 5), blk, 0, stream>>>(x, w1, a1, v1, g1,
        x_w, x_a, x_v, x_g, tw, ta, tv, tg);
    lora2_kernel<<<dim3(BT / LR), blk, 0, stream>>>(tw, ta, tv, tg, w2, a2, v2, g2,
        w0, a0, v0, vfirst, vb, decb, ab, gb);

    // chunked bidirectional WKV (wkvC first-writer batches store, rest accumulate)
    hipMemsetAsync(Scur, 0, (size_t)128 * 4096 * sizeof(float), stream);
    for (int cb = 0; cb < NB; ++cb) {
        wkvA<<<dim3(1024), blk, 0, stream>>>(kb, ab, vb, decb, k_k, k_a,
                                             Gb, Ub, Bpb, Kpb, wcb, cb);
        wkvB<<<dim3(128), blk, 0, stream>>>(vb, Gb, Ub, Bpb, Kpb, wcb, S0b, Scur, cb);
        wkvC<<<dim3(1024), blk, 0, stream>>>(rb, vb, Bpb, Kpb, Ub, S0b, wcb,
                                             alpha, yb, cb);
    }

    // groupnorm + bonus + gate -> split bf16 z (into decb's slot, dead now)
    post_kernel<<<dim3(BT), blk, 0, stream>>>(yb, rb, kb, ab, vb, gb, k_a, r_k,
                                              ln_w, ln_b, zAh, zAl);
    // final projection
    conv_split<false><<<gridW, blk, 0, stream>>>(Wo, nullptr, Whb, Wlb, NG_W);
    hipMemcpyAsync(outp + SZ, vfirst, SZ * sizeof(float),
                   hipMemcpyDeviceToDevice, stream);
    gemm_split_bf16<<<gridG, blk, 0, stream>>>(zAh, zAl, Whb, Wlb, outp);
}

// Round 10
// 4211.195 us; speedup vs baseline: 2.5763x; 1.0484x over previous
//
#include <hip/hip_runtime.h>
#include <hip/hip_bf16.h>
#include <math.h>

#define BB 4
#define TT 4096
#define CC 1024
#define HH 16
#define NN 64
#define BT (BB*TT)            // 16384 rows
#define EPS_GN 6.4e-4f        // 1e-5 * 8^2
#define TMAX (TT-1)
#define LCH 64                // chunk length
#define CB 8                  // chunks per batch
#define NB 8                  // batches  (LCH*CB*NB == TT)
#define STR 68                // padded LDS row stride (multiple of 4 -> b128)

typedef __attribute__((ext_vector_type(8))) short bf16x8;
typedef __attribute__((ext_vector_type(4))) float f32x4;

__device__ __forceinline__ float sigmoidf_(float x) {
    return 1.0f / (1.0f + expf(-x));
}

__device__ __forceinline__ float waveReduceSum(float v) {
    #pragma unroll
    for (int off = 32; off > 0; off >>= 1)
        v += __shfl_xor(v, off, 64);
    return v;
}

__device__ __forceinline__ unsigned short f2bf(float f) {
    unsigned u = __float_as_uint(f);
    u += 0x7FFFu + ((u >> 16) & 1u);
    return (unsigned short)(u >> 16);
}
__device__ __forceinline__ float bf2f(unsigned short h) {
    return __uint_as_float(((unsigned)h) << 16);
}

__device__ __forceinline__ void gll16(const unsigned short* g, unsigned short* l) {
    __builtin_amdgcn_global_load_lds(
        (__attribute__((address_space(1))) void*)(g),
        (__attribute__((address_space(3))) void*)(l), 16, 0, 0);
}

// acc[r][c] += sum_k A(tr+r,k)*B(tc+c,k); element A(i,k)=A[i*SA0+k*SA1].
// All LDS traffic as b128 (requires STR%4==0, tr/tc%4==0).
template<int SA0,int SA1,int SB0,int SB1>
__device__ __forceinline__ void gemm64(const float* __restrict__ A,
                                       const float* __restrict__ B,
                                       float acc[4][4], int tr, int tc) {
    #pragma unroll 2
    for (int kx = 0; kx < 64; kx += 4) {
        float a_[4][4];   // [r][kk]
        if (SA0 == 1) {
            #pragma unroll
            for (int kk = 0; kk < 4; kk++) {
                float4 t = *(const float4*)&A[tr + (kx + kk) * SA1];
                a_[0][kk] = t.x; a_[1][kk] = t.y; a_[2][kk] = t.z; a_[3][kk] = t.w;
            }
        } else {
            #pragma unroll
            for (int r = 0; r < 4; r++) {
                float4 t = *(const float4*)&A[(tr + r) * SA0 + kx];
                a_[r][0] = t.x; a_[r][1] = t.y; a_[r][2] = t.z; a_[r][3] = t.w;
            }
        }
        float b_[4][4];   // [cq][kk]
        if (SB0 == 1) {
            #pragma unroll
            for (int kk = 0; kk < 4; kk++) {
                float4 t = *(const float4*)&B[tc + (kx + kk) * SB1];
                b_[0][kk] = t.x; b_[1][kk] = t.y; b_[2][kk] = t.z; b_[3][kk] = t.w;
            }
        } else {
            #pragma unroll
            for (int cq = 0; cq < 4; cq++) {
                float4 t = *(const float4*)&B[(tc + cq) * SB0 + kx];
                b_[cq][0] = t.x; b_[cq][1] = t.y; b_[cq][2] = t.z; b_[cq][3] = t.w;
            }
        }
        #pragma unroll
        for (int r = 0; r < 4; r++)
            #pragma unroll
            for (int cq = 0; cq < 4; cq++)
                #pragma unroll
                for (int kk = 0; kk < 4; kk++)
                    acc[r][cq] = fmaf(a_[r][kk], b_[cq][kk], acc[r][cq]);
    }
}

// ---------------------------------------------------------------------------
// Split-conversion: fp32 (rows x CC, k-contig) -> bf16 hi + bf16 lo residual.
// ---------------------------------------------------------------------------
template<bool DOMIX>
__global__ __launch_bounds__(256) void conv_split(
    const float* __restrict__ X, const float* __restrict__ mix,
    unsigned short* __restrict__ Hi, unsigned short* __restrict__ Lo,
    int ngroups)
{
    int g = blockIdx.x * 256 + threadIdx.x;
    if (g >= ngroups) return;
    int m = g >> 7;                 // CC/8 = 128 groups per row
    int k = (g & 127) * 8;
    const float* px = X + (size_t)m * CC + k;
    float a[8];
    {
        float4 x0 = *(const float4*)px;
        float4 x1 = *(const float4*)(px + 4);
        a[0]=x0.x; a[1]=x0.y; a[2]=x0.z; a[3]=x0.w;
        a[4]=x1.x; a[5]=x1.y; a[6]=x1.z; a[7]=x1.w;
    }
    if (DOMIX) {
        float4 p0, p1;
        if ((m & (TT - 1)) == 0) {
            p0 = make_float4(0.f,0.f,0.f,0.f); p1 = p0;
        } else {
            p0 = *(const float4*)(px - CC);
            p1 = *(const float4*)(px - CC + 4);
        }
        float4 m0 = *(const float4*)(mix + k);
        float4 m1 = *(const float4*)(mix + k + 4);
        float pv[8] = {p0.x,p0.y,p0.z,p0.w,p1.x,p1.y,p1.z,p1.w};
        float mv[8] = {m0.x,m0.y,m0.z,m0.w,m1.x,m1.y,m1.z,m1.w};
        #pragma unroll
        for (int j = 0; j < 8; j++) a[j] += (pv[j] - a[j]) * mv[j];
    }
    unsigned short hi[8], lo[8];
    #pragma unroll
    for (int j = 0; j < 8; j++) {
        hi[j] = f2bf(a[j]);
        lo[j] = f2bf(a[j] - bf2f(hi[j]));
    }
    uint4 H, L;
    H.x = (unsigned)hi[0] | ((unsigned)hi[1] << 16);
    H.y = (unsigned)hi[2] | ((unsigned)hi[3] << 16);
    H.z = (unsigned)hi[4] | ((unsigned)hi[5] << 16);
    H.w = (unsigned)hi[6] | ((unsigned)hi[7] << 16);
    L.x = (unsigned)lo[0] | ((unsigned)lo[1] << 16);
    L.y = (unsigned)lo[2] | ((unsigned)lo[3] << 16);
    L.z = (unsigned)lo[4] | ((unsigned)lo[5] << 16);
    L.w = (unsigned)lo[6] | ((unsigned)lo[7] << 16);
    *(uint4*)(Hi + (size_t)g * 8) = H;
    *(uint4*)(Lo + (size_t)g * 8) = L;
}

// ---------------------------------------------------------------------------
// Stage-2 weight transpose+split: W (K,CC) n-contig -> (CC,Kp) k-contig hi/lo
// with zero pad for k in [K, Kp).
// ---------------------------------------------------------------------------
__global__ __launch_bounds__(256) void conv_w2(
    const float* __restrict__ W, int K, int Kp,
    unsigned short* __restrict__ Hi, unsigned short* __restrict__ Lo)
{
    int idx = blockIdx.x * 256 + threadIdx.x;
    int nk8 = Kp >> 3;
    if (idx >= CC * nk8) return;
    int n = idx / nk8, k0 = (idx - n * nk8) * 8;
    unsigned short h8[8], l8[8];
    #pragma unroll
    for (int j = 0; j < 8; j++) {
        int k = k0 + j;
        float v = (k < K) ? W[(size_t)k * CC + n] : 0.f;
        h8[j] = f2bf(v);
        l8[j] = f2bf(v - bf2f(h8[j]));
    }
    uint4 H, L;
    H.x = (unsigned)h8[0] | ((unsigned)h8[1] << 16);
    H.y = (unsigned)h8[2] | ((unsigned)h8[3] << 16);
    H.z = (unsigned)h8[4] | ((unsigned)h8[5] << 16);
    H.w = (unsigned)h8[6] | ((unsigned)h8[7] << 16);
    L.x = (unsigned)l8[0] | ((unsigned)l8[1] << 16);
    L.y = (unsigned)l8[2] | ((unsigned)l8[3] << 16);
    L.z = (unsigned)l8[4] | ((unsigned)l8[5] << 16);
    L.w = (unsigned)l8[6] | ((unsigned)l8[7] << 16);
    *(uint4*)(Hi + (size_t)n * Kp + k0) = H;
    *(uint4*)(Lo + (size_t)n * Kp + k0) = L;
}

// ---------------------------------------------------------------------------
// Split-bf16 MFMA GEMM for big projections (unchanged — passed)
// ---------------------------------------------------------------------------
__global__ __launch_bounds__(256, 2) void gemm_split_bf16(
    const unsigned short* __restrict__ Ah, const unsigned short* __restrict__ Al,
    const unsigned short* __restrict__ Bh, const unsigned short* __restrict__ Bl,
    float* __restrict__ Out)
{
    __shared__ __align__(16) unsigned short lds[4][128 * 64];  // Ah,Al,Bh,Bl
    const int tid = threadIdx.x;
    const int lane = tid & 63;
    const int wave = tid >> 6;
    const int wm = (wave >> 1) * 64, wn = (wave & 1) * 64;
    const int wg = blockIdx.x;
    const int xcd = wg & 7;
    const int j = wg >> 3;
    const int m0 = ((j >> 3) * 8 + xcd) * 128;
    const int n0 = (j & 7) * 128;

    f32x4 acc[4][4];
    #pragma unroll
    for (int i = 0; i < 4; i++)
        #pragma unroll
        for (int jj = 0; jj < 4; jj++)
            acc[i][jj] = (f32x4){0.f, 0.f, 0.f, 0.f};

    for (int k0 = 0; k0 < CC; k0 += 64) {
        #pragma unroll
        for (int p = 0; p < 4; p++) {
            const unsigned short* sbase = (p == 0) ? Ah : (p == 1) ? Al
                                        : (p == 2) ? Bh : Bl;
            const int rbase = (p < 2) ? m0 : n0;
            #pragma unroll
            for (int i = 0; i < 4; i++) {
                int slot = i * 256 + wave * 64 + lane;
                int row = slot >> 3, gsl = slot & 7;
                const unsigned short* src = sbase
                    + (size_t)(rbase + row) * CC + k0 + ((gsl ^ (row & 7)) * 8);
                gll16(src, &lds[p][(size_t)(i * 256 + wave * 64) * 8]);
            }
        }
        __syncthreads();

        #pragma unroll
        for (int ks = 0; ks < 2; ks++) {
            bf16x8 bhf[4], blf[4];
            #pragma unroll
            for (int nt = 0; nt < 4; nt++) {
                int col = wn + nt * 16 + (lane & 15);
                int gk = ks * 4 + (lane >> 4);
                int el = col * 64 + ((gk ^ (col & 7)) * 8);
                bhf[nt] = *(const bf16x8*)&lds[2][el];
                blf[nt] = *(const bf16x8*)&lds[3][el];
            }
            #pragma unroll
            for (int mt = 0; mt < 4; mt++) {
                int row = wm + mt * 16 + (lane & 15);
                int gk = ks * 4 + (lane >> 4);
                int el = row * 64 + ((gk ^ (row & 7)) * 8);
                bf16x8 ahf = *(const bf16x8*)&lds[0][el];
                bf16x8 alf = *(const bf16x8*)&lds[1][el];
                #pragma unroll
                for (int nt = 0; nt < 4; nt++) {
                    acc[mt][nt] = __builtin_amdgcn_mfma_f32_16x16x32_bf16(
                        ahf, bhf[nt], acc[mt][nt], 0, 0, 0);
                    acc[mt][nt] = __builtin_amdgcn_mfma_f32_16x16x32_bf16(
                        alf, bhf[nt], acc[mt][nt], 0, 0, 0);
                    acc[mt][nt] = __builtin_amdgcn_mfma_f32_16x16x32_bf16(
                        ahf, blf[nt], acc[mt][nt], 0, 0, 0);
                }
            }
        }
        __syncthreads();
    }
    float* cf = (float*)&lds[0][0];    // 64*132*4 = 33.8 KB
    #pragma unroll
    for (int pass = 0; pass < 2; ++pass) {
        __syncthreads();
        if ((wave >> 1) == pass) {
            #pragma unroll
            for (int mt = 0; mt < 4; mt++)
                #pragma unroll
                for (int nt = 0; nt < 4; nt++)
                    #pragma unroll
                    for (int r = 0; r < 4; r++) {
                        int row = mt * 16 + (lane >> 4) * 4 + r;
                        int col = wn + nt * 16 + (lane & 15);
                        cf[row * 132 + col] = acc[mt][nt][r];
                    }
        }
        __syncthreads();
        #pragma unroll
        for (int i = 0; i < 8; i++) {
            int g = tid + 256 * i;
            int row = g >> 5, c4 = (g & 31) * 4;
            float4 v = *(float4*)&cf[row * 132 + c4];
            *(float4*)&Out[(size_t)(m0 + pass * 64 + row) * CC + n0 + c4] = v;
        }
    }
}

// ---------------------------------------------------------------------------
// LoRA stage-1, merged; epilogue emits split-bf16 activations (K-padded).
// y=0: w1 (64, tanh, Kp=64)  y=1: a1 (64)  y=2: v1 (32, Kp=64)
// y=3/4: g1 (160, sigmoid, Kp=192).
// ---------------------------------------------------------------------------
__global__ __launch_bounds__(256) void lora1_all(
    const float* __restrict__ X,
    const float* __restrict__ w1, const float* __restrict__ a1,
    const float* __restrict__ v1, const float* __restrict__ g1,
    const float* __restrict__ xw, const float* __restrict__ xa,
    const float* __restrict__ xv, const float* __restrict__ xg,
    unsigned short* __restrict__ awh, unsigned short* __restrict__ awl,
    unsigned short* __restrict__ aah, unsigned short* __restrict__ aal,
    unsigned short* __restrict__ avh, unsigned short* __restrict__ avl,
    unsigned short* __restrict__ agh, unsigned short* __restrict__ agl)
{
    const int y = blockIdx.y;
    const float* W; const float* mix; unsigned short *Hi, *Lo;
    int Ncols, n0, epi, Kp;
    if (y == 0)      { W=w1; mix=xw; Hi=awh; Lo=awl; Ncols=64;  n0=0;   epi=1; Kp=64;  }
    else if (y == 1) { W=a1; mix=xa; Hi=aah; Lo=aal; Ncols=64;  n0=0;   epi=0; Kp=64;  }
    else if (y == 2) { W=v1; mix=xv; Hi=avh; Lo=avl; Ncols=32;  n0=0;   epi=0; Kp=64;  }
    else if (y == 3) { W=g1; mix=xg; Hi=agh; Lo=agl; Ncols=160; n0=0;   epi=2; Kp=192; }
    else             { W=g1; mix=xg; Hi=agh; Lo=agl; Ncols=160; n0=128; epi=2; Kp=192; }

    __shared__ float As[8][128];
    __shared__ float Bs[8][128];
    const int tid = threadIdx.x;
    const int m0 = blockIdx.x * 128;
    const int sr  = tid >> 1;
    const int skq = (tid & 1) * 4;
    const int bkr = tid >> 5;
    const int bnq = (tid & 31) * 4;
    const int tm = (tid >> 4) * 8;
    const int tn = (tid & 15) * 8;

    float acc[8][8];
    #pragma unroll
    for (int i = 0; i < 8; i++)
        #pragma unroll
        for (int j = 0; j < 8; j++) acc[i][j] = 0.f;

    auto ldAm = [&](int gm, int gk) -> float4 {
        const float* px = X + (size_t)gm * CC + gk;
        float4 xvv = *(const float4*)px;
        float4 pv;
        if ((gm & (TT - 1)) == 0) pv = make_float4(0.f, 0.f, 0.f, 0.f);
        else pv = *(const float4*)(px - CC);
        float4 mv = *(const float4*)(mix + gk);
        xvv.x += (pv.x - xvv.x) * mv.x;
        xvv.y += (pv.y - xvv.y) * mv.y;
        xvv.z += (pv.z - xvv.z) * mv.z;
        xvv.w += (pv.w - xvv.w) * mv.w;
        return xvv;
    };

    float4 aR, bR;
    aR = ldAm(m0 + sr, skq);
    {
        int gn = n0 + bnq;
        bR = (gn < Ncols) ? *(const float4*)(W + (size_t)bkr * Ncols + gn)
                          : make_float4(0.f, 0.f, 0.f, 0.f);
    }

    for (int k0 = 0; k0 < CC; k0 += 8) {
        __syncthreads();
        As[skq + 0][sr] = aR.x;
        As[skq + 1][sr] = aR.y;
        As[skq + 2][sr] = aR.z;
        As[skq + 3][sr] = aR.w;
        *(float4*)&Bs[bkr][bnq] = bR;
        __syncthreads();

        if (k0 + 8 < CC) {
            aR = ldAm(m0 + sr, k0 + 8 + skq);
            int gn = n0 + bnq;
            bR = (gn < Ncols) ? *(const float4*)(W + (size_t)(k0 + 8 + bkr) * Ncols + gn)
                              : make_float4(0.f, 0.f, 0.f, 0.f);
        }

        #pragma unroll
        for (int kk = 0; kk < 8; ++kk) {
            float av[8], bv[8];
            *(float4*)&av[0] = *(const float4*)&As[kk][tm];
            *(float4*)&av[4] = *(const float4*)&As[kk][tm + 4];
            *(float4*)&bv[0] = *(const float4*)&Bs[kk][tn];
            *(float4*)&bv[4] = *(const float4*)&Bs[kk][tn + 4];
            #pragma unroll
            for (int i = 0; i < 8; i++)
                #pragma unroll
                for (int j = 0; j < 8; j++)
                    acc[i][j] = fmaf(av[i], bv[j], acc[i][j]);
        }
    }

    #pragma unroll
    for (int i = 0; i < 8; i++) {
        int gm = m0 + tm + i;
        int gn = n0 + tn;
        if (gn < Kp) {
            unsigned short h8[8], l8[8];
            #pragma unroll
            for (int j = 0; j < 8; j++) {
                float v = 0.f;
                if (gn + j < Ncols) {
                    v = acc[i][j];
                    if (epi == 1) v = tanhf(v);
                    else if (epi == 2) v = sigmoidf_(v);
                }
                h8[j] = f2bf(v);
                l8[j] = f2bf(v - bf2f(h8[j]));
            }
            uint4 H, L;
            H.x = (unsigned)h8[0] | ((unsigned)h8[1] << 16);
            H.y = (unsigned)h8[2] | ((unsigned)h8[3] << 16);
            H.z = (unsigned)h8[4] | ((unsigned)h8[5] << 16);
            H.w = (unsigned)h8[6] | ((unsigned)h8[7] << 16);
            L.x = (unsigned)l8[0] | ((unsigned)l8[1] << 16);
            L.y = (unsigned)l8[2] | ((unsigned)l8[3] << 16);
            L.z = (unsigned)l8[4] | ((unsigned)l8[5] << 16);
            L.w = (unsigned)l8[6] | ((unsigned)l8[7] << 16);
            *(uint4*)(Hi + (size_t)gm * Kp + gn) = H;
            *(uint4*)(Lo + (size_t)gm * Kp + gn) = L;
        }
    }
}

// ---------------------------------------------------------------------------
// LoRA stage-2 on MFMA: Out[BT][1024] = A (BT,Kp) @ W (1024,Kp)^T, split-bf16
// 3-term; blockIdx.z selects {w->dec, a->ab, v->vbuf blend, g->gb} with the
// elementwise epilogue fused into the LDS-staged coalesced store.
// ---------------------------------------------------------------------------
__global__ __launch_bounds__(256, 2) void lora2_mfma(
    const unsigned short* __restrict__ awh, const unsigned short* __restrict__ awl,
    const unsigned short* __restrict__ aah, const unsigned short* __restrict__ aal,
    const unsigned short* __restrict__ avh, const unsigned short* __restrict__ avl,
    const unsigned short* __restrict__ agh, const unsigned short* __restrict__ agl,
    const unsigned short* __restrict__ w2h, const unsigned short* __restrict__ w2l,
    const unsigned short* __restrict__ a2h, const unsigned short* __restrict__ a2l,
    const unsigned short* __restrict__ v2h, const unsigned short* __restrict__ v2l,
    const unsigned short* __restrict__ g2h, const unsigned short* __restrict__ g2l,
    const float* __restrict__ w0, const float* __restrict__ a0v,
    const float* __restrict__ v0v, const float* __restrict__ v_first,
    float* __restrict__ decb, float* __restrict__ ab,
    float* __restrict__ vbuf, float* __restrict__ gb)
{
    __shared__ __align__(16) unsigned short lds[4][128 * 64];
    const int z = blockIdx.z;
    const unsigned short *Ah, *Al, *Bh, *Bl; int Kp;
    if (z == 0)      { Ah = awh; Al = awl; Bh = w2h; Bl = w2l; Kp = 64;  }
    else if (z == 1) { Ah = aah; Al = aal; Bh = a2h; Bl = a2l; Kp = 64;  }
    else if (z == 2) { Ah = avh; Al = avl; Bh = v2h; Bl = v2l; Kp = 64;  }
    else             { Ah = agh; Al = agl; Bh = g2h; Bl = g2l; Kp = 192; }

    const int tid = threadIdx.x, lane = tid & 63, wave = tid >> 6;
    const int wm = (wave >> 1) * 64, wn = (wave & 1) * 64;
    const int m0 = blockIdx.x * 128, n0 = blockIdx.y * 128;

    f32x4 acc[4][4];
    #pragma unroll
    for (int i = 0; i < 4; i++)
        #pragma unroll
        for (int jj = 0; jj < 4; jj++)
            acc[i][jj] = (f32x4){0.f, 0.f, 0.f, 0.f};

    for (int k0 = 0; k0 < Kp; k0 += 64) {
        #pragma unroll
        for (int p = 0; p < 4; p++) {
            const unsigned short* sbase = (p == 0) ? Ah : (p == 1) ? Al
                                        : (p == 2) ? Bh : Bl;
            const int rbase = (p < 2) ? m0 : n0;
            #pragma unroll
            for (int i = 0; i < 4; i++) {
                int slot = i * 256 + wave * 64 + lane;
                int row = slot >> 3, gsl = slot & 7;
                const unsigned short* src = sbase
                    + (size_t)(rbase + row) * Kp + k0 + ((gsl ^ (row & 7)) * 8);
                gll16(src, &lds[p][(size_t)(i * 256 + wave * 64) * 8]);
            }
        }
        __syncthreads();

        #pragma unroll
        for (int ks = 0; ks < 2; ks++) {
            bf16x8 bhf[4], blf[4];
            #pragma unroll
            for (int nt = 0; nt < 4; nt++) {
                int col = wn + nt * 16 + (lane & 15);
                int gk = ks * 4 + (lane >> 4);
                int el = col * 64 + ((gk ^ (col & 7)) * 8);
                bhf[nt] = *(const bf16x8*)&lds[2][el];
                blf[nt] = *(const bf16x8*)&lds[3][el];
            }
            #pragma unroll
            for (int mt = 0; mt < 4; mt++) {
                int row = wm + mt * 16 + (lane & 15);
                int gk = ks * 4 + (lane >> 4);
                int el = row * 64 + ((gk ^ (row & 7)) * 8);
                bf16x8 ahf = *(const bf16x8*)&lds[0][el];
                bf16x8 alf = *(const bf16x8*)&lds[1][el];
                #pragma unroll
                for (int nt = 0; nt < 4; nt++) {
                    acc[mt][nt] = __builtin_amdgcn_mfma_f32_16x16x32_bf16(
                        ahf, bhf[nt], acc[mt][nt], 0, 0, 0);
                    acc[mt][nt] = __builtin_amdgcn_mfma_f32_16x16x32_bf16(
                        alf, bhf[nt], acc[mt][nt], 0, 0, 0);
                    acc[mt][nt] = __builtin_amdgcn_mfma_f32_16x16x32_bf16(
                        ahf, blf[nt], acc[mt][nt], 0, 0, 0);
                }
            }
        }
        __syncthreads();
    }
    // LDS-staged epilogue with fused per-z elementwise ops
    float* cf = (float*)&lds[0][0];
    #pragma unroll
    for (int pass = 0; pass < 2; ++pass) {
        __syncthreads();
        if ((wave >> 1) == pass) {
            #pragma unroll
            for (int mt = 0; mt < 4; mt++)
                #pragma unroll
                for (int nt = 0; nt < 4; nt++)
                    #pragma unroll
                    for (int r = 0; r < 4; r++) {
                        int row = mt * 16 + (lane >> 4) * 4 + r;
                        int col = wn + nt * 16 + (lane & 15);
                        cf[row * 132 + col] = acc[mt][nt][r];
                    }
        }
        __syncthreads();
        #pragma unroll
        for (int i = 0; i < 8; i++) {
            int g = tid + 256 * i;
            int row = g >> 5, c4 = (g & 31) * 4;
            float4 v = *(float4*)&cf[row * 132 + c4];
            int gm = m0 + pass * 64 + row;
            int c = n0 + c4;
            size_t off = (size_t)gm * CC + c;
            if (z == 0) {
                float4 w0q = *(const float4*)(w0 + c);
                float4 o;
                o.x = expf(-expf(-log1pf(expf(-(w0q.x + v.x))) - 0.5f));
                o.y = expf(-expf(-log1pf(expf(-(w0q.y + v.y))) - 0.5f));
                o.z = expf(-expf(-log1pf(expf(-(w0q.z + v.z))) - 0.5f));
                o.w = expf(-expf(-log1pf(expf(-(w0q.w + v.w))) - 0.5f));
                *(float4*)&decb[off] = o;
            } else if (z == 1) {
                float4 a0q = *(const float4*)(a0v + c);
                float4 o;
                o.x = sigmoidf_(a0q.x + v.x);
                o.y = sigmoidf_(a0q.y + v.y);
                o.z = sigmoidf_(a0q.z + v.z);
                o.w = sigmoidf_(a0q.w + v.w);
                *(float4*)&ab[off] = o;
            } else if (z == 2) {
                float4 v0q = *(const float4*)(v0v + c);
                float4 vr = *(const float4*)&vbuf[off];
                float4 vf = *(const float4*)&v_first[off];
                float4 o;
                o.x = vr.x + (vf.x - vr.x) * sigmoidf_(v0q.x + v.x);
                o.y = vr.y + (vf.y - vr.y) * sigmoidf_(v0q.y + v.y);
                o.z = vr.z + (vf.z - vr.z) * sigmoidf_(v0q.z + v.z);
                o.w = vr.w + (vf.w - vr.w) * sigmoidf_(v0q.w + v.w);
                *(float4*)&vbuf[off] = o;
            } else {
                *(float4*)&gb[off] = v;
            }
        }
    }
}

// ---------------------------------------------------------------------------
// Chunked WKV phases A, B, C (unchanged from round 8 — passed)
// ---------------------------------------------------------------------------
__global__ __launch_bounds__(256) void wkvA(
    const float* __restrict__ kb, const float* __restrict__ ab,
    const float* __restrict__ vb, const float* __restrict__ decb,
    const float* __restrict__ k_k, const float* __restrict__ k_a,
    float* __restrict__ Gb, float* __restrict__ Ub,
    float* __restrict__ Bpb, float* __restrict__ Kpb,
    float* __restrict__ wcb, int cb)
{
    __shared__ __align__(16) float sm[6][64 * STR];
    __shared__ float sSeg[4][64];
    const int inst = blockIdx.x;
    const int bhd = inst >> 3, lc = inst & 7;
    const int dir = bhd & 1, bh = bhd >> 1, b = bh >> 4, h = bh & 15;
    const int c64 = (cb * CB + lc) * LCH;
    const int tid = threadIdx.x;
    const int lane = tid & 63, seg = tid >> 6;
    const int ch = h * 64 + lane;
    const size_t gbase = (size_t)inst * 4096;
    float* sWC = sm[0];
    float* sAp = sm[1];
    float* sBp = sm[2];
    float* sKp = sm[3];
    float* sX  = sm[4];
    float* sYk = sm[5];

    {
        float run = 1.f; float loc[16];
        #pragma unroll
        for (int i = 0; i < 16; i++) {
            int p = seg * 16 + i;
            int t = dir ? (TMAX - (c64 + p)) : (c64 + p);
            float d = decb[((size_t)(b * TT + t)) * CC + ch];
            run *= d; loc[i] = run;
        }
        sSeg[seg][lane] = run;
        __syncthreads();
        float pre = 1.f;
        for (int s2 = 0; s2 < seg; ++s2) pre *= sSeg[s2][lane];
        #pragma unroll
        for (int i = 0; i < 16; i++) {
            int p = seg * 16 + i;
            float wcv = pre * loc[i];
            sWC[p * STR + lane] = wcv;
            wcb[gbase + p * 64 + lane] = wcv;
        }
    }
    __syncthreads();
    {
        const float kkl = k_k[ch], kal = k_a[ch];
        for (int i = 0; i < 16; i++) {
            int p = seg * 16 + i;
            int t = dir ? (TMAX - (c64 + p)) : (c64 + p);
            size_t ra = ((size_t)(b * TT + t)) * CC + ch;
            float kraw = kb[ra], asig = ab[ra];
            float kkv = kraw * kkl;
            float s2 = waveReduceSum(kkv * kkv);
            float kkn = kkv / fmaxf(sqrtf(s2), 1e-12f);
            float wc = sWC[p * STR + lane];
            float wx = (p == 0) ? 1.f : sWC[(p - 1) * STR + lane];
            float apv = -kkn * wx;
            float bpv = kkn * asig / wc;
            float kpv = kraw * (1.f + (asig - 1.f) * kal) / wc;
            sAp[lane * STR + p] = apv;
            sBp[lane * STR + p] = bpv;
            sKp[lane * STR + p] = kpv;
            Bpb[gbase + p * 64 + lane] = bpv;
            Kpb[gbase + p * 64 + lane] = kpv;
        }
    }
    __syncthreads();

    const int tr = (tid >> 4) * 4, tc = (tid & 15) * 4;
    #pragma unroll
    for (int i = 0; i < 16; i++) {
        int p = seg * 16 + i;
        int t = dir ? (TMAX - (c64 + p)) : (c64 + p);
        sWC[p * STR + lane] = vb[((size_t)(b * TT + t)) * CC + ch];
    }
    {
        float acc[4][4] = {};
        gemm64<1, STR, 1, STR>(sAp, sBp, acc, tr, tc);
        #pragma unroll
        for (int r = 0; r < 4; r++)
            #pragma unroll
            for (int cq = 0; cq < 4; cq++)
                sX[(tr + r) * STR + tc + cq] = (tc + cq < tr + r) ? acc[r][cq] : 0.f;
    }
    {
        float acc[4][4] = {};
        gemm64<1, STR, 1, STR>(sAp, sKp, acc, tr, tc);
        #pragma unroll
        for (int r = 0; r < 4; r++)
            #pragma unroll
            for (int cq = 0; cq < 4; cq++)
                sYk[(tr + r) * STR + tc + cq] = (tc + cq < tr + r) ? acc[r][cq] : 0.f;
    }
    __syncthreads();
    {
        float acc[4][4] = {};
        gemm64<STR, 1, 1, STR>(sYk, sWC, acc, tr, tc);
        __syncthreads();
        #pragma unroll
        for (int r = 0; r < 4; r++)
            #pragma unroll
            for (int cq = 0; cq < 4; cq++)
                sKp[(tr + r) * STR + tc + cq] = acc[r][cq];
    }
    __syncthreads();
    if (tid < 64) {
        for (int r = 0; r < 64; ++r) {
            float acc = 0.f;
            for (int s = 0; s < r; ++s)
                acc = fmaf(sX[r * STR + s], sBp[s * STR + tid], acc);
            sBp[r * STR + tid] = (r == tid) ? 1.f : acc;
        }
    }
    __syncthreads();
    {
        float accG[4][4] = {};
        gemm64<STR, 1, STR, 1>(sBp, sAp, accG, tr, tc);
        float accU[4][4] = {};
        gemm64<STR, 1, 1, STR>(sBp, sKp, accU, tr, tc);
        #pragma unroll
        for (int r = 0; r < 4; r++) {
            *(float4*)&Gb[gbase + (tr + r) * 64 + tc] =
                make_float4(accG[r][0], accG[r][1], accG[r][2], accG[r][3]);
            *(float4*)&Ub[gbase + (tr + r) * 64 + tc] =
                make_float4(accU[r][0], accU[r][1], accU[r][2], accU[r][3]);
        }
    }
}

__global__ __launch_bounds__(256) void wkvB(
    const float* __restrict__ vb,
    const float* __restrict__ Gb, float* __restrict__ Ub,
    const float* __restrict__ Bpb, const float* __restrict__ Kpb,
    const float* __restrict__ wcb, float* __restrict__ S0b,
    float* __restrict__ Scur, int cb)
{
    __shared__ __align__(16) float sS[64 * STR];
    __shared__ __align__(16) float sG[64 * STR];
    __shared__ __align__(16) float sU[64 * STR];
    __shared__ __align__(16) float sB[64 * STR];
    __shared__ __align__(16) float sK[64 * STR];
    __shared__ __align__(16) float sV[64 * STR];
    const int bhd = blockIdx.x;
    const int dir = bhd & 1, bh = bhd >> 1, b = bh >> 4, h = bh & 15;
    const int tid = threadIdx.x;
    const int tr = (tid >> 4) * 4, tc = (tid & 15) * 4;

    for (int i = tid; i < 4096; i += 256)
        sS[(i >> 6) * STR + (i & 63)] = Scur[(size_t)bhd * 4096 + i];
    __syncthreads();

    for (int lc = 0; lc < CB; ++lc) {
        const int inst = bhd * CB + lc;
        const size_t gbase = (size_t)inst * 4096;
        const int c64 = (cb * CB + lc) * LCH;
        for (int i = tid; i < 4096; i += 256) {
            int rr = i >> 6, jj = i & 63;
            sG[rr * STR + jj] = Gb[gbase + i];
            sB[rr * STR + jj] = Bpb[gbase + i];
            sK[rr * STR + jj] = Kpb[gbase + i];
            int t = dir ? (TMAX - (c64 + rr)) : (c64 + rr);
            sV[rr * STR + jj] = vb[((size_t)(b * TT + t)) * CC + h * 64 + jj];
            S0b[gbase + i] = sS[rr * STR + jj];
        }
        __syncthreads();
        {
            float acc[4][4];
            #pragma unroll
            for (int r = 0; r < 4; r++) {
                float4 u0 = *(const float4*)&Ub[gbase + (tr + r) * 64 + tc];
                acc[r][0] = u0.x; acc[r][1] = u0.y; acc[r][2] = u0.z; acc[r][3] = u0.w;
            }
            gemm64<STR, 1, STR, 1>(sG, sS, acc, tr, tc);
            #pragma unroll
            for (int r = 0; r < 4; r++) {
                #pragma unroll
                for (int cq = 0; cq < 4; cq++) sU[(tr + r) * STR + tc + cq] = acc[r][cq];
                *(float4*)&Ub[gbase + (tr + r) * 64 + tc] =
                    make_float4(acc[r][0], acc[r][1], acc[r][2], acc[r][3]);
            }
        }
        __syncthreads();
        {
            float acc[4][4] = {};
            gemm64<1, STR, 1, STR>(sU, sB, acc, tr, tc);
            gemm64<1, STR, 1, STR>(sV, sK, acc, tr, tc);
            float w63[4];
            #pragma unroll
            for (int cq = 0; cq < 4; cq++) w63[cq] = wcb[gbase + 63 * 64 + tc + cq];
            #pragma unroll
            for (int r = 0; r < 4; r++)
                #pragma unroll
                for (int cq = 0; cq < 4; cq++) {
                    float sv = sS[(tr + r) * STR + tc + cq];
                    acc[r][cq] = (sv + acc[r][cq]) * w63[cq];
                }
            #pragma unroll
            for (int r = 0; r < 4; r++)
                #pragma unroll
                for (int cq = 0; cq < 4; cq++)
                    sS[(tr + r) * STR + tc + cq] = acc[r][cq];
        }
        __syncthreads();
    }
    for (int i = tid; i < 4096; i += 256)
        Scur[(size_t)bhd * 4096 + i] = sS[(i >> 6) * STR + (i & 63)];
}

__global__ __launch_bounds__(256) void wkvC(
    const float* __restrict__ rb, const float* __restrict__ vb,
    const float* __restrict__ Bpb, const float* __restrict__ Kpb,
    const float* __restrict__ Ub, const float* __restrict__ S0b,
    const float* __restrict__ wcb, const float* __restrict__ alpha_p,
    float* __restrict__ yb, int cb)
{
    __shared__ __align__(16) float sm[6][64 * STR];
    float* sRp = sm[0];
    float* sBt = sm[1];
    float* sKt = sm[2];
    float* sMb = sm[3];
    float* sMk = sm[4];
    float* sV  = sm[5];
    const int inst = blockIdx.x;
    const int bhd = inst >> 3, lc = inst & 7;
    const int dir = bhd & 1, bh = bhd >> 1, b = bh >> 4, h = bh & 15;
    const int c64 = (cb * CB + lc) * LCH;
    const int tid = threadIdx.x, lane = tid & 63, seg = tid >> 6;
    const size_t gbase = (size_t)inst * 4096;
    const float alpha = alpha_p[0];
    const float wscale = dir ? (1.f - alpha) : alpha;
    const bool first = (cb < NB / 2);

    #pragma unroll
    for (int i = 0; i < 16; i++) {
        int p = seg * 16 + i;
        int t = dir ? (TMAX - (c64 + p)) : (c64 + p);
        size_t ra = ((size_t)(b * TT + t)) * CC + h * 64 + lane;
        float wc = wcb[gbase + p * 64 + lane];
        sRp[lane * STR + p] = rb[ra] * wc;
        sBt[lane * STR + p] = Bpb[gbase + p * 64 + lane];
        sKt[lane * STR + p] = Kpb[gbase + p * 64 + lane];
        sV[p * STR + lane]  = vb[ra];
    }
    __syncthreads();
    const int tr = (tid >> 4) * 4, tc = (tid & 15) * 4;
    {
        float acc[4][4] = {};
        gemm64<1, STR, 1, STR>(sRp, sBt, acc, tr, tc);
        #pragma unroll
        for (int r = 0; r < 4; r++)
            #pragma unroll
            for (int cq = 0; cq < 4; cq++)
                sMb[(tr + r) * STR + tc + cq] = (tc + cq <= tr + r) ? acc[r][cq] : 0.f;
        float acc2[4][4] = {};
        gemm64<1, STR, 1, STR>(sRp, sKt, acc2, tr, tc);
        #pragma unroll
        for (int r = 0; r < 4; r++)
            #pragma unroll
            for (int cq = 0; cq < 4; cq++)
                sMk[(tr + r) * STR + tc + cq] = (tc + cq <= tr + r) ? acc2[r][cq] : 0.f;
    }
    __syncthreads();
    #pragma unroll
    for (int i = 0; i < 16; i++) {
        int rr = seg * 16 + i;
        sBt[rr * STR + lane] = Ub[gbase + rr * 64 + lane];
        sKt[rr * STR + lane] = S0b[gbase + rr * 64 + lane];
    }
    __syncthreads();
    {
        float acc[4][4] = {};
        gemm64<1, STR, STR, 1>(sRp, sKt, acc, tr, tc);
        gemm64<STR, 1, 1, STR>(sMb, sBt, acc, tr, tc);
        gemm64<STR, 1, 1, STR>(sMk, sV,  acc, tr, tc);
        #pragma unroll
        for (int r = 0; r < 4; r++) {
            int p = tr + r;
            int t = dir ? (TMAX - (c64 + p)) : (c64 + p);
            float* yp = &yb[((size_t)(b * TT + t)) * CC + h * 64 + tc];
            float4 o;
            if (first) {
                o.x = wscale * acc[r][0];
                o.y = wscale * acc[r][1];
                o.z = wscale * acc[r][2];
                o.w = wscale * acc[r][3];
            } else {
                float4 old = *(float4*)yp;
                o.x = old.x + wscale * acc[r][0];
                o.y = old.y + wscale * acc[r][1];
                o.z = old.z + wscale * acc[r][2];
                o.w = old.w + wscale * acc[r][3];
            }
            *(float4*)yp = o;
        }
    }
}

// ---------------------------------------------------------------------------
// Post: GroupNorm + affine + bonus + gating; emits z as split bf16 (hi+lo).
// ---------------------------------------------------------------------------
__global__ __launch_bounds__(256) void post_kernel(
    const float* __restrict__ yb, const float* __restrict__ rbv,
    const float* __restrict__ kbv, const float* __restrict__ abv,
    const float* __restrict__ vbv, const float* __restrict__ gbv,
    const float* __restrict__ kaw, const float* __restrict__ r_k,
    const float* __restrict__ ln_w, const float* __restrict__ ln_b,
    unsigned short* __restrict__ zh, unsigned short* __restrict__ zl)
{
    const int t = blockIdx.x;
    const int tid = threadIdx.x;
    const size_t base = (size_t)t * CC;
    #pragma unroll
    for (int j = 0; j < 4; j++) {
        int c = tid + 256 * j;
        float y = yb[base + c];
        float s1 = waveReduceSum(y);
        float s2 = waveReduceSum(y * y);
        float mu = s1 * (1.0f / 64.0f);
        float var = s2 * (1.0f / 64.0f) - mu * mu;
        float yn = (y - mu) * rsqrtf(var + EPS_GN);
        yn = yn * ln_w[c] + ln_b[c];
        float rv = rbv[base + c];
        float kf = kbv[base + c] * (1.0f + (abv[base + c] - 1.0f) * kaw[c]);
        float vv = vbv[base + c];
        float dot = waveReduceSum(rv * kf * r_k[c]);
        yn += dot * vv;
        float z = yn * gbv[base + c];
        unsigned short h = f2bf(z);
        zh[base + c] = h;
        zl[base + c] = f2bf(z - bf2f(h));
    }
}

// ---------------------------------------------------------------------------
extern "C" void kernel_launch(void* const* d_in, const int* in_sizes, int n_in,
                              void* d_out, int out_size, void* d_ws, size_t ws_size,
                              hipStream_t stream)
{
    (void)in_sizes; (void)n_in; (void)out_size; (void)ws_size;
    const float* x      = (const float*)d_in[0];
    const float* vfirst = (const float*)d_in[1];
    const float* x_r    = (const float*)d_in[2];
    const float* x_w    = (const float*)d_in[3];
    const float* x_k    = (const float*)d_in[4];
    const float* x_v    = (const float*)d_in[5];
    const float* x_a    = (const float*)d_in[6];
    const float* x_g    = (const float*)d_in[7];
    const float* w0     = (const float*)d_in[8];
    const float* w1     = (const float*)d_in[9];
    const float* w2     = (const float*)d_in[10];
    const float* a0     = (const float*)d_in[11];
    const float* a1     = (const float*)d_in[12];
    const float* a2     = (const float*)d_in[13];
    const float* v0     = (const float*)d_in[14];
    const float* v1     = (const float*)d_in[15];
    const float* v2     = (const float*)d_in[16];
    const float* g1     = (const float*)d_in[17];
    const float* g2     = (const float*)d_in[18];
    const float* k_k    = (const float*)d_in[19];
    const float* k_a    = (const float*)d_in[20];
    const float* r_k    = (const float*)d_in[21];
    const float* Wr     = (const float*)d_in[22];
    const float* Wk     = (const float*)d_in[23];
    const float* Wv     = (const float*)d_in[24];
    const float* Wo     = (const float*)d_in[25];
    const float* ln_w   = (const float*)d_in[26];
    const float* ln_b   = (const float*)d_in[27];
    const float* alpha  = (const float*)d_in[28];

    const size_t SZ = (size_t)BT * CC;
    const size_t CHB = (size_t)1024 * 4096;
    float* ws   = (float*)d_ws;
    float* rb   = ws + 0 * SZ;
    float* kb   = ws + 1 * SZ;
    float* vb   = ws + 2 * SZ;
    float* decb = ws + 3 * SZ;
    float* ab   = ws + 4 * SZ;
    // activation split-bf16 temps (BT*768 ushort = BT*384 float)
    float* actf = ws + 5 * SZ;
    unsigned short* awh = (unsigned short*)actf;
    unsigned short* awl = awh + (size_t)BT * 64;
    unsigned short* aah = awl + (size_t)BT * 64;
    unsigned short* aal = aah + (size_t)BT * 64;
    unsigned short* avh = aal + (size_t)BT * 64;
    unsigned short* avl = avh + (size_t)BT * 64;
    unsigned short* agh = avl + (size_t)BT * 64;
    unsigned short* agl = agh + (size_t)BT * 192;
    float* Gb   = actf + (size_t)BT * 384;
    float* Ub   = Gb + CHB;
    float* Bpb  = Ub + CHB;
    float* Kpb  = Bpb + CHB;
    float* S0b  = Kpb + CHB;
    float* wcb  = S0b + CHB;
    float* Scur = wcb + CHB;                     // 128*4096 floats
    unsigned short* Whb = (unsigned short*)(Scur + (size_t)128 * 4096);
    unsigned short* Wlb = Whb + (size_t)CC * CC;
    // stage-2 weight split-bf16 temps (transposed, K-padded)
    unsigned short* w2th = Wlb + (size_t)CC * CC;
    unsigned short* w2tl = w2th + (size_t)CC * 64;
    unsigned short* a2th = w2tl + (size_t)CC * 64;
    unsigned short* a2tl = a2th + (size_t)CC * 64;
    unsigned short* v2th = a2tl + (size_t)CC * 64;
    unsigned short* v2tl = v2th + (size_t)CC * 64;
    unsigned short* g2th = v2tl + (size_t)CC * 64;
    unsigned short* g2tl = g2th + (size_t)CC * 192;
    float* outp = (float*)d_out;
    float* gb   = outp;                          // g in out[0:SZ] until final GEMM
    float* yb   = outp + SZ;                     // y in out[SZ:2SZ] until v_first copy
    unsigned short* Ahp = (unsigned short*)(outp + SZ);   // projections phase
    unsigned short* Alp = Ahp + SZ;
    unsigned short* zAh = (unsigned short*)decb;          // z split (decb dead after scan)
    unsigned short* zAl = zAh + SZ;

    dim3 blk(256);
    const int NG_A = BT * (CC / 8);
    const int NG_W = CC * (CC / 8);
    dim3 gridA(NG_A / 256), gridW(NG_W / 256);
    dim3 gridG(1024);

    // big projections: split-convert then MFMA (3-term split-bf16)
    conv_split<false><<<gridW, blk, 0, stream>>>(Wr, nullptr, Whb, Wlb, NG_W);
    conv_split<true ><<<gridA, blk, 0, stream>>>(x, x_r, Ahp, Alp, NG_A);
    gemm_split_bf16<<<gridG, blk, 0, stream>>>(Ahp, Alp, Whb, Wlb, rb);
    conv_split<false><<<gridW, blk, 0, stream>>>(Wk, nullptr, Whb, Wlb, NG_W);
    conv_split<true ><<<gridA, blk, 0, stream>>>(x, x_k, Ahp, Alp, NG_A);
    gemm_split_bf16<<<gridG, blk, 0, stream>>>(Ahp, Alp, Whb, Wlb, kb);
    conv_split<false><<<gridW, blk, 0, stream>>>(Wv, nullptr, Whb, Wlb, NG_W);
    conv_split<true ><<<gridA, blk, 0, stream>>>(x, x_v, Ahp, Alp, NG_A);
    gemm_split_bf16<<<gridG, blk, 0, stream>>>(Ahp, Alp, Whb, Wlb, vb);

    // stage-2 weight conversion (transpose + split + K-pad)
    conv_w2<<<dim3(32), blk, 0, stream>>>(w2, 64, 64, w2th, w2tl);
    conv_w2<<<dim3(32), blk, 0, stream>>>(a2, 64, 64, a2th, a2tl);
    conv_w2<<<dim3(32), blk, 0, stream>>>(v2, 32, 64, v2th, v2tl);
    conv_w2<<<dim3(96), blk, 0, stream>>>(g2, 160, 192, g2th, g2tl);

    // LoRA stage-1 (merged, emits split-bf16 activations) then stage-2 on MFMA
    lora1_all<<<dim3(BT / 128, 5), blk, 0, stream>>>(x, w1, a1, v1, g1,
        x_w, x_a, x_v, x_g, awh, awl, aah, aal, avh, avl, agh, agl);
    lora2_mfma<<<dim3(BT / 128, CC / 128, 4), blk, 0, stream>>>(
        awh, awl, aah, aal, avh, avl, agh, agl,
        w2th, w2tl, a2th, a2tl, v2th, v2tl, g2th, g2tl,
        w0, a0, v0, vfirst, decb, ab, vb, gb);

    // chunked bidirectional WKV (wkvC first-writer batches store, rest accumulate)
    hipMemsetAsync(Scur, 0, (size_t)128 * 4096 * sizeof(float), stream);
    for (int cb = 0; cb < NB; ++cb) {
        wkvA<<<dim3(1024), blk, 0, stream>>>(kb, ab, vb, decb, k_k, k_a,
                                             Gb, Ub, Bpb, Kpb, wcb, cb);
        wkvB<<<dim3(128), blk, 0, stream>>>(vb, Gb, Ub, Bpb, Kpb, wcb, S0b, Scur, cb);
        wkvC<<<dim3(1024), blk, 0, stream>>>(rb, vb, Bpb, Kpb, Ub, S0b, wcb,
                                             alpha, yb, cb);
    }

    // groupnorm + bonus + gate -> split bf16 z (into decb's slot, dead now)
    post_kernel<<<dim3(BT), blk, 0, stream>>>(yb, rb, kb, ab, vb, gb, k_a, r_k,
                                              ln_w, ln_b, zAh, zAl);
    // final projection
    conv_split<false><<<gridW, blk, 0, stream>>>(Wo, nullptr, Whb, Wlb, NG_W);
    hipMemcpyAsync(outp + SZ, vfirst, SZ * sizeof(float),
                   hipMemcpyDeviceToDevice, stream);
    gemm_split_bf16<<<gridG, blk, 0, stream>>>(zAh, zAl, Whb, Wlb, outp);
}

// Round 11
// 3212.057 us; speedup vs baseline: 3.3776x; 1.3111x over previous
//
#include <hip/hip_runtime.h>
#include <hip/hip_bf16.h>
#include <math.h>

#define BB 4
#define TT 4096
#define CC 1024
#define HH 16
#define NN 64
#define BT (BB*TT)            // 16384 rows
#define EPS_GN 6.4e-4f        // 1e-5 * 8^2
#define TMAX (TT-1)
#define LCH 64                // chunk length
#define CB 8                  // chunks per batch
#define NB 8                  // batches  (LCH*CB*NB == TT)
#define STR 68                // padded LDS row stride (multiple of 4 -> b128)

typedef __attribute__((ext_vector_type(8))) short bf16x8;
typedef __attribute__((ext_vector_type(4))) float f32x4;

__device__ __forceinline__ float sigmoidf_(float x) {
    return 1.0f / (1.0f + expf(-x));
}

__device__ __forceinline__ float waveReduceSum(float v) {
    #pragma unroll
    for (int off = 32; off > 0; off >>= 1)
        v += __shfl_xor(v, off, 64);
    return v;
}

__device__ __forceinline__ unsigned short f2bf(float f) {
    unsigned u = __float_as_uint(f);
    u += 0x7FFFu + ((u >> 16) & 1u);
    return (unsigned short)(u >> 16);
}
__device__ __forceinline__ float bf2f(unsigned short h) {
    return __uint_as_float(((unsigned)h) << 16);
}

__device__ __forceinline__ void gll16(const unsigned short* g, unsigned short* l) {
    __builtin_amdgcn_global_load_lds(
        (__attribute__((address_space(1))) void*)(g),
        (__attribute__((address_space(3))) void*)(l), 16, 0, 0);
}

// acc[r][c] += sum_k A(tr+r,k)*B(tc+c,k); element A(i,k)=A[i*SA0+k*SA1].
// All LDS traffic as b128 (requires STR%4==0, tr/tc%4==0).
template<int SA0,int SA1,int SB0,int SB1>
__device__ __forceinline__ void gemm64(const float* __restrict__ A,
                                       const float* __restrict__ B,
                                       float acc[4][4], int tr, int tc) {
    #pragma unroll 2
    for (int kx = 0; kx < 64; kx += 4) {
        float a_[4][4];   // [r][kk]
        if (SA0 == 1) {
            #pragma unroll
            for (int kk = 0; kk < 4; kk++) {
                float4 t = *(const float4*)&A[tr + (kx + kk) * SA1];
                a_[0][kk] = t.x; a_[1][kk] = t.y; a_[2][kk] = t.z; a_[3][kk] = t.w;
            }
        } else {
            #pragma unroll
            for (int r = 0; r < 4; r++) {
                float4 t = *(const float4*)&A[(tr + r) * SA0 + kx];
                a_[r][0] = t.x; a_[r][1] = t.y; a_[r][2] = t.z; a_[r][3] = t.w;
            }
        }
        float b_[4][4];   // [cq][kk]
        if (SB0 == 1) {
            #pragma unroll
            for (int kk = 0; kk < 4; kk++) {
                float4 t = *(const float4*)&B[tc + (kx + kk) * SB1];
                b_[0][kk] = t.x; b_[1][kk] = t.y; b_[2][kk] = t.z; b_[3][kk] = t.w;
            }
        } else {
            #pragma unroll
            for (int cq = 0; cq < 4; cq++) {
                float4 t = *(const float4*)&B[(tc + cq) * SB0 + kx];
                b_[cq][0] = t.x; b_[cq][1] = t.y; b_[cq][2] = t.z; b_[cq][3] = t.w;
            }
        }
        #pragma unroll
        for (int r = 0; r < 4; r++)
            #pragma unroll
            for (int cq = 0; cq < 4; cq++)
                #pragma unroll
                for (int kk = 0; kk < 4; kk++)
                    acc[r][cq] = fmaf(a_[r][kk], b_[cq][kk], acc[r][cq]);
    }
}

// ---------------------------------------------------------------------------
// Split-conversion: fp32 (rows x CC, k-contig) -> bf16 hi + bf16 lo residual.
// ---------------------------------------------------------------------------
template<bool DOMIX>
__global__ __launch_bounds__(256) void conv_split(
    const float* __restrict__ X, const float* __restrict__ mix,
    unsigned short* __restrict__ Hi, unsigned short* __restrict__ Lo,
    int ngroups)
{
    int g = blockIdx.x * 256 + threadIdx.x;
    if (g >= ngroups) return;
    int m = g >> 7;                 // CC/8 = 128 groups per row
    int k = (g & 127) * 8;
    const float* px = X + (size_t)m * CC + k;
    float a[8];
    {
        float4 x0 = *(const float4*)px;
        float4 x1 = *(const float4*)(px + 4);
        a[0]=x0.x; a[1]=x0.y; a[2]=x0.z; a[3]=x0.w;
        a[4]=x1.x; a[5]=x1.y; a[6]=x1.z; a[7]=x1.w;
    }
    if (DOMIX) {
        float4 p0, p1;
        if ((m & (TT - 1)) == 0) {
            p0 = make_float4(0.f,0.f,0.f,0.f); p1 = p0;
        } else {
            p0 = *(const float4*)(px - CC);
            p1 = *(const float4*)(px - CC + 4);
        }
        float4 m0 = *(const float4*)(mix + k);
        float4 m1 = *(const float4*)(mix + k + 4);
        float pv[8] = {p0.x,p0.y,p0.z,p0.w,p1.x,p1.y,p1.z,p1.w};
        float mv[8] = {m0.x,m0.y,m0.z,m0.w,m1.x,m1.y,m1.z,m1.w};
        #pragma unroll
        for (int j = 0; j < 8; j++) a[j] += (pv[j] - a[j]) * mv[j];
    }
    unsigned short hi[8], lo[8];
    #pragma unroll
    for (int j = 0; j < 8; j++) {
        hi[j] = f2bf(a[j]);
        lo[j] = f2bf(a[j] - bf2f(hi[j]));
    }
    uint4 H, L;
    H.x = (unsigned)hi[0] | ((unsigned)hi[1] << 16);
    H.y = (unsigned)hi[2] | ((unsigned)hi[3] << 16);
    H.z = (unsigned)hi[4] | ((unsigned)hi[5] << 16);
    H.w = (unsigned)hi[6] | ((unsigned)hi[7] << 16);
    L.x = (unsigned)lo[0] | ((unsigned)lo[1] << 16);
    L.y = (unsigned)lo[2] | ((unsigned)lo[3] << 16);
    L.z = (unsigned)lo[4] | ((unsigned)lo[5] << 16);
    L.w = (unsigned)lo[6] | ((unsigned)lo[7] << 16);
    *(uint4*)(Hi + (size_t)g * 8) = H;
    *(uint4*)(Lo + (size_t)g * 8) = L;
}

// ---------------------------------------------------------------------------
// Stage-2 weight transpose+split: W (K,CC) n-contig -> (CC,Kp) k-contig hi/lo
// ---------------------------------------------------------------------------
__global__ __launch_bounds__(256) void conv_w2(
    const float* __restrict__ W, int K, int Kp,
    unsigned short* __restrict__ Hi, unsigned short* __restrict__ Lo)
{
    int idx = blockIdx.x * 256 + threadIdx.x;
    int nk8 = Kp >> 3;
    if (idx >= CC * nk8) return;
    int n = idx / nk8, k0 = (idx - n * nk8) * 8;
    unsigned short h8[8], l8[8];
    #pragma unroll
    for (int j = 0; j < 8; j++) {
        int k = k0 + j;
        float v = (k < K) ? W[(size_t)k * CC + n] : 0.f;
        h8[j] = f2bf(v);
        l8[j] = f2bf(v - bf2f(h8[j]));
    }
    uint4 H, L;
    H.x = (unsigned)h8[0] | ((unsigned)h8[1] << 16);
    H.y = (unsigned)h8[2] | ((unsigned)h8[3] << 16);
    H.z = (unsigned)h8[4] | ((unsigned)h8[5] << 16);
    H.w = (unsigned)h8[6] | ((unsigned)h8[7] << 16);
    L.x = (unsigned)l8[0] | ((unsigned)l8[1] << 16);
    L.y = (unsigned)l8[2] | ((unsigned)l8[3] << 16);
    L.z = (unsigned)l8[4] | ((unsigned)l8[5] << 16);
    L.w = (unsigned)l8[6] | ((unsigned)l8[7] << 16);
    *(uint4*)(Hi + (size_t)n * Kp + k0) = H;
    *(uint4*)(Lo + (size_t)n * Kp + k0) = L;
}

// ---------------------------------------------------------------------------
// Split-bf16 MFMA GEMM for big projections (unchanged — passed)
// ---------------------------------------------------------------------------
__global__ __launch_bounds__(256, 2) void gemm_split_bf16(
    const unsigned short* __restrict__ Ah, const unsigned short* __restrict__ Al,
    const unsigned short* __restrict__ Bh, const unsigned short* __restrict__ Bl,
    float* __restrict__ Out)
{
    __shared__ __align__(16) unsigned short lds[4][128 * 64];  // Ah,Al,Bh,Bl
    const int tid = threadIdx.x;
    const int lane = tid & 63;
    const int wave = tid >> 6;
    const int wm = (wave >> 1) * 64, wn = (wave & 1) * 64;
    const int wg = blockIdx.x;
    const int xcd = wg & 7;
    const int j = wg >> 3;
    const int m0 = ((j >> 3) * 8 + xcd) * 128;
    const int n0 = (j & 7) * 128;

    f32x4 acc[4][4];
    #pragma unroll
    for (int i = 0; i < 4; i++)
        #pragma unroll
        for (int jj = 0; jj < 4; jj++)
            acc[i][jj] = (f32x4){0.f, 0.f, 0.f, 0.f};

    for (int k0 = 0; k0 < CC; k0 += 64) {
        #pragma unroll
        for (int p = 0; p < 4; p++) {
            const unsigned short* sbase = (p == 0) ? Ah : (p == 1) ? Al
                                        : (p == 2) ? Bh : Bl;
            const int rbase = (p < 2) ? m0 : n0;
            #pragma unroll
            for (int i = 0; i < 4; i++) {
                int slot = i * 256 + wave * 64 + lane;
                int row = slot >> 3, gsl = slot & 7;
                const unsigned short* src = sbase
                    + (size_t)(rbase + row) * CC + k0 + ((gsl ^ (row & 7)) * 8);
                gll16(src, &lds[p][(size_t)(i * 256 + wave * 64) * 8]);
            }
        }
        __syncthreads();

        #pragma unroll
        for (int ks = 0; ks < 2; ks++) {
            bf16x8 bhf[4], blf[4];
            #pragma unroll
            for (int nt = 0; nt < 4; nt++) {
                int col = wn + nt * 16 + (lane & 15);
                int gk = ks * 4 + (lane >> 4);
                int el = col * 64 + ((gk ^ (col & 7)) * 8);
                bhf[nt] = *(const bf16x8*)&lds[2][el];
                blf[nt] = *(const bf16x8*)&lds[3][el];
            }
            #pragma unroll
            for (int mt = 0; mt < 4; mt++) {
                int row = wm + mt * 16 + (lane & 15);
                int gk = ks * 4 + (lane >> 4);
                int el = row * 64 + ((gk ^ (row & 7)) * 8);
                bf16x8 ahf = *(const bf16x8*)&lds[0][el];
                bf16x8 alf = *(const bf16x8*)&lds[1][el];
                #pragma unroll
                for (int nt = 0; nt < 4; nt++) {
                    acc[mt][nt] = __builtin_amdgcn_mfma_f32_16x16x32_bf16(
                        ahf, bhf[nt], acc[mt][nt], 0, 0, 0);
                    acc[mt][nt] = __builtin_amdgcn_mfma_f32_16x16x32_bf16(
                        alf, bhf[nt], acc[mt][nt], 0, 0, 0);
                    acc[mt][nt] = __builtin_amdgcn_mfma_f32_16x16x32_bf16(
                        ahf, blf[nt], acc[mt][nt], 0, 0, 0);
                }
            }
        }
        __syncthreads();
    }
    float* cf = (float*)&lds[0][0];    // 64*132*4 = 33.8 KB
    #pragma unroll
    for (int pass = 0; pass < 2; ++pass) {
        __syncthreads();
        if ((wave >> 1) == pass) {
            #pragma unroll
            for (int mt = 0; mt < 4; mt++)
                #pragma unroll
                for (int nt = 0; nt < 4; nt++)
                    #pragma unroll
                    for (int r = 0; r < 4; r++) {
                        int row = mt * 16 + (lane >> 4) * 4 + r;
                        int col = wn + nt * 16 + (lane & 15);
                        cf[row * 132 + col] = acc[mt][nt][r];
                    }
        }
        __syncthreads();
        #pragma unroll
        for (int i = 0; i < 8; i++) {
            int g = tid + 256 * i;
            int row = g >> 5, c4 = (g & 31) * 4;
            float4 v = *(float4*)&cf[row * 132 + c4];
            *(float4*)&Out[(size_t)(m0 + pass * 64 + row) * CC + n0 + c4] = v;
        }
    }
}

// ---------------------------------------------------------------------------
// LoRA stage-1, v2: 128x64 tiles (no wasted columns except v's 32-pad),
// 6 y-slices: 0=w1(64,tanh) 1=a1(64) 2=v1(32) 3..5=g1(160,sigmoid).
// Epilogue emits split-bf16 activations (K-padded).
// ---------------------------------------------------------------------------
__global__ __launch_bounds__(256) void lora1_all(
    const float* __restrict__ X,
    const float* __restrict__ w1, const float* __restrict__ a1,
    const float* __restrict__ v1, const float* __restrict__ g1,
    const float* __restrict__ xw, const float* __restrict__ xa,
    const float* __restrict__ xv, const float* __restrict__ xg,
    unsigned short* __restrict__ awh, unsigned short* __restrict__ awl,
    unsigned short* __restrict__ aah, unsigned short* __restrict__ aal,
    unsigned short* __restrict__ avh, unsigned short* __restrict__ avl,
    unsigned short* __restrict__ agh, unsigned short* __restrict__ agl)
{
    const int y = blockIdx.y;
    const float* W; const float* mix; unsigned short *Hi, *Lo;
    int Ncols, n0, epi, Kp;
    if (y == 0)      { W=w1; mix=xw; Hi=awh; Lo=awl; Ncols=64;  n0=0;          epi=1; Kp=64;  }
    else if (y == 1) { W=a1; mix=xa; Hi=aah; Lo=aal; Ncols=64;  n0=0;          epi=0; Kp=64;  }
    else if (y == 2) { W=v1; mix=xv; Hi=avh; Lo=avl; Ncols=32;  n0=0;          epi=0; Kp=64;  }
    else             { W=g1; mix=xg; Hi=agh; Lo=agl; Ncols=160; n0=(y-3)*64;   epi=2; Kp=192; }

    __shared__ float As[8][128];
    __shared__ float Bs[8][64];
    const int tid = threadIdx.x;
    const int m0 = blockIdx.x * 128;
    const int sr  = tid >> 1;          // A staging row
    const int skq = (tid & 1) * 4;     // A staging k offset
    const int bkr = tid >> 4;          // B staging k row (tid<128)
    const int bnq = (tid & 15) * 4;    // B staging n offset
    const int tm = (tid >> 3) * 4;     // 32 row-groups x 4
    const int tn = (tid & 7) * 8;      // 8 col-groups x 8

    float acc[4][8];
    #pragma unroll
    for (int i = 0; i < 4; i++)
        #pragma unroll
        for (int j = 0; j < 8; j++) acc[i][j] = 0.f;

    auto ldAm = [&](int gm, int gk) -> float4 {
        const float* px = X + (size_t)gm * CC + gk;
        float4 xvv = *(const float4*)px;
        float4 pv;
        if ((gm & (TT - 1)) == 0) pv = make_float4(0.f, 0.f, 0.f, 0.f);
        else pv = *(const float4*)(px - CC);
        float4 mv = *(const float4*)(mix + gk);
        xvv.x += (pv.x - xvv.x) * mv.x;
        xvv.y += (pv.y - xvv.y) * mv.y;
        xvv.z += (pv.z - xvv.z) * mv.z;
        xvv.w += (pv.w - xvv.w) * mv.w;
        return xvv;
    };

    float4 aR, bR = make_float4(0.f, 0.f, 0.f, 0.f);
    aR = ldAm(m0 + sr, skq);
    if (tid < 128) {
        int gn = n0 + bnq;
        bR = (gn < Ncols) ? *(const float4*)(W + (size_t)bkr * Ncols + gn)
                          : make_float4(0.f, 0.f, 0.f, 0.f);
    }

    for (int k0 = 0; k0 < CC; k0 += 8) {
        __syncthreads();
        As[skq + 0][sr] = aR.x;
        As[skq + 1][sr] = aR.y;
        As[skq + 2][sr] = aR.z;
        As[skq + 3][sr] = aR.w;
        if (tid < 128) *(float4*)&Bs[bkr][bnq] = bR;
        __syncthreads();

        if (k0 + 8 < CC) {
            aR = ldAm(m0 + sr, k0 + 8 + skq);
            if (tid < 128) {
                int gn = n0 + bnq;
                bR = (gn < Ncols) ? *(const float4*)(W + (size_t)(k0 + 8 + bkr) * Ncols + gn)
                                  : make_float4(0.f, 0.f, 0.f, 0.f);
            }
        }

        #pragma unroll
        for (int kk = 0; kk < 8; ++kk) {
            float av[4], bv[8];
            *(float4*)&av[0] = *(const float4*)&As[kk][tm];
            *(float4*)&bv[0] = *(const float4*)&Bs[kk][tn];
            *(float4*)&bv[4] = *(const float4*)&Bs[kk][tn + 4];
            #pragma unroll
            for (int i = 0; i < 4; i++)
                #pragma unroll
                for (int j = 0; j < 8; j++)
                    acc[i][j] = fmaf(av[i], bv[j], acc[i][j]);
        }
    }

    #pragma unroll
    for (int i = 0; i < 4; i++) {
        int gm = m0 + tm + i;
        int gn = n0 + tn;
        if (gn < Kp) {
            unsigned short h8[8], l8[8];
            #pragma unroll
            for (int j = 0; j < 8; j++) {
                float v = 0.f;
                if (gn + j < Ncols) {
                    v = acc[i][j];
                    if (epi == 1) v = tanhf(v);
                    else if (epi == 2) v = sigmoidf_(v);
                }
                h8[j] = f2bf(v);
                l8[j] = f2bf(v - bf2f(h8[j]));
            }
            uint4 H, L;
            H.x = (unsigned)h8[0] | ((unsigned)h8[1] << 16);
            H.y = (unsigned)h8[2] | ((unsigned)h8[3] << 16);
            H.z = (unsigned)h8[4] | ((unsigned)h8[5] << 16);
            H.w = (unsigned)h8[6] | ((unsigned)h8[7] << 16);
            L.x = (unsigned)l8[0] | ((unsigned)l8[1] << 16);
            L.y = (unsigned)l8[2] | ((unsigned)l8[3] << 16);
            L.z = (unsigned)l8[4] | ((unsigned)l8[5] << 16);
            L.w = (unsigned)l8[6] | ((unsigned)l8[7] << 16);
            *(uint4*)(Hi + (size_t)gm * Kp + gn) = H;
            *(uint4*)(Lo + (size_t)gm * Kp + gn) = L;
        }
    }
}

// ---------------------------------------------------------------------------
// LoRA stage-2 on MFMA (unchanged from round 10 — passed)
// ---------------------------------------------------------------------------
__global__ __launch_bounds__(256, 2) void lora2_mfma(
    const unsigned short* __restrict__ awh, const unsigned short* __restrict__ awl,
    const unsigned short* __restrict__ aah, const unsigned short* __restrict__ aal,
    const unsigned short* __restrict__ avh, const unsigned short* __restrict__ avl,
    const unsigned short* __restrict__ agh, const unsigned short* __restrict__ agl,
    const unsigned short* __restrict__ w2h, const unsigned short* __restrict__ w2l,
    const unsigned short* __restrict__ a2h, const unsigned short* __restrict__ a2l,
    const unsigned short* __restrict__ v2h, const unsigned short* __restrict__ v2l,
    const unsigned short* __restrict__ g2h, const unsigned short* __restrict__ g2l,
    const float* __restrict__ w0, const float* __restrict__ a0v,
    const float* __restrict__ v0v, const float* __restrict__ v_first,
    float* __restrict__ decb, float* __restrict__ ab,
    float* __restrict__ vbuf, float* __restrict__ gb)
{
    __shared__ __align__(16) unsigned short lds[4][128 * 64];
    const int z = blockIdx.z;
    const unsigned short *Ah, *Al, *Bh, *Bl; int Kp;
    if (z == 0)      { Ah = awh; Al = awl; Bh = w2h; Bl = w2l; Kp = 64;  }
    else if (z == 1) { Ah = aah; Al = aal; Bh = a2h; Bl = a2l; Kp = 64;  }
    else if (z == 2) { Ah = avh; Al = avl; Bh = v2h; Bl = v2l; Kp = 64;  }
    else             { Ah = agh; Al = agl; Bh = g2h; Bl = g2l; Kp = 192; }

    const int tid = threadIdx.x, lane = tid & 63, wave = tid >> 6;
    const int wm = (wave >> 1) * 64, wn = (wave & 1) * 64;
    const int m0 = blockIdx.x * 128, n0 = blockIdx.y * 128;

    f32x4 acc[4][4];
    #pragma unroll
    for (int i = 0; i < 4; i++)
        #pragma unroll
        for (int jj = 0; jj < 4; jj++)
            acc[i][jj] = (f32x4){0.f, 0.f, 0.f, 0.f};

    for (int k0 = 0; k0 < Kp; k0 += 64) {
        #pragma unroll
        for (int p = 0; p < 4; p++) {
            const unsigned short* sbase = (p == 0) ? Ah : (p == 1) ? Al
                                        : (p == 2) ? Bh : Bl;
            const int rbase = (p < 2) ? m0 : n0;
            #pragma unroll
            for (int i = 0; i < 4; i++) {
                int slot = i * 256 + wave * 64 + lane;
                int row = slot >> 3, gsl = slot & 7;
                const unsigned short* src = sbase
                    + (size_t)(rbase + row) * Kp + k0 + ((gsl ^ (row & 7)) * 8);
                gll16(src, &lds[p][(size_t)(i * 256 + wave * 64) * 8]);
            }
        }
        __syncthreads();

        #pragma unroll
        for (int ks = 0; ks < 2; ks++) {
            bf16x8 bhf[4], blf[4];
            #pragma unroll
            for (int nt = 0; nt < 4; nt++) {
                int col = wn + nt * 16 + (lane & 15);
                int gk = ks * 4 + (lane >> 4);
                int el = col * 64 + ((gk ^ (col & 7)) * 8);
                bhf[nt] = *(const bf16x8*)&lds[2][el];
                blf[nt] = *(const bf16x8*)&lds[3][el];
            }
            #pragma unroll
            for (int mt = 0; mt < 4; mt++) {
                int row = wm + mt * 16 + (lane & 15);
                int gk = ks * 4 + (lane >> 4);
                int el = row * 64 + ((gk ^ (row & 7)) * 8);
                bf16x8 ahf = *(const bf16x8*)&lds[0][el];
                bf16x8 alf = *(const bf16x8*)&lds[1][el];
                #pragma unroll
                for (int nt = 0; nt < 4; nt++) {
                    acc[mt][nt] = __builtin_amdgcn_mfma_f32_16x16x32_bf16(
                        ahf, bhf[nt], acc[mt][nt], 0, 0, 0);
                    acc[mt][nt] = __builtin_amdgcn_mfma_f32_16x16x32_bf16(
                        alf, bhf[nt], acc[mt][nt], 0, 0, 0);
                    acc[mt][nt] = __builtin_amdgcn_mfma_f32_16x16x32_bf16(
                        ahf, blf[nt], acc[mt][nt], 0, 0, 0);
                }
            }
        }
        __syncthreads();
    }
    float* cf = (float*)&lds[0][0];
    #pragma unroll
    for (int pass = 0; pass < 2; ++pass) {
        __syncthreads();
        if ((wave >> 1) == pass) {
            #pragma unroll
            for (int mt = 0; mt < 4; mt++)
                #pragma unroll
                for (int nt = 0; nt < 4; nt++)
                    #pragma unroll
                    for (int r = 0; r < 4; r++) {
                        int row = mt * 16 + (lane >> 4) * 4 + r;
                        int col = wn + nt * 16 + (lane & 15);
                        cf[row * 132 + col] = acc[mt][nt][r];
                    }
        }
        __syncthreads();
        #pragma unroll
        for (int i = 0; i < 8; i++) {
            int g = tid + 256 * i;
            int row = g >> 5, c4 = (g & 31) * 4;
            float4 v = *(float4*)&cf[row * 132 + c4];
            int gm = m0 + pass * 64 + row;
            int c = n0 + c4;
            size_t off = (size_t)gm * CC + c;
            if (z == 0) {
                float4 w0q = *(const float4*)(w0 + c);
                float4 o;
                o.x = expf(-expf(-log1pf(expf(-(w0q.x + v.x))) - 0.5f));
                o.y = expf(-expf(-log1pf(expf(-(w0q.y + v.y))) - 0.5f));
                o.z = expf(-expf(-log1pf(expf(-(w0q.z + v.z))) - 0.5f));
                o.w = expf(-expf(-log1pf(expf(-(w0q.w + v.w))) - 0.5f));
                *(float4*)&decb[off] = o;
            } else if (z == 1) {
                float4 a0q = *(const float4*)(a0v + c);
                float4 o;
                o.x = sigmoidf_(a0q.x + v.x);
                o.y = sigmoidf_(a0q.y + v.y);
                o.z = sigmoidf_(a0q.z + v.z);
                o.w = sigmoidf_(a0q.w + v.w);
                *(float4*)&ab[off] = o;
            } else if (z == 2) {
                float4 v0q = *(const float4*)(v0v + c);
                float4 vr = *(const float4*)&vbuf[off];
                float4 vf = *(const float4*)&v_first[off];
                float4 o;
                o.x = vr.x + (vf.x - vr.x) * sigmoidf_(v0q.x + v.x);
                o.y = vr.y + (vf.y - vr.y) * sigmoidf_(v0q.y + v.y);
                o.z = vr.z + (vf.z - vr.z) * sigmoidf_(v0q.z + v.z);
                o.w = vr.w + (vf.w - vr.w) * sigmoidf_(v0q.w + v.w);
                *(float4*)&vbuf[off] = o;
            } else {
                *(float4*)&gb[off] = v;
            }
        }
    }
}

// ---------------------------------------------------------------------------
// Chunked WKV phase A, v2: 4 LDS buffers (69 KB -> 2 blocks/CU).
// wc cumprod in registers; YkV reads V from global (L1-resident);
// phases: Yk -> YkV -> X -> Tinv -> {G, U0}.
// ---------------------------------------------------------------------------
__global__ __launch_bounds__(256) void wkvA(
    const float* __restrict__ kb, const float* __restrict__ ab,
    const float* __restrict__ vb, const float* __restrict__ decb,
    const float* __restrict__ k_k, const float* __restrict__ k_a,
    float* __restrict__ Gb, float* __restrict__ Ub,
    float* __restrict__ Bpb, float* __restrict__ Kpb,
    float* __restrict__ wcb, int cb)
{
    __shared__ __align__(16) float sAp[64 * STR];
    __shared__ __align__(16) float sBp[64 * STR];   // BpT -> Tinv
    __shared__ __align__(16) float sKp[64 * STR];   // KpT -> YkV
    __shared__ __align__(16) float sT [64 * STR];   // Yk  -> X
    __shared__ float sSeg[4][64];
    const int inst = blockIdx.x;
    const int bhd = inst >> 3, lc = inst & 7;
    const int dir = bhd & 1, bh = bhd >> 1, b = bh >> 4, h = bh & 15;
    const int c64 = (cb * CB + lc) * LCH;
    const int tid = threadIdx.x;
    const int lane = tid & 63, seg = tid >> 6;
    const int ch = h * 64 + lane;
    const size_t gbase = (size_t)inst * 4096;

    // stage 0: local decay cumprods
    float loc[16];
    {
        float run = 1.f;
        #pragma unroll
        for (int i = 0; i < 16; i++) {
            int p = seg * 16 + i;
            int t = dir ? (TMAX - (c64 + p)) : (c64 + p);
            float d = decb[((size_t)(b * TT + t)) * CC + ch];
            run *= d; loc[i] = run;
        }
        sSeg[seg][lane] = run;
    }
    __syncthreads();
    float pre = 1.f;
    for (int s2 = 0; s2 < seg; ++s2) pre *= sSeg[s2][lane];
    // stage 1: scaled vectors (wc/wx from registers)
    {
        const float kkl = k_k[ch], kal = k_a[ch];
        #pragma unroll
        for (int i = 0; i < 16; i++) {
            int p = seg * 16 + i;
            int t = dir ? (TMAX - (c64 + p)) : (c64 + p);
            size_t ra = ((size_t)(b * TT + t)) * CC + ch;
            float kraw = kb[ra], asig = ab[ra];
            float kkv = kraw * kkl;
            float s2 = waveReduceSum(kkv * kkv);
            float kkn = kkv / fmaxf(sqrtf(s2), 1e-12f);
            float wc = loc[i] * pre;
            float wx = (i == 0) ? pre : loc[i - 1] * pre;
            float apv = -kkn * wx;
            float bpv = kkn * asig / wc;
            float kpv = kraw * (1.f + (asig - 1.f) * kal) / wc;
            sAp[lane * STR + p] = apv;
            sBp[lane * STR + p] = bpv;
            sKp[lane * STR + p] = kpv;
            Bpb[gbase + p * 64 + lane] = bpv;
            Kpb[gbase + p * 64 + lane] = kpv;
            wcb[gbase + p * 64 + lane] = wc;
        }
    }
    __syncthreads();   // bar A

    const int tr = (tid >> 4) * 4, tc = (tid & 15) * 4;
    // (a) Yk = tril(Ap @ Kp^T, -1) -> sT
    {
        float acc[4][4] = {};
        gemm64<1, STR, 1, STR>(sAp, sKp, acc, tr, tc);
        #pragma unroll
        for (int r = 0; r < 4; r++)
            #pragma unroll
            for (int cq = 0; cq < 4; cq++)
                sT[(tr + r) * STR + tc + cq] = (tc + cq < tr + r) ? acc[r][cq] : 0.f;
    }
    __syncthreads();   // bar B (sT ready; sKp dead)
    // (b) YkV = Yk @ V (V from global) -> sKp
    {
        float accY[4][4] = {};
        const float* vbase = vb + ((size_t)(b * TT + (dir ? (TMAX - c64) : c64))) * CC
                           + h * 64 + tc;
        const ptrdiff_t vstep = dir ? -(ptrdiff_t)CC : (ptrdiff_t)CC;
        #pragma unroll 2
        for (int j4 = 0; j4 < 64; j4 += 4) {
            float a_[4][4];
            #pragma unroll
            for (int r = 0; r < 4; r++) {
                float4 t4 = *(const float4*)&sT[(tr + r) * STR + j4];
                a_[r][0] = t4.x; a_[r][1] = t4.y; a_[r][2] = t4.z; a_[r][3] = t4.w;
            }
            float4 vq[4];
            #pragma unroll
            for (int kk = 0; kk < 4; kk++)
                vq[kk] = *(const float4*)(vbase + (ptrdiff_t)(j4 + kk) * vstep);
            #pragma unroll
            for (int r = 0; r < 4; r++) {
                accY[r][0] = fmaf(a_[r][0], vq[0].x, fmaf(a_[r][1], vq[1].x,
                             fmaf(a_[r][2], vq[2].x, fmaf(a_[r][3], vq[3].x, accY[r][0]))));
                accY[r][1] = fmaf(a_[r][0], vq[0].y, fmaf(a_[r][1], vq[1].y,
                             fmaf(a_[r][2], vq[2].y, fmaf(a_[r][3], vq[3].y, accY[r][1]))));
                accY[r][2] = fmaf(a_[r][0], vq[0].z, fmaf(a_[r][1], vq[1].z,
                             fmaf(a_[r][2], vq[2].z, fmaf(a_[r][3], vq[3].z, accY[r][2]))));
                accY[r][3] = fmaf(a_[r][0], vq[0].w, fmaf(a_[r][1], vq[1].w,
                             fmaf(a_[r][2], vq[2].w, fmaf(a_[r][3], vq[3].w, accY[r][3]))));
            }
        }
        #pragma unroll
        for (int r = 0; r < 4; r++)
            #pragma unroll
            for (int cq = 0; cq < 4; cq++)
                sKp[(tr + r) * STR + tc + cq] = accY[r][cq];
    }
    __syncthreads();   // bar C (sKp=YkV ready; sT readers done)
    // (c) X = tril(Ap @ Bp^T, -1) -> sT
    {
        float acc[4][4] = {};
        gemm64<1, STR, 1, STR>(sAp, sBp, acc, tr, tc);
        #pragma unroll
        for (int r = 0; r < 4; r++)
            #pragma unroll
            for (int cq = 0; cq < 4; cq++)
                sT[(tr + r) * STR + tc + cq] = (tc + cq < tr + r) ? acc[r][cq] : 0.f;
    }
    __syncthreads();   // bar D (sT=X ready; sBp readers done)
    // (d) Tinv = (I - X)^{-1} -> sBp (column per lane; single wave)
    if (tid < 64) {
        for (int r = 0; r < 64; ++r) {
            float acc = 0.f;
            for (int s = 0; s < r; ++s)
                acc = fmaf(sT[r * STR + s], sBp[s * STR + tid], acc);
            sBp[r * STR + tid] = (r == tid) ? 1.f : acc;
        }
    }
    __syncthreads();   // bar E
    // (e) G = Tinv @ Ap ; U0 = Tinv @ YkV
    {
        float accG[4][4] = {};
        gemm64<STR, 1, STR, 1>(sBp, sAp, accG, tr, tc);
        float accU[4][4] = {};
        gemm64<STR, 1, 1, STR>(sBp, sKp, accU, tr, tc);
        #pragma unroll
        for (int r = 0; r < 4; r++) {
            *(float4*)&Gb[gbase + (tr + r) * 64 + tc] =
                make_float4(accG[r][0], accG[r][1], accG[r][2], accG[r][3]);
            *(float4*)&Ub[gbase + (tr + r) * 64 + tc] =
                make_float4(accU[r][0], accU[r][1], accU[r][2], accU[r][3]);
        }
    }
}

// ---------------------------------------------------------------------------
// wkvB (unchanged — passed; only 128 blocks, occupancy immaterial)
// ---------------------------------------------------------------------------
__global__ __launch_bounds__(256) void wkvB(
    const float* __restrict__ vb,
    const float* __restrict__ Gb, float* __restrict__ Ub,
    const float* __restrict__ Bpb, const float* __restrict__ Kpb,
    const float* __restrict__ wcb, float* __restrict__ S0b,
    float* __restrict__ Scur, int cb)
{
    __shared__ __align__(16) float sS[64 * STR];
    __shared__ __align__(16) float sG[64 * STR];
    __shared__ __align__(16) float sU[64 * STR];
    __shared__ __align__(16) float sB[64 * STR];
    __shared__ __align__(16) float sK[64 * STR];
    __shared__ __align__(16) float sV[64 * STR];
    const int bhd = blockIdx.x;
    const int dir = bhd & 1, bh = bhd >> 1, b = bh >> 4, h = bh & 15;
    const int tid = threadIdx.x;
    const int tr = (tid >> 4) * 4, tc = (tid & 15) * 4;

    for (int i = tid; i < 4096; i += 256)
        sS[(i >> 6) * STR + (i & 63)] = Scur[(size_t)bhd * 4096 + i];
    __syncthreads();

    for (int lc = 0; lc < CB; ++lc) {
        const int inst = bhd * CB + lc;
        const size_t gbase = (size_t)inst * 4096;
        const int c64 = (cb * CB + lc) * LCH;
        for (int i = tid; i < 4096; i += 256) {
            int rr = i >> 6, jj = i & 63;
            sG[rr * STR + jj] = Gb[gbase + i];
            sB[rr * STR + jj] = Bpb[gbase + i];
            sK[rr * STR + jj] = Kpb[gbase + i];
            int t = dir ? (TMAX - (c64 + rr)) : (c64 + rr);
            sV[rr * STR + jj] = vb[((size_t)(b * TT + t)) * CC + h * 64 + jj];
            S0b[gbase + i] = sS[rr * STR + jj];
        }
        __syncthreads();
        {
            float acc[4][4];
            #pragma unroll
            for (int r = 0; r < 4; r++) {
                float4 u0 = *(const float4*)&Ub[gbase + (tr + r) * 64 + tc];
                acc[r][0] = u0.x; acc[r][1] = u0.y; acc[r][2] = u0.z; acc[r][3] = u0.w;
            }
            gemm64<STR, 1, STR, 1>(sG, sS, acc, tr, tc);
            #pragma unroll
            for (int r = 0; r < 4; r++) {
                #pragma unroll
                for (int cq = 0; cq < 4; cq++) sU[(tr + r) * STR + tc + cq] = acc[r][cq];
                *(float4*)&Ub[gbase + (tr + r) * 64 + tc] =
                    make_float4(acc[r][0], acc[r][1], acc[r][2], acc[r][3]);
            }
        }
        __syncthreads();
        {
            float acc[4][4] = {};
            gemm64<1, STR, 1, STR>(sU, sB, acc, tr, tc);
            gemm64<1, STR, 1, STR>(sV, sK, acc, tr, tc);
            float w63[4];
            #pragma unroll
            for (int cq = 0; cq < 4; cq++) w63[cq] = wcb[gbase + 63 * 64 + tc + cq];
            #pragma unroll
            for (int r = 0; r < 4; r++)
                #pragma unroll
                for (int cq = 0; cq < 4; cq++) {
                    float sv = sS[(tr + r) * STR + tc + cq];
                    acc[r][cq] = (sv + acc[r][cq]) * w63[cq];
                }
            #pragma unroll
            for (int r = 0; r < 4; r++)
                #pragma unroll
                for (int cq = 0; cq < 4; cq++)
                    sS[(tr + r) * STR + tc + cq] = acc[r][cq];
        }
        __syncthreads();
    }
    for (int i = tid; i < 4096; i += 256)
        Scur[(size_t)bhd * 4096 + i] = sS[(i >> 6) * STR + (i & 63)];
}

// ---------------------------------------------------------------------------
// wkvC, v2: 3 LDS buffers (52 KB -> 3 blocks/CU), sequential accumulate.
// ---------------------------------------------------------------------------
__global__ __launch_bounds__(256) void wkvC(
    const float* __restrict__ rb, const float* __restrict__ vb,
    const float* __restrict__ Bpb, const float* __restrict__ Kpb,
    const float* __restrict__ Ub, const float* __restrict__ S0b,
    const float* __restrict__ wcb, const float* __restrict__ alpha_p,
    float* __restrict__ yb, int cb)
{
    __shared__ __align__(16) float sR[64 * STR];   // RpT
    __shared__ __align__(16) float sO[64 * STR];   // operand (BpT/U/KpT/V/S0)
    __shared__ __align__(16) float sT2[64 * STR];  // triangular (Mrb/Mrk)
    const int inst = blockIdx.x;
    const int bhd = inst >> 3, lc = inst & 7;
    const int dir = bhd & 1, bh = bhd >> 1, b = bh >> 4, h = bh & 15;
    const int c64 = (cb * CB + lc) * LCH;
    const int tid = threadIdx.x, lane = tid & 63, seg = tid >> 6;
    const size_t gbase = (size_t)inst * 4096;
    const float alpha = alpha_p[0];
    const float wscale = dir ? (1.f - alpha) : alpha;
    const bool first = (cb < NB / 2);

    #pragma unroll
    for (int i = 0; i < 16; i++) {
        int p = seg * 16 + i;
        int t = dir ? (TMAX - (c64 + p)) : (c64 + p);
        size_t ra = ((size_t)(b * TT + t)) * CC + h * 64 + lane;
        float wc = wcb[gbase + p * 64 + lane];
        sR[lane * STR + p] = rb[ra] * wc;
        sO[lane * STR + p] = Bpb[gbase + p * 64 + lane];
    }
    __syncthreads();
    const int tr = (tid >> 4) * 4, tc = (tid & 15) * 4;
    float accO[4][4] = {};
    // Mrb = tril(R' Bp^T, 0) -> sT2
    {
        float acc[4][4] = {};
        gemm64<1, STR, 1, STR>(sR, sO, acc, tr, tc);
        #pragma unroll
        for (int r = 0; r < 4; r++)
            #pragma unroll
            for (int cq = 0; cq < 4; cq++)
                sT2[(tr + r) * STR + tc + cq] = (tc + cq <= tr + r) ? acc[r][cq] : 0.f;
    }
    __syncthreads();
    // sO <- U
    for (int i = tid; i < 4096; i += 256)
        sO[(i >> 6) * STR + (i & 63)] = Ub[gbase + i];
    __syncthreads();
    // acc += Mrb @ U
    gemm64<STR, 1, 1, STR>(sT2, sO, accO, tr, tc);
    __syncthreads();
    // sO <- KpT
    #pragma unroll
    for (int i = 0; i < 16; i++) {
        int p = seg * 16 + i;
        sO[lane * STR + p] = Kpb[gbase + p * 64 + lane];
    }
    __syncthreads();
    // Mrk = tril(R' Kp^T, 0) -> sT2
    {
        float acc[4][4] = {};
        gemm64<1, STR, 1, STR>(sR, sO, acc, tr, tc);
        #pragma unroll
        for (int r = 0; r < 4; r++)
            #pragma unroll
            for (int cq = 0; cq < 4; cq++)
                sT2[(tr + r) * STR + tc + cq] = (tc + cq <= tr + r) ? acc[r][cq] : 0.f;
    }
    __syncthreads();
    // sO <- V
    #pragma unroll
    for (int i = 0; i < 16; i++) {
        int p = seg * 16 + i;
        int t = dir ? (TMAX - (c64 + p)) : (c64 + p);
        sO[p * STR + lane] = vb[((size_t)(b * TT + t)) * CC + h * 64 + lane];
    }
    __syncthreads();
    // acc += Mrk @ V
    gemm64<STR, 1, 1, STR>(sT2, sO, accO, tr, tc);
    __syncthreads();
    // sO <- S0
    for (int i = tid; i < 4096; i += 256)
        sO[(i >> 6) * STR + (i & 63)] = S0b[gbase + i];
    __syncthreads();
    // acc += R' @ S0^T
    gemm64<1, STR, STR, 1>(sR, sO, accO, tr, tc);
    // write y
    #pragma unroll
    for (int r = 0; r < 4; r++) {
        int p = tr + r;
        int t = dir ? (TMAX - (c64 + p)) : (c64 + p);
        float* yp = &yb[((size_t)(b * TT + t)) * CC + h * 64 + tc];
        float4 o;
        if (first) {
            o.x = wscale * accO[r][0];
            o.y = wscale * accO[r][1];
            o.z = wscale * accO[r][2];
            o.w = wscale * accO[r][3];
        } else {
            float4 old = *(float4*)yp;
            o.x = old.x + wscale * accO[r][0];
            o.y = old.y + wscale * accO[r][1];
            o.z = old.z + wscale * accO[r][2];
            o.w = old.w + wscale * accO[r][3];
        }
        *(float4*)yp = o;
    }
}

// ---------------------------------------------------------------------------
// Post: GroupNorm + affine + bonus + gating; emits z as split bf16 (hi+lo).
// ---------------------------------------------------------------------------
__global__ __launch_bounds__(256) void post_kernel(
    const float* __restrict__ yb, const float* __restrict__ rbv,
    const float* __restrict__ kbv, const float* __restrict__ abv,
    const float* __restrict__ vbv, const float* __restrict__ gbv,
    const float* __restrict__ kaw, const float* __restrict__ r_k,
    const float* __restrict__ ln_w, const float* __restrict__ ln_b,
    unsigned short* __restrict__ zh, unsigned short* __restrict__ zl)
{
    const int t = blockIdx.x;
    const int tid = threadIdx.x;
    const size_t base = (size_t)t * CC;
    #pragma unroll
    for (int j = 0; j < 4; j++) {
        int c = tid + 256 * j;
        float y = yb[base + c];
        float s1 = waveReduceSum(y);
        float s2 = waveReduceSum(y * y);
        float mu = s1 * (1.0f / 64.0f);
        float var = s2 * (1.0f / 64.0f) - mu * mu;
        float yn = (y - mu) * rsqrtf(var + EPS_GN);
        yn = yn * ln_w[c] + ln_b[c];
        float rv = rbv[base + c];
        float kf = kbv[base + c] * (1.0f + (abv[base + c] - 1.0f) * kaw[c]);
        float vv = vbv[base + c];
        float dot = waveReduceSum(rv * kf * r_k[c]);
        yn += dot * vv;
        float z = yn * gbv[base + c];
        unsigned short h = f2bf(z);
        zh[base + c] = h;
        zl[base + c] = f2bf(z - bf2f(h));
    }
}

// ---------------------------------------------------------------------------
extern "C" void kernel_launch(void* const* d_in, const int* in_sizes, int n_in,
                              void* d_out, int out_size, void* d_ws, size_t ws_size,
                              hipStream_t stream)
{
    (void)in_sizes; (void)n_in; (void)out_size; (void)ws_size;
    const float* x      = (const float*)d_in[0];
    const float* vfirst = (const float*)d_in[1];
    const float* x_r    = (const float*)d_in[2];
    const float* x_w    = (const float*)d_in[3];
    const float* x_k    = (const float*)d_in[4];
    const float* x_v    = (const float*)d_in[5];
    const float* x_a    = (const float*)d_in[6];
    const float* x_g    = (const float*)d_in[7];
    const float* w0     = (const float*)d_in[8];
    const float* w1     = (const float*)d_in[9];
    const float* w2     = (const float*)d_in[10];
    const float* a0     = (const float*)d_in[11];
    const float* a1     = (const float*)d_in[12];
    const float* a2     = (const float*)d_in[13];
    const float* v0     = (const float*)d_in[14];
    const float* v1     = (const float*)d_in[15];
    const float* v2     = (const float*)d_in[16];
    const float* g1     = (const float*)d_in[17];
    const float* g2     = (const float*)d_in[18];
    const float* k_k    = (const float*)d_in[19];
    const float* k_a    = (const float*)d_in[20];
    const float* r_k    = (const float*)d_in[21];
    const float* Wr     = (const float*)d_in[22];
    const float* Wk     = (const float*)d_in[23];
    const float* Wv     = (const float*)d_in[24];
    const float* Wo     = (const float*)d_in[25];
    const float* ln_w   = (const float*)d_in[26];
    const float* ln_b   = (const float*)d_in[27];
    const float* alpha  = (const float*)d_in[28];

    const size_t SZ = (size_t)BT * CC;
    const size_t CHB = (size_t)1024 * 4096;
    float* ws   = (float*)d_ws;
    float* rb   = ws + 0 * SZ;
    float* kb   = ws + 1 * SZ;
    float* vb   = ws + 2 * SZ;
    float* decb = ws + 3 * SZ;
    float* ab   = ws + 4 * SZ;
    float* actf = ws + 5 * SZ;
    unsigned short* awh = (unsigned short*)actf;
    unsigned short* awl = awh + (size_t)BT * 64;
    unsigned short* aah = awl + (size_t)BT * 64;
    unsigned short* aal = aah + (size_t)BT * 64;
    unsigned short* avh = aal + (size_t)BT * 64;
    unsigned short* avl = avh + (size_t)BT * 64;
    unsigned short* agh = avl + (size_t)BT * 64;
    unsigned short* agl = agh + (size_t)BT * 192;
    float* Gb   = actf + (size_t)BT * 384;
    float* Ub   = Gb + CHB;
    float* Bpb  = Ub + CHB;
    float* Kpb  = Bpb + CHB;
    float* S0b  = Kpb + CHB;
    float* wcb  = S0b + CHB;
    float* Scur = wcb + CHB;
    unsigned short* Whb = (unsigned short*)(Scur + (size_t)128 * 4096);
    unsigned short* Wlb = Whb + (size_t)CC * CC;
    unsigned short* w2th = Wlb + (size_t)CC * CC;
    unsigned short* w2tl = w2th + (size_t)CC * 64;
    unsigned short* a2th = w2tl + (size_t)CC * 64;
    unsigned short* a2tl = a2th + (size_t)CC * 64;
    unsigned short* v2th = a2tl + (size_t)CC * 64;
    unsigned short* v2tl = v2th + (size_t)CC * 64;
    unsigned short* g2th = v2tl + (size_t)CC * 64;
    unsigned short* g2tl = g2th + (size_t)CC * 192;
    float* outp = (float*)d_out;
    float* gb   = outp;
    float* yb   = outp + SZ;
    unsigned short* Ahp = (unsigned short*)(outp + SZ);
    unsigned short* Alp = Ahp + SZ;
    unsigned short* zAh = (unsigned short*)decb;
    unsigned short* zAl = zAh + SZ;

    dim3 blk(256);
    const int NG_A = BT * (CC / 8);
    const int NG_W = CC * (CC / 8);
    dim3 gridA(NG_A / 256), gridW(NG_W / 256);
    dim3 gridG(1024);

    // big projections: split-convert then MFMA (3-term split-bf16)
    conv_split<false><<<gridW, blk, 0, stream>>>(Wr, nullptr, Whb, Wlb, NG_W);
    conv_split<true ><<<gridA, blk, 0, stream>>>(x, x_r, Ahp, Alp, NG_A);
    gemm_split_bf16<<<gridG, blk, 0, stream>>>(Ahp, Alp, Whb, Wlb, rb);
    conv_split<false><<<gridW, blk, 0, stream>>>(Wk, nullptr, Whb, Wlb, NG_W);
    conv_split<true ><<<gridA, blk, 0, stream>>>(x, x_k, Ahp, Alp, NG_A);
    gemm_split_bf16<<<gridG, blk, 0, stream>>>(Ahp, Alp, Whb, Wlb, kb);
    conv_split<false><<<gridW, blk, 0, stream>>>(Wv, nullptr, Whb, Wlb, NG_W);
    conv_split<true ><<<gridA, blk, 0, stream>>>(x, x_v, Ahp, Alp, NG_A);
    gemm_split_bf16<<<gridG, blk, 0, stream>>>(Ahp, Alp, Whb, Wlb, vb);

    // stage-2 weight conversion (transpose + split + K-pad)
    conv_w2<<<dim3(32), blk, 0, stream>>>(w2, 64, 64, w2th, w2tl);
    conv_w2<<<dim3(32), blk, 0, stream>>>(a2, 64, 64, a2th, a2tl);
    conv_w2<<<dim3(32), blk, 0, stream>>>(v2, 32, 64, v2th, v2tl);
    conv_w2<<<dim3(96), blk, 0, stream>>>(g2, 160, 192, g2th, g2tl);

    // LoRA stage-1 (64-col tiles, 6 slices) then stage-2 on MFMA
    lora1_all<<<dim3(BT / 128, 6), blk, 0, stream>>>(x, w1, a1, v1, g1,
        x_w, x_a, x_v, x_g, awh, awl, aah, aal, avh, avl, agh, agl);
    lora2_mfma<<<dim3(BT / 128, CC / 128, 4), blk, 0, stream>>>(
        awh, awl, aah, aal, avh, avl, agh, agl,
        w2th, w2tl, a2th, a2tl, v2th, v2tl, g2th, g2tl,
        w0, a0, v0, vfirst, decb, ab, vb, gb);

    // chunked bidirectional WKV
    hipMemsetAsync(Scur, 0, (size_t)128 * 4096 * sizeof(float), stream);
    for (int cb = 0; cb < NB; ++cb) {
        wkvA<<<dim3(1024), blk, 0, stream>>>(kb, ab, vb, decb, k_k, k_a,
                                             Gb, Ub, Bpb, Kpb, wcb, cb);
        wkvB<<<dim3(128), blk, 0, stream>>>(vb, Gb, Ub, Bpb, Kpb, wcb, S0b, Scur, cb);
        wkvC<<<dim3(1024), blk, 0, stream>>>(rb, vb, Bpb, Kpb, Ub, S0b, wcb,
                                             alpha, yb, cb);
    }

    // groupnorm + bonus + gate -> split bf16 z
    post_kernel<<<dim3(BT), blk, 0, stream>>>(yb, rb, kb, ab, vb, gb, k_a, r_k,
                                              ln_w, ln_b, zAh, zAl);
    // final projection
    conv_split<false><<<gridW, blk, 0, stream>>>(Wo, nullptr, Whb, Wlb, NG_W);
    hipMemcpyAsync(outp + SZ, vfirst, SZ * sizeof(float),
                   hipMemcpyDeviceToDevice, stream);
    gemm_split_bf16<<<gridG, blk, 0, stream>>>(zAh, zAl, Whb, Wlb, outp);
}

// Round 12
// 3111.452 us; speedup vs baseline: 3.4868x; 1.0323x over previous
//
#include <hip/hip_runtime.h>
#include <hip/hip_bf16.h>
#include <math.h>

#define BB 4
#define TT 4096
#define CC 1024
#define HH 16
#define NN 64
#define BT (BB*TT)            // 16384 rows
#define EPS_GN 6.4e-4f        // 1e-5 * 8^2
#define TMAX (TT-1)
#define LCH 64                // chunk length
#define CB 8                  // chunks per batch
#define NB 8                  // batches  (LCH*CB*NB == TT)
#define STR 68                // padded LDS row stride (multiple of 4 -> b128)

typedef __attribute__((ext_vector_type(8))) short bf16x8;
typedef __attribute__((ext_vector_type(4))) float f32x4;

__device__ __forceinline__ float sigmoidf_(float x) {
    return 1.0f / (1.0f + expf(-x));
}

__device__ __forceinline__ float waveReduceSum(float v) {
    #pragma unroll
    for (int off = 32; off > 0; off >>= 1)
        v += __shfl_xor(v, off, 64);
    return v;
}

__device__ __forceinline__ unsigned short f2bf(float f) {
    unsigned u = __float_as_uint(f);
    u += 0x7FFFu + ((u >> 16) & 1u);
    return (unsigned short)(u >> 16);
}
__device__ __forceinline__ float bf2f(unsigned short h) {
    return __uint_as_float(((unsigned)h) << 16);
}

__device__ __forceinline__ void gll16(const unsigned short* g, unsigned short* l) {
    __builtin_amdgcn_global_load_lds(
        (__attribute__((address_space(1))) void*)(g),
        (__attribute__((address_space(3))) void*)(l), 16, 0, 0);
}

// acc[r][c] += sum_k A(tr+r,k)*B(tc+c,k); element A(i,k)=A[i*SA0+k*SA1].
template<int SA0,int SA1,int SB0,int SB1>
__device__ __forceinline__ void gemm64(const float* __restrict__ A,
                                       const float* __restrict__ B,
                                       float acc[4][4], int tr, int tc) {
    #pragma unroll 2
    for (int kx = 0; kx < 64; kx += 4) {
        float a_[4][4];   // [r][kk]
        if (SA0 == 1) {
            #pragma unroll
            for (int kk = 0; kk < 4; kk++) {
                float4 t = *(const float4*)&A[tr + (kx + kk) * SA1];
                a_[0][kk] = t.x; a_[1][kk] = t.y; a_[2][kk] = t.z; a_[3][kk] = t.w;
            }
        } else {
            #pragma unroll
            for (int r = 0; r < 4; r++) {
                float4 t = *(const float4*)&A[(tr + r) * SA0 + kx];
                a_[r][0] = t.x; a_[r][1] = t.y; a_[r][2] = t.z; a_[r][3] = t.w;
            }
        }
        float b_[4][4];   // [cq][kk]
        if (SB0 == 1) {
            #pragma unroll
            for (int kk = 0; kk < 4; kk++) {
                float4 t = *(const float4*)&B[tc + (kx + kk) * SB1];
                b_[0][kk] = t.x; b_[1][kk] = t.y; b_[2][kk] = t.z; b_[3][kk] = t.w;
            }
        } else {
            #pragma unroll
            for (int cq = 0; cq < 4; cq++) {
                float4 t = *(const float4*)&B[(tc + cq) * SB0 + kx];
                b_[cq][0] = t.x; b_[cq][1] = t.y; b_[cq][2] = t.z; b_[cq][3] = t.w;
            }
        }
        #pragma unroll
        for (int r = 0; r < 4; r++)
            #pragma unroll
            for (int cq = 0; cq < 4; cq++)
                #pragma unroll
                for (int kk = 0; kk < 4; kk++)
                    acc[r][cq] = fmaf(a_[r][kk], b_[cq][kk], acc[r][cq]);
    }
}

// ---------------------------------------------------------------------------
// Split-conversion: fp32 (rows x CC, k-contig) -> bf16 hi + bf16 lo residual.
// ---------------------------------------------------------------------------
template<bool DOMIX>
__global__ __launch_bounds__(256) void conv_split(
    const float* __restrict__ X, const float* __restrict__ mix,
    unsigned short* __restrict__ Hi, unsigned short* __restrict__ Lo,
    int ngroups)
{
    int g = blockIdx.x * 256 + threadIdx.x;
    if (g >= ngroups) return;
    int m = g >> 7;                 // CC/8 = 128 groups per row
    int k = (g & 127) * 8;
    const float* px = X + (size_t)m * CC + k;
    float a[8];
    {
        float4 x0 = *(const float4*)px;
        float4 x1 = *(const float4*)(px + 4);
        a[0]=x0.x; a[1]=x0.y; a[2]=x0.z; a[3]=x0.w;
        a[4]=x1.x; a[5]=x1.y; a[6]=x1.z; a[7]=x1.w;
    }
    if (DOMIX) {
        float4 p0, p1;
        if ((m & (TT - 1)) == 0) {
            p0 = make_float4(0.f,0.f,0.f,0.f); p1 = p0;
        } else {
            p0 = *(const float4*)(px - CC);
            p1 = *(const float4*)(px - CC + 4);
        }
        float4 m0 = *(const float4*)(mix + k);
        float4 m1 = *(const float4*)(mix + k + 4);
        float pv[8] = {p0.x,p0.y,p0.z,p0.w,p1.x,p1.y,p1.z,p1.w};
        float mv[8] = {m0.x,m0.y,m0.z,m0.w,m1.x,m1.y,m1.z,m1.w};
        #pragma unroll
        for (int j = 0; j < 8; j++) a[j] += (pv[j] - a[j]) * mv[j];
    }
    unsigned short hi[8], lo[8];
    #pragma unroll
    for (int j = 0; j < 8; j++) {
        hi[j] = f2bf(a[j]);
        lo[j] = f2bf(a[j] - bf2f(hi[j]));
    }
    uint4 H, L;
    H.x = (unsigned)hi[0] | ((unsigned)hi[1] << 16);
    H.y = (unsigned)hi[2] | ((unsigned)hi[3] << 16);
    H.z = (unsigned)hi[4] | ((unsigned)hi[5] << 16);
    H.w = (unsigned)hi[6] | ((unsigned)hi[7] << 16);
    L.x = (unsigned)lo[0] | ((unsigned)lo[1] << 16);
    L.y = (unsigned)lo[2] | ((unsigned)lo[3] << 16);
    L.z = (unsigned)lo[4] | ((unsigned)lo[5] << 16);
    L.w = (unsigned)lo[6] | ((unsigned)lo[7] << 16);
    *(uint4*)(Hi + (size_t)g * 8) = H;
    *(uint4*)(Lo + (size_t)g * 8) = L;
}

// ---------------------------------------------------------------------------
// Fused mix+split for xr, xk, xv: reads x (+prev) ONCE, emits 3 hi/lo pairs.
// ---------------------------------------------------------------------------
__global__ __launch_bounds__(256) void conv_split_x3(
    const float* __restrict__ X,
    const float* __restrict__ mr, const float* __restrict__ mk,
    const float* __restrict__ mv,
    unsigned short* __restrict__ rH, unsigned short* __restrict__ rL,
    unsigned short* __restrict__ kH, unsigned short* __restrict__ kL,
    unsigned short* __restrict__ vH, unsigned short* __restrict__ vL)
{
    int g = blockIdx.x * 256 + threadIdx.x;
    int m = g >> 7;
    int k = (g & 127) * 8;
    const float* px = X + (size_t)m * CC + k;
    float xv8[8], pv[8];
    {
        float4 x0 = *(const float4*)px;
        float4 x1 = *(const float4*)(px + 4);
        xv8[0]=x0.x; xv8[1]=x0.y; xv8[2]=x0.z; xv8[3]=x0.w;
        xv8[4]=x1.x; xv8[5]=x1.y; xv8[6]=x1.z; xv8[7]=x1.w;
    }
    if ((m & (TT - 1)) == 0) {
        #pragma unroll
        for (int j = 0; j < 8; j++) pv[j] = 0.f;
    } else {
        float4 p0 = *(const float4*)(px - CC);
        float4 p1 = *(const float4*)(px - CC + 4);
        pv[0]=p0.x; pv[1]=p0.y; pv[2]=p0.z; pv[3]=p0.w;
        pv[4]=p1.x; pv[5]=p1.y; pv[6]=p1.z; pv[7]=p1.w;
    }
    const float* mixes[3] = {mr, mk, mv};
    unsigned short* His[3] = {rH, kH, vH};
    unsigned short* Los[3] = {rL, kL, vL};
    #pragma unroll
    for (int s = 0; s < 3; s++) {
        float4 m0 = *(const float4*)(mixes[s] + k);
        float4 m1 = *(const float4*)(mixes[s] + k + 4);
        float mv8[8] = {m0.x,m0.y,m0.z,m0.w,m1.x,m1.y,m1.z,m1.w};
        unsigned short hi[8], lo[8];
        #pragma unroll
        for (int j = 0; j < 8; j++) {
            float a = xv8[j] + (pv[j] - xv8[j]) * mv8[j];
            hi[j] = f2bf(a);
            lo[j] = f2bf(a - bf2f(hi[j]));
        }
        uint4 H, L;
        H.x = (unsigned)hi[0] | ((unsigned)hi[1] << 16);
        H.y = (unsigned)hi[2] | ((unsigned)hi[3] << 16);
        H.z = (unsigned)hi[4] | ((unsigned)hi[5] << 16);
        H.w = (unsigned)hi[6] | ((unsigned)hi[7] << 16);
        L.x = (unsigned)lo[0] | ((unsigned)lo[1] << 16);
        L.y = (unsigned)lo[2] | ((unsigned)lo[3] << 16);
        L.z = (unsigned)lo[4] | ((unsigned)lo[5] << 16);
        L.w = (unsigned)lo[6] | ((unsigned)lo[7] << 16);
        *(uint4*)(His[s] + (size_t)g * 8) = H;
        *(uint4*)(Los[s] + (size_t)g * 8) = L;
    }
}

// ---------------------------------------------------------------------------
// Stage-2 weight transpose+split: W (K,CC) n-contig -> (CC,Kp) k-contig hi/lo
// ---------------------------------------------------------------------------
__global__ __launch_bounds__(256) void conv_w2(
    const float* __restrict__ W, int K, int Kp,
    unsigned short* __restrict__ Hi, unsigned short* __restrict__ Lo)
{
    int idx = blockIdx.x * 256 + threadIdx.x;
    int nk8 = Kp >> 3;
    if (idx >= CC * nk8) return;
    int n = idx / nk8, k0 = (idx - n * nk8) * 8;
    unsigned short h8[8], l8[8];
    #pragma unroll
    for (int j = 0; j < 8; j++) {
        int k = k0 + j;
        float v = (k < K) ? W[(size_t)k * CC + n] : 0.f;
        h8[j] = f2bf(v);
        l8[j] = f2bf(v - bf2f(h8[j]));
    }
    uint4 H, L;
    H.x = (unsigned)h8[0] | ((unsigned)h8[1] << 16);
    H.y = (unsigned)h8[2] | ((unsigned)h8[3] << 16);
    H.z = (unsigned)h8[4] | ((unsigned)h8[5] << 16);
    H.w = (unsigned)h8[6] | ((unsigned)h8[7] << 16);
    L.x = (unsigned)l8[0] | ((unsigned)l8[1] << 16);
    L.y = (unsigned)l8[2] | ((unsigned)l8[3] << 16);
    L.z = (unsigned)l8[4] | ((unsigned)l8[5] << 16);
    L.w = (unsigned)l8[6] | ((unsigned)l8[7] << 16);
    *(uint4*)(Hi + (size_t)n * Kp + k0) = H;
    *(uint4*)(Lo + (size_t)n * Kp + k0) = L;
}

// ---------------------------------------------------------------------------
// Split-bf16 MFMA GEMM for big projections (unchanged — passed)
// ---------------------------------------------------------------------------
__global__ __launch_bounds__(256, 2) void gemm_split_bf16(
    const unsigned short* __restrict__ Ah, const unsigned short* __restrict__ Al,
    const unsigned short* __restrict__ Bh, const unsigned short* __restrict__ Bl,
    float* __restrict__ Out)
{
    __shared__ __align__(16) unsigned short lds[4][128 * 64];  // Ah,Al,Bh,Bl
    const int tid = threadIdx.x;
    const int lane = tid & 63;
    const int wave = tid >> 6;
    const int wm = (wave >> 1) * 64, wn = (wave & 1) * 64;
    const int wg = blockIdx.x;
    const int xcd = wg & 7;
    const int j = wg >> 3;
    const int m0 = ((j >> 3) * 8 + xcd) * 128;
    const int n0 = (j & 7) * 128;

    f32x4 acc[4][4];
    #pragma unroll
    for (int i = 0; i < 4; i++)
        #pragma unroll
        for (int jj = 0; jj < 4; jj++)
            acc[i][jj] = (f32x4){0.f, 0.f, 0.f, 0.f};

    for (int k0 = 0; k0 < CC; k0 += 64) {
        #pragma unroll
        for (int p = 0; p < 4; p++) {
            const unsigned short* sbase = (p == 0) ? Ah : (p == 1) ? Al
                                        : (p == 2) ? Bh : Bl;
            const int rbase = (p < 2) ? m0 : n0;
            #pragma unroll
            for (int i = 0; i < 4; i++) {
                int slot = i * 256 + wave * 64 + lane;
                int row = slot >> 3, gsl = slot & 7;
                const unsigned short* src = sbase
                    + (size_t)(rbase + row) * CC + k0 + ((gsl ^ (row & 7)) * 8);
                gll16(src, &lds[p][(size_t)(i * 256 + wave * 64) * 8]);
            }
        }
        __syncthreads();

        #pragma unroll
        for (int ks = 0; ks < 2; ks++) {
            bf16x8 bhf[4], blf[4];
            #pragma unroll
            for (int nt = 0; nt < 4; nt++) {
                int col = wn + nt * 16 + (lane & 15);
                int gk = ks * 4 + (lane >> 4);
                int el = col * 64 + ((gk ^ (col & 7)) * 8);
                bhf[nt] = *(const bf16x8*)&lds[2][el];
                blf[nt] = *(const bf16x8*)&lds[3][el];
            }
            #pragma unroll
            for (int mt = 0; mt < 4; mt++) {
                int row = wm + mt * 16 + (lane & 15);
                int gk = ks * 4 + (lane >> 4);
                int el = row * 64 + ((gk ^ (row & 7)) * 8);
                bf16x8 ahf = *(const bf16x8*)&lds[0][el];
                bf16x8 alf = *(const bf16x8*)&lds[1][el];
                #pragma unroll
                for (int nt = 0; nt < 4; nt++) {
                    acc[mt][nt] = __builtin_amdgcn_mfma_f32_16x16x32_bf16(
                        ahf, bhf[nt], acc[mt][nt], 0, 0, 0);
                    acc[mt][nt] = __builtin_amdgcn_mfma_f32_16x16x32_bf16(
                        alf, bhf[nt], acc[mt][nt], 0, 0, 0);
                    acc[mt][nt] = __builtin_amdgcn_mfma_f32_16x16x32_bf16(
                        ahf, blf[nt], acc[mt][nt], 0, 0, 0);
                }
            }
        }
        __syncthreads();
    }
    float* cf = (float*)&lds[0][0];    // 64*132*4 = 33.8 KB
    #pragma unroll
    for (int pass = 0; pass < 2; ++pass) {
        __syncthreads();
        if ((wave >> 1) == pass) {
            #pragma unroll
            for (int mt = 0; mt < 4; mt++)
                #pragma unroll
                for (int nt = 0; nt < 4; nt++)
                    #pragma unroll
                    for (int r = 0; r < 4; r++) {
                        int row = mt * 16 + (lane >> 4) * 4 + r;
                        int col = wn + nt * 16 + (lane & 15);
                        cf[row * 132 + col] = acc[mt][nt][r];
                    }
        }
        __syncthreads();
        #pragma unroll
        for (int i = 0; i < 8; i++) {
            int g = tid + 256 * i;
            int row = g >> 5, c4 = (g & 31) * 4;
            float4 v = *(float4*)&cf[row * 132 + c4];
            *(float4*)&Out[(size_t)(m0 + pass * 64 + row) * CC + n0 + c4] = v;
        }
    }
}

// ---------------------------------------------------------------------------
// LoRA stage-1 (unchanged from round 11 — passed): 128x64 tiles, 6 y-slices.
// ---------------------------------------------------------------------------
__global__ __launch_bounds__(256) void lora1_all(
    const float* __restrict__ X,
    const float* __restrict__ w1, const float* __restrict__ a1,
    const float* __restrict__ v1, const float* __restrict__ g1,
    const float* __restrict__ xw, const float* __restrict__ xa,
    const float* __restrict__ xv, const float* __restrict__ xg,
    unsigned short* __restrict__ awh, unsigned short* __restrict__ awl,
    unsigned short* __restrict__ aah, unsigned short* __restrict__ aal,
    unsigned short* __restrict__ avh, unsigned short* __restrict__ avl,
    unsigned short* __restrict__ agh, unsigned short* __restrict__ agl)
{
    const int y = blockIdx.y;
    const float* W; const float* mix; unsigned short *Hi, *Lo;
    int Ncols, n0, epi, Kp;
    if (y == 0)      { W=w1; mix=xw; Hi=awh; Lo=awl; Ncols=64;  n0=0;          epi=1; Kp=64;  }
    else if (y == 1) { W=a1; mix=xa; Hi=aah; Lo=aal; Ncols=64;  n0=0;          epi=0; Kp=64;  }
    else if (y == 2) { W=v1; mix=xv; Hi=avh; Lo=avl; Ncols=32;  n0=0;          epi=0; Kp=64;  }
    else             { W=g1; mix=xg; Hi=agh; Lo=agl; Ncols=160; n0=(y-3)*64;   epi=2; Kp=192; }

    __shared__ float As[8][128];
    __shared__ float Bs[8][64];
    const int tid = threadIdx.x;
    const int m0 = blockIdx.x * 128;
    const int sr  = tid >> 1;
    const int skq = (tid & 1) * 4;
    const int bkr = tid >> 4;
    const int bnq = (tid & 15) * 4;
    const int tm = (tid >> 3) * 4;
    const int tn = (tid & 7) * 8;

    float acc[4][8];
    #pragma unroll
    for (int i = 0; i < 4; i++)
        #pragma unroll
        for (int j = 0; j < 8; j++) acc[i][j] = 0.f;

    auto ldAm = [&](int gm, int gk) -> float4 {
        const float* px = X + (size_t)gm * CC + gk;
        float4 xvv = *(const float4*)px;
        float4 pv;
        if ((gm & (TT - 1)) == 0) pv = make_float4(0.f, 0.f, 0.f, 0.f);
        else pv = *(const float4*)(px - CC);
        float4 mv = *(const float4*)(mix + gk);
        xvv.x += (pv.x - xvv.x) * mv.x;
        xvv.y += (pv.y - xvv.y) * mv.y;
        xvv.z += (pv.z - xvv.z) * mv.z;
        xvv.w += (pv.w - xvv.w) * mv.w;
        return xvv;
    };

    float4 aR, bR = make_float4(0.f, 0.f, 0.f, 0.f);
    aR = ldAm(m0 + sr, skq);
    if (tid < 128) {
        int gn = n0 + bnq;
        bR = (gn < Ncols) ? *(const float4*)(W + (size_t)bkr * Ncols + gn)
                          : make_float4(0.f, 0.f, 0.f, 0.f);
    }

    for (int k0 = 0; k0 < CC; k0 += 8) {
        __syncthreads();
        As[skq + 0][sr] = aR.x;
        As[skq + 1][sr] = aR.y;
        As[skq + 2][sr] = aR.z;
        As[skq + 3][sr] = aR.w;
        if (tid < 128) *(float4*)&Bs[bkr][bnq] = bR;
        __syncthreads();

        if (k0 + 8 < CC) {
            aR = ldAm(m0 + sr, k0 + 8 + skq);
            if (tid < 128) {
                int gn = n0 + bnq;
                bR = (gn < Ncols) ? *(const float4*)(W + (size_t)(k0 + 8 + bkr) * Ncols + gn)
                                  : make_float4(0.f, 0.f, 0.f, 0.f);
            }
        }

        #pragma unroll
        for (int kk = 0; kk < 8; ++kk) {
            float av[4], bv[8];
            *(float4*)&av[0] = *(const float4*)&As[kk][tm];
            *(float4*)&bv[0] = *(const float4*)&Bs[kk][tn];
            *(float4*)&bv[4] = *(const float4*)&Bs[kk][tn + 4];
            #pragma unroll
            for (int i = 0; i < 4; i++)
                #pragma unroll
                for (int j = 0; j < 8; j++)
                    acc[i][j] = fmaf(av[i], bv[j], acc[i][j]);
        }
    }

    #pragma unroll
    for (int i = 0; i < 4; i++) {
        int gm = m0 + tm + i;
        int gn = n0 + tn;
        if (gn < Kp) {
            unsigned short h8[8], l8[8];
            #pragma unroll
            for (int j = 0; j < 8; j++) {
                float v = 0.f;
                if (gn + j < Ncols) {
                    v = acc[i][j];
                    if (epi == 1) v = tanhf(v);
                    else if (epi == 2) v = sigmoidf_(v);
                }
                h8[j] = f2bf(v);
                l8[j] = f2bf(v - bf2f(h8[j]));
            }
            uint4 H, L;
            H.x = (unsigned)h8[0] | ((unsigned)h8[1] << 16);
            H.y = (unsigned)h8[2] | ((unsigned)h8[3] << 16);
            H.z = (unsigned)h8[4] | ((unsigned)h8[5] << 16);
            H.w = (unsigned)h8[6] | ((unsigned)h8[7] << 16);
            L.x = (unsigned)l8[0] | ((unsigned)l8[1] << 16);
            L.y = (unsigned)l8[2] | ((unsigned)l8[3] << 16);
            L.z = (unsigned)l8[4] | ((unsigned)l8[5] << 16);
            L.w = (unsigned)l8[6] | ((unsigned)l8[7] << 16);
            *(uint4*)(Hi + (size_t)gm * Kp + gn) = H;
            *(uint4*)(Lo + (size_t)gm * Kp + gn) = L;
        }
    }
}

// ---------------------------------------------------------------------------
// LoRA stage-2 on MFMA, v2: 128x64 tiles, 48 KB LDS (3 blocks/CU),
// single-pass LDS epilogue. z selects {w->dec, a->ab, v->vbuf blend, g->gb}.
// LDS layout (ushort elems): Ah[0:8192) Al[8192:16384) Bh[16384:20480)
// Bl[20480:24576). cf reuses as float (128x68 = 34.8 KB <= 48 KB).
// ---------------------------------------------------------------------------
__global__ __launch_bounds__(256, 3) void lora2_mfma(
    const unsigned short* __restrict__ awh, const unsigned short* __restrict__ awl,
    const unsigned short* __restrict__ aah, const unsigned short* __restrict__ aal,
    const unsigned short* __restrict__ avh, const unsigned short* __restrict__ avl,
    const unsigned short* __restrict__ agh, const unsigned short* __restrict__ agl,
    const unsigned short* __restrict__ w2h, const unsigned short* __restrict__ w2l,
    const unsigned short* __restrict__ a2h, const unsigned short* __restrict__ a2l,
    const unsigned short* __restrict__ v2h, const unsigned short* __restrict__ v2l,
    const unsigned short* __restrict__ g2h, const unsigned short* __restrict__ g2l,
    const float* __restrict__ w0, const float* __restrict__ a0v,
    const float* __restrict__ v0v, const float* __restrict__ v_first,
    float* __restrict__ decb, float* __restrict__ ab,
    float* __restrict__ vbuf, float* __restrict__ gb)
{
    __shared__ __align__(16) unsigned short lds[24576];   // 48 KB
    const int z = blockIdx.z;
    const unsigned short *Ah, *Al, *Bh, *Bl; int Kp;
    if (z == 0)      { Ah = awh; Al = awl; Bh = w2h; Bl = w2l; Kp = 64;  }
    else if (z == 1) { Ah = aah; Al = aal; Bh = a2h; Bl = a2l; Kp = 64;  }
    else if (z == 2) { Ah = avh; Al = avl; Bh = v2h; Bl = v2l; Kp = 64;  }
    else             { Ah = agh; Al = agl; Bh = g2h; Bl = g2l; Kp = 192; }

    const int tid = threadIdx.x, lane = tid & 63, wave = tid >> 6;
    const int wm = (wave >> 1) * 64, wn = (wave & 1) * 32;
    const int m0 = blockIdx.x * 128, n0 = blockIdx.y * 64;

    f32x4 acc[4][2];
    #pragma unroll
    for (int i = 0; i < 4; i++)
        #pragma unroll
        for (int jj = 0; jj < 2; jj++)
            acc[i][jj] = (f32x4){0.f, 0.f, 0.f, 0.f};

    for (int k0 = 0; k0 < Kp; k0 += 64) {
        // A planes: 1024 granules each; 4 gll16/thread/plane
        #pragma unroll
        for (int p = 0; p < 2; p++) {
            const unsigned short* sbase = (p == 0) ? Ah : Al;
            #pragma unroll
            for (int i = 0; i < 4; i++) {
                int slot = i * 256 + wave * 64 + lane;
                int row = slot >> 3, gsl = slot & 7;
                const unsigned short* src = sbase
                    + (size_t)(m0 + row) * Kp + k0 + ((gsl ^ (row & 7)) * 8);
                gll16(src, &lds[(size_t)(p * 8192) + (size_t)(i * 256 + wave * 64) * 8]);
            }
        }
        // B planes: 512 granules each; 2 gll16/thread/plane
        #pragma unroll
        for (int p = 0; p < 2; p++) {
            const unsigned short* sbase = (p == 0) ? Bh : Bl;
            #pragma unroll
            for (int i = 0; i < 2; i++) {
                int slot = i * 256 + wave * 64 + lane;
                int row = slot >> 3, gsl = slot & 7;
                const unsigned short* src = sbase
                    + (size_t)(n0 + row) * Kp + k0 + ((gsl ^ (row & 7)) * 8);
                gll16(src, &lds[(size_t)(16384 + p * 4096) + (size_t)(i * 256 + wave * 64) * 8]);
            }
        }
        __syncthreads();

        #pragma unroll
        for (int ks = 0; ks < 2; ks++) {
            bf16x8 bhf[2], blf[2];
            #pragma unroll
            for (int nt = 0; nt < 2; nt++) {
                int col = wn + nt * 16 + (lane & 15);
                int gk = ks * 4 + (lane >> 4);
                int el = col * 64 + ((gk ^ (col & 7)) * 8);
                bhf[nt] = *(const bf16x8*)&lds[16384 + el];
                blf[nt] = *(const bf16x8*)&lds[20480 + el];
            }
            #pragma unroll
            for (int mt = 0; mt < 4; mt++) {
                int row = wm + mt * 16 + (lane & 15);
                int gk = ks * 4 + (lane >> 4);
                int el = row * 64 + ((gk ^ (row & 7)) * 8);
                bf16x8 ahf = *(const bf16x8*)&lds[el];
                bf16x8 alf = *(const bf16x8*)&lds[8192 + el];
                #pragma unroll
                for (int nt = 0; nt < 2; nt++) {
                    acc[mt][nt] = __builtin_amdgcn_mfma_f32_16x16x32_bf16(
                        ahf, bhf[nt], acc[mt][nt], 0, 0, 0);
                    acc[mt][nt] = __builtin_amdgcn_mfma_f32_16x16x32_bf16(
                        alf, bhf[nt], acc[mt][nt], 0, 0, 0);
                    acc[mt][nt] = __builtin_amdgcn_mfma_f32_16x16x32_bf16(
                        ahf, blf[nt], acc[mt][nt], 0, 0, 0);
                }
            }
        }
        __syncthreads();
    }
    // single-pass LDS epilogue: all waves write fragments, then coalesced
    // float4 stores with fused per-z elementwise ops.
    float* cf = (float*)&lds[0];
    #pragma unroll
    for (int mt = 0; mt < 4; mt++)
        #pragma unroll
        for (int nt = 0; nt < 2; nt++)
            #pragma unroll
            for (int r = 0; r < 4; r++) {
                int row = wm + mt * 16 + (lane >> 4) * 4 + r;   // 0..127
                int col = wn + nt * 16 + (lane & 15);           // 0..63
                cf[row * 68 + col] = acc[mt][nt][r];
            }
    __syncthreads();
    #pragma unroll
    for (int i = 0; i < 8; i++) {
        int idx = tid + 256 * i;            // 0..2047 float4 slots
        int row = idx >> 4, c4 = (idx & 15) * 4;
        float4 v = *(float4*)&cf[row * 68 + c4];
        int gm = m0 + row;
        int c = n0 + c4;
        size_t off = (size_t)gm * CC + c;
        if (z == 0) {
            float4 w0q = *(const float4*)(w0 + c);
            float4 o;
            o.x = expf(-expf(-log1pf(expf(-(w0q.x + v.x))) - 0.5f));
            o.y = expf(-expf(-log1pf(expf(-(w0q.y + v.y))) - 0.5f));
            o.z = expf(-expf(-log1pf(expf(-(w0q.z + v.z))) - 0.5f));
            o.w = expf(-expf(-log1pf(expf(-(w0q.w + v.w))) - 0.5f));
            *(float4*)&decb[off] = o;
        } else if (z == 1) {
            float4 a0q = *(const float4*)(a0v + c);
            float4 o;
            o.x = sigmoidf_(a0q.x + v.x);
            o.y = sigmoidf_(a0q.y + v.y);
            o.z = sigmoidf_(a0q.z + v.z);
            o.w = sigmoidf_(a0q.w + v.w);
            *(float4*)&ab[off] = o;
        } else if (z == 2) {
            float4 v0q = *(const float4*)(v0v + c);
            float4 vr = *(const float4*)&vbuf[off];
            float4 vf = *(const float4*)&v_first[off];
            float4 o;
            o.x = vr.x + (vf.x - vr.x) * sigmoidf_(v0q.x + v.x);
            o.y = vr.y + (vf.y - vr.y) * sigmoidf_(v0q.y + v.y);
            o.z = vr.z + (vf.z - vr.z) * sigmoidf_(v0q.z + v.z);
            o.w = vr.w + (vf.w - vr.w) * sigmoidf_(v0q.w + v.w);
            *(float4*)&vbuf[off] = o;
        } else {
            *(float4*)&gb[off] = v;
        }
    }
}

// ---------------------------------------------------------------------------
// Chunked WKV phases A, B, C (unchanged from round 11 — passed)
// ---------------------------------------------------------------------------
__global__ __launch_bounds__(256) void wkvA(
    const float* __restrict__ kb, const float* __restrict__ ab,
    const float* __restrict__ vb, const float* __restrict__ decb,
    const float* __restrict__ k_k, const float* __restrict__ k_a,
    float* __restrict__ Gb, float* __restrict__ Ub,
    float* __restrict__ Bpb, float* __restrict__ Kpb,
    float* __restrict__ wcb, int cb)
{
    __shared__ __align__(16) float sAp[64 * STR];
    __shared__ __align__(16) float sBp[64 * STR];
    __shared__ __align__(16) float sKp[64 * STR];
    __shared__ __align__(16) float sT [64 * STR];
    __shared__ float sSeg[4][64];
    const int inst = blockIdx.x;
    const int bhd = inst >> 3, lc = inst & 7;
    const int dir = bhd & 1, bh = bhd >> 1, b = bh >> 4, h = bh & 15;
    const int c64 = (cb * CB + lc) * LCH;
    const int tid = threadIdx.x;
    const int lane = tid & 63, seg = tid >> 6;
    const int ch = h * 64 + lane;
    const size_t gbase = (size_t)inst * 4096;

    float loc[16];
    {
        float run = 1.f;
        #pragma unroll
        for (int i = 0; i < 16; i++) {
            int p = seg * 16 + i;
            int t = dir ? (TMAX - (c64 + p)) : (c64 + p);
            float d = decb[((size_t)(b * TT + t)) * CC + ch];
            run *= d; loc[i] = run;
        }
        sSeg[seg][lane] = run;
    }
    __syncthreads();
    float pre = 1.f;
    for (int s2 = 0; s2 < seg; ++s2) pre *= sSeg[s2][lane];
    {
        const float kkl = k_k[ch], kal = k_a[ch];
        #pragma unroll
        for (int i = 0; i < 16; i++) {
            int p = seg * 16 + i;
            int t = dir ? (TMAX - (c64 + p)) : (c64 + p);
            size_t ra = ((size_t)(b * TT + t)) * CC + ch;
            float kraw = kb[ra], asig = ab[ra];
            float kkv = kraw * kkl;
            float s2 = waveReduceSum(kkv * kkv);
            float kkn = kkv / fmaxf(sqrtf(s2), 1e-12f);
            float wc = loc[i] * pre;
            float wx = (i == 0) ? pre : loc[i - 1] * pre;
            float apv = -kkn * wx;
            float bpv = kkn * asig / wc;
            float kpv = kraw * (1.f + (asig - 1.f) * kal) / wc;
            sAp[lane * STR + p] = apv;
            sBp[lane * STR + p] = bpv;
            sKp[lane * STR + p] = kpv;
            Bpb[gbase + p * 64 + lane] = bpv;
            Kpb[gbase + p * 64 + lane] = kpv;
            wcb[gbase + p * 64 + lane] = wc;
        }
    }
    __syncthreads();

    const int tr = (tid >> 4) * 4, tc = (tid & 15) * 4;
    {
        float acc[4][4] = {};
        gemm64<1, STR, 1, STR>(sAp, sKp, acc, tr, tc);
        #pragma unroll
        for (int r = 0; r < 4; r++)
            #pragma unroll
            for (int cq = 0; cq < 4; cq++)
                sT[(tr + r) * STR + tc + cq] = (tc + cq < tr + r) ? acc[r][cq] : 0.f;
    }
    __syncthreads();
    {
        float accY[4][4] = {};
        const float* vbase = vb + ((size_t)(b * TT + (dir ? (TMAX - c64) : c64))) * CC
                           + h * 64 + tc;
        const ptrdiff_t vstep = dir ? -(ptrdiff_t)CC : (ptrdiff_t)CC;
        #pragma unroll 2
        for (int j4 = 0; j4 < 64; j4 += 4) {
            float a_[4][4];
            #pragma unroll
            for (int r = 0; r < 4; r++) {
                float4 t4 = *(const float4*)&sT[(tr + r) * STR + j4];
                a_[r][0] = t4.x; a_[r][1] = t4.y; a_[r][2] = t4.z; a_[r][3] = t4.w;
            }
            float4 vq[4];
            #pragma unroll
            for (int kk = 0; kk < 4; kk++)
                vq[kk] = *(const float4*)(vbase + (ptrdiff_t)(j4 + kk) * vstep);
            #pragma unroll
            for (int r = 0; r < 4; r++) {
                accY[r][0] = fmaf(a_[r][0], vq[0].x, fmaf(a_[r][1], vq[1].x,
                             fmaf(a_[r][2], vq[2].x, fmaf(a_[r][3], vq[3].x, accY[r][0]))));
                accY[r][1] = fmaf(a_[r][0], vq[0].y, fmaf(a_[r][1], vq[1].y,
                             fmaf(a_[r][2], vq[2].y, fmaf(a_[r][3], vq[3].y, accY[r][1]))));
                accY[r][2] = fmaf(a_[r][0], vq[0].z, fmaf(a_[r][1], vq[1].z,
                             fmaf(a_[r][2], vq[2].z, fmaf(a_[r][3], vq[3].z, accY[r][2]))));
                accY[r][3] = fmaf(a_[r][0], vq[0].w, fmaf(a_[r][1], vq[1].w,
                             fmaf(a_[r][2], vq[2].w, fmaf(a_[r][3], vq[3].w, accY[r][3]))));
            }
        }
        #pragma unroll
        for (int r = 0; r < 4; r++)
            #pragma unroll
            for (int cq = 0; cq < 4; cq++)
                sKp[(tr + r) * STR + tc + cq] = accY[r][cq];
    }
    __syncthreads();
    {
        float acc[4][4] = {};
        gemm64<1, STR, 1, STR>(sAp, sBp, acc, tr, tc);
        #pragma unroll
        for (int r = 0; r < 4; r++)
            #pragma unroll
            for (int cq = 0; cq < 4; cq++)
                sT[(tr + r) * STR + tc + cq] = (tc + cq < tr + r) ? acc[r][cq] : 0.f;
    }
    __syncthreads();
    if (tid < 64) {
        for (int r = 0; r < 64; ++r) {
            float acc = 0.f;
            for (int s = 0; s < r; ++s)
                acc = fmaf(sT[r * STR + s], sBp[s * STR + tid], acc);
            sBp[r * STR + tid] = (r == tid) ? 1.f : acc;
        }
    }
    __syncthreads();
    {
        float accG[4][4] = {};
        gemm64<STR, 1, STR, 1>(sBp, sAp, accG, tr, tc);
        float accU[4][4] = {};
        gemm64<STR, 1, 1, STR>(sBp, sKp, accU, tr, tc);
        #pragma unroll
        for (int r = 0; r < 4; r++) {
            *(float4*)&Gb[gbase + (tr + r) * 64 + tc] =
                make_float4(accG[r][0], accG[r][1], accG[r][2], accG[r][3]);
            *(float4*)&Ub[gbase + (tr + r) * 64 + tc] =
                make_float4(accU[r][0], accU[r][1], accU[r][2], accU[r][3]);
        }
    }
}

__global__ __launch_bounds__(256) void wkvB(
    const float* __restrict__ vb,
    const float* __restrict__ Gb, float* __restrict__ Ub,
    const float* __restrict__ Bpb, const float* __restrict__ Kpb,
    const float* __restrict__ wcb, float* __restrict__ S0b,
    float* __restrict__ Scur, int cb)
{
    __shared__ __align__(16) float sS[64 * STR];
    __shared__ __align__(16) float sG[64 * STR];
    __shared__ __align__(16) float sU[64 * STR];
    __shared__ __align__(16) float sB[64 * STR];
    __shared__ __align__(16) float sK[64 * STR];
    __shared__ __align__(16) float sV[64 * STR];
    const int bhd = blockIdx.x;
    const int dir = bhd & 1, bh = bhd >> 1, b = bh >> 4, h = bh & 15;
    const int tid = threadIdx.x;
    const int tr = (tid >> 4) * 4, tc = (tid & 15) * 4;

    for (int i = tid; i < 4096; i += 256)
        sS[(i >> 6) * STR + (i & 63)] = Scur[(size_t)bhd * 4096 + i];
    __syncthreads();

    for (int lc = 0; lc < CB; ++lc) {
        const int inst = bhd * CB + lc;
        const size_t gbase = (size_t)inst * 4096;
        const int c64 = (cb * CB + lc) * LCH;
        for (int i = tid; i < 4096; i += 256) {
            int rr = i >> 6, jj = i & 63;
            sG[rr * STR + jj] = Gb[gbase + i];
            sB[rr * STR + jj] = Bpb[gbase + i];
            sK[rr * STR + jj] = Kpb[gbase + i];
            int t = dir ? (TMAX - (c64 + rr)) : (c64 + rr);
            sV[rr * STR + jj] = vb[((size_t)(b * TT + t)) * CC + h * 64 + jj];
            S0b[gbase + i] = sS[rr * STR + jj];
        }
        __syncthreads();
        {
            float acc[4][4];
            #pragma unroll
            for (int r = 0; r < 4; r++) {
                float4 u0 = *(const float4*)&Ub[gbase + (tr + r) * 64 + tc];
                acc[r][0] = u0.x; acc[r][1] = u0.y; acc[r][2] = u0.z; acc[r][3] = u0.w;
            }
            gemm64<STR, 1, STR, 1>(sG, sS, acc, tr, tc);
            #pragma unroll
            for (int r = 0; r < 4; r++) {
                #pragma unroll
                for (int cq = 0; cq < 4; cq++) sU[(tr + r) * STR + tc + cq] = acc[r][cq];
                *(float4*)&Ub[gbase + (tr + r) * 64 + tc] =
                    make_float4(acc[r][0], acc[r][1], acc[r][2], acc[r][3]);
            }
        }
        __syncthreads();
        {
            float acc[4][4] = {};
            gemm64<1, STR, 1, STR>(sU, sB, acc, tr, tc);
            gemm64<1, STR, 1, STR>(sV, sK, acc, tr, tc);
            float w63[4];
            #pragma unroll
            for (int cq = 0; cq < 4; cq++) w63[cq] = wcb[gbase + 63 * 64 + tc + cq];
            #pragma unroll
            for (int r = 0; r < 4; r++)
                #pragma unroll
                for (int cq = 0; cq < 4; cq++) {
                    float sv = sS[(tr + r) * STR + tc + cq];
                    acc[r][cq] = (sv + acc[r][cq]) * w63[cq];
                }
            #pragma unroll
            for (int r = 0; r < 4; r++)
                #pragma unroll
                for (int cq = 0; cq < 4; cq++)
                    sS[(tr + r) * STR + tc + cq] = acc[r][cq];
        }
        __syncthreads();
    }
    for (int i = tid; i < 4096; i += 256)
        Scur[(size_t)bhd * 4096 + i] = sS[(i >> 6) * STR + (i & 63)];
}

__global__ __launch_bounds__(256) void wkvC(
    const float* __restrict__ rb, const float* __restrict__ vb,
    const float* __restrict__ Bpb, const float* __restrict__ Kpb,
    const float* __restrict__ Ub, const float* __restrict__ S0b,
    const float* __restrict__ wcb, const float* __restrict__ alpha_p,
    float* __restrict__ yb, int cb)
{
    __shared__ __align__(16) float sR[64 * STR];
    __shared__ __align__(16) float sO[64 * STR];
    __shared__ __align__(16) float sT2[64 * STR];
    const int inst = blockIdx.x;
    const int bhd = inst >> 3, lc = inst & 7;
    const int dir = bhd & 1, bh = bhd >> 1, b = bh >> 4, h = bh & 15;
    const int c64 = (cb * CB + lc) * LCH;
    const int tid = threadIdx.x, lane = tid & 63, seg = tid >> 6;
    const size_t gbase = (size_t)inst * 4096;
    const float alpha = alpha_p[0];
    const float wscale = dir ? (1.f - alpha) : alpha;
    const bool first = (cb < NB / 2);

    #pragma unroll
    for (int i = 0; i < 16; i++) {
        int p = seg * 16 + i;
        int t = dir ? (TMAX - (c64 + p)) : (c64 + p);
        size_t ra = ((size_t)(b * TT + t)) * CC + h * 64 + lane;
        float wc = wcb[gbase + p * 64 + lane];
        sR[lane * STR + p] = rb[ra] * wc;
        sO[lane * STR + p] = Bpb[gbase + p * 64 + lane];
    }
    __syncthreads();
    const int tr = (tid >> 4) * 4, tc = (tid & 15) * 4;
    float accO[4][4] = {};
    {
        float acc[4][4] = {};
        gemm64<1, STR, 1, STR>(sR, sO, acc, tr, tc);
        #pragma unroll
        for (int r = 0; r < 4; r++)
            #pragma unroll
            for (int cq = 0; cq < 4; cq++)
                sT2[(tr + r) * STR + tc + cq] = (tc + cq <= tr + r) ? acc[r][cq] : 0.f;
    }
    __syncthreads();
    for (int i = tid; i < 4096; i += 256)
        sO[(i >> 6) * STR + (i & 63)] = Ub[gbase + i];
    __syncthreads();
    gemm64<STR, 1, 1, STR>(sT2, sO, accO, tr, tc);
    __syncthreads();
    #pragma unroll
    for (int i = 0; i < 16; i++) {
        int p = seg * 16 + i;
        sO[lane * STR + p] = Kpb[gbase + p * 64 + lane];
    }
    __syncthreads();
    {
        float acc[4][4] = {};
        gemm64<1, STR, 1, STR>(sR, sO, acc, tr, tc);
        #pragma unroll
        for (int r = 0; r < 4; r++)
            #pragma unroll
            for (int cq = 0; cq < 4; cq++)
                sT2[(tr + r) * STR + tc + cq] = (tc + cq <= tr + r) ? acc[r][cq] : 0.f;
    }
    __syncthreads();
    #pragma unroll
    for (int i = 0; i < 16; i++) {
        int p = seg * 16 + i;
        int t = dir ? (TMAX - (c64 + p)) : (c64 + p);
        sO[p * STR + lane] = vb[((size_t)(b * TT + t)) * CC + h * 64 + lane];
    }
    __syncthreads();
    gemm64<STR, 1, 1, STR>(sT2, sO, accO, tr, tc);
    __syncthreads();
    for (int i = tid; i < 4096; i += 256)
        sO[(i >> 6) * STR + (i & 63)] = S0b[gbase + i];
    __syncthreads();
    gemm64<1, STR, STR, 1>(sR, sO, accO, tr, tc);
    #pragma unroll
    for (int r = 0; r < 4; r++) {
        int p = tr + r;
        int t = dir ? (TMAX - (c64 + p)) : (c64 + p);
        float* yp = &yb[((size_t)(b * TT + t)) * CC + h * 64 + tc];
        float4 o;
        if (first) {
            o.x = wscale * accO[r][0];
            o.y = wscale * accO[r][1];
            o.z = wscale * accO[r][2];
            o.w = wscale * accO[r][3];
        } else {
            float4 old = *(float4*)yp;
            o.x = old.x + wscale * accO[r][0];
            o.y = old.y + wscale * accO[r][1];
            o.z = old.z + wscale * accO[r][2];
            o.w = old.w + wscale * accO[r][3];
        }
        *(float4*)yp = o;
    }
}

// ---------------------------------------------------------------------------
// Post: GroupNorm + affine + bonus + gating; emits z as split bf16 (hi+lo).
// ---------------------------------------------------------------------------
__global__ __launch_bounds__(256) void post_kernel(
    const float* __restrict__ yb, const float* __restrict__ rbv,
    const float* __restrict__ kbv, const float* __restrict__ abv,
    const float* __restrict__ vbv, const float* __restrict__ gbv,
    const float* __restrict__ kaw, const float* __restrict__ r_k,
    const float* __restrict__ ln_w, const float* __restrict__ ln_b,
    unsigned short* __restrict__ zh, unsigned short* __restrict__ zl)
{
    const int t = blockIdx.x;
    const int tid = threadIdx.x;
    const size_t base = (size_t)t * CC;
    #pragma unroll
    for (int j = 0; j < 4; j++) {
        int c = tid + 256 * j;
        float y = yb[base + c];
        float s1 = waveReduceSum(y);
        float s2 = waveReduceSum(y * y);
        float mu = s1 * (1.0f / 64.0f);
        float var = s2 * (1.0f / 64.0f) - mu * mu;
        float yn = (y - mu) * rsqrtf(var + EPS_GN);
        yn = yn * ln_w[c] + ln_b[c];
        float rv = rbv[base + c];
        float kf = kbv[base + c] * (1.0f + (abv[base + c] - 1.0f) * kaw[c]);
        float vv = vbv[base + c];
        float dot = waveReduceSum(rv * kf * r_k[c]);
        yn += dot * vv;
        float z = yn * gbv[base + c];
        unsigned short h = f2bf(z);
        zh[base + c] = h;
        zl[base + c] = f2bf(z - bf2f(h));
    }
}

// ---------------------------------------------------------------------------
extern "C" void kernel_launch(void* const* d_in, const int* in_sizes, int n_in,
                              void* d_out, int out_size, void* d_ws, size_t ws_size,
                              hipStream_t stream)
{
    (void)in_sizes; (void)n_in; (void)out_size; (void)ws_size;
    const float* x      = (const float*)d_in[0];
    const float* vfirst = (const float*)d_in[1];
    const float* x_r    = (const float*)d_in[2];
    const float* x_w    = (const float*)d_in[3];
    const float* x_k    = (const float*)d_in[4];
    const float* x_v    = (const float*)d_in[5];
    const float* x_a    = (const float*)d_in[6];
    const float* x_g    = (const float*)d_in[7];
    const float* w0     = (const float*)d_in[8];
    const float* w1     = (const float*)d_in[9];
    const float* w2     = (const float*)d_in[10];
    const float* a0     = (const float*)d_in[11];
    const float* a1     = (const float*)d_in[12];
    const float* a2     = (const float*)d_in[13];
    const float* v0     = (const float*)d_in[14];
    const float* v1     = (const float*)d_in[15];
    const float* v2     = (const float*)d_in[16];
    const float* g1     = (const float*)d_in[17];
    const float* g2     = (const float*)d_in[18];
    const float* k_k    = (const float*)d_in[19];
    const float* k_a    = (const float*)d_in[20];
    const float* r_k    = (const float*)d_in[21];
    const float* Wr     = (const float*)d_in[22];
    const float* Wk     = (const float*)d_in[23];
    const float* Wv     = (const float*)d_in[24];
    const float* Wo     = (const float*)d_in[25];
    const float* ln_w   = (const float*)d_in[26];
    const float* ln_b   = (const float*)d_in[27];
    const float* alpha  = (const float*)d_in[28];

    const size_t SZ = (size_t)BT * CC;
    const size_t CHB = (size_t)1024 * 4096;
    float* ws   = (float*)d_ws;
    float* rb   = ws + 0 * SZ;
    float* kb   = ws + 1 * SZ;
    float* vb   = ws + 2 * SZ;
    float* decb = ws + 3 * SZ;
    float* ab   = ws + 4 * SZ;
    float* actf = ws + 5 * SZ;
    unsigned short* awh = (unsigned short*)actf;
    unsigned short* awl = awh + (size_t)BT * 64;
    unsigned short* aah = awl + (size_t)BT * 64;
    unsigned short* aal = aah + (size_t)BT * 64;
    unsigned short* avh = aal + (size_t)BT * 64;
    unsigned short* avl = avh + (size_t)BT * 64;
    unsigned short* agh = avl + (size_t)BT * 64;
    unsigned short* agl = agh + (size_t)BT * 192;
    float* Gb   = actf + (size_t)BT * 384;
    float* Ub   = Gb + CHB;
    float* Bpb  = Ub + CHB;
    float* Kpb  = Bpb + CHB;
    float* S0b  = Kpb + CHB;
    float* wcb  = S0b + CHB;
    float* Scur = wcb + CHB;
    unsigned short* Whb = (unsigned short*)(Scur + (size_t)128 * 4096);
    unsigned short* Wlb = Whb + (size_t)CC * CC;
    unsigned short* w2th = Wlb + (size_t)CC * CC;
    unsigned short* w2tl = w2th + (size_t)CC * 64;
    unsigned short* a2th = w2tl + (size_t)CC * 64;
    unsigned short* a2tl = a2th + (size_t)CC * 64;
    unsigned short* v2th = a2tl + (size_t)CC * 64;
    unsigned short* v2tl = v2th + (size_t)CC * 64;
    unsigned short* g2th = v2tl + (size_t)CC * 64;
    unsigned short* g2tl = g2th + (size_t)CC * 192;
    float* outp = (float*)d_out;
    // A-split aliases: xr/xk pairs occupy d_out (dead until gb/yb writers,
    // which run after gemm r/k consume them); xv pair in decb's slot (dead
    // until lora2 writes dec, after gemm v).
    unsigned short* xrh = (unsigned short*)outp;          // [0, SZ)
    unsigned short* xrl = xrh + SZ;                       // [SZ, 2SZ)
    unsigned short* xkh = xrl + SZ;                       // [2SZ, 3SZ)
    unsigned short* xkl = xkh + SZ;                       // [3SZ, 4SZ)
    unsigned short* xvh = (unsigned short*)decb;
    unsigned short* xvl = xvh + SZ;
    float* gb   = outp;                                   // after gemms
    float* yb   = outp + SZ;                              // from wkvC on
    unsigned short* zAh = (unsigned short*)decb;          // post phase
    unsigned short* zAl = zAh + SZ;

    dim3 blk(256);
    const int NG_A = BT * (CC / 8);
    const int NG_W = CC * (CC / 8);
    dim3 gridA(NG_A / 256), gridW(NG_W / 256);
    dim3 gridG(1024);

    // fused x-mix split (xr, xk, xv) — reads x once
    conv_split_x3<<<gridA, blk, 0, stream>>>(x, x_r, x_k, x_v,
                                             xrh, xrl, xkh, xkl, xvh, xvl);
    // big projections
    conv_split<false><<<gridW, blk, 0, stream>>>(Wr, nullptr, Whb, Wlb, NG_W);
    gemm_split_bf16<<<gridG, blk, 0, stream>>>(xrh, xrl, Whb, Wlb, rb);
    conv_split<false><<<gridW, blk, 0, stream>>>(Wk, nullptr, Whb, Wlb, NG_W);
    gemm_split_bf16<<<gridG, blk, 0, stream>>>(xkh, xkl, Whb, Wlb, kb);
    conv_split<false><<<gridW, blk, 0, stream>>>(Wv, nullptr, Whb, Wlb, NG_W);
    gemm_split_bf16<<<gridG, blk, 0, stream>>>(xvh, xvl, Whb, Wlb, vb);

    // stage-2 weight conversion (transpose + split + K-pad)
    conv_w2<<<dim3(32), blk, 0, stream>>>(w2, 64, 64, w2th, w2tl);
    conv_w2<<<dim3(32), blk, 0, stream>>>(a2, 64, 64, a2th, a2tl);
    conv_w2<<<dim3(32), blk, 0, stream>>>(v2, 32, 64, v2th, v2tl);
    conv_w2<<<dim3(96), blk, 0, stream>>>(g2, 160, 192, g2th, g2tl);

    // LoRA stage-1 then stage-2 on MFMA
    lora1_all<<<dim3(BT / 128, 6), blk, 0, stream>>>(x, w1, a1, v1, g1,
        x_w, x_a, x_v, x_g, awh, awl, aah, aal, avh, avl, agh, agl);
    lora2_mfma<<<dim3(BT / 128, CC / 64, 4), blk, 0, stream>>>(
        awh, awl, aah, aal, avh, avl, agh, agl,
        w2th, w2tl, a2th, a2tl, v2th, v2tl, g2th, g2tl,
        w0, a0, v0, vfirst, decb, ab, vb, gb);

    // chunked bidirectional WKV
    hipMemsetAsync(Scur, 0, (size_t)128 * 4096 * sizeof(float), stream);
    for (int cb = 0; cb < NB; ++cb) {
        wkvA<<<dim3(1024), blk, 0, stream>>>(kb, ab, vb, decb, k_k, k_a,
                                             Gb, Ub, Bpb, Kpb, wcb, cb);
        wkvB<<<dim3(128), blk, 0, stream>>>(vb, Gb, Ub, Bpb, Kpb, wcb, S0b, Scur, cb);
        wkvC<<<dim3(1024), blk, 0, stream>>>(rb, vb, Bpb, Kpb, Ub, S0b, wcb,
                                             alpha, yb, cb);
    }

    // groupnorm + bonus + gate -> split bf16 z (into decb's slot)
    post_kernel<<<dim3(BT), blk, 0, stream>>>(yb, rb, kb, ab, vb, gb, k_a, r_k,
                                              ln_w, ln_b, zAh, zAl);
    // final projection
    conv_split<false><<<gridW, blk, 0, stream>>>(Wo, nullptr, Whb, Wlb, NG_W);
    hipMemcpyAsync(outp + SZ, vfirst, SZ * sizeof(float),
                   hipMemcpyDeviceToDevice, stream);
    gemm_split_bf16<<<gridG, blk, 0, stream>>>(zAh, zAl, Whb, Wlb, outp);
}